// Round 1
// baseline (1641.829 us; speedup 1.0000x reference)
//
#include <hip/hip_runtime.h>

#define EPSF 1e-5f
#define SCALEF 0.25f   // hd=16 -> 16^-0.5

// ---------------------------------------------------------------------------
// Small GEMM: iq_emb (100,128) @ w_iqp (128,256) + b -> (100,256)
// ---------------------------------------------------------------------------
__global__ __launch_bounds__(256) void iqp_kernel(
    const float* __restrict__ iq, const float* __restrict__ W,
    const float* __restrict__ b, float* __restrict__ out) {
  __shared__ float row[128];
  int r = blockIdx.x;
  if (threadIdx.x < 128) row[threadIdx.x] = iq[r * 128 + threadIdx.x];
  __syncthreads();
  int c = threadIdx.x;
  float acc = b[c];
#pragma unroll 8
  for (int k = 0; k < 128; ++k) acc += row[k] * W[k * 256 + c];
  out[r * 256 + c] = acc;
}

// ---------------------------------------------------------------------------
// Fused projection + LayerNorm: x (rows,K) @ W (K,256) + b, then LN(g,be).
// Block: 256 threads, R rows per block.
// ---------------------------------------------------------------------------
template <int K, int R>
__global__ __launch_bounds__(256) void proj_ln_kernel(
    const float* __restrict__ x, const float* __restrict__ W,
    const float* __restrict__ b, const float* __restrict__ g,
    const float* __restrict__ be, float* __restrict__ out) {
  __shared__ float rows[R][K];
  __shared__ float vals[R][256];
  int r0 = blockIdx.x * R;
  for (int e = threadIdx.x; e < R * K; e += 256) {
    int rr = e / K, k = e - rr * K;
    rows[rr][k] = x[(size_t)(r0 + rr) * K + k];
  }
  __syncthreads();
  int c = threadIdx.x;
  float acc[R];
  float bb = b[c];
#pragma unroll
  for (int rr = 0; rr < R; rr++) acc[rr] = bb;
  for (int k = 0; k < K; k += 4) {
    float w0 = W[(size_t)k * 256 + c];
    float w1 = W[(size_t)(k + 1) * 256 + c];
    float w2 = W[(size_t)(k + 2) * 256 + c];
    float w3 = W[(size_t)(k + 3) * 256 + c];
#pragma unroll
    for (int rr = 0; rr < R; rr++) {
      float4 r4 = *reinterpret_cast<const float4*>(&rows[rr][k]);
      acc[rr] = fmaf(r4.x, w0, acc[rr]);
      acc[rr] = fmaf(r4.y, w1, acc[rr]);
      acc[rr] = fmaf(r4.z, w2, acc[rr]);
      acc[rr] = fmaf(r4.w, w3, acc[rr]);
    }
  }
#pragma unroll
  for (int rr = 0; rr < R; rr++) vals[rr][c] = acc[rr];
  __syncthreads();
  int wid = threadIdx.x >> 6, lane = threadIdx.x & 63;
  for (int rr = wid; rr < R; rr += 4) {
    float x0 = vals[rr][lane], x1 = vals[rr][lane + 64];
    float x2 = vals[rr][lane + 128], x3 = vals[rr][lane + 192];
    float s = x0 + x1 + x2 + x3;
#pragma unroll
    for (int off = 32; off; off >>= 1) s += __shfl_xor(s, off);
    float mean = s * (1.f / 256.f);
    float d0 = x0 - mean, d1 = x1 - mean, d2 = x2 - mean, d3 = x3 - mean;
    float v = d0 * d0 + d1 * d1 + d2 * d2 + d3 * d3;
#pragma unroll
    for (int off = 32; off; off >>= 1) v += __shfl_xor(v, off);
    float rstd = rsqrtf(v * (1.f / 256.f) + EPSF);
    size_t ro = (size_t)(r0 + rr) * 256;
    out[ro + lane]       = d0 * rstd * g[lane]       + be[lane];
    out[ro + lane + 64]  = d1 * rstd * g[lane + 64]  + be[lane + 64];
    out[ro + lane + 128] = d2 * rstd * g[lane + 128] + be[lane + 128];
    out[ro + lane + 192] = d3 * rstd * g[lane + 192] + be[lane + 192];
  }
}

// ---------------------------------------------------------------------------
// Generic row-blocked GEMM: out[r,c] = dot(in[ir,:K], W[:,c]) + bias[c]
//  PRE:  input row += in2[r,:K] before GEMM (audio residual pre-proj)
//  POST: output += post[r,c]               (vis residual post-proj)
//  rowmode 1: ir = (r/100)*200 + rowoff + r%100  (gather aiq2/viq2 rows)
// Block: N threads, R rows per block.
// ---------------------------------------------------------------------------
template <int K, int N, int R, bool PRE, bool POST>
__global__ __launch_bounds__(N) void gemm_kernel(
    const float* __restrict__ in, const float* __restrict__ in2,
    const float* __restrict__ W, const float* __restrict__ bias,
    const float* __restrict__ post, float* __restrict__ out,
    int rowmode, int rowoff) {
  __shared__ float rows[R][K];
  int r0 = blockIdx.x * R;
  for (int e = threadIdx.x; e < R * K; e += N) {
    int rr = e / K, k = e - rr * K;
    size_t r = r0 + rr;
    size_t ir = r;
    if (rowmode) ir = (r / 100) * 200 + rowoff + (r % 100);
    float v = in[ir * K + k];
    if (PRE) v += in2[r * K + k];
    rows[rr][k] = v;
  }
  __syncthreads();
  int c = threadIdx.x;
  float acc[R];
  float bb = bias[c];
#pragma unroll
  for (int rr = 0; rr < R; rr++) acc[rr] = bb;
  for (int k = 0; k < K; k += 4) {
    float w0 = W[(size_t)k * N + c];
    float w1 = W[(size_t)(k + 1) * N + c];
    float w2 = W[(size_t)(k + 2) * N + c];
    float w3 = W[(size_t)(k + 3) * N + c];
#pragma unroll
    for (int rr = 0; rr < R; rr++) {
      float4 r4 = *reinterpret_cast<const float4*>(&rows[rr][k]);
      acc[rr] = fmaf(r4.x, w0, acc[rr]);
      acc[rr] = fmaf(r4.y, w1, acc[rr]);
      acc[rr] = fmaf(r4.z, w2, acc[rr]);
      acc[rr] = fmaf(r4.w, w3, acc[rr]);
    }
  }
#pragma unroll
  for (int rr = 0; rr < R; rr++) {
    size_t r = r0 + rr;
    float v = acc[rr];
    if (POST) v += post[r * N + c];
    out[r * N + c] = v;
  }
}

// ---------------------------------------------------------------------------
// Generic flash attention (one query per thread, online softmax).
// q[b,h,qi,d] = qp[b*qbs + qi*qts + h*16 + d], similarly k/v/out.
// addq: add query to output (stage-1 residual).
// grid: (ceil(nq/256), H=8, B); block 256.
// ---------------------------------------------------------------------------
#define TK 64
__global__ __launch_bounds__(256) void attn_kernel(
    const float* __restrict__ qp, size_t qbs, int qts,
    const float* __restrict__ kp, size_t kbs, int kts,
    const float* __restrict__ vp, size_t vbs, int vts,
    float* __restrict__ op, size_t obs, int ots,
    int nq, int nk, int addq) {
  __shared__ float ks[TK][16];
  __shared__ float vs[TK][16];
  int b = blockIdx.z, h = blockIdx.y;
  int qi = blockIdx.x * 256 + threadIdx.x;
  bool act = qi < nq;
  float q[16];
#pragma unroll
  for (int d = 0; d < 16; d++) q[d] = 0.f;
  if (act) {
    const float* qr = qp + b * qbs + (size_t)qi * qts + h * 16;
#pragma unroll
    for (int d = 0; d < 16; d++) q[d] = qr[d];
  }
  float m = -1e30f, l = 0.f, acc[16];
#pragma unroll
  for (int d = 0; d < 16; d++) acc[d] = 0.f;
  const float* kb = kp + b * kbs + h * 16;
  const float* vb = vp + b * vbs + h * 16;
  for (int t0 = 0; t0 < nk; t0 += TK) {
    int tkn = min(TK, nk - t0);
    __syncthreads();
    for (int e = threadIdx.x; e < tkn * 16; e += 256) {
      int j = e >> 4, d = e & 15;
      ks[j][d] = kb[(size_t)(t0 + j) * kts + d];
      vs[j][d] = vb[(size_t)(t0 + j) * vts + d];
    }
    __syncthreads();
    if (act) {
      for (int j = 0; j < tkn; ++j) {
        float s = 0.f;
#pragma unroll
        for (int d = 0; d < 16; d++) s += q[d] * ks[j][d];
        s *= SCALEF;
        if (s > m) {
          float cf = __expf(m - s);
          l *= cf;
#pragma unroll
          for (int d = 0; d < 16; d++) acc[d] *= cf;
          m = s;
        }
        float p = __expf(s - m);
        l += p;
#pragma unroll
        for (int d = 0; d < 16; d++) acc[d] += p * vs[j][d];
      }
    }
  }
  if (act) {
    float inv = 1.f / l;
    float* orow = op + b * obs + (size_t)qi * ots + h * 16;
#pragma unroll
    for (int d = 0; d < 16; d++) orow[d] = acc[d] * inv + (addq ? q[d] : 0.f);
  }
}

// aiq2 (40,100,128) copy out of SA (viewed as (40,200,128) rows 0..99)
__global__ __launch_bounds__(128) void copy_aiq2_kernel(
    const float* __restrict__ SA, float* __restrict__ out) {
  int r = blockIdx.x, c = threadIdx.x;
  size_t ir = (size_t)(r / 100) * 200 + (r % 100);
  out[(size_t)r * 128 + c] = SA[ir * 128 + c];
}

// ---------------------------------------------------------------------------
extern "C" void kernel_launch(void* const* d_in, const int* in_sizes, int n_in,
                              void* d_out, int out_size, void* d_ws, size_t ws_size,
                              hipStream_t stream) {
  const float* audio = (const float*)d_in[0];   // (40,1024,128)
  const float* vis   = (const float*)d_in[1];   // (40,1024,512)
  const float* iq    = (const float*)d_in[2];   // (100,128)
  const float* w_iqp = (const float*)d_in[3];
  const float* b_iqp = (const float*)d_in[4];
  const float* w_afp = (const float*)d_in[5];
  const float* b_afp = (const float*)d_in[6];
  const float* w_vfp = (const float*)d_in[7];
  const float* b_vfp = (const float*)d_in[8];
  const float* g_an  = (const float*)d_in[9];
  const float* be_an = (const float*)d_in[10];
  const float* g_vn  = (const float*)d_in[11];
  const float* be_vn = (const float*)d_in[12];
  const float* w_aqp = (const float*)d_in[13];
  const float* b_aqp = (const float*)d_in[14];
  const float* w_vqp = (const float*)d_in[15];
  const float* b_vqp = (const float*)d_in[16];
  const float* w_aq  = (const float*)d_in[17];
  const float* b_aq  = (const float*)d_in[18];
  const float* w_vq  = (const float*)d_in[19];
  const float* b_vq  = (const float*)d_in[20];
  const float* w_in  = (const float*)d_in[21];
  const float* b_in  = (const float*)d_in[22];
  const float* w_o   = (const float*)d_in[23];
  const float* b_o   = (const float*)d_in[24];
  const float* w_ao  = (const float*)d_in[25];
  const float* b_ao  = (const float*)d_in[26];
  const float* w_vo  = (const float*)d_in[27];
  const float* b_vo  = (const float*)d_in[28];

  float* out = (float*)d_out;
  float* ws  = (float*)d_ws;

  // d_out scratch (regions dead until the final writes; stream-ordered):
  const size_t O_ALN  = 0;           // (40960,256) = 10,485,760
  const size_t O_VLN  = 10485760;    // (40960,256)
  const size_t O_A    = 20971520;    // _a   (40960,128) = 5,242,880
  const size_t O_V    = 26214400;    // _v   (40960,128)
  const size_t O_AATT = 31457280;    // a_att(40960,128)
  // final outputs: audio_out @ 0, vis_out @ 20,971,520, aiq2 @ 41,943,040
  const size_t O_AOUT = 0, O_VOUT = 20971520, O_AIQ2 = 41943040;

  // ws layout (floats):
  const size_t W_AQVQ = 0;          // (100,256)      25,600
  const size_t W_Q1   = 25600;      // (8000,128)  1,024,000
  const size_t W_QKV  = 1049600;    // (8000,384)  3,072,000
  const size_t W_SAP  = 4121600;    // (8000,128)  1,024,000
  const size_t W_SA   = 5145600;    // (8000,128)  1,024,000
  const size_t W_AKV  = 6169600;    // (4000,256)  1,024,000
  const size_t W_VKV  = 7193600;    // (4000,256)  1,024,000
  const size_t W_VATT = 8217600;    // (40960,128) 5,242,880   total 13,460,480 f

  float* aqvq  = ws + W_AQVQ;
  float* Q1    = ws + W_Q1;
  float* qkv   = ws + W_QKV;
  float* sap   = ws + W_SAP;
  float* SA    = ws + W_SA;
  float* akv   = ws + W_AKV;
  float* vkv   = ws + W_VKV;
  float* vatt  = ws + W_VATT;
  float* aln   = out + O_ALN;
  float* vln   = out + O_VLN;
  float* _a    = out + O_A;
  float* _v    = out + O_V;
  float* aatt  = out + O_AATT;

  // 1. iq_emb @ w_iqp + b  -> aq0|vq0
  iqp_kernel<<<100, 256, 0, stream>>>(iq, w_iqp, b_iqp, aqvq);

  // 2. audio/vis projection + LN
  proj_ln_kernel<128, 16><<<2560, 256, 0, stream>>>(audio, w_afp, b_afp, g_an, be_an, aln);
  proj_ln_kernel<512, 16><<<2560, 256, 0, stream>>>(vis, w_vfp, b_vfp, g_vn, be_vn, vln);

  // 3. stage-1 cross-attn (queries=100 learned, keys=1024 tokens), +q residual
  //    out written directly into "queries" layout (40,200,128) == (8,1000,128)
  attn_kernel<<<dim3(1, 8, 40), 256, 0, stream>>>(
      aqvq, 0, 256, aln, 1024 * 256, 256, aln + 128, 1024 * 256, 256,
      Q1, 200 * 128, 128, 100, 1024, 1);
  attn_kernel<<<dim3(1, 8, 40), 256, 0, stream>>>(
      aqvq + 128, 0, 256, vln, 1024 * 256, 256, vln + 128, 1024 * 256, 256,
      Q1 + 100 * 128, 200 * 128, 128, 100, 1024, 1);

  // 4. qkv = queries @ w_in + b_in  (8000,128)->(8000,384)
  gemm_kernel<128, 384, 8, false, false><<<1000, 384, 0, stream>>>(
      Q1, nullptr, w_in, b_in, nullptr, qkv, 0, 0);

  // 5. self-attention over 1000 tokens, 8 batches
  attn_kernel<<<dim3(4, 8, 8), 256, 0, stream>>>(
      qkv, 1000 * 384, 384, qkv + 128, 1000 * 384, 384, qkv + 256, 1000 * 384, 384,
      sap, 1000 * 128, 128, 1000, 1000, 0);

  // 6. SA = sa_pre @ w_o + b_o
  gemm_kernel<128, 128, 16, false, false><<<500, 128, 0, stream>>>(
      sap, nullptr, w_o, b_o, nullptr, SA, 0, 0);

  // 7. aiq2 -> output #3
  copy_aiq2_kernel<<<4000, 128, 0, stream>>>(SA, out + O_AIQ2);

  // 8. kf/vf projections from aiq2 / viq2 (gathered rows of SA)
  gemm_kernel<128, 256, 16, false, false><<<250, 256, 0, stream>>>(
      SA, nullptr, w_aqp, b_aqp, nullptr, akv, 1, 0);
  gemm_kernel<128, 256, 16, false, false><<<250, 256, 0, stream>>>(
      SA, nullptr, w_vqp, b_vqp, nullptr, vkv, 1, 100);

  // 9. _a = audio @ w_aq + b_aq ; _v = vis @ w_vq + b_vq
  gemm_kernel<128, 128, 16, false, false><<<2560, 128, 0, stream>>>(
      audio, nullptr, w_aq, b_aq, nullptr, _a, 0, 0);
  gemm_kernel<512, 128, 16, false, false><<<2560, 128, 0, stream>>>(
      vis, nullptr, w_vq, b_vq, nullptr, _v, 0, 0);

  // 10. stage-3 cross-attn: audio tokens attend to visual queries & vice versa
  attn_kernel<<<dim3(4, 8, 40), 256, 0, stream>>>(
      _a, 1024 * 128, 128, vkv, 100 * 256, 256, vkv + 128, 100 * 256, 256,
      aatt, 1024 * 128, 128, 1024, 100, 0);
  attn_kernel<<<dim3(4, 8, 40), 256, 0, stream>>>(
      _v, 1024 * 128, 128, akv, 100 * 256, 256, akv + 128, 100 * 256, 256,
      vatt, 1024 * 128, 128, 1024, 100, 0);

  // 11. output projections (audio first: it reads a_att which lives in the
  //     vis_out region; stream order protects it)
  gemm_kernel<128, 512, 16, true, false><<<2560, 512, 0, stream>>>(
      aatt, audio, w_ao, b_ao, nullptr, out + O_AOUT, 0, 0);
  gemm_kernel<128, 512, 16, false, true><<<2560, 512, 0, stream>>>(
      vatt, nullptr, w_vo, b_vo, vis, out + O_VOUT, 0, 0);
}

// Round 3
// 1134.000 us; speedup vs baseline: 1.4478x; 1.4478x over previous
//
#include <hip/hip_runtime.h>

#define EPSF 1e-5f
#define SCALEF 0.25f   // hd=16 -> 16^-0.5

typedef __attribute__((ext_vector_type(8))) __bf16 bf16x8;
typedef __attribute__((ext_vector_type(8))) unsigned short sh8;
typedef __attribute__((ext_vector_type(4))) float f32x4;

__device__ __forceinline__ unsigned short f2bf(float f) {
  unsigned u = __float_as_uint(f);
  return (unsigned short)((u + 0x7FFFu + ((u >> 16) & 1u)) >> 16);
}

// async global->LDS, 16B per lane; LDS dest = uniform base + lane*16
__device__ __forceinline__ void gll16(const void* g, void* l) {
  __builtin_amdgcn_global_load_lds((const __attribute__((address_space(1))) void*)g,
                                   (__attribute__((address_space(3))) void*)l,
                                   16, 0, 0);
}

// ---------------------------------------------------------------------------
// MFMA GEMM: C[M][Ntot](f32) = A[M][K](bf16) x Wt[N][K](bf16)^T + bias
//  tile 128 x BN, block = BN*2 threads (2 x BN/64 waves, 64x64 per wave)
//  LN: fused LayerNorm over Ntot==BN==256 columns (bias added pre-stats)
//  POST: += post[M][Ntot] (f32) at store
//  LDS slot-swizzle: slot' = slot ^ ((row>>1)&3), applied at stage (via global
//  src addr) and at fragment read -> max 2-way bank conflict (free).
// ---------------------------------------------------------------------------
template <int K, int BN, bool LN, bool POST>
__global__ __launch_bounds__(BN * 2) void mfma_gemm(
    const unsigned short* __restrict__ A, const unsigned short* __restrict__ Wt,
    const float* __restrict__ bias, const float* __restrict__ gg,
    const float* __restrict__ be, const float* __restrict__ post,
    float* __restrict__ C, int M, int Ntot) {
  constexpr int NW = BN / 32;   // waves per block
  constexpr int NCW = BN / 64;  // wave columns
  __shared__ __align__(16) unsigned short As[128 * 32];
  __shared__ __align__(16) unsigned short Bs[BN * 32];
  __shared__ float2 part[128][4];
  const int tid = threadIdx.x;
  const int wid = tid >> 6, lane = tid & 63;
  const int wr = wid / NCW, wc = wid % NCW;
  const int m0t = blockIdx.x * 128, n0t = blockIdx.y * BN;
  const int ir = lane >> 2, sl = lane & 3;   // staging: row-in-16, slot
  const int sg = lane >> 4, li = lane & 15;  // frags: k-group, row/col
  f32x4 acc[4][4];
#pragma unroll
  for (int i = 0; i < 4; i++)
#pragma unroll
    for (int j = 0; j < 4; j++) acc[i][j] = (f32x4){0.f, 0.f, 0.f, 0.f};
  constexpr int nIss = 8 + BN / 16;  // 1KB issues: 8 for A, BN/16 for B

  for (int k0 = 0; k0 < K; k0 += 32) {
    __syncthreads();  // prev iter's ds_reads drained before overwrite
    for (int is = wid; is < nIss; is += NW) {
      if (is < 8) {
        int r = is * 16 + ir;
        int sp = sl ^ ((r >> 1) & 3);
        gll16(A + (size_t)(m0t + r) * K + k0 + sp * 8, (void*)&As[is * 512]);
      } else {
        int r = (is - 8) * 16 + ir;
        int sp = sl ^ ((r >> 1) & 3);
        gll16(Wt + (size_t)(n0t + r) * K + k0 + sp * 8, (void*)&Bs[(is - 8) * 512]);
      }
    }
    __syncthreads();  // compiler drains vmcnt(0) before s_barrier
    bf16x8 af[4], bfr[4];
#pragma unroll
    for (int mi = 0; mi < 4; mi++) {
      int m = wr * 64 + mi * 16 + li;
      sh8 t = *(const sh8*)&As[m * 32 + ((sg ^ ((m >> 1) & 3)) << 3)];
      af[mi] = __builtin_bit_cast(bf16x8, t);
    }
#pragma unroll
    for (int ni = 0; ni < 4; ni++) {
      int n = wc * 64 + ni * 16 + li;
      sh8 t = *(const sh8*)&Bs[n * 32 + ((sg ^ ((n >> 1) & 3)) << 3)];
      bfr[ni] = __builtin_bit_cast(bf16x8, t);
    }
#pragma unroll
    for (int mi = 0; mi < 4; mi++)
#pragma unroll
      for (int ni = 0; ni < 4; ni++)
        acc[mi][ni] = __builtin_amdgcn_mfma_f32_16x16x32_bf16(af[mi], bfr[ni],
                                                              acc[mi][ni], 0, 0, 0);
  }

  float bv[4];
#pragma unroll
  for (int ni = 0; ni < 4; ni++) bv[ni] = bias[n0t + wc * 64 + ni * 16 + li];

  if (LN) {
    // bias before stats
#pragma unroll
    for (int mi = 0; mi < 4; mi++)
#pragma unroll
      for (int ni = 0; ni < 4; ni++)
#pragma unroll
        for (int r = 0; r < 4; r++) acc[mi][ni][r] += bv[ni];
    // per-row partial sum/sumsq over this wave's 64 cols
#pragma unroll
    for (int mi = 0; mi < 4; mi++)
#pragma unroll
      for (int r = 0; r < 4; r++) {
        float s = acc[mi][0][r] + acc[mi][1][r] + acc[mi][2][r] + acc[mi][3][r];
        float q2 = acc[mi][0][r] * acc[mi][0][r] + acc[mi][1][r] * acc[mi][1][r] +
                   acc[mi][2][r] * acc[mi][2][r] + acc[mi][3][r] * acc[mi][3][r];
#pragma unroll
        for (int off = 1; off < 16; off <<= 1) {
          s += __shfl_xor(s, off);
          q2 += __shfl_xor(q2, off);
        }
        if (li == 0) part[wr * 64 + mi * 16 + sg * 4 + r][wc] = make_float2(s, q2);
      }
    __syncthreads();
    float gv[4], bev[4];
#pragma unroll
    for (int ni = 0; ni < 4; ni++) {
      int col = wc * 64 + ni * 16 + li;
      gv[ni] = gg[col];
      bev[ni] = be[col];
    }
#pragma unroll
    for (int mi = 0; mi < 4; mi++)
#pragma unroll
      for (int r = 0; r < 4; r++) {
        int mrow = wr * 64 + mi * 16 + sg * 4 + r;
        float2 p0 = part[mrow][0], p1 = part[mrow][1], p2 = part[mrow][2], p3 = part[mrow][3];
        float S = p0.x + p1.x + p2.x + p3.x;
        float Qq = p0.y + p1.y + p2.y + p3.y;
        float mean = S * (1.f / 256.f);
        float var = Qq * (1.f / 256.f) - mean * mean;
        float rstd = rsqrtf(var + EPSF);
        size_t m = (size_t)(m0t + mrow);
#pragma unroll
        for (int ni = 0; ni < 4; ni++) {
          int col = wc * 64 + ni * 16 + li;
          C[m * 256 + col] = (acc[mi][ni][r] - mean) * rstd * gv[ni] + bev[ni];
        }
      }
  } else {
#pragma unroll
    for (int mi = 0; mi < 4; mi++)
#pragma unroll
      for (int r = 0; r < 4; r++) {
        int mrow = m0t + wr * 64 + mi * 16 + sg * 4 + r;
        if (mrow < M) {
#pragma unroll
          for (int ni = 0; ni < 4; ni++) {
            int col = n0t + wc * 64 + ni * 16 + li;
            float v = acc[mi][ni][r] + bv[ni];
            if (POST) v += post[(size_t)mrow * Ntot + col];
            C[(size_t)mrow * Ntot + col] = v;
          }
        }
      }
  }
}

// ---------------------------------------------------------------------------
// weight transpose + f32->bf16:  Wt[n*K+k] = bf16(W[k*N+n])
// ---------------------------------------------------------------------------
__global__ __launch_bounds__(256) void wtrans_kernel(
    const float* __restrict__ W, unsigned short* __restrict__ Wt, int K, int N) {
  int idx = blockIdx.x * 256 + threadIdx.x;
  if (idx >= K * N) return;
  int k = idx / N, n = idx - k * N;
  Wt[(size_t)n * K + k] = f2bf(W[idx]);
}

// f32 -> bf16 bulk convert, 8 elems/thread
__global__ __launch_bounds__(256) void cvt_kernel(
    const float* __restrict__ in, unsigned short* __restrict__ out, int n8) {
  int i = blockIdx.x * 256 + threadIdx.x;
  if (i >= n8) return;
  float4 a = ((const float4*)in)[i * 2];
  float4 b = ((const float4*)in)[i * 2 + 1];
  uint4 o;
  o.x = f2bf(a.x) | ((unsigned)f2bf(a.y) << 16);
  o.y = f2bf(a.z) | ((unsigned)f2bf(a.w) << 16);
  o.z = f2bf(b.x) | ((unsigned)f2bf(b.y) << 16);
  o.w = f2bf(b.z) | ((unsigned)f2bf(b.w) << 16);
  ((uint4*)out)[i] = o;
}

// ---------------------------------------------------------------------------
// iq_emb (100,128) @ w_iqp (128,256) + b -> (100,256) f32
// ---------------------------------------------------------------------------
__global__ __launch_bounds__(256) void iqp_kernel(
    const float* __restrict__ iq, const float* __restrict__ W,
    const float* __restrict__ b, float* __restrict__ out) {
  __shared__ float row[128];
  int r = blockIdx.x;
  if (threadIdx.x < 128) row[threadIdx.x] = iq[r * 128 + threadIdx.x];
  __syncthreads();
  int c = threadIdx.x;
  float acc = b[c];
#pragma unroll 8
  for (int k = 0; k < 128; ++k) acc += row[k] * W[k * 256 + c];
  out[r * 256 + c] = acc;
}

// ---------------------------------------------------------------------------
// fp32 row-blocked GEMM (kept for the small gathered aqp/vqp projections)
// rowmode 1: ir = (r/100)*200 + rowoff + r%100
// ---------------------------------------------------------------------------
template <int K, int N, int R>
__global__ __launch_bounds__(N) void gemm_kernel(
    const float* __restrict__ in, const float* __restrict__ W,
    const float* __restrict__ bias, float* __restrict__ out,
    int rowmode, int rowoff) {
  __shared__ float rows[R][K];
  int r0 = blockIdx.x * R;
  for (int e = threadIdx.x; e < R * K; e += N) {
    int rr = e / K, k = e - rr * K;
    size_t r = r0 + rr;
    size_t irx = r;
    if (rowmode) irx = (r / 100) * 200 + rowoff + (r % 100);
    rows[rr][k] = in[irx * K + k];
  }
  __syncthreads();
  int c = threadIdx.x;
  float acc[R];
  float bb = bias[c];
#pragma unroll
  for (int rr = 0; rr < R; rr++) acc[rr] = bb;
  for (int k = 0; k < K; k += 4) {
    float w0 = W[(size_t)k * N + c];
    float w1 = W[(size_t)(k + 1) * N + c];
    float w2 = W[(size_t)(k + 2) * N + c];
    float w3 = W[(size_t)(k + 3) * N + c];
#pragma unroll
    for (int rr = 0; rr < R; rr++) {
      float4 r4 = *reinterpret_cast<const float4*>(&rows[rr][k]);
      acc[rr] = fmaf(r4.x, w0, acc[rr]);
      acc[rr] = fmaf(r4.y, w1, acc[rr]);
      acc[rr] = fmaf(r4.z, w2, acc[rr]);
      acc[rr] = fmaf(r4.w, w3, acc[rr]);
    }
  }
#pragma unroll
  for (int rr = 0; rr < R; rr++) out[(size_t)(r0 + rr) * N + c] = acc[rr];
}

// ---------------------------------------------------------------------------
// fp32 flash attention, one query/thread, online softmax; bf16 output with
// optional +q residual (addq) and optional +global f32 residual (rp).
// ---------------------------------------------------------------------------
#define TK 64
__global__ __launch_bounds__(256) void attn_kernel(
    const float* __restrict__ qp, size_t qbs, int qts,
    const float* __restrict__ kp, size_t kbs, int kts,
    const float* __restrict__ vp, size_t vbs, int vts,
    unsigned short* __restrict__ op, size_t obs, int ots,
    const float* __restrict__ rp, size_t rbs, int rts,
    int nq, int nk, int addq) {
  __shared__ float ks[TK][16];
  __shared__ float vs[TK][16];
  int b = blockIdx.z, h = blockIdx.y;
  int qi = blockIdx.x * 256 + threadIdx.x;
  bool act = qi < nq;
  float q[16];
#pragma unroll
  for (int d = 0; d < 16; d++) q[d] = 0.f;
  if (act) {
    const float* qr = qp + b * qbs + (size_t)qi * qts + h * 16;
#pragma unroll
    for (int d = 0; d < 16; d++) q[d] = qr[d];
  }
  float m = -1e30f, l = 0.f, acc[16];
#pragma unroll
  for (int d = 0; d < 16; d++) acc[d] = 0.f;
  const float* kb = kp + b * kbs + h * 16;
  const float* vb = vp + b * vbs + h * 16;
  for (int t0 = 0; t0 < nk; t0 += TK) {
    int tkn = min(TK, nk - t0);
    __syncthreads();
    for (int e = threadIdx.x; e < tkn * 16; e += 256) {
      int j = e >> 4, d = e & 15;
      ks[j][d] = kb[(size_t)(t0 + j) * kts + d];
      vs[j][d] = vb[(size_t)(t0 + j) * vts + d];
    }
    __syncthreads();
    if (act) {
      for (int j = 0; j < tkn; ++j) {
        float s = 0.f;
#pragma unroll
        for (int d = 0; d < 16; d++) s += q[d] * ks[j][d];
        s *= SCALEF;
        if (s > m) {
          float cf = __expf(m - s);
          l *= cf;
#pragma unroll
          for (int d = 0; d < 16; d++) acc[d] *= cf;
          m = s;
        }
        float p = __expf(s - m);
        l += p;
#pragma unroll
        for (int d = 0; d < 16; d++) acc[d] += p * vs[j][d];
      }
    }
  }
  if (act) {
    float inv = 1.f / l;
    unsigned short* orow = op + b * obs + (size_t)qi * ots + h * 16;
    const float* rrow = rp ? (rp + b * rbs + (size_t)qi * rts + h * 16) : nullptr;
#pragma unroll
    for (int d = 0; d < 16; d++) {
      float v = acc[d] * inv + (addq ? q[d] : 0.f) + (rrow ? rrow[d] : 0.f);
      orow[d] = f2bf(v);
    }
  }
}

// aiq2 (40,100,128) copy out of SA (viewed as (40,200,128) rows 0..99)
__global__ __launch_bounds__(128) void copy_aiq2_kernel(
    const float* __restrict__ SA, float* __restrict__ out) {
  int r = blockIdx.x, c = threadIdx.x;
  size_t irx = (size_t)(r / 100) * 200 + (r % 100);
  out[(size_t)r * 128 + c] = SA[irx * 128 + c];
}

// ---------------------------------------------------------------------------
extern "C" void kernel_launch(void* const* d_in, const int* in_sizes, int n_in,
                              void* d_out, int out_size, void* d_ws, size_t ws_size,
                              hipStream_t stream) {
  const float* audio = (const float*)d_in[0];   // (40,1024,128)
  const float* vis   = (const float*)d_in[1];   // (40,1024,512)
  const float* iq    = (const float*)d_in[2];
  const float* w_iqp = (const float*)d_in[3];
  const float* b_iqp = (const float*)d_in[4];
  const float* w_afp = (const float*)d_in[5];
  const float* b_afp = (const float*)d_in[6];
  const float* w_vfp = (const float*)d_in[7];
  const float* b_vfp = (const float*)d_in[8];
  const float* g_an  = (const float*)d_in[9];
  const float* be_an = (const float*)d_in[10];
  const float* g_vn  = (const float*)d_in[11];
  const float* be_vn = (const float*)d_in[12];
  const float* w_aqp = (const float*)d_in[13];
  const float* b_aqp = (const float*)d_in[14];
  const float* w_vqp = (const float*)d_in[15];
  const float* b_vqp = (const float*)d_in[16];
  const float* w_aq  = (const float*)d_in[17];
  const float* b_aq  = (const float*)d_in[18];
  const float* w_vq  = (const float*)d_in[19];
  const float* b_vq  = (const float*)d_in[20];
  const float* w_in  = (const float*)d_in[21];
  const float* b_in  = (const float*)d_in[22];
  const float* w_o   = (const float*)d_in[23];
  const float* b_o   = (const float*)d_in[24];
  const float* w_ao  = (const float*)d_in[25];
  const float* b_ao  = (const float*)d_in[26];
  const float* w_vo  = (const float*)d_in[27];
  const float* b_vo  = (const float*)d_in[28];

  float* out = (float*)d_out;
  float* ws  = (float*)d_ws;

  // ---- d_out scratch (dead until final writes; stream-ordered) ----
  unsigned short* vis_bf = (unsigned short*)(out);  // [0,10485760) words; dead after step 9
  float* aln = out + 10485760;   // (40960,256) f32, dead after stage-1 attn
  float* vln = out + 20971520;   // (40960,256) f32, dead after stage-1 attn
  float* _a  = out + 31457280;   // (40960,128) f32, dead after stage-3 attn
  float* _v  = out + 36700160;   // (40960,128) f32, dead after stage-3 attn
  float* aiq2_out = out + 41943040;
  float* audio_out = out;              // written last (covers vis_bf+aln, both dead)
  float* vis_out   = out + 20971520;   // written last (covers vln+_a+_v, all dead)

  // ---- ws layout (f32-word offsets; total 12,706,816 words = 50.8 MB) ----
  // aattb is 40960x128 bf16 = 5,242,880 shorts = 2,621,440 WORDS (R2 bug: halved twice)
  unsigned short* WT       = (unsigned short*)(ws);            // [0, 262144)
  unsigned short* audio_bf = (unsigned short*)(ws + 262144);   // [262144, 2883584)
  unsigned short* Q1b      = (unsigned short*)(ws + 2883584);  // [.., 3399680) 8064x128
  unsigned short* sapb     = (unsigned short*)(ws + 3399680);  // [.., 3915776) 8064x128
  float* qkv               = ws + 3915776;                     // [.., 6987776) (8000,384) f32
  unsigned short* aattb    = (unsigned short*)(ws + 3915776);  // overlays qkv (disjoint lifetime), [..,6537216)
  unsigned short* vattb    = (unsigned short*)(ws + 6987776);  // [.., 9609216)
  float* SA                = ws + 9609216;                     // [.., 10633216) (8000,128)
  float* akv               = ws + 10633216;                    // [.., 11657216) (4000,256)
  float* vkv               = ws + 11657216;                    // [.., 12681216) (4000,256)
  float* aqvq              = ws + 12681216;                    // [.., 12706816) (100,256)

  // transposed bf16 weights (offsets in bf16 elems within WT)
  unsigned short* afp_t = WT + 0;
  unsigned short* vfp_t = WT + 32768;
  unsigned short* aq_t  = WT + 163840;
  unsigned short* vq_t  = WT + 180224;
  unsigned short* in_t  = WT + 245760;
  unsigned short* o_t   = WT + 294912;
  unsigned short* ao_t  = WT + 311296;
  unsigned short* vo_t  = WT + 376832;

  // 0. weight transpose+convert, activation convert
  wtrans_kernel<<<128, 256, 0, stream>>>(w_afp, afp_t, 128, 256);
  wtrans_kernel<<<512, 256, 0, stream>>>(w_vfp, vfp_t, 512, 256);
  wtrans_kernel<<<64,  256, 0, stream>>>(w_aq,  aq_t,  128, 128);
  wtrans_kernel<<<256, 256, 0, stream>>>(w_vq,  vq_t,  512, 128);
  wtrans_kernel<<<192, 256, 0, stream>>>(w_in,  in_t,  128, 384);
  wtrans_kernel<<<64,  256, 0, stream>>>(w_o,   o_t,   128, 128);
  wtrans_kernel<<<256, 256, 0, stream>>>(w_ao,  ao_t,  128, 512);
  wtrans_kernel<<<256, 256, 0, stream>>>(w_vo,  vo_t,  128, 512);
  cvt_kernel<<<2560,  256, 0, stream>>>(audio, audio_bf, 655360);
  cvt_kernel<<<10240, 256, 0, stream>>>(vis,   vis_bf,   2621440);

  // 1. iq_emb projection (f32)
  iqp_kernel<<<100, 256, 0, stream>>>(iq, w_iqp, b_iqp, aqvq);

  // 2. proj + fused LN  (MFMA)
  mfma_gemm<128, 256, true, false><<<dim3(320, 1), 512, 0, stream>>>(
      audio_bf, afp_t, b_afp, g_an, be_an, nullptr, aln, 40960, 256);
  mfma_gemm<512, 256, true, false><<<dim3(320, 1), 512, 0, stream>>>(
      vis_bf, vfp_t, b_vfp, g_vn, be_vn, nullptr, vln, 40960, 256);

  // 3. stage-1 cross-attn (+q residual), bf16 out into (40,200,128) layout
  attn_kernel<<<dim3(1, 8, 40), 256, 0, stream>>>(
      aqvq, 0, 256, aln, 1024 * 256, 256, aln + 128, 1024 * 256, 256,
      Q1b, 200 * 128, 128, nullptr, 0, 0, 100, 1024, 1);
  attn_kernel<<<dim3(1, 8, 40), 256, 0, stream>>>(
      aqvq + 128, 0, 256, vln, 1024 * 256, 256, vln + 128, 1024 * 256, 256,
      Q1b + 100 * 128, 200 * 128, 128, nullptr, 0, 0, 100, 1024, 1);

  // 4. qkv = queries @ w_in + b_in  (MFMA, M=8000 padded to 8064)
  mfma_gemm<128, 128, false, false><<<dim3(63, 3), 256, 0, stream>>>(
      Q1b, in_t, b_in, nullptr, nullptr, nullptr, qkv, 8000, 384);

  // 5. self-attention (1000 tokens x 8 batches), bf16 out
  attn_kernel<<<dim3(4, 8, 8), 256, 0, stream>>>(
      qkv, 1000 * 384, 384, qkv + 128, 1000 * 384, 384, qkv + 256, 1000 * 384, 384,
      sapb, 1000 * 128, 128, nullptr, 0, 0, 1000, 1000, 0);

  // 6. SA = sa_pre @ w_o + b_o (MFMA)
  mfma_gemm<128, 128, false, false><<<dim3(63, 1), 256, 0, stream>>>(
      sapb, o_t, b_o, nullptr, nullptr, nullptr, SA, 8000, 128);

  // 7. aiq2 output
  copy_aiq2_kernel<<<4000, 128, 0, stream>>>(SA, aiq2_out);

  // 8. kf/vf projections (fp32, gathered rows of SA)
  gemm_kernel<128, 256, 16><<<250, 256, 0, stream>>>(SA, w_aqp, b_aqp, akv, 1, 0);
  gemm_kernel<128, 256, 16><<<250, 256, 0, stream>>>(SA, w_vqp, b_vqp, vkv, 1, 100);

  // 9. _a / _v projections (MFMA)
  mfma_gemm<128, 128, false, false><<<dim3(320, 1), 256, 0, stream>>>(
      audio_bf, aq_t, b_aq, nullptr, nullptr, nullptr, _a, 40960, 128);
  mfma_gemm<512, 128, false, false><<<dim3(320, 1), 256, 0, stream>>>(
      vis_bf, vq_t, b_vq, nullptr, nullptr, nullptr, _v, 40960, 128);

  // 10. stage-3 cross-attn; audio side fuses +audio residual, bf16 out
  attn_kernel<<<dim3(4, 8, 40), 256, 0, stream>>>(
      _a, 1024 * 128, 128, vkv, 100 * 256, 256, vkv + 128, 100 * 256, 256,
      aattb, 1024 * 128, 128, audio, 1024 * 128, 128, 1024, 100, 0);
  attn_kernel<<<dim3(4, 8, 40), 256, 0, stream>>>(
      _v, 1024 * 128, 128, akv, 100 * 256, 256, akv + 128, 100 * 256, 256,
      vattb, 1024 * 128, 128, nullptr, 0, 0, 1024, 100, 0);

  // 11. output projections (MFMA); w_vo fuses +vis residual
  mfma_gemm<128, 128, false, false><<<dim3(320, 4), 256, 0, stream>>>(
      aattb, ao_t, b_ao, nullptr, nullptr, nullptr, audio_out, 40960, 512);
  mfma_gemm<128, 128, false, true><<<dim3(320, 4), 256, 0, stream>>>(
      vattb, vo_t, b_vo, nullptr, nullptr, vis, vis_out, 40960, 512);
}

// Round 4
// 741.395 us; speedup vs baseline: 2.2145x; 1.5295x over previous
//
#include <hip/hip_runtime.h>

#define EPSF 1e-5f
#define SCALEF 0.25f   // hd=16 -> 16^-0.5

typedef __attribute__((ext_vector_type(8))) __bf16 bf16x8;
typedef __attribute__((ext_vector_type(8))) unsigned short sh8;
typedef __attribute__((ext_vector_type(4))) float f32x4;

__device__ __forceinline__ unsigned short f2bf(float f) {
  unsigned u = __float_as_uint(f);
  return (unsigned short)((u + 0x7FFFu + ((u >> 16) & 1u)) >> 16);
}

// async global->LDS, 16B per lane; LDS dest = uniform base + lane*16
__device__ __forceinline__ void gll16(const void* g, void* l) {
  __builtin_amdgcn_global_load_lds((const __attribute__((address_space(1))) void*)g,
                                   (__attribute__((address_space(3))) void*)l,
                                   16, 0, 0);
}

// ---------------------------------------------------------------------------
// MFMA GEMM: C[M][Ntot](f32) = A[M][K](bf16) x Wt[N][K](bf16)^T + bias
//  tile 128 x BN, block = BN*2 threads; LN / POST epilogue variants.
// ---------------------------------------------------------------------------
template <int K, int BN, bool LN, bool POST>
__global__ __launch_bounds__(BN * 2) void mfma_gemm(
    const unsigned short* __restrict__ A, const unsigned short* __restrict__ Wt,
    const float* __restrict__ bias, const float* __restrict__ gg,
    const float* __restrict__ be, const float* __restrict__ post,
    float* __restrict__ C, int M, int Ntot) {
  constexpr int NW = BN / 32;   // waves per block
  constexpr int NCW = BN / 64;  // wave columns
  __shared__ __align__(16) unsigned short As[128 * 32];
  __shared__ __align__(16) unsigned short Bs[BN * 32];
  __shared__ float2 part[128][4];
  const int tid = threadIdx.x;
  const int wid = tid >> 6, lane = tid & 63;
  const int wr = wid / NCW, wc = wid % NCW;
  const int m0t = blockIdx.x * 128, n0t = blockIdx.y * BN;
  const int ir = lane >> 2, sl = lane & 3;   // staging: row-in-16, slot
  const int sg = lane >> 4, li = lane & 15;  // frags: k-group, row/col
  f32x4 acc[4][4];
#pragma unroll
  for (int i = 0; i < 4; i++)
#pragma unroll
    for (int j = 0; j < 4; j++) acc[i][j] = (f32x4){0.f, 0.f, 0.f, 0.f};
  constexpr int nIss = 8 + BN / 16;  // 1KB issues: 8 for A, BN/16 for B

  for (int k0 = 0; k0 < K; k0 += 32) {
    __syncthreads();
    for (int is = wid; is < nIss; is += NW) {
      if (is < 8) {
        int r = is * 16 + ir;
        int sp = sl ^ ((r >> 1) & 3);
        gll16(A + (size_t)(m0t + r) * K + k0 + sp * 8, (void*)&As[is * 512]);
      } else {
        int r = (is - 8) * 16 + ir;
        int sp = sl ^ ((r >> 1) & 3);
        gll16(Wt + (size_t)(n0t + r) * K + k0 + sp * 8, (void*)&Bs[(is - 8) * 512]);
      }
    }
    __syncthreads();
    bf16x8 af[4], bfr[4];
#pragma unroll
    for (int mi = 0; mi < 4; mi++) {
      int m = wr * 64 + mi * 16 + li;
      sh8 t = *(const sh8*)&As[m * 32 + ((sg ^ ((m >> 1) & 3)) << 3)];
      af[mi] = __builtin_bit_cast(bf16x8, t);
    }
#pragma unroll
    for (int ni = 0; ni < 4; ni++) {
      int n = wc * 64 + ni * 16 + li;
      sh8 t = *(const sh8*)&Bs[n * 32 + ((sg ^ ((n >> 1) & 3)) << 3)];
      bfr[ni] = __builtin_bit_cast(bf16x8, t);
    }
#pragma unroll
    for (int mi = 0; mi < 4; mi++)
#pragma unroll
      for (int ni = 0; ni < 4; ni++)
        acc[mi][ni] = __builtin_amdgcn_mfma_f32_16x16x32_bf16(af[mi], bfr[ni],
                                                              acc[mi][ni], 0, 0, 0);
  }

  float bv[4];
#pragma unroll
  for (int ni = 0; ni < 4; ni++) bv[ni] = bias[n0t + wc * 64 + ni * 16 + li];

  if (LN) {
#pragma unroll
    for (int mi = 0; mi < 4; mi++)
#pragma unroll
      for (int ni = 0; ni < 4; ni++)
#pragma unroll
        for (int r = 0; r < 4; r++) acc[mi][ni][r] += bv[ni];
#pragma unroll
    for (int mi = 0; mi < 4; mi++)
#pragma unroll
      for (int r = 0; r < 4; r++) {
        float s = acc[mi][0][r] + acc[mi][1][r] + acc[mi][2][r] + acc[mi][3][r];
        float q2 = acc[mi][0][r] * acc[mi][0][r] + acc[mi][1][r] * acc[mi][1][r] +
                   acc[mi][2][r] * acc[mi][2][r] + acc[mi][3][r] * acc[mi][3][r];
#pragma unroll
        for (int off = 1; off < 16; off <<= 1) {
          s += __shfl_xor(s, off);
          q2 += __shfl_xor(q2, off);
        }
        if (li == 0) part[wr * 64 + mi * 16 + sg * 4 + r][wc] = make_float2(s, q2);
      }
    __syncthreads();
    float gv[4], bev[4];
#pragma unroll
    for (int ni = 0; ni < 4; ni++) {
      int col = wc * 64 + ni * 16 + li;
      gv[ni] = gg[col];
      bev[ni] = be[col];
    }
#pragma unroll
    for (int mi = 0; mi < 4; mi++)
#pragma unroll
      for (int r = 0; r < 4; r++) {
        int mrow = wr * 64 + mi * 16 + sg * 4 + r;
        float2 p0 = part[mrow][0], p1 = part[mrow][1], p2 = part[mrow][2], p3 = part[mrow][3];
        float S = p0.x + p1.x + p2.x + p3.x;
        float Qq = p0.y + p1.y + p2.y + p3.y;
        float mean = S * (1.f / 256.f);
        float var = Qq * (1.f / 256.f) - mean * mean;
        float rstd = rsqrtf(var + EPSF);
        size_t m = (size_t)(m0t + mrow);
#pragma unroll
        for (int ni = 0; ni < 4; ni++) {
          int col = wc * 64 + ni * 16 + li;
          C[m * 256 + col] = (acc[mi][ni][r] - mean) * rstd * gv[ni] + bev[ni];
        }
      }
  } else {
#pragma unroll
    for (int mi = 0; mi < 4; mi++)
#pragma unroll
      for (int r = 0; r < 4; r++) {
        int mrow = m0t + wr * 64 + mi * 16 + sg * 4 + r;
        if (mrow < M) {
#pragma unroll
          for (int ni = 0; ni < 4; ni++) {
            int col = n0t + wc * 64 + ni * 16 + li;
            float v = acc[mi][ni][r] + bv[ni];
            if (POST) v += post[(size_t)mrow * Ntot + col];
            C[(size_t)mrow * Ntot + col] = v;
          }
        }
      }
  }
}

// ---------------------------------------------------------------------------
__global__ __launch_bounds__(256) void wtrans_kernel(
    const float* __restrict__ W, unsigned short* __restrict__ Wt, int K, int N) {
  int idx = blockIdx.x * 256 + threadIdx.x;
  if (idx >= K * N) return;
  int k = idx / N, n = idx - k * N;
  Wt[(size_t)n * K + k] = f2bf(W[idx]);
}

__global__ __launch_bounds__(256) void cvt_kernel(
    const float* __restrict__ in, unsigned short* __restrict__ out, int n8) {
  int i = blockIdx.x * 256 + threadIdx.x;
  if (i >= n8) return;
  float4 a = ((const float4*)in)[i * 2];
  float4 b = ((const float4*)in)[i * 2 + 1];
  uint4 o;
  o.x = f2bf(a.x) | ((unsigned)f2bf(a.y) << 16);
  o.y = f2bf(a.z) | ((unsigned)f2bf(a.w) << 16);
  o.z = f2bf(b.x) | ((unsigned)f2bf(b.y) << 16);
  o.w = f2bf(b.z) | ((unsigned)f2bf(b.w) << 16);
  ((uint4*)out)[i] = o;
}

__global__ __launch_bounds__(256) void iqp_kernel(
    const float* __restrict__ iq, const float* __restrict__ W,
    const float* __restrict__ b, float* __restrict__ out) {
  __shared__ float row[128];
  int r = blockIdx.x;
  if (threadIdx.x < 128) row[threadIdx.x] = iq[r * 128 + threadIdx.x];
  __syncthreads();
  int c = threadIdx.x;
  float acc = b[c];
#pragma unroll 8
  for (int k = 0; k < 128; ++k) acc += row[k] * W[k * 256 + c];
  out[r * 256 + c] = acc;
}

// fp32 row-blocked GEMM (small gathered aqp/vqp projections)
template <int K, int N, int R>
__global__ __launch_bounds__(N) void gemm_kernel(
    const float* __restrict__ in, const float* __restrict__ W,
    const float* __restrict__ bias, float* __restrict__ out,
    int rowmode, int rowoff) {
  __shared__ float rows[R][K];
  int r0 = blockIdx.x * R;
  for (int e = threadIdx.x; e < R * K; e += N) {
    int rr = e / K, k = e - rr * K;
    size_t r = r0 + rr;
    size_t irx = r;
    if (rowmode) irx = (r / 100) * 200 + rowoff + (r % 100);
    rows[rr][k] = in[irx * K + k];
  }
  __syncthreads();
  int c = threadIdx.x;
  float acc[R];
  float bb = bias[c];
#pragma unroll
  for (int rr = 0; rr < R; rr++) acc[rr] = bb;
  for (int k = 0; k < K; k += 4) {
    float w0 = W[(size_t)k * N + c];
    float w1 = W[(size_t)(k + 1) * N + c];
    float w2 = W[(size_t)(k + 2) * N + c];
    float w3 = W[(size_t)(k + 3) * N + c];
#pragma unroll
    for (int rr = 0; rr < R; rr++) {
      float4 r4 = *reinterpret_cast<const float4*>(&rows[rr][k]);
      acc[rr] = fmaf(r4.x, w0, acc[rr]);
      acc[rr] = fmaf(r4.y, w1, acc[rr]);
      acc[rr] = fmaf(r4.z, w2, acc[rr]);
      acc[rr] = fmaf(r4.w, w3, acc[rr]);
    }
  }
#pragma unroll
  for (int rr = 0; rr < R; rr++) out[(size_t)(r0 + rr) * N + c] = acc[rr];
}

// ---------------------------------------------------------------------------
// fp32 flash attention, direct (no split) path — used for stage-3 (nk=100).
// ---------------------------------------------------------------------------
#define TK 64
__global__ __launch_bounds__(256) void attn_kernel(
    const float* __restrict__ qp, size_t qbs, int qts,
    const float* __restrict__ kp, size_t kbs, int kts,
    const float* __restrict__ vp, size_t vbs, int vts,
    unsigned short* __restrict__ op, size_t obs, int ots,
    const float* __restrict__ rp, size_t rbs, int rts,
    int nq, int nk, int addq) {
  __shared__ float ks[TK][16];
  __shared__ float vs[TK][16];
  int b = blockIdx.z, h = blockIdx.y;
  int qi = blockIdx.x * 256 + threadIdx.x;
  bool act = qi < nq;
  float q[16];
#pragma unroll
  for (int d = 0; d < 16; d++) q[d] = 0.f;
  if (act) {
    const float* qr = qp + b * qbs + (size_t)qi * qts + h * 16;
#pragma unroll
    for (int d = 0; d < 16; d++) q[d] = qr[d];
  }
  float m = -1e30f, l = 0.f, acc[16];
#pragma unroll
  for (int d = 0; d < 16; d++) acc[d] = 0.f;
  const float* kb = kp + b * kbs + h * 16;
  const float* vb = vp + b * vbs + h * 16;
  for (int t0 = 0; t0 < nk; t0 += TK) {
    int tkn = min(TK, nk - t0);
    __syncthreads();
    for (int e = threadIdx.x; e < tkn * 16; e += 256) {
      int j = e >> 4, d = e & 15;
      ks[j][d] = kb[(size_t)(t0 + j) * kts + d];
      vs[j][d] = vb[(size_t)(t0 + j) * vts + d];
    }
    __syncthreads();
    if (act) {
      for (int j = 0; j < tkn; ++j) {
        float s = 0.f;
#pragma unroll
        for (int d = 0; d < 16; d++) s += q[d] * ks[j][d];
        s *= SCALEF;
        if (s > m) {
          float cf = __expf(m - s);
          l *= cf;
#pragma unroll
          for (int d = 0; d < 16; d++) acc[d] *= cf;
          m = s;
        }
        float p = __expf(s - m);
        l += p;
#pragma unroll
        for (int d = 0; d < 16; d++) acc[d] += p * vs[j][d];
      }
    }
  }
  if (act) {
    float inv = 1.f / l;
    unsigned short* orow = op + b * obs + (size_t)qi * ots + h * 16;
    const float* rrow = rp ? (rp + b * rbs + (size_t)qi * rts + h * 16) : nullptr;
#pragma unroll
    for (int d = 0; d < 16; d++) {
      float v = acc[d] * inv + (addq ? q[d] : 0.f) + (rrow ? rrow[d] : 0.f);
      orow[d] = f2bf(v);
    }
  }
}

// ---------------------------------------------------------------------------
// Split-K flash partial: block = (q-chunk, key-split s) of one (b,h).
// Writes unnormalized acc[16], m, l to pbuf[((b*8+h)*nq+qi)*NS+s][18].
// grid.x = nqb*NS (s = blockIdx.x % NS), grid.y = H, grid.z = B.
// ---------------------------------------------------------------------------
__global__ __launch_bounds__(256) void attn_partial_kernel(
    const float* __restrict__ qp, size_t qbs, int qts,
    const float* __restrict__ kp, size_t kbs, int kts,
    const float* __restrict__ vp, size_t vbs, int vts,
    float* __restrict__ pbuf, int nq, int nk, int NS) {
  __shared__ float ks[TK][16];
  __shared__ float vs[TK][16];
  int s = blockIdx.x % NS, qb = blockIdx.x / NS;
  int b = blockIdx.z, h = blockIdx.y;
  int qi = qb * 256 + threadIdx.x;
  bool act = qi < nq;
  int chunk = nk / NS;
  int k0r = s * chunk, k1 = k0r + chunk;
  float q[16];
#pragma unroll
  for (int d = 0; d < 16; d++) q[d] = 0.f;
  if (act) {
    const float* qr = qp + b * qbs + (size_t)qi * qts + h * 16;
#pragma unroll
    for (int d = 0; d < 16; d++) q[d] = qr[d];
  }
  float m = -1e30f, l = 0.f, acc[16];
#pragma unroll
  for (int d = 0; d < 16; d++) acc[d] = 0.f;
  const float* kb = kp + b * kbs + h * 16;
  const float* vb = vp + b * vbs + h * 16;
  for (int t0 = k0r; t0 < k1; t0 += TK) {
    int tkn = min(TK, k1 - t0);
    __syncthreads();
    for (int e = threadIdx.x; e < tkn * 16; e += 256) {
      int j = e >> 4, d = e & 15;
      ks[j][d] = kb[(size_t)(t0 + j) * kts + d];
      vs[j][d] = vb[(size_t)(t0 + j) * vts + d];
    }
    __syncthreads();
    if (act) {
      for (int j = 0; j < tkn; ++j) {
        float sc = 0.f;
#pragma unroll
        for (int d = 0; d < 16; d++) sc += q[d] * ks[j][d];
        sc *= SCALEF;
        if (sc > m) {
          float cf = __expf(m - sc);
          l *= cf;
#pragma unroll
          for (int d = 0; d < 16; d++) acc[d] *= cf;
          m = sc;
        }
        float p = __expf(sc - m);
        l += p;
#pragma unroll
        for (int d = 0; d < 16; d++) acc[d] += p * vs[j][d];
      }
    }
  }
  if (act) {
    size_t pidx = ((((size_t)b * 8 + h) * nq + qi) * NS + s) * 18;
#pragma unroll
    for (int d = 0; d < 16; d++) pbuf[pidx + d] = acc[d];
    pbuf[pidx + 16] = m;
    pbuf[pidx + 17] = l;
  }
}

// Combine NS partials per (b,h,qi); optional +q residual; bf16 out.
__global__ __launch_bounds__(256) void attn_combine_kernel(
    const float* __restrict__ pbuf,
    const float* __restrict__ qp, size_t qbs, int qts,
    unsigned short* __restrict__ op, size_t obs, int ots,
    int nq, int NS, int addq, int total) {
  int gid = blockIdx.x * 256 + threadIdx.x;
  if (gid >= total) return;
  int qi = gid % nq;
  int bh = gid / nq;
  int h = bh & 7, b = bh >> 3;
  size_t pb = ((size_t)bh * nq + qi) * (size_t)NS * 18;
  float m = -1e30f;
  for (int s = 0; s < NS; s++) m = fmaxf(m, pbuf[pb + s * 18 + 16]);
  float l = 0.f, acc[16];
#pragma unroll
  for (int d = 0; d < 16; d++) acc[d] = 0.f;
  for (int s = 0; s < NS; s++) {
    const float* pp = pbuf + pb + s * 18;
    float w = __expf(pp[16] - m);
    l += pp[17] * w;
#pragma unroll
    for (int d = 0; d < 16; d++) acc[d] += pp[d] * w;
  }
  float inv = 1.f / l;
  unsigned short* orow = op + b * obs + (size_t)qi * ots + h * 16;
  if (addq) {
    const float* qr = qp + b * qbs + (size_t)qi * qts + h * 16;
#pragma unroll
    for (int d = 0; d < 16; d++) orow[d] = f2bf(acc[d] * inv + qr[d]);
  } else {
#pragma unroll
    for (int d = 0; d < 16; d++) orow[d] = f2bf(acc[d] * inv);
  }
}

// aiq2 (40,100,128) copy out of SA (viewed as (40,200,128) rows 0..99)
__global__ __launch_bounds__(128) void copy_aiq2_kernel(
    const float* __restrict__ SA, float* __restrict__ out) {
  int r = blockIdx.x, c = threadIdx.x;
  size_t irx = (size_t)(r / 100) * 200 + (r % 100);
  out[(size_t)r * 128 + c] = SA[irx * 128 + c];
}

// ---------------------------------------------------------------------------
extern "C" void kernel_launch(void* const* d_in, const int* in_sizes, int n_in,
                              void* d_out, int out_size, void* d_ws, size_t ws_size,
                              hipStream_t stream) {
  const float* audio = (const float*)d_in[0];   // (40,1024,128)
  const float* vis   = (const float*)d_in[1];   // (40,1024,512)
  const float* iq    = (const float*)d_in[2];
  const float* w_iqp = (const float*)d_in[3];
  const float* b_iqp = (const float*)d_in[4];
  const float* w_afp = (const float*)d_in[5];
  const float* b_afp = (const float*)d_in[6];
  const float* w_vfp = (const float*)d_in[7];
  const float* b_vfp = (const float*)d_in[8];
  const float* g_an  = (const float*)d_in[9];
  const float* be_an = (const float*)d_in[10];
  const float* g_vn  = (const float*)d_in[11];
  const float* be_vn = (const float*)d_in[12];
  const float* w_aqp = (const float*)d_in[13];
  const float* b_aqp = (const float*)d_in[14];
  const float* w_vqp = (const float*)d_in[15];
  const float* b_vqp = (const float*)d_in[16];
  const float* w_aq  = (const float*)d_in[17];
  const float* b_aq  = (const float*)d_in[18];
  const float* w_vq  = (const float*)d_in[19];
  const float* b_vq  = (const float*)d_in[20];
  const float* w_in  = (const float*)d_in[21];
  const float* b_in  = (const float*)d_in[22];
  const float* w_o   = (const float*)d_in[23];
  const float* b_o   = (const float*)d_in[24];
  const float* w_ao  = (const float*)d_in[25];
  const float* b_ao  = (const float*)d_in[26];
  const float* w_vo  = (const float*)d_in[27];
  const float* b_vo  = (const float*)d_in[28];

  float* out = (float*)d_out;
  float* ws  = (float*)d_ws;

  // ---- d_out scratch (dead until final writes; stream-ordered) ----
  unsigned short* vis_bf = (unsigned short*)(out);  // [0,10485760) words
  float* aln = out + 10485760;   // (40960,256) f32, dead after stage-1 attn
  float* vln = out + 20971520;   // (40960,256) f32, dead after stage-1 attn
  float* _a  = out + 31457280;   // (40960,128) f32, written step 9
  float* _v  = out + 36700160;   // (40960,128) f32, written step 9
  float* pbuf = out + 31457280;  // 4,608,000 words of partials; dead before step 9
  float* aiq2_out = out + 41943040;
  float* audio_out = out;
  float* vis_out   = out + 20971520;

  // ---- ws layout (f32-word offsets; total 12,706,816 words = 50.8 MB) ----
  unsigned short* WT       = (unsigned short*)(ws);            // [0, 262144)
  unsigned short* audio_bf = (unsigned short*)(ws + 262144);   // [262144, 2883584)
  unsigned short* Q1b      = (unsigned short*)(ws + 2883584);  // 8064x128
  unsigned short* sapb     = (unsigned short*)(ws + 3399680);  // 8064x128
  float* qkv               = ws + 3915776;                     // (8000,384) f32
  unsigned short* aattb    = (unsigned short*)(ws + 3915776);  // overlays qkv
  unsigned short* vattb    = (unsigned short*)(ws + 6987776);  // 2,621,440 words
  float* SA                = ws + 9609216;                     // (8000,128)
  float* akv               = ws + 10633216;                    // (4000,256)
  float* vkv               = ws + 11657216;                    // (4000,256)
  float* aqvq              = ws + 12681216;                    // (100,256)

  unsigned short* afp_t = WT + 0;
  unsigned short* vfp_t = WT + 32768;
  unsigned short* aq_t  = WT + 163840;
  unsigned short* vq_t  = WT + 180224;
  unsigned short* in_t  = WT + 245760;
  unsigned short* o_t   = WT + 294912;
  unsigned short* ao_t  = WT + 311296;
  unsigned short* vo_t  = WT + 376832;

  // 0. weight transpose+convert, activation convert
  wtrans_kernel<<<128, 256, 0, stream>>>(w_afp, afp_t, 128, 256);
  wtrans_kernel<<<512, 256, 0, stream>>>(w_vfp, vfp_t, 512, 256);
  wtrans_kernel<<<64,  256, 0, stream>>>(w_aq,  aq_t,  128, 128);
  wtrans_kernel<<<256, 256, 0, stream>>>(w_vq,  vq_t,  512, 128);
  wtrans_kernel<<<192, 256, 0, stream>>>(w_in,  in_t,  128, 384);
  wtrans_kernel<<<64,  256, 0, stream>>>(w_o,   o_t,   128, 128);
  wtrans_kernel<<<256, 256, 0, stream>>>(w_ao,  ao_t,  128, 512);
  wtrans_kernel<<<256, 256, 0, stream>>>(w_vo,  vo_t,  128, 512);
  cvt_kernel<<<2560,  256, 0, stream>>>(audio, audio_bf, 655360);
  cvt_kernel<<<10240, 256, 0, stream>>>(vis,   vis_bf,   2621440);

  // 1. iq_emb projection (f32)
  iqp_kernel<<<100, 256, 0, stream>>>(iq, w_iqp, b_iqp, aqvq);

  // 2. proj + fused LN  (MFMA)
  mfma_gemm<128, 256, true, false><<<dim3(320, 1), 512, 0, stream>>>(
      audio_bf, afp_t, b_afp, g_an, be_an, nullptr, aln, 40960, 256);
  mfma_gemm<512, 256, true, false><<<dim3(320, 1), 512, 0, stream>>>(
      vis_bf, vfp_t, b_vfp, g_vn, be_vn, nullptr, vln, 40960, 256);

  // 3. stage-1 cross-attn: split-K (NS=8) partial + combine, +q residual
  attn_partial_kernel<<<dim3(8, 8, 40), 256, 0, stream>>>(
      aqvq, 0, 256, aln, 1024 * 256, 256, aln + 128, 1024 * 256, 256,
      pbuf, 100, 1024, 8);
  attn_combine_kernel<<<125, 256, 0, stream>>>(
      pbuf, aqvq, 0, 256, Q1b, 200 * 128, 128, 100, 8, 1, 32000);
  attn_partial_kernel<<<dim3(8, 8, 40), 256, 0, stream>>>(
      aqvq + 128, 0, 256, vln, 1024 * 256, 256, vln + 128, 1024 * 256, 256,
      pbuf, 100, 1024, 8);
  attn_combine_kernel<<<125, 256, 0, stream>>>(
      pbuf, aqvq + 128, 0, 256, Q1b + 100 * 128, 200 * 128, 128, 100, 8, 1, 32000);

  // 4. qkv = queries @ w_in + b_in  (MFMA, M=8000 padded to 8064)
  mfma_gemm<128, 128, false, false><<<dim3(63, 3), 256, 0, stream>>>(
      Q1b, in_t, b_in, nullptr, nullptr, nullptr, qkv, 8000, 384);

  // 5. self-attention (1000 tokens x 8 batches): split-K NS=4
  attn_partial_kernel<<<dim3(16, 8, 8), 256, 0, stream>>>(
      qkv, 1000 * 384, 384, qkv + 128, 1000 * 384, 384, qkv + 256, 1000 * 384, 384,
      pbuf, 1000, 1000, 4);
  attn_combine_kernel<<<250, 256, 0, stream>>>(
      pbuf, nullptr, 0, 0, sapb, 1000 * 128, 128, 1000, 4, 0, 64000);

  // 6. SA = sa_pre @ w_o + b_o (MFMA)
  mfma_gemm<128, 128, false, false><<<dim3(63, 1), 256, 0, stream>>>(
      sapb, o_t, b_o, nullptr, nullptr, nullptr, SA, 8000, 128);

  // 7. aiq2 output
  copy_aiq2_kernel<<<4000, 128, 0, stream>>>(SA, aiq2_out);

  // 8. kf/vf projections (fp32, gathered rows of SA)
  gemm_kernel<128, 256, 16><<<250, 256, 0, stream>>>(SA, w_aqp, b_aqp, akv, 1, 0);
  gemm_kernel<128, 256, 16><<<250, 256, 0, stream>>>(SA, w_vqp, b_vqp, vkv, 1, 100);

  // 9. _a / _v projections (MFMA)
  mfma_gemm<128, 128, false, false><<<dim3(320, 1), 256, 0, stream>>>(
      audio_bf, aq_t, b_aq, nullptr, nullptr, nullptr, _a, 40960, 128);
  mfma_gemm<512, 128, false, false><<<dim3(320, 1), 256, 0, stream>>>(
      vis_bf, vq_t, b_vq, nullptr, nullptr, nullptr, _v, 40960, 128);

  // 10. stage-3 cross-attn (direct path; nk=100); audio side fuses +audio
  attn_kernel<<<dim3(4, 8, 40), 256, 0, stream>>>(
      _a, 1024 * 128, 128, vkv, 100 * 256, 256, vkv + 128, 100 * 256, 256,
      aattb, 1024 * 128, 128, audio, 1024 * 128, 128, 1024, 100, 0);
  attn_kernel<<<dim3(4, 8, 40), 256, 0, stream>>>(
      _v, 1024 * 128, 128, akv, 100 * 256, 256, akv + 128, 100 * 256, 256,
      vattb, 1024 * 128, 128, nullptr, 0, 0, 1024, 100, 0);

  // 11. output projections (MFMA); w_vo fuses +vis residual
  mfma_gemm<128, 128, false, false><<<dim3(320, 4), 256, 0, stream>>>(
      aattb, ao_t, b_ao, nullptr, nullptr, nullptr, audio_out, 40960, 512);
  mfma_gemm<128, 128, false, true><<<dim3(320, 4), 256, 0, stream>>>(
      vattb, vo_t, b_vo, nullptr, nullptr, vis, vis_out, 40960, 512);
}

// Round 5
// 657.360 us; speedup vs baseline: 2.4976x; 1.1278x over previous
//
#include <hip/hip_runtime.h>

#define EPSF 1e-5f
#define SCALEF 0.25f   // hd=16 -> 16^-0.5

typedef __attribute__((ext_vector_type(8))) __bf16 bf16x8;
typedef __attribute__((ext_vector_type(8))) unsigned short sh8;
typedef __attribute__((ext_vector_type(4))) float f32x4;

__device__ __forceinline__ unsigned short f2bf(float f) {
  unsigned u = __float_as_uint(f);
  return (unsigned short)((u + 0x7FFFu + ((u >> 16) & 1u)) >> 16);
}
__device__ __forceinline__ unsigned pk2(float lo, float hi) {
  return (unsigned)f2bf(lo) | ((unsigned)f2bf(hi) << 16);
}
__device__ __forceinline__ float dot4(float4 a, float4 b) {
  return a.x * b.x + a.y * b.y + a.z * b.z + a.w * b.w;
}

// async global->LDS, 16B per lane; LDS dest = uniform base + lane*16
__device__ __forceinline__ void gll16(const void* g, void* l) {
  __builtin_amdgcn_global_load_lds((const __attribute__((address_space(1))) void*)g,
                                   (__attribute__((address_space(3))) void*)l,
                                   16, 0, 0);
}

// ---------------------------------------------------------------------------
// MFMA GEMM: C = A[M][K](bf16) x Wt[N][K](bf16)^T + bias
//  AHEAD: A stored head-major [B][8][ATPB][16] bf16 (per-lane gather source)
//  EPI 0: token-major f32 store (+POST residual)
//  EPI 1: fused LayerNorm (Ntot=256) then head-major split-2 f32 store
//         (K part -> C, V part -> C + CPS), token geometry CTPB
//  EPI 2: head-major split-(Ntot/128) f32 store, part p -> C + p*CPS
// ---------------------------------------------------------------------------
template <int K, int BN, int EPI, bool POST, bool AHEAD>
__global__ __launch_bounds__(BN * 2) void mfma_gemm(
    const unsigned short* __restrict__ A, const unsigned short* __restrict__ Wt,
    const float* __restrict__ bias, const float* __restrict__ gg,
    const float* __restrict__ be, const float* __restrict__ post,
    float* __restrict__ C, int M, int Ntot, int ATPB, int CTPB, size_t CPS) {
  constexpr int NW = BN / 32;   // waves per block
  constexpr int NCW = BN / 64;  // wave columns
  __shared__ __align__(16) unsigned short As[128 * 32];
  __shared__ __align__(16) unsigned short Bs[BN * 32];
  __shared__ float2 part[128][4];
  const int tid = threadIdx.x;
  const int wid = tid >> 6, lane = tid & 63;
  const int wr = wid / NCW, wc = wid % NCW;
  const int m0t = blockIdx.x * 128, n0t = blockIdx.y * BN;
  const int ir = lane >> 2, sl = lane & 3;   // staging: row-in-16, slot
  const int sg = lane >> 4, li = lane & 15;  // frags: k-group, row/col
  f32x4 acc[4][4];
#pragma unroll
  for (int i = 0; i < 4; i++)
#pragma unroll
    for (int j = 0; j < 4; j++) acc[i][j] = (f32x4){0.f, 0.f, 0.f, 0.f};
  constexpr int nIss = 8 + BN / 16;  // 1KB issues: 8 for A, BN/16 for B

  for (int k0 = 0; k0 < K; k0 += 32) {
    __syncthreads();
    for (int is = wid; is < nIss; is += NW) {
      if (is < 8) {
        int r = is * 16 + ir;
        int sp = sl ^ ((r >> 1) & 3);
        const unsigned short* gsrc;
        if (AHEAD) {
          int rg = m0t + r;
          if (rg >= M) rg = M - 1;
          int b = rg / ATPB, tok = rg - b * ATPB;
          int e = k0 + sp * 8;
          gsrc = A + ((((size_t)b * 8 + (e >> 4)) * ATPB + tok) << 4) + (e & 15);
        } else {
          gsrc = A + (size_t)(m0t + r) * K + k0 + sp * 8;
        }
        gll16(gsrc, (void*)&As[is * 512]);
      } else {
        int r = (is - 8) * 16 + ir;
        int sp = sl ^ ((r >> 1) & 3);
        gll16(Wt + (size_t)(n0t + r) * K + k0 + sp * 8, (void*)&Bs[(is - 8) * 512]);
      }
    }
    __syncthreads();
    bf16x8 af[4], bfr[4];
#pragma unroll
    for (int mi = 0; mi < 4; mi++) {
      int m = wr * 64 + mi * 16 + li;
      sh8 t = *(const sh8*)&As[m * 32 + ((sg ^ ((m >> 1) & 3)) << 3)];
      af[mi] = __builtin_bit_cast(bf16x8, t);
    }
#pragma unroll
    for (int ni = 0; ni < 4; ni++) {
      int n = wc * 64 + ni * 16 + li;
      sh8 t = *(const sh8*)&Bs[n * 32 + ((sg ^ ((n >> 1) & 3)) << 3)];
      bfr[ni] = __builtin_bit_cast(bf16x8, t);
    }
#pragma unroll
    for (int mi = 0; mi < 4; mi++)
#pragma unroll
      for (int ni = 0; ni < 4; ni++)
        acc[mi][ni] = __builtin_amdgcn_mfma_f32_16x16x32_bf16(af[mi], bfr[ni],
                                                              acc[mi][ni], 0, 0, 0);
  }

  float bv[4];
#pragma unroll
  for (int ni = 0; ni < 4; ni++) bv[ni] = bias[n0t + wc * 64 + ni * 16 + li];

  if constexpr (EPI == 1) {
#pragma unroll
    for (int mi = 0; mi < 4; mi++)
#pragma unroll
      for (int ni = 0; ni < 4; ni++)
#pragma unroll
        for (int r = 0; r < 4; r++) acc[mi][ni][r] += bv[ni];
#pragma unroll
    for (int mi = 0; mi < 4; mi++)
#pragma unroll
      for (int r = 0; r < 4; r++) {
        float s = acc[mi][0][r] + acc[mi][1][r] + acc[mi][2][r] + acc[mi][3][r];
        float q2 = acc[mi][0][r] * acc[mi][0][r] + acc[mi][1][r] * acc[mi][1][r] +
                   acc[mi][2][r] * acc[mi][2][r] + acc[mi][3][r] * acc[mi][3][r];
#pragma unroll
        for (int off = 1; off < 16; off <<= 1) {
          s += __shfl_xor(s, off);
          q2 += __shfl_xor(q2, off);
        }
        if (li == 0) part[wr * 64 + mi * 16 + sg * 4 + r][wc] = make_float2(s, q2);
      }
    __syncthreads();
    float gv[4], bev[4];
#pragma unroll
    for (int ni = 0; ni < 4; ni++) {
      int col = wc * 64 + ni * 16 + li;
      gv[ni] = gg[col];
      bev[ni] = be[col];
    }
#pragma unroll
    for (int mi = 0; mi < 4; mi++)
#pragma unroll
      for (int r = 0; r < 4; r++) {
        int mrow = wr * 64 + mi * 16 + sg * 4 + r;
        float2 p0 = part[mrow][0], p1 = part[mrow][1], p2 = part[mrow][2], p3 = part[mrow][3];
        float S = p0.x + p1.x + p2.x + p3.x;
        float Qq = p0.y + p1.y + p2.y + p3.y;
        float mean = S * (1.f / 256.f);
        float var = Qq * (1.f / 256.f) - mean * mean;
        float rstd = rsqrtf(var + EPSF);
        int mg = m0t + mrow;
        int b = mg / CTPB, tok = mg - b * CTPB;
#pragma unroll
        for (int ni = 0; ni < 4; ni++) {
          int col = wc * 64 + ni * 16 + li;
          float val = (acc[mi][ni][r] - mean) * rstd * gv[ni] + bev[ni];
          int half = col >> 7, h = (col >> 4) & 7, d = col & 15;
          float* dst = half ? (C + CPS) : C;
          dst[((((size_t)b * 8 + h) * CTPB + tok) << 4) + d] = val;
        }
      }
  } else if constexpr (EPI == 2) {
#pragma unroll
    for (int mi = 0; mi < 4; mi++)
#pragma unroll
      for (int r = 0; r < 4; r++) {
        int mg = m0t + wr * 64 + mi * 16 + sg * 4 + r;
        if (mg < M) {
          int b = mg / CTPB, tok = mg - b * CTPB;
#pragma unroll
          for (int ni = 0; ni < 4; ni++) {
            int col = n0t + wc * 64 + ni * 16 + li;
            float v = acc[mi][ni][r] + bv[ni];
            int pt = col >> 7, h = (col >> 4) & 7, d = col & 15;
            (C + (size_t)pt * CPS)[((((size_t)b * 8 + h) * CTPB + tok) << 4) + d] = v;
          }
        }
      }
  } else {
#pragma unroll
    for (int mi = 0; mi < 4; mi++)
#pragma unroll
      for (int r = 0; r < 4; r++) {
        int mrow = m0t + wr * 64 + mi * 16 + sg * 4 + r;
        if (mrow < M) {
#pragma unroll
          for (int ni = 0; ni < 4; ni++) {
            int col = n0t + wc * 64 + ni * 16 + li;
            float v = acc[mi][ni][r] + bv[ni];
            if (POST) v += post[(size_t)mrow * Ntot + col];
            C[(size_t)mrow * Ntot + col] = v;
          }
        }
      }
  }
}

// ---------------------------------------------------------------------------
__global__ __launch_bounds__(256) void wtrans_kernel(
    const float* __restrict__ W, unsigned short* __restrict__ Wt, int K, int N) {
  int idx = blockIdx.x * 256 + threadIdx.x;
  if (idx >= K * N) return;
  int k = idx / N, n = idx - k * N;
  Wt[(size_t)n * K + k] = f2bf(W[idx]);
}

__global__ __launch_bounds__(256) void cvt_kernel(
    const float* __restrict__ in, unsigned short* __restrict__ out, int n8) {
  int i = blockIdx.x * 256 + threadIdx.x;
  if (i >= n8) return;
  float4 a = ((const float4*)in)[i * 2];
  float4 b = ((const float4*)in)[i * 2 + 1];
  uint4 o;
  o.x = pk2(a.x, a.y);
  o.y = pk2(a.z, a.w);
  o.z = pk2(b.x, b.y);
  o.w = pk2(b.z, b.w);
  ((uint4*)out)[i] = o;
}

__global__ __launch_bounds__(256) void iqp_kernel(
    const float* __restrict__ iq, const float* __restrict__ W,
    const float* __restrict__ b, float* __restrict__ out) {
  __shared__ float row[128];
  int r = blockIdx.x;
  if (threadIdx.x < 128) row[threadIdx.x] = iq[r * 128 + threadIdx.x];
  __syncthreads();
  int c = threadIdx.x;
  float acc = b[c];
#pragma unroll 8
  for (int k = 0; k < 128; ++k) acc += row[k] * W[k * 256 + c];
  out[r * 256 + c] = acc;
}

// ---------------------------------------------------------------------------
// fp32 row-blocked GEMM, gathered input rows, head-major K/V split store:
// rows r (0..4000) -> b=r/100, rr=r%100; col c: half,h,d ->
//   (half? outV : outK)[(((b*8+h)*100)+rr)*16 + d]
// ---------------------------------------------------------------------------
template <int K, int N, int R>
__global__ __launch_bounds__(N) void gemm_kv_kernel(
    const float* __restrict__ in, const float* __restrict__ W,
    const float* __restrict__ bias, float* __restrict__ outK,
    float* __restrict__ outV, int rowoff) {
  __shared__ float rows[R][K];
  int r0 = blockIdx.x * R;
  for (int e = threadIdx.x; e < R * K; e += N) {
    int rr = e / K, k = e - rr * K;
    size_t r = r0 + rr;
    size_t irx = (r / 100) * 200 + rowoff + (r % 100);
    rows[rr][k] = in[irx * K + k];
  }
  __syncthreads();
  int c = threadIdx.x;
  float acc[R];
  float bb = bias[c];
#pragma unroll
  for (int rr = 0; rr < R; rr++) acc[rr] = bb;
  for (int k = 0; k < K; k += 4) {
    float w0 = W[(size_t)k * N + c];
    float w1 = W[(size_t)(k + 1) * N + c];
    float w2 = W[(size_t)(k + 2) * N + c];
    float w3 = W[(size_t)(k + 3) * N + c];
#pragma unroll
    for (int rr = 0; rr < R; rr++) {
      float4 r4 = *reinterpret_cast<const float4*>(&rows[rr][k]);
      acc[rr] = fmaf(r4.x, w0, acc[rr]);
      acc[rr] = fmaf(r4.y, w1, acc[rr]);
      acc[rr] = fmaf(r4.z, w2, acc[rr]);
      acc[rr] = fmaf(r4.w, w3, acc[rr]);
    }
  }
  int half = c >> 7, h = (c >> 4) & 7, d = c & 15;
  float* dst = half ? outV : outK;
#pragma unroll
  for (int rr = 0; rr < R; rr++) {
    int r = r0 + rr;
    int b = r / 100, tok = r - b * 100;
    dst[((((size_t)b * 8 + h) * 100 + tok) << 4) + d] = acc[rr];
  }
}

// ---------------------------------------------------------------------------
// Stage-3 attention, all operands head-major. nk=100 keys staged once in LDS.
// O (bf16 head-major) = softmax(Q K^T * s) V  [+ resid (token-major f32)]
// grid (4, 8, B); block 256. nq=1024.
// ---------------------------------------------------------------------------
__global__ __launch_bounds__(256) void attn3_kernel(
    const float* __restrict__ qhm, const float* __restrict__ khm,
    const float* __restrict__ vhm, unsigned short* __restrict__ ohm,
    const float* __restrict__ resid) {
  __shared__ float ks[1600];
  __shared__ float vs[1600];
  int h = blockIdx.y, b = blockIdx.z;
  int bh = b * 8 + h;
  int qi = blockIdx.x * 256 + threadIdx.x;
  const float4* K4 = (const float4*)(khm + ((size_t)bh * 100) * 16);
  const float4* V4 = (const float4*)(vhm + ((size_t)bh * 100) * 16);
  for (int e = threadIdx.x; e < 400; e += 256) {
    ((float4*)ks)[e] = K4[e];
    ((float4*)vs)[e] = V4[e];
  }
  __syncthreads();
  const float4* qp = (const float4*)(qhm + ((size_t)bh * 1024 + qi) * 16);
  float4 q0 = qp[0], q1 = qp[1], q2 = qp[2], q3 = qp[3];
  float m = -1e30f, l = 0.f;
  float4 a0 = {0, 0, 0, 0}, a1 = a0, a2 = a0, a3 = a0;
  for (int j = 0; j < 100; ++j) {
    const float4* kr = ((const float4*)ks) + j * 4;
    float s = dot4(q0, kr[0]) + dot4(q1, kr[1]) + dot4(q2, kr[2]) + dot4(q3, kr[3]);
    s *= SCALEF;
    if (s > m) {
      float cf = __expf(m - s);
      l *= cf;
      a0 *= cf; a1 *= cf; a2 *= cf; a3 *= cf;
      m = s;
    }
    float p = __expf(s - m);
    l += p;
    const float4* vr = ((const float4*)vs) + j * 4;
    a0 += p * vr[0]; a1 += p * vr[1]; a2 += p * vr[2]; a3 += p * vr[3];
  }
  float inv = 1.f / l;
  float o[16];
  ((float4*)o)[0] = a0 * inv; ((float4*)o)[1] = a1 * inv;
  ((float4*)o)[2] = a2 * inv; ((float4*)o)[3] = a3 * inv;
  if (resid) {
    const float4* rr = (const float4*)(resid + ((size_t)b * 1024 + qi) * 128 + h * 16);
#pragma unroll
    for (int dd = 0; dd < 4; dd++) {
      float4 rv = rr[dd];
      o[dd * 4 + 0] += rv.x; o[dd * 4 + 1] += rv.y;
      o[dd * 4 + 2] += rv.z; o[dd * 4 + 3] += rv.w;
    }
  }
  uint4* dst = (uint4*)(ohm + ((size_t)bh * 1024 + qi) * 16);
  dst[0] = make_uint4(pk2(o[0], o[1]), pk2(o[2], o[3]), pk2(o[4], o[5]), pk2(o[6], o[7]));
  dst[1] = make_uint4(pk2(o[8], o[9]), pk2(o[10], o[11]), pk2(o[12], o[13]), pk2(o[14], o[15]));
}

// ---------------------------------------------------------------------------
// Split-K flash partial; K/V head-major [B][8][nkTot][16]; Q generic strides.
// pacc[((bh*nq+qi)*NS+s)*16], pml[((bh*nq+qi)*NS+s)*2]
// grid.x = nqb*NS, grid.y = 8, grid.z = B.
// ---------------------------------------------------------------------------
#define TK 64
__global__ __launch_bounds__(256) void attn_partial_kernel(
    const float* __restrict__ qp, size_t qsb, size_t qsh, int qsr,
    const float* __restrict__ kp, const float* __restrict__ vp, int nkTot,
    float* __restrict__ pacc, float* __restrict__ pml, int nq, int NS) {
  __shared__ float ks[TK * 16];
  __shared__ float vs[TK * 16];
  int s = blockIdx.x % NS, qb = blockIdx.x / NS;
  int b = blockIdx.z, h = blockIdx.y;
  int bh = b * 8 + h;
  int qi = qb * 256 + threadIdx.x;
  bool act = qi < nq;
  int chunk = nkTot / NS;
  int k0r = s * chunk, k1 = k0r + chunk;
  float4 q0 = {0, 0, 0, 0}, q1 = q0, q2 = q0, q3 = q0;
  if (act) {
    const float* qr = qp + b * qsb + h * qsh + (size_t)qi * qsr;
    q0 = ((const float4*)qr)[0]; q1 = ((const float4*)qr)[1];
    q2 = ((const float4*)qr)[2]; q3 = ((const float4*)qr)[3];
  }
  float m = -1e30f, l = 0.f;
  float4 a0 = {0, 0, 0, 0}, a1 = a0, a2 = a0, a3 = a0;
  const float4* Kb = (const float4*)(kp + ((size_t)bh * nkTot) * 16);
  const float4* Vb = (const float4*)(vp + ((size_t)bh * nkTot) * 16);
  for (int t0 = k0r; t0 < k1; t0 += TK) {
    int tkn = min(TK, k1 - t0);
    __syncthreads();
    for (int e = threadIdx.x; e < tkn * 4; e += 256) {
      ((float4*)ks)[e] = Kb[t0 * 4 + e];
      ((float4*)vs)[e] = Vb[t0 * 4 + e];
    }
    __syncthreads();
    if (act) {
      for (int j = 0; j < tkn; ++j) {
        const float4* kr = ((const float4*)ks) + j * 4;
        float sc = dot4(q0, kr[0]) + dot4(q1, kr[1]) + dot4(q2, kr[2]) + dot4(q3, kr[3]);
        sc *= SCALEF;
        if (sc > m) {
          float cf = __expf(m - sc);
          l *= cf;
          a0 *= cf; a1 *= cf; a2 *= cf; a3 *= cf;
          m = sc;
        }
        float p = __expf(sc - m);
        l += p;
        const float4* vr = ((const float4*)vs) + j * 4;
        a0 += p * vr[0]; a1 += p * vr[1]; a2 += p * vr[2]; a3 += p * vr[3];
      }
    }
  }
  if (act) {
    size_t pidx = ((size_t)bh * nq + qi) * NS + s;
    float4* pa = ((float4*)pacc) + pidx * 4;
    pa[0] = a0; pa[1] = a1; pa[2] = a2; pa[3] = a3;
    ((float2*)pml)[pidx] = make_float2(m, l);
  }
}

// ---------------------------------------------------------------------------
// Combine NS partials; head-major bf16 output.
// mode 0 (stage-1): b 0..39 -> obh=(b/5)*8+h, tok=(b%5)*200+qoff+qi (TPB 1000)
//                   +q residual from qp (aqvq layout: qi*256 + h*16)
// mode 1 (SA):      b 0..7  -> obh=b*8+h, tok=qi (TPB nq)
// ---------------------------------------------------------------------------
__global__ __launch_bounds__(256) void attn_combine_kernel(
    const float* __restrict__ pacc, const float* __restrict__ pml,
    const float* __restrict__ qp, unsigned short* __restrict__ op,
    int nq, int NS, int mode, int qoff, int total) {
  int gid = blockIdx.x * 256 + threadIdx.x;
  if (gid >= total) return;
  int qi = gid % nq;
  int bh = gid / nq;
  int h = bh & 7, b = bh >> 3;
  size_t pidx0 = ((size_t)bh * nq + qi) * NS;
  float m = -1e30f;
  for (int s = 0; s < NS; s++) m = fmaxf(m, ((const float2*)pml)[pidx0 + s].x);
  float l = 0.f;
  float4 a0 = {0, 0, 0, 0}, a1 = a0, a2 = a0, a3 = a0;
  for (int s = 0; s < NS; s++) {
    float2 ml = ((const float2*)pml)[pidx0 + s];
    float w = __expf(ml.x - m);
    l += ml.y * w;
    const float4* pa = ((const float4*)pacc) + (pidx0 + s) * 4;
    a0 += w * pa[0]; a1 += w * pa[1]; a2 += w * pa[2]; a3 += w * pa[3];
  }
  float inv = 1.f / l;
  float o[16];
  ((float4*)o)[0] = a0 * inv; ((float4*)o)[1] = a1 * inv;
  ((float4*)o)[2] = a2 * inv; ((float4*)o)[3] = a3 * inv;
  size_t obase;
  if (mode == 0) {
    obase = (((size_t)(b / 5) * 8 + h) * 1000 + (b % 5) * 200 + qoff + qi) << 4;
    const float4* qr = (const float4*)(qp + (size_t)qi * 256 + h * 16);
#pragma unroll
    for (int dd = 0; dd < 4; dd++) {
      float4 qv = qr[dd];
      o[dd * 4 + 0] += qv.x; o[dd * 4 + 1] += qv.y;
      o[dd * 4 + 2] += qv.z; o[dd * 4 + 3] += qv.w;
    }
  } else {
    obase = ((size_t)bh * nq + qi) << 4;
  }
  uint4* dst = (uint4*)(op + obase);
  dst[0] = make_uint4(pk2(o[0], o[1]), pk2(o[2], o[3]), pk2(o[4], o[5]), pk2(o[6], o[7]));
  dst[1] = make_uint4(pk2(o[8], o[9]), pk2(o[10], o[11]), pk2(o[12], o[13]), pk2(o[14], o[15]));
}

// aiq2 (40,100,128) copy out of SA (viewed as (40,200,128) rows 0..99)
__global__ __launch_bounds__(128) void copy_aiq2_kernel(
    const float* __restrict__ SA, float* __restrict__ out) {
  int r = blockIdx.x, c = threadIdx.x;
  size_t irx = (size_t)(r / 100) * 200 + (r % 100);
  out[(size_t)r * 128 + c] = SA[irx * 128 + c];
}

// ---------------------------------------------------------------------------
extern "C" void kernel_launch(void* const* d_in, const int* in_sizes, int n_in,
                              void* d_out, int out_size, void* d_ws, size_t ws_size,
                              hipStream_t stream) {
  const float* audio = (const float*)d_in[0];   // (40,1024,128)
  const float* vis   = (const float*)d_in[1];   // (40,1024,512)
  const float* iq    = (const float*)d_in[2];
  const float* w_iqp = (const float*)d_in[3];
  const float* b_iqp = (const float*)d_in[4];
  const float* w_afp = (const float*)d_in[5];
  const float* b_afp = (const float*)d_in[6];
  const float* w_vfp = (const float*)d_in[7];
  const float* b_vfp = (const float*)d_in[8];
  const float* g_an  = (const float*)d_in[9];
  const float* be_an = (const float*)d_in[10];
  const float* g_vn  = (const float*)d_in[11];
  const float* be_vn = (const float*)d_in[12];
  const float* w_aqp = (const float*)d_in[13];
  const float* b_aqp = (const float*)d_in[14];
  const float* w_vqp = (const float*)d_in[15];
  const float* b_vqp = (const float*)d_in[16];
  const float* w_aq  = (const float*)d_in[17];
  const float* b_aq  = (const float*)d_in[18];
  const float* w_vq  = (const float*)d_in[19];
  const float* b_vq  = (const float*)d_in[20];
  const float* w_in  = (const float*)d_in[21];
  const float* b_in  = (const float*)d_in[22];
  const float* w_o   = (const float*)d_in[23];
  const float* b_o   = (const float*)d_in[24];
  const float* w_ao  = (const float*)d_in[25];
  const float* b_ao  = (const float*)d_in[26];
  const float* w_vo  = (const float*)d_in[27];
  const float* b_vo  = (const float*)d_in[28];

  float* out = (float*)d_out;
  float* ws  = (float*)d_ws;

  // ---- d_out scratch (dead until final writes; stream-ordered) ----
  unsigned short* vis_bf = (unsigned short*)(out);  // [0,10485760) words
  float* akn = out + 10485760;   // K hm (40,8,1024,16); dead after stage-1
  float* avn = out + 15728640;   // V hm
  float* vkn = out + 20971520;
  float* vvn = out + 26214400;
  float* a_hm = out + 31457280;  // _a hm f32, written step 9
  float* v_hm = out + 36700160;  // _v hm f32, written step 9
  float* pacc = out + 31457280;  // partials (steps 3,5); dead before step 9
  float* pml  = out + 35553280;  // [.., 36065280) max
  float* aiq2_out = out + 41943040;
  float* audio_out = out;
  float* vis_out   = out + 20971520;

  // ---- ws layout (f32-word offsets; total 12,706,816 words = 50.8 MB) ----
  unsigned short* WT       = (unsigned short*)(ws);            // [0, 262144)
  unsigned short* audio_bf = (unsigned short*)(ws + 262144);   // [.., 2883584)
  unsigned short* Q1hm     = (unsigned short*)(ws + 2883584);  // [8][8][1000][16] bf16 -> 512000 w
  unsigned short* saphm    = (unsigned short*)(ws + 3395584);  // [8][8][1000][16] bf16
  float* qkvhm             = ws + 3915776;                     // 3 x [8][8][1000][16] f32 = 3,072,000 w
  unsigned short* aatthm   = (unsigned short*)(ws + 3915776);  // overlays qkvhm; [40][8][1024][16] bf16
  unsigned short* vatthm   = (unsigned short*)(ws + 6987776);  // 2,621,440 w
  float* SA                = ws + 9609216;                     // (8000,128) f32
  float* Ka = ws + 10633216;  // [40][8][100][16] f32 (from aiq2 / w_aqp)
  float* Va = ws + 11145216;
  float* Kv = ws + 11657216;  // (from viq2 / w_vqp)
  float* Vv = ws + 12169216;
  float* aqvq = ws + 12681216;  // (100,256) f32

  unsigned short* afp_t = WT + 0;
  unsigned short* vfp_t = WT + 32768;
  unsigned short* aq_t  = WT + 163840;
  unsigned short* vq_t  = WT + 180224;
  unsigned short* in_t  = WT + 245760;
  unsigned short* o_t   = WT + 294912;
  unsigned short* ao_t  = WT + 311296;
  unsigned short* vo_t  = WT + 376832;

  // 0. weight transpose+convert, activation convert
  wtrans_kernel<<<128, 256, 0, stream>>>(w_afp, afp_t, 128, 256);
  wtrans_kernel<<<512, 256, 0, stream>>>(w_vfp, vfp_t, 512, 256);
  wtrans_kernel<<<64,  256, 0, stream>>>(w_aq,  aq_t,  128, 128);
  wtrans_kernel<<<256, 256, 0, stream>>>(w_vq,  vq_t,  512, 128);
  wtrans_kernel<<<192, 256, 0, stream>>>(w_in,  in_t,  128, 384);
  wtrans_kernel<<<64,  256, 0, stream>>>(w_o,   o_t,   128, 128);
  wtrans_kernel<<<256, 256, 0, stream>>>(w_ao,  ao_t,  128, 512);
  wtrans_kernel<<<256, 256, 0, stream>>>(w_vo,  vo_t,  128, 512);
  cvt_kernel<<<2560,  256, 0, stream>>>(audio, audio_bf, 655360);
  cvt_kernel<<<10240, 256, 0, stream>>>(vis,   vis_bf,   2621440);

  // 1. iq_emb projection (f32)
  iqp_kernel<<<100, 256, 0, stream>>>(iq, w_iqp, b_iqp, aqvq);

  // 2. proj + fused LN -> head-major K/V split (EPI1)
  mfma_gemm<128, 256, 1, false, false><<<dim3(320, 1), 512, 0, stream>>>(
      audio_bf, afp_t, b_afp, g_an, be_an, nullptr, akn, 40960, 256, 0, 1024, 5242880);
  mfma_gemm<512, 256, 1, false, false><<<dim3(320, 1), 512, 0, stream>>>(
      vis_bf, vfp_t, b_vfp, g_vn, be_vn, nullptr, vkn, 40960, 256, 0, 1024, 5242880);

  // 3. stage-1 cross-attn: split-K NS=8, combine with +q residual -> Q1hm
  attn_partial_kernel<<<dim3(8, 8, 40), 256, 0, stream>>>(
      aqvq, 0, 16, 256, akn, avn, 1024, pacc, pml, 100, 8);
  attn_combine_kernel<<<125, 256, 0, stream>>>(
      pacc, pml, aqvq, Q1hm, 100, 8, 0, 0, 32000);
  attn_partial_kernel<<<dim3(8, 8, 40), 256, 0, stream>>>(
      aqvq + 128, 0, 16, 256, vkn, vvn, 1024, pacc, pml, 100, 8);
  attn_combine_kernel<<<125, 256, 0, stream>>>(
      pacc, pml, aqvq + 128, Q1hm, 100, 8, 0, 100, 32000);

  // 4. qkv = queries @ w_in + b_in (A head-major, out 3-part head-major)
  mfma_gemm<128, 128, 2, false, true><<<dim3(63, 3), 256, 0, stream>>>(
      Q1hm, in_t, b_in, nullptr, nullptr, nullptr, qkvhm, 8000, 384, 1000, 1000, 1024000);

  // 5. self-attention: split-K NS=4 -> sap head-major
  attn_partial_kernel<<<dim3(16, 8, 8), 256, 0, stream>>>(
      qkvhm, 128000, 16000, 16, qkvhm + 1024000, qkvhm + 2048000, 1000,
      pacc, pml, 1000, 4);
  attn_combine_kernel<<<250, 256, 0, stream>>>(
      pacc, pml, nullptr, saphm, 1000, 4, 1, 0, 64000);

  // 6. SA = sa_pre @ w_o + b_o (A head-major -> token-major f32)
  mfma_gemm<128, 128, 0, false, true><<<dim3(63, 1), 256, 0, stream>>>(
      saphm, o_t, b_o, nullptr, nullptr, nullptr, SA, 8000, 128, 1000, 0, 0);

  // 7. aiq2 output
  copy_aiq2_kernel<<<4000, 128, 0, stream>>>(SA, aiq2_out);

  // 8. kf/vf projections -> head-major K/V
  gemm_kv_kernel<128, 256, 16><<<250, 256, 0, stream>>>(SA, w_aqp, b_aqp, Ka, Va, 0);
  gemm_kv_kernel<128, 256, 16><<<250, 256, 0, stream>>>(SA, w_vqp, b_vqp, Kv, Vv, 100);

  // 9. _a / _v projections -> head-major f32 (EPI2, 1 part)
  mfma_gemm<128, 128, 2, false, false><<<dim3(320, 1), 256, 0, stream>>>(
      audio_bf, aq_t, b_aq, nullptr, nullptr, nullptr, a_hm, 40960, 128, 0, 1024, 0);
  mfma_gemm<512, 128, 2, false, false><<<dim3(320, 1), 256, 0, stream>>>(
      vis_bf, vq_t, b_vq, nullptr, nullptr, nullptr, v_hm, 40960, 128, 0, 1024, 0);

  // 10. stage-3 cross-attn (head-major everywhere); audio fuses +audio resid
  attn3_kernel<<<dim3(4, 8, 40), 256, 0, stream>>>(a_hm, Kv, Vv, aatthm, audio);
  attn3_kernel<<<dim3(4, 8, 40), 256, 0, stream>>>(v_hm, Ka, Va, vatthm, nullptr);

  // 11. output projections (A head-major); w_vo fuses +vis residual
  mfma_gemm<128, 128, 0, false, true><<<dim3(320, 4), 256, 0, stream>>>(
      aatthm, ao_t, b_ao, nullptr, nullptr, nullptr, audio_out, 40960, 512, 1024, 0, 0);
  mfma_gemm<128, 128, 0, true, true><<<dim3(320, 4), 256, 0, stream>>>(
      vatthm, vo_t, b_vo, nullptr, nullptr, vis, vis_out, 40960, 512, 1024, 0, 0);
}

// Round 6
// 613.586 us; speedup vs baseline: 2.6758x; 1.0713x over previous
//
#include <hip/hip_runtime.h>

#define EPSF 1e-5f
#define SCALEF 0.25f   // hd=16 -> 16^-0.5

typedef __attribute__((ext_vector_type(8))) __bf16 bf16x8;
typedef __attribute__((ext_vector_type(8))) unsigned short sh8;
typedef __attribute__((ext_vector_type(4))) float f32x4;

__device__ __forceinline__ unsigned short f2bf(float f) {
  unsigned u = __float_as_uint(f);
  return (unsigned short)((u + 0x7FFFu + ((u >> 16) & 1u)) >> 16);
}
__device__ __forceinline__ unsigned pk2(float lo, float hi) {
  return (unsigned)f2bf(lo) | ((unsigned)f2bf(hi) << 16);
}
__device__ __forceinline__ float dot4(float4 a, float4 b) {
  return a.x * b.x + a.y * b.y + a.z * b.z + a.w * b.w;
}

// async global->LDS, 16B per lane; LDS dest = uniform base + lane*16
__device__ __forceinline__ void gll16(const void* g, void* l) {
  __builtin_amdgcn_global_load_lds((const __attribute__((address_space(1))) void*)g,
                                   (__attribute__((address_space(3))) void*)l,
                                   16, 0, 0);
}

// 4-key online-softmax step from LDS (kb/vb in float4 units, 4 per row)
__device__ __forceinline__ void proc4(
    const float4* __restrict__ kb, const float4* __restrict__ vb, int j,
    float4 q0, float4 q1, float4 q2, float4 q3,
    float& m, float& l, float4& a0, float4& a1, float4& a2, float4& a3) {
  const float4* k0 = kb + j * 4;
  const float4* k1 = kb + j * 4 + 4;
  const float4* k2 = kb + j * 4 + 8;
  const float4* k3 = kb + j * 4 + 12;
  float s0 = (dot4(q0, k0[0]) + dot4(q1, k0[1]) + dot4(q2, k0[2]) + dot4(q3, k0[3])) * SCALEF;
  float s1 = (dot4(q0, k1[0]) + dot4(q1, k1[1]) + dot4(q2, k1[2]) + dot4(q3, k1[3])) * SCALEF;
  float s2 = (dot4(q0, k2[0]) + dot4(q1, k2[1]) + dot4(q2, k2[2]) + dot4(q3, k2[3])) * SCALEF;
  float s3 = (dot4(q0, k3[0]) + dot4(q1, k3[1]) + dot4(q2, k3[2]) + dot4(q3, k3[3])) * SCALEF;
  float mx = fmaxf(fmaxf(s0, s1), fmaxf(s2, s3));
  if (mx > m) {
    float cf = __expf(m - mx);
    l *= cf;
    a0 *= cf; a1 *= cf; a2 *= cf; a3 *= cf;
    m = mx;
  }
  float p0 = __expf(s0 - m), p1 = __expf(s1 - m);
  float p2 = __expf(s2 - m), p3 = __expf(s3 - m);
  l += (p0 + p1) + (p2 + p3);
  const float4* v0 = vb + j * 4;
  const float4* v1 = vb + j * 4 + 4;
  const float4* v2 = vb + j * 4 + 8;
  const float4* v3 = vb + j * 4 + 12;
  a0 += p0 * v0[0]; a1 += p0 * v0[1]; a2 += p0 * v0[2]; a3 += p0 * v0[3];
  a0 += p1 * v1[0]; a1 += p1 * v1[1]; a2 += p1 * v1[2]; a3 += p1 * v1[3];
  a0 += p2 * v2[0]; a1 += p2 * v2[1]; a2 += p2 * v2[2]; a3 += p2 * v2[3];
  a0 += p3 * v3[0]; a1 += p3 * v3[1]; a2 += p3 * v3[2]; a3 += p3 * v3[3];
}

// ---------------------------------------------------------------------------
// MFMA GEMM: C = A[M][K](bf16) x Wt[N][K](bf16)^T + bias
//  AHEAD: A stored head-major [B][8][ATPB][16] bf16 (per-lane gather source)
//  EPI 0: token-major f32 store (+POST residual)
//  EPI 1: fused LayerNorm (Ntot=256) then head-major split-2 f32 store
//  EPI 2: head-major split-(Ntot/128) f32 store, part p -> C + p*CPS
// ---------------------------------------------------------------------------
template <int K, int BN, int EPI, bool POST, bool AHEAD>
__global__ __launch_bounds__(BN * 2) void mfma_gemm(
    const unsigned short* __restrict__ A, const unsigned short* __restrict__ Wt,
    const float* __restrict__ bias, const float* __restrict__ gg,
    const float* __restrict__ be, const float* __restrict__ post,
    float* __restrict__ C, int M, int Ntot, int ATPB, int CTPB, size_t CPS) {
  constexpr int NW = BN / 32;   // waves per block
  constexpr int NCW = BN / 64;  // wave columns
  __shared__ __align__(16) unsigned short As[128 * 32];
  __shared__ __align__(16) unsigned short Bs[BN * 32];
  __shared__ float2 part[128][4];
  const int tid = threadIdx.x;
  const int wid = tid >> 6, lane = tid & 63;
  const int wr = wid / NCW, wc = wid % NCW;
  const int m0t = blockIdx.x * 128, n0t = blockIdx.y * BN;
  const int ir = lane >> 2, sl = lane & 3;   // staging: row-in-16, slot
  const int sg = lane >> 4, li = lane & 15;  // frags: k-group, row/col
  f32x4 acc[4][4];
#pragma unroll
  for (int i = 0; i < 4; i++)
#pragma unroll
    for (int j = 0; j < 4; j++) acc[i][j] = (f32x4){0.f, 0.f, 0.f, 0.f};
  constexpr int nIss = 8 + BN / 16;  // 1KB issues: 8 for A, BN/16 for B

  for (int k0 = 0; k0 < K; k0 += 32) {
    __syncthreads();
    for (int is = wid; is < nIss; is += NW) {
      if (is < 8) {
        int r = is * 16 + ir;
        int sp = sl ^ ((r >> 1) & 3);
        const unsigned short* gsrc;
        if (AHEAD) {
          int rg = m0t + r;
          if (rg >= M) rg = M - 1;
          int b = rg / ATPB, tok = rg - b * ATPB;
          int e = k0 + sp * 8;
          gsrc = A + ((((size_t)b * 8 + (e >> 4)) * ATPB + tok) << 4) + (e & 15);
        } else {
          gsrc = A + (size_t)(m0t + r) * K + k0 + sp * 8;
        }
        gll16(gsrc, (void*)&As[is * 512]);
      } else {
        int r = (is - 8) * 16 + ir;
        int sp = sl ^ ((r >> 1) & 3);
        gll16(Wt + (size_t)(n0t + r) * K + k0 + sp * 8, (void*)&Bs[(is - 8) * 512]);
      }
    }
    __syncthreads();
    bf16x8 af[4], bfr[4];
#pragma unroll
    for (int mi = 0; mi < 4; mi++) {
      int m = wr * 64 + mi * 16 + li;
      sh8 t = *(const sh8*)&As[m * 32 + ((sg ^ ((m >> 1) & 3)) << 3)];
      af[mi] = __builtin_bit_cast(bf16x8, t);
    }
#pragma unroll
    for (int ni = 0; ni < 4; ni++) {
      int n = wc * 64 + ni * 16 + li;
      sh8 t = *(const sh8*)&Bs[n * 32 + ((sg ^ ((n >> 1) & 3)) << 3)];
      bfr[ni] = __builtin_bit_cast(bf16x8, t);
    }
#pragma unroll
    for (int mi = 0; mi < 4; mi++)
#pragma unroll
      for (int ni = 0; ni < 4; ni++)
        acc[mi][ni] = __builtin_amdgcn_mfma_f32_16x16x32_bf16(af[mi], bfr[ni],
                                                              acc[mi][ni], 0, 0, 0);
  }

  float bv[4];
#pragma unroll
  for (int ni = 0; ni < 4; ni++) bv[ni] = bias[n0t + wc * 64 + ni * 16 + li];

  if constexpr (EPI == 1) {
#pragma unroll
    for (int mi = 0; mi < 4; mi++)
#pragma unroll
      for (int ni = 0; ni < 4; ni++)
#pragma unroll
        for (int r = 0; r < 4; r++) acc[mi][ni][r] += bv[ni];
#pragma unroll
    for (int mi = 0; mi < 4; mi++)
#pragma unroll
      for (int r = 0; r < 4; r++) {
        float s = acc[mi][0][r] + acc[mi][1][r] + acc[mi][2][r] + acc[mi][3][r];
        float q2 = acc[mi][0][r] * acc[mi][0][r] + acc[mi][1][r] * acc[mi][1][r] +
                   acc[mi][2][r] * acc[mi][2][r] + acc[mi][3][r] * acc[mi][3][r];
#pragma unroll
        for (int off = 1; off < 16; off <<= 1) {
          s += __shfl_xor(s, off);
          q2 += __shfl_xor(q2, off);
        }
        if (li == 0) part[wr * 64 + mi * 16 + sg * 4 + r][wc] = make_float2(s, q2);
      }
    __syncthreads();
    float gv[4], bev[4];
#pragma unroll
    for (int ni = 0; ni < 4; ni++) {
      int col = wc * 64 + ni * 16 + li;
      gv[ni] = gg[col];
      bev[ni] = be[col];
    }
#pragma unroll
    for (int mi = 0; mi < 4; mi++)
#pragma unroll
      for (int r = 0; r < 4; r++) {
        int mrow = wr * 64 + mi * 16 + sg * 4 + r;
        float2 p0 = part[mrow][0], p1 = part[mrow][1], p2 = part[mrow][2], p3 = part[mrow][3];
        float S = p0.x + p1.x + p2.x + p3.x;
        float Qq = p0.y + p1.y + p2.y + p3.y;
        float mean = S * (1.f / 256.f);
        float var = Qq * (1.f / 256.f) - mean * mean;
        float rstd = rsqrtf(var + EPSF);
        int mg = m0t + mrow;
        int b = mg / CTPB, tok = mg - b * CTPB;
#pragma unroll
        for (int ni = 0; ni < 4; ni++) {
          int col = wc * 64 + ni * 16 + li;
          float val = (acc[mi][ni][r] - mean) * rstd * gv[ni] + bev[ni];
          int half = col >> 7, h = (col >> 4) & 7, d = col & 15;
          float* dst = half ? (C + CPS) : C;
          dst[((((size_t)b * 8 + h) * CTPB + tok) << 4) + d] = val;
        }
      }
  } else if constexpr (EPI == 2) {
#pragma unroll
    for (int mi = 0; mi < 4; mi++)
#pragma unroll
      for (int r = 0; r < 4; r++) {
        int mg = m0t + wr * 64 + mi * 16 + sg * 4 + r;
        if (mg < M) {
          int b = mg / CTPB, tok = mg - b * CTPB;
#pragma unroll
          for (int ni = 0; ni < 4; ni++) {
            int col = n0t + wc * 64 + ni * 16 + li;
            float v = acc[mi][ni][r] + bv[ni];
            int pt = col >> 7, h = (col >> 4) & 7, d = col & 15;
            (C + (size_t)pt * CPS)[((((size_t)b * 8 + h) * CTPB + tok) << 4) + d] = v;
          }
        }
      }
  } else {
#pragma unroll
    for (int mi = 0; mi < 4; mi++)
#pragma unroll
      for (int r = 0; r < 4; r++) {
        int mrow = m0t + wr * 64 + mi * 16 + sg * 4 + r;
        if (mrow < M) {
#pragma unroll
          for (int ni = 0; ni < 4; ni++) {
            int col = n0t + wc * 64 + ni * 16 + li;
            float v = acc[mi][ni][r] + bv[ni];
            if (POST) v += post[(size_t)mrow * Ntot + col];
            C[(size_t)mrow * Ntot + col] = v;
          }
        }
      }
  }
}

// ---------------------------------------------------------------------------
__global__ __launch_bounds__(256) void wtrans_kernel(
    const float* __restrict__ W, unsigned short* __restrict__ Wt, int K, int N) {
  int idx = blockIdx.x * 256 + threadIdx.x;
  if (idx >= K * N) return;
  int k = idx / N, n = idx - k * N;
  Wt[(size_t)n * K + k] = f2bf(W[idx]);
}

__global__ __launch_bounds__(256) void cvt_kernel(
    const float* __restrict__ in, unsigned short* __restrict__ out, int n8) {
  int i = blockIdx.x * 256 + threadIdx.x;
  if (i >= n8) return;
  float4 a = ((const float4*)in)[i * 2];
  float4 b = ((const float4*)in)[i * 2 + 1];
  uint4 o;
  o.x = pk2(a.x, a.y);
  o.y = pk2(a.z, a.w);
  o.z = pk2(b.x, b.y);
  o.w = pk2(b.z, b.w);
  ((uint4*)out)[i] = o;
}

__global__ __launch_bounds__(256) void iqp_kernel(
    const float* __restrict__ iq, const float* __restrict__ W,
    const float* __restrict__ b, float* __restrict__ out) {
  __shared__ float row[128];
  int r = blockIdx.x;
  if (threadIdx.x < 128) row[threadIdx.x] = iq[r * 128 + threadIdx.x];
  __syncthreads();
  int c = threadIdx.x;
  float acc = b[c];
#pragma unroll 8
  for (int k = 0; k < 128; ++k) acc += row[k] * W[k * 256 + c];
  out[r * 256 + c] = acc;
}

// ---------------------------------------------------------------------------
// fp32 row-blocked GEMM, gathered input rows, head-major K/V split store
// ---------------------------------------------------------------------------
template <int K, int N, int R>
__global__ __launch_bounds__(N) void gemm_kv_kernel(
    const float* __restrict__ in, const float* __restrict__ W,
    const float* __restrict__ bias, float* __restrict__ outK,
    float* __restrict__ outV, int rowoff) {
  __shared__ float rows[R][K];
  int r0 = blockIdx.x * R;
  for (int e = threadIdx.x; e < R * K; e += N) {
    int rr = e / K, k = e - rr * K;
    size_t r = r0 + rr;
    size_t irx = (r / 100) * 200 + rowoff + (r % 100);
    rows[rr][k] = in[irx * K + k];
  }
  __syncthreads();
  int c = threadIdx.x;
  float acc[R];
  float bb = bias[c];
#pragma unroll
  for (int rr = 0; rr < R; rr++) acc[rr] = bb;
  for (int k = 0; k < K; k += 4) {
    float w0 = W[(size_t)k * N + c];
    float w1 = W[(size_t)(k + 1) * N + c];
    float w2 = W[(size_t)(k + 2) * N + c];
    float w3 = W[(size_t)(k + 3) * N + c];
#pragma unroll
    for (int rr = 0; rr < R; rr++) {
      float4 r4 = *reinterpret_cast<const float4*>(&rows[rr][k]);
      acc[rr] = fmaf(r4.x, w0, acc[rr]);
      acc[rr] = fmaf(r4.y, w1, acc[rr]);
      acc[rr] = fmaf(r4.z, w2, acc[rr]);
      acc[rr] = fmaf(r4.w, w3, acc[rr]);
    }
  }
  int half = c >> 7, h = (c >> 4) & 7, d = c & 15;
  float* dst = half ? outV : outK;
#pragma unroll
  for (int rr = 0; rr < R; rr++) {
    int r = r0 + rr;
    int b = r / 100, tok = r - b * 100;
    dst[((((size_t)b * 8 + h) * 100 + tok) << 4) + d] = acc[rr];
  }
}

// ---------------------------------------------------------------------------
// Stage-3 attention (head-major, nk=100 staged once, 4-key blocked)
// ---------------------------------------------------------------------------
__global__ __launch_bounds__(256) void attn3_kernel(
    const float* __restrict__ qhm, const float* __restrict__ khm,
    const float* __restrict__ vhm, unsigned short* __restrict__ ohm,
    const float* __restrict__ resid) {
  __shared__ float4 ks[400];
  __shared__ float4 vs[400];
  int h = blockIdx.y, b = blockIdx.z;
  int bh = b * 8 + h;
  int qi = blockIdx.x * 256 + threadIdx.x;
  const float4* K4 = (const float4*)(khm + ((size_t)bh * 100) * 16);
  const float4* V4 = (const float4*)(vhm + ((size_t)bh * 100) * 16);
  for (int e = threadIdx.x; e < 400; e += 256) {
    ks[e] = K4[e];
    vs[e] = V4[e];
  }
  __syncthreads();
  const float4* qp = (const float4*)(qhm + ((size_t)bh * 1024 + qi) * 16);
  float4 q0 = qp[0], q1 = qp[1], q2 = qp[2], q3 = qp[3];
  float m = -1e30f, l = 0.f;
  float4 a0 = {0, 0, 0, 0}, a1 = a0, a2 = a0, a3 = a0;
#pragma unroll 2
  for (int j = 0; j < 100; j += 4)
    proc4(ks, vs, j, q0, q1, q2, q3, m, l, a0, a1, a2, a3);
  float inv = 1.f / l;
  float o[16];
  ((float4*)o)[0] = a0 * inv; ((float4*)o)[1] = a1 * inv;
  ((float4*)o)[2] = a2 * inv; ((float4*)o)[3] = a3 * inv;
  if (resid) {
    const float4* rr = (const float4*)(resid + ((size_t)b * 1024 + qi) * 128 + h * 16);
#pragma unroll
    for (int dd = 0; dd < 4; dd++) {
      float4 rv = rr[dd];
      o[dd * 4 + 0] += rv.x; o[dd * 4 + 1] += rv.y;
      o[dd * 4 + 2] += rv.z; o[dd * 4 + 3] += rv.w;
    }
  }
  uint4* dst = (uint4*)(ohm + ((size_t)bh * 1024 + qi) * 16);
  dst[0] = make_uint4(pk2(o[0], o[1]), pk2(o[2], o[3]), pk2(o[4], o[5]), pk2(o[6], o[7]));
  dst[1] = make_uint4(pk2(o[8], o[9]), pk2(o[10], o[11]), pk2(o[12], o[13]), pk2(o[14], o[15]));
}

// ---------------------------------------------------------------------------
// Stage-1 partial: both modalities in one dispatch, 2 heads per block.
// grid (NS=8, 4, 80): z<40 audio (K/V=akn/avn, q cols 0-127),
//                     z>=40 visual (vkn/vvn, q cols 128-255).
// tid: hl=tid>>7 (head in pair), qi=tid&127 (query, active<100).
// pacc[(z*8+h)*100+qi][NS][16], pml same x2.
// ---------------------------------------------------------------------------
__global__ __launch_bounds__(256) void attn1_partial_kernel(
    const float* __restrict__ aqvq,
    const float* __restrict__ akn, const float* __restrict__ avn,
    const float* __restrict__ vkn, const float* __restrict__ vvn,
    float* __restrict__ pacc, float* __restrict__ pml) {
  __shared__ float4 ks[512];  // [2][64][4]
  __shared__ float4 vs[512];
  int s = blockIdx.x, hp = blockIdx.y, z = blockIdx.z;
  int mod = z >= 40 ? 1 : 0;
  int b = z - mod * 40;
  int tid = threadIdx.x;
  int hl = tid >> 7, qi = tid & 127;
  int h = hp * 2 + hl;
  bool act = qi < 100;
  int qil = act ? qi : 0;
  const float* kp = mod ? vkn : akn;
  const float* vp = mod ? vvn : avn;
  const float* qr = aqvq + mod * 128 + (size_t)qil * 256 + h * 16;
  float4 q0 = ((const float4*)qr)[0], q1 = ((const float4*)qr)[1];
  float4 q2 = ((const float4*)qr)[2], q3 = ((const float4*)qr)[3];
  float m = -1e30f, l = 0.f;
  float4 a0 = {0, 0, 0, 0}, a1 = a0, a2 = a0, a3 = a0;
  int k0r = s * 128;
  for (int t0 = k0r; t0 < k0r + 128; t0 += 64) {
    __syncthreads();
    for (int e = tid; e < 512; e += 256) {
      int hh = e >> 8, idx = e & 255;
      size_t rb = (((size_t)b * 8 + hp * 2 + hh) * 1024 + t0) * 4;  // float4 units
      ks[hh * 256 + idx] = ((const float4*)kp)[rb + idx];
      vs[hh * 256 + idx] = ((const float4*)vp)[rb + idx];
    }
    __syncthreads();
    const float4* kbase = ks + hl * 256;
    const float4* vbase = vs + hl * 256;
#pragma unroll 2
    for (int j = 0; j < 64; j += 4)
      proc4(kbase, vbase, j, q0, q1, q2, q3, m, l, a0, a1, a2, a3);
  }
  if (act) {
    size_t pidx = (((size_t)z * 8 + h) * 100 + qi) * 8 + s;
    float4* pa = ((float4*)pacc) + pidx * 4;
    pa[0] = a0; pa[1] = a1; pa[2] = a2; pa[3] = a3;
    ((float2*)pml)[pidx] = make_float2(m, l);
  }
}

// ---------------------------------------------------------------------------
// Generic split-K flash partial (used for SA); 4-key blocked with tail.
// ---------------------------------------------------------------------------
#define TK 64
__global__ __launch_bounds__(256) void attn_partial_kernel(
    const float* __restrict__ qp, size_t qsb, size_t qsh, int qsr,
    const float* __restrict__ kp, const float* __restrict__ vp, int nkTot,
    float* __restrict__ pacc, float* __restrict__ pml, int nq, int NS) {
  __shared__ float4 ks[TK * 4];
  __shared__ float4 vs[TK * 4];
  int s = blockIdx.x % NS, qb = blockIdx.x / NS;
  int b = blockIdx.z, h = blockIdx.y;
  int bh = b * 8 + h;
  int qi = qb * 256 + threadIdx.x;
  bool act = qi < nq;
  int qil = act ? qi : 0;
  int chunk = nkTot / NS;
  int k0r = s * chunk, k1 = k0r + chunk;
  const float* qr = qp + b * qsb + h * qsh + (size_t)qil * qsr;
  float4 q0 = ((const float4*)qr)[0], q1 = ((const float4*)qr)[1];
  float4 q2 = ((const float4*)qr)[2], q3 = ((const float4*)qr)[3];
  float m = -1e30f, l = 0.f;
  float4 a0 = {0, 0, 0, 0}, a1 = a0, a2 = a0, a3 = a0;
  const float4* Kb = (const float4*)(kp + ((size_t)bh * nkTot) * 16);
  const float4* Vb = (const float4*)(vp + ((size_t)bh * nkTot) * 16);
  for (int t0 = k0r; t0 < k1; t0 += TK) {
    int tkn = min(TK, k1 - t0);
    __syncthreads();
    for (int e = threadIdx.x; e < tkn * 4; e += 256) {
      ks[e] = Kb[t0 * 4 + e];
      vs[e] = Vb[t0 * 4 + e];
    }
    __syncthreads();
    int j = 0;
    for (; j + 4 <= tkn; j += 4)
      proc4(ks, vs, j, q0, q1, q2, q3, m, l, a0, a1, a2, a3);
    for (; j < tkn; ++j) {
      const float4* kr = ks + j * 4;
      float sc = (dot4(q0, kr[0]) + dot4(q1, kr[1]) + dot4(q2, kr[2]) + dot4(q3, kr[3])) * SCALEF;
      if (sc > m) {
        float cf = __expf(m - sc);
        l *= cf;
        a0 *= cf; a1 *= cf; a2 *= cf; a3 *= cf;
        m = sc;
      }
      float p = __expf(sc - m);
      l += p;
      const float4* vr = vs + j * 4;
      a0 += p * vr[0]; a1 += p * vr[1]; a2 += p * vr[2]; a3 += p * vr[3];
    }
  }
  if (act) {
    size_t pidx = ((size_t)bh * nq + qi) * NS + s;
    float4* pa = ((float4*)pacc) + pidx * 4;
    pa[0] = a0; pa[1] = a1; pa[2] = a2; pa[3] = a3;
    ((float2*)pml)[pidx] = make_float2(m, l);
  }
}

// ---------------------------------------------------------------------------
// Combine NS partials; head-major bf16 output. pacc/pml indexed by gid*NS.
// mode 0 (stage-1 merged): gid in [0,64000): mod=gid>=32000, rem: qi=rem%100,
//   bh=rem/100 (b*8+h, b 0..39); out tok=(b%5)*200+mod*100+qi, obh=(b/5)*8+h;
//   +q residual from aqvq col offset mod*128.
// mode 1 (SA): gid = bh*nq+qi; out tok=qi, obh=bh.
// ---------------------------------------------------------------------------
__global__ __launch_bounds__(256) void attn_combine_kernel(
    const float* __restrict__ pacc, const float* __restrict__ pml,
    const float* __restrict__ qp, unsigned short* __restrict__ op,
    int nq, int NS, int mode, int total) {
  int gid = blockIdx.x * 256 + threadIdx.x;
  if (gid >= total) return;
  size_t pidx0 = (size_t)gid * NS;
  float m = -1e30f;
  for (int s = 0; s < NS; s++) m = fmaxf(m, ((const float2*)pml)[pidx0 + s].x);
  float l = 0.f;
  float4 a0 = {0, 0, 0, 0}, a1 = a0, a2 = a0, a3 = a0;
  for (int s = 0; s < NS; s++) {
    float2 ml = ((const float2*)pml)[pidx0 + s];
    float w = __expf(ml.x - m);
    l += ml.y * w;
    const float4* pa = ((const float4*)pacc) + (pidx0 + s) * 4;
    a0 += w * pa[0]; a1 += w * pa[1]; a2 += w * pa[2]; a3 += w * pa[3];
  }
  float inv = 1.f / l;
  float o[16];
  ((float4*)o)[0] = a0 * inv; ((float4*)o)[1] = a1 * inv;
  ((float4*)o)[2] = a2 * inv; ((float4*)o)[3] = a3 * inv;
  size_t obase;
  if (mode == 0) {
    int mod = gid >= 32000 ? 1 : 0;
    int rem = gid - mod * 32000;
    int qi = rem % 100;
    int bh = rem / 100;
    int h = bh & 7, b = bh >> 3;
    obase = (((size_t)(b / 5) * 8 + h) * 1000 + (b % 5) * 200 + mod * 100 + qi) << 4;
    const float4* qr = (const float4*)(qp + mod * 128 + (size_t)qi * 256 + h * 16);
#pragma unroll
    for (int dd = 0; dd < 4; dd++) {
      float4 qv = qr[dd];
      o[dd * 4 + 0] += qv.x; o[dd * 4 + 1] += qv.y;
      o[dd * 4 + 2] += qv.z; o[dd * 4 + 3] += qv.w;
    }
  } else {
    obase = (size_t)gid << 4;
  }
  uint4* dst = (uint4*)(op + obase);
  dst[0] = make_uint4(pk2(o[0], o[1]), pk2(o[2], o[3]), pk2(o[4], o[5]), pk2(o[6], o[7]));
  dst[1] = make_uint4(pk2(o[8], o[9]), pk2(o[10], o[11]), pk2(o[12], o[13]), pk2(o[14], o[15]));
}

// aiq2 (40,100,128) copy out of SA (viewed as (40,200,128) rows 0..99)
__global__ __launch_bounds__(128) void copy_aiq2_kernel(
    const float* __restrict__ SA, float* __restrict__ out) {
  int r = blockIdx.x, c = threadIdx.x;
  size_t irx = (size_t)(r / 100) * 200 + (r % 100);
  out[(size_t)r * 128 + c] = SA[irx * 128 + c];
}

// ---------------------------------------------------------------------------
extern "C" void kernel_launch(void* const* d_in, const int* in_sizes, int n_in,
                              void* d_out, int out_size, void* d_ws, size_t ws_size,
                              hipStream_t stream) {
  const float* audio = (const float*)d_in[0];   // (40,1024,128)
  const float* vis   = (const float*)d_in[1];   // (40,1024,512)
  const float* iq    = (const float*)d_in[2];
  const float* w_iqp = (const float*)d_in[3];
  const float* b_iqp = (const float*)d_in[4];
  const float* w_afp = (const float*)d_in[5];
  const float* b_afp = (const float*)d_in[6];
  const float* w_vfp = (const float*)d_in[7];
  const float* b_vfp = (const float*)d_in[8];
  const float* g_an  = (const float*)d_in[9];
  const float* be_an = (const float*)d_in[10];
  const float* g_vn  = (const float*)d_in[11];
  const float* be_vn = (const float*)d_in[12];
  const float* w_aqp = (const float*)d_in[13];
  const float* b_aqp = (const float*)d_in[14];
  const float* w_vqp = (const float*)d_in[15];
  const float* b_vqp = (const float*)d_in[16];
  const float* w_aq  = (const float*)d_in[17];
  const float* b_aq  = (const float*)d_in[18];
  const float* w_vq  = (const float*)d_in[19];
  const float* b_vq  = (const float*)d_in[20];
  const float* w_in  = (const float*)d_in[21];
  const float* b_in  = (const float*)d_in[22];
  const float* w_o   = (const float*)d_in[23];
  const float* b_o   = (const float*)d_in[24];
  const float* w_ao  = (const float*)d_in[25];
  const float* b_ao  = (const float*)d_in[26];
  const float* w_vo  = (const float*)d_in[27];
  const float* b_vo  = (const float*)d_in[28];

  float* out = (float*)d_out;
  float* ws  = (float*)d_ws;

  // ---- d_out scratch (dead until final writes; stream-ordered) ----
  unsigned short* vis_bf = (unsigned short*)(out);  // [0,10485760) words
  float* akn = out + 10485760;   // K hm (40,8,1024,16); dead after stage-1
  float* avn = out + 15728640;   // V hm
  float* vkn = out + 20971520;
  float* vvn = out + 26214400;
  float* a_hm = out + 31457280;  // _a hm f32, written step 9
  float* v_hm = out + 36700160;  // _v hm f32, written step 9
  float* pacc = out + 31457280;  // [.., 39649280) partials; dead before step 9
  float* pml  = out + 39649280;  // [.., 40673280)
  float* aiq2_out = out + 41943040;
  float* audio_out = out;
  float* vis_out   = out + 20971520;

  // ---- ws layout (f32-word offsets; total 12,706,816 words = 50.8 MB) ----
  unsigned short* WT       = (unsigned short*)(ws);            // [0, 262144)
  unsigned short* audio_bf = (unsigned short*)(ws + 262144);   // [.., 2883584)
  unsigned short* Q1hm     = (unsigned short*)(ws + 2883584);  // [8][8][1000][16] bf16
  unsigned short* saphm    = (unsigned short*)(ws + 3395584);  // [8][8][1000][16] bf16
  float* qkvhm             = ws + 3915776;                     // 3 x [8][8][1000][16] f32
  unsigned short* aatthm   = (unsigned short*)(ws + 3915776);  // overlays qkvhm
  unsigned short* vatthm   = (unsigned short*)(ws + 6987776);  // 2,621,440 w
  float* SA                = ws + 9609216;                     // (8000,128) f32
  float* Ka = ws + 10633216;  // [40][8][100][16] f32
  float* Va = ws + 11145216;
  float* Kv = ws + 11657216;
  float* Vv = ws + 12169216;
  float* aqvq = ws + 12681216;  // (100,256) f32

  unsigned short* afp_t = WT + 0;
  unsigned short* vfp_t = WT + 32768;
  unsigned short* aq_t  = WT + 163840;
  unsigned short* vq_t  = WT + 180224;
  unsigned short* in_t  = WT + 245760;
  unsigned short* o_t   = WT + 294912;
  unsigned short* ao_t  = WT + 311296;
  unsigned short* vo_t  = WT + 376832;

  // 0. weight transpose+convert, activation convert
  wtrans_kernel<<<128, 256, 0, stream>>>(w_afp, afp_t, 128, 256);
  wtrans_kernel<<<512, 256, 0, stream>>>(w_vfp, vfp_t, 512, 256);
  wtrans_kernel<<<64,  256, 0, stream>>>(w_aq,  aq_t,  128, 128);
  wtrans_kernel<<<256, 256, 0, stream>>>(w_vq,  vq_t,  512, 128);
  wtrans_kernel<<<192, 256, 0, stream>>>(w_in,  in_t,  128, 384);
  wtrans_kernel<<<64,  256, 0, stream>>>(w_o,   o_t,   128, 128);
  wtrans_kernel<<<256, 256, 0, stream>>>(w_ao,  ao_t,  128, 512);
  wtrans_kernel<<<256, 256, 0, stream>>>(w_vo,  vo_t,  128, 512);
  cvt_kernel<<<2560,  256, 0, stream>>>(audio, audio_bf, 655360);
  cvt_kernel<<<10240, 256, 0, stream>>>(vis,   vis_bf,   2621440);

  // 1. iq_emb projection (f32)
  iqp_kernel<<<100, 256, 0, stream>>>(iq, w_iqp, b_iqp, aqvq);

  // 2. proj + fused LN -> head-major K/V split (EPI1)
  mfma_gemm<128, 256, 1, false, false><<<dim3(320, 1), 512, 0, stream>>>(
      audio_bf, afp_t, b_afp, g_an, be_an, nullptr, akn, 40960, 256, 0, 1024, 5242880);
  mfma_gemm<512, 256, 1, false, false><<<dim3(320, 1), 512, 0, stream>>>(
      vis_bf, vfp_t, b_vfp, g_vn, be_vn, nullptr, vkn, 40960, 256, 0, 1024, 5242880);

  // 3. stage-1 cross-attn: merged modalities, 2 heads/block, NS=8
  attn1_partial_kernel<<<dim3(8, 4, 80), 256, 0, stream>>>(
      aqvq, akn, avn, vkn, vvn, pacc, pml);
  attn_combine_kernel<<<250, 256, 0, stream>>>(
      pacc, pml, aqvq, Q1hm, 100, 8, 0, 64000);

  // 4. qkv = queries @ w_in + b_in (A head-major, out 3-part head-major)
  mfma_gemm<128, 128, 2, false, true><<<dim3(63, 3), 256, 0, stream>>>(
      Q1hm, in_t, b_in, nullptr, nullptr, nullptr, qkvhm, 8000, 384, 1000, 1000, 1024000);

  // 5. self-attention: split-K NS=4 -> sap head-major
  attn_partial_kernel<<<dim3(16, 8, 8), 256, 0, stream>>>(
      qkvhm, 128000, 16000, 16, qkvhm + 1024000, qkvhm + 2048000, 1000,
      pacc, pml, 1000, 4);
  attn_combine_kernel<<<250, 256, 0, stream>>>(
      pacc, pml, nullptr, saphm, 1000, 4, 1, 64000);

  // 6. SA = sa_pre @ w_o + b_o (A head-major -> token-major f32)
  mfma_gemm<128, 128, 0, false, true><<<dim3(63, 1), 256, 0, stream>>>(
      saphm, o_t, b_o, nullptr, nullptr, nullptr, SA, 8000, 128, 1000, 0, 0);

  // 7. aiq2 output
  copy_aiq2_kernel<<<4000, 128, 0, stream>>>(SA, aiq2_out);

  // 8. kf/vf projections -> head-major K/V
  gemm_kv_kernel<128, 256, 16><<<250, 256, 0, stream>>>(SA, w_aqp, b_aqp, Ka, Va, 0);
  gemm_kv_kernel<128, 256, 16><<<250, 256, 0, stream>>>(SA, w_vqp, b_vqp, Kv, Vv, 100);

  // 9. _a / _v projections -> head-major f32 (EPI2, 1 part)
  mfma_gemm<128, 128, 2, false, false><<<dim3(320, 1), 256, 0, stream>>>(
      audio_bf, aq_t, b_aq, nullptr, nullptr, nullptr, a_hm, 40960, 128, 0, 1024, 0);
  mfma_gemm<512, 128, 2, false, false><<<dim3(320, 1), 256, 0, stream>>>(
      vis_bf, vq_t, b_vq, nullptr, nullptr, nullptr, v_hm, 40960, 128, 0, 1024, 0);

  // 10. stage-3 cross-attn (head-major); audio fuses +audio resid
  attn3_kernel<<<dim3(4, 8, 40), 256, 0, stream>>>(a_hm, Kv, Vv, aatthm, audio);
  attn3_kernel<<<dim3(4, 8, 40), 256, 0, stream>>>(v_hm, Ka, Va, vatthm, nullptr);

  // 11. output projections (A head-major); w_vo fuses +vis residual
  mfma_gemm<128, 128, 0, false, true><<<dim3(320, 4), 256, 0, stream>>>(
      aatthm, ao_t, b_ao, nullptr, nullptr, nullptr, audio_out, 40960, 512, 1024, 0, 0);
  mfma_gemm<128, 128, 0, true, true><<<dim3(320, 4), 256, 0, stream>>>(
      vatthm, vo_t, b_vo, nullptr, nullptr, vis, vis_out, 40960, 512, 1024, 0, 0);
}

// Round 7
// 420.113 us; speedup vs baseline: 3.9081x; 1.4605x over previous
//
#include <hip/hip_runtime.h>

#define EPSF 1e-5f
#define SCALEF 0.25f   // hd=16 -> 16^-0.5

typedef __attribute__((ext_vector_type(8))) __bf16 bf16x8;
typedef __attribute__((ext_vector_type(8))) unsigned short sh8;
typedef __attribute__((ext_vector_type(4))) float f32x4;

__device__ __forceinline__ unsigned short f2bf(float f) {
  unsigned u = __float_as_uint(f);
  return (unsigned short)((u + 0x7FFFu + ((u >> 16) & 1u)) >> 16);
}
__device__ __forceinline__ unsigned pk2(float lo, float hi) {
  return (unsigned)f2bf(lo) | ((unsigned)f2bf(hi) << 16);
}

// async global->LDS, 16B per lane; LDS dest = uniform base + lane*16
__device__ __forceinline__ void gll16(const void* g, void* l) {
  __builtin_amdgcn_global_load_lds((const __attribute__((address_space(1))) void*)g,
                                   (__attribute__((address_space(3))) void*)l,
                                   16, 0, 0);
}

// ---------------------------------------------------------------------------
// MFMA GEMM: C = A[M][K](bf16) x Wt[N][K](bf16)^T + bias
//  AHEAD: A stored head-major [B][8][ATPB][16] bf16 (per-lane gather source)
//  EPI 0: token-major f32 store (+POST residual)
//  EPI 1: fused LayerNorm (Ntot=256) then head-major split-2 f32 store
//  EPI 2: head-major split-(Ntot/128) f32 store, part p -> C + p*CPS
// ---------------------------------------------------------------------------
template <int K, int BN, int EPI, bool POST, bool AHEAD>
__global__ __launch_bounds__(BN * 2) void mfma_gemm(
    const unsigned short* __restrict__ A, const unsigned short* __restrict__ Wt,
    const float* __restrict__ bias, const float* __restrict__ gg,
    const float* __restrict__ be, const float* __restrict__ post,
    float* __restrict__ C, int M, int Ntot, int ATPB, int CTPB, size_t CPS) {
  constexpr int NW = BN / 32;   // waves per block
  constexpr int NCW = BN / 64;  // wave columns
  __shared__ __align__(16) unsigned short As[128 * 32];
  __shared__ __align__(16) unsigned short Bs[BN * 32];
  __shared__ float2 part[128][4];
  const int tid = threadIdx.x;
  const int wid = tid >> 6, lane = tid & 63;
  const int wr = wid / NCW, wc = wid % NCW;
  const int m0t = blockIdx.x * 128, n0t = blockIdx.y * BN;
  const int ir = lane >> 2, sl = lane & 3;   // staging: row-in-16, slot
  const int sg = lane >> 4, li = lane & 15;  // frags: k-group, row/col
  f32x4 acc[4][4];
#pragma unroll
  for (int i = 0; i < 4; i++)
#pragma unroll
    for (int j = 0; j < 4; j++) acc[i][j] = (f32x4){0.f, 0.f, 0.f, 0.f};
  constexpr int nIss = 8 + BN / 16;  // 1KB issues: 8 for A, BN/16 for B

  for (int k0 = 0; k0 < K; k0 += 32) {
    __syncthreads();
    for (int is = wid; is < nIss; is += NW) {
      if (is < 8) {
        int r = is * 16 + ir;
        int sp = sl ^ ((r >> 1) & 3);
        const unsigned short* gsrc;
        if (AHEAD) {
          int rg = m0t + r;
          if (rg >= M) rg = M - 1;
          int b = rg / ATPB, tok = rg - b * ATPB;
          int e = k0 + sp * 8;
          gsrc = A + ((((size_t)b * 8 + (e >> 4)) * ATPB + tok) << 4) + (e & 15);
        } else {
          gsrc = A + (size_t)(m0t + r) * K + k0 + sp * 8;
        }
        gll16(gsrc, (void*)&As[is * 512]);
      } else {
        int r = (is - 8) * 16 + ir;
        int sp = sl ^ ((r >> 1) & 3);
        gll16(Wt + (size_t)(n0t + r) * K + k0 + sp * 8, (void*)&Bs[(is - 8) * 512]);
      }
    }
    __syncthreads();
    bf16x8 af[4], bfr[4];
#pragma unroll
    for (int mi = 0; mi < 4; mi++) {
      int m = wr * 64 + mi * 16 + li;
      sh8 t = *(const sh8*)&As[m * 32 + ((sg ^ ((m >> 1) & 3)) << 3)];
      af[mi] = __builtin_bit_cast(bf16x8, t);
    }
#pragma unroll
    for (int ni = 0; ni < 4; ni++) {
      int n = wc * 64 + ni * 16 + li;
      sh8 t = *(const sh8*)&Bs[n * 32 + ((sg ^ ((n >> 1) & 3)) << 3)];
      bfr[ni] = __builtin_bit_cast(bf16x8, t);
    }
#pragma unroll
    for (int mi = 0; mi < 4; mi++)
#pragma unroll
      for (int ni = 0; ni < 4; ni++)
        acc[mi][ni] = __builtin_amdgcn_mfma_f32_16x16x32_bf16(af[mi], bfr[ni],
                                                              acc[mi][ni], 0, 0, 0);
  }

  float bv[4];
#pragma unroll
  for (int ni = 0; ni < 4; ni++) bv[ni] = bias[n0t + wc * 64 + ni * 16 + li];

  if constexpr (EPI == 1) {
#pragma unroll
    for (int mi = 0; mi < 4; mi++)
#pragma unroll
      for (int ni = 0; ni < 4; ni++)
#pragma unroll
        for (int r = 0; r < 4; r++) acc[mi][ni][r] += bv[ni];
#pragma unroll
    for (int mi = 0; mi < 4; mi++)
#pragma unroll
      for (int r = 0; r < 4; r++) {
        float s = acc[mi][0][r] + acc[mi][1][r] + acc[mi][2][r] + acc[mi][3][r];
        float q2 = acc[mi][0][r] * acc[mi][0][r] + acc[mi][1][r] * acc[mi][1][r] +
                   acc[mi][2][r] * acc[mi][2][r] + acc[mi][3][r] * acc[mi][3][r];
#pragma unroll
        for (int off = 1; off < 16; off <<= 1) {
          s += __shfl_xor(s, off);
          q2 += __shfl_xor(q2, off);
        }
        if (li == 0) part[wr * 64 + mi * 16 + sg * 4 + r][wc] = make_float2(s, q2);
      }
    __syncthreads();
    float gv[4], bev[4];
#pragma unroll
    for (int ni = 0; ni < 4; ni++) {
      int col = wc * 64 + ni * 16 + li;
      gv[ni] = gg[col];
      bev[ni] = be[col];
    }
#pragma unroll
    for (int mi = 0; mi < 4; mi++)
#pragma unroll
      for (int r = 0; r < 4; r++) {
        int mrow = wr * 64 + mi * 16 + sg * 4 + r;
        float2 p0 = part[mrow][0], p1 = part[mrow][1], p2 = part[mrow][2], p3 = part[mrow][3];
        float S = p0.x + p1.x + p2.x + p3.x;
        float Qq = p0.y + p1.y + p2.y + p3.y;
        float mean = S * (1.f / 256.f);
        float var = Qq * (1.f / 256.f) - mean * mean;
        float rstd = rsqrtf(var + EPSF);
        int mg = m0t + mrow;
        int b = mg / CTPB, tok = mg - b * CTPB;
#pragma unroll
        for (int ni = 0; ni < 4; ni++) {
          int col = wc * 64 + ni * 16 + li;
          float val = (acc[mi][ni][r] - mean) * rstd * gv[ni] + bev[ni];
          int half = col >> 7, h = (col >> 4) & 7, d = col & 15;
          float* dst = half ? (C + CPS) : C;
          dst[((((size_t)b * 8 + h) * CTPB + tok) << 4) + d] = val;
        }
      }
  } else if constexpr (EPI == 2) {
#pragma unroll
    for (int mi = 0; mi < 4; mi++)
#pragma unroll
      for (int r = 0; r < 4; r++) {
        int mg = m0t + wr * 64 + mi * 16 + sg * 4 + r;
        if (mg < M) {
          int b = mg / CTPB, tok = mg - b * CTPB;
#pragma unroll
          for (int ni = 0; ni < 4; ni++) {
            int col = n0t + wc * 64 + ni * 16 + li;
            float v = acc[mi][ni][r] + bv[ni];
            int pt = col >> 7, h = (col >> 4) & 7, d = col & 15;
            (C + (size_t)pt * CPS)[((((size_t)b * 8 + h) * CTPB + tok) << 4) + d] = v;
          }
        }
      }
  } else {
#pragma unroll
    for (int mi = 0; mi < 4; mi++)
#pragma unroll
      for (int r = 0; r < 4; r++) {
        int mrow = m0t + wr * 64 + mi * 16 + sg * 4 + r;
        if (mrow < M) {
#pragma unroll
          for (int ni = 0; ni < 4; ni++) {
            int col = n0t + wc * 64 + ni * 16 + li;
            float v = acc[mi][ni][r] + bv[ni];
            if (POST) v += post[(size_t)mrow * Ntot + col];
            C[(size_t)mrow * Ntot + col] = v;
          }
        }
      }
  }
}

// ---------------------------------------------------------------------------
// MFMA flash attention. All K/V head-major f32 [bh][nk][16]; out bf16
// head-major. One wave = 16 queries of one (b,h); block = 4 waves; K/V
// staged per 64-key block in LDS (bf16), V transposed. Swapped QK
// (mfma(K,Q)) -> lane holds 16 scores for query lane&15 -> lane-local
// online softmax. PV = mfma(V^T, P) accumulates O^T over all key blocks.
// MODE 0: stage-1 (out tok = (b%5)*200 + qoff + qi, obh=(b/5)*8+h, +q resid)
// MODE 1: plain (out tok = qi, obh = b*8+h)
// MODE 2: plain + optional token-major f32 residual
// ---------------------------------------------------------------------------
template <int MODE>
__global__ __launch_bounds__(256) void mattn(
    const float* __restrict__ qp, size_t qsb, size_t qsh, int qsr,
    const float* __restrict__ kp, const float* __restrict__ vp,
    int nk, int nq, unsigned short* __restrict__ op, int OTPB, int qoff,
    const float* __restrict__ resid) {
  __shared__ __align__(16) unsigned short Klds[64][24];    // 48B rows
  __shared__ __align__(16) unsigned short VTlds[16][72];   // 144B rows
  __shared__ __align__(16) unsigned short Plds[4][16][72]; // per-wave P
  const int tid = threadIdx.x, wid = tid >> 6, lane = tid & 63;
  const int li = lane & 15, gr = lane >> 4;
  const int b = blockIdx.z, h = blockIdx.y;
  const int bh = b * 8 + h;
  const int qi = blockIdx.x * 64 + wid * 16 + li;
  const bool qact = qi < nq;
  const int qic = qact ? qi : nq - 1;
  const float* qrow = qp + b * qsb + h * qsh + (size_t)qic * qsr;

  // Q fragment: lane holds Q[q=li][d=gr*8+j], zero for d>=16
  sh8 z8 = (sh8)0;
  bf16x8 qf = __builtin_bit_cast(bf16x8, z8);
  if (gr < 2) {
    const float4* q4 = (const float4*)(qrow + gr * 8);
    float4 qa = q4[0], qb = q4[1];
    sh8 tt;
    tt[0] = f2bf(qa.x); tt[1] = f2bf(qa.y); tt[2] = f2bf(qa.z); tt[3] = f2bf(qa.w);
    tt[4] = f2bf(qb.x); tt[5] = f2bf(qb.y); tt[6] = f2bf(qb.z); tt[7] = f2bf(qb.w);
    qf = __builtin_bit_cast(bf16x8, tt);
  }

  float mrun = -3e38f, lrun = 0.f;
  f32x4 acc = (f32x4){0.f, 0.f, 0.f, 0.f};
  const f32x4 zero4 = (f32x4){0.f, 0.f, 0.f, 0.f};
  const float4* K4 = (const float4*)(kp + (size_t)bh * nk * 16);
  const float4* V4 = (const float4*)(vp + (size_t)bh * nk * 16);
  const int skey = tid >> 2, sdb = tid & 3;  // staging roles

  for (int kb = 0; kb < nk; kb += 64) {
    __syncthreads();  // prior compute done before overwriting K/V
    // ---- stage K (row-major bf16) and V^T (transposed bf16) ----
    int gk = kb + skey;
    bool ok = gk < nk;
    float4 kr = ok ? K4[(size_t)gk * 4 + sdb] : make_float4(0.f, 0.f, 0.f, 0.f);
    float4 vr = ok ? V4[(size_t)gk * 4 + sdb] : make_float4(0.f, 0.f, 0.f, 0.f);
    *(uint2*)&Klds[skey][sdb * 4] = make_uint2(pk2(kr.x, kr.y), pk2(kr.z, kr.w));
    VTlds[sdb * 4 + 0][skey] = f2bf(vr.x);
    VTlds[sdb * 4 + 1][skey] = f2bf(vr.y);
    VTlds[sdb * 4 + 2][skey] = f2bf(vr.z);
    VTlds[sdb * 4 + 3][skey] = f2bf(vr.w);
    __syncthreads();
    // ---- QK^T swapped: D[key][q] per 16-key tile ----
    f32x4 st[4];
#pragma unroll
    for (int t = 0; t < 4; t++) {
      sh8 kk = *(const sh8*)&Klds[t * 16 + li][(gr & 1) * 8];
      st[t] = __builtin_amdgcn_mfma_f32_16x16x32_bf16(
          __builtin_bit_cast(bf16x8, kk), qf, zero4, 0, 0, 0);
    }
    float sv[4][4];
#pragma unroll
    for (int t = 0; t < 4; t++)
#pragma unroll
      for (int r = 0; r < 4; r++) sv[t][r] = st[t][r] * SCALEF;
    if (kb + 64 > nk) {
#pragma unroll
      for (int t = 0; t < 4; t++) {
        int kbase = kb + t * 16 + gr * 4;
#pragma unroll
        for (int r = 0; r < 4; r++)
          if (kbase + r >= nk) sv[t][r] = -1e30f;
      }
    }
    // ---- online softmax (lane-local for query li) ----
    float bm = sv[0][0];
#pragma unroll
    for (int t = 0; t < 4; t++)
#pragma unroll
      for (int r = 0; r < 4; r++) bm = fmaxf(bm, sv[t][r]);
    bm = fmaxf(bm, __shfl_xor(bm, 16));
    bm = fmaxf(bm, __shfl_xor(bm, 32));
    float mnew = fmaxf(mrun, bm);
    float cf = __expf(mrun - mnew);
    mrun = mnew;
    lrun *= cf;
    acc[0] *= cf; acc[1] *= cf; acc[2] *= cf; acc[3] *= cf;
    float ls = 0.f;
    unsigned pw[4][2];
#pragma unroll
    for (int t = 0; t < 4; t++) {
      float p0 = __expf(sv[t][0] - mnew), p1 = __expf(sv[t][1] - mnew);
      float p2 = __expf(sv[t][2] - mnew), p3 = __expf(sv[t][3] - mnew);
      ls += (p0 + p1) + (p2 + p3);
      pw[t][0] = pk2(p0, p1);
      pw[t][1] = pk2(p2, p3);
    }
    ls += __shfl_xor(ls, 16);
    ls += __shfl_xor(ls, 32);
    lrun += ls;
#pragma unroll
    for (int t = 0; t < 4; t++)
      *(uint2*)&Plds[wid][li][t * 16 + gr * 4] = make_uint2(pw[t][0], pw[t][1]);
    // ---- PV: O^T += V^T(16d x 32k) @ P^T(32k x 16q), 2 halves ----
#pragma unroll
    for (int hh = 0; hh < 2; hh++) {
      sh8 vt = *(const sh8*)&VTlds[li][hh * 32 + gr * 8];
      sh8 pt = *(const sh8*)&Plds[wid][li][hh * 32 + gr * 8];
      acc = __builtin_amdgcn_mfma_f32_16x16x32_bf16(
          __builtin_bit_cast(bf16x8, vt), __builtin_bit_cast(bf16x8, pt), acc, 0, 0, 0);
    }
  }
  // ---- epilogue: lane holds O[q=li][d=gr*4+r] ----
  float inv = 1.f / lrun;
  float o[4];
#pragma unroll
  for (int r = 0; r < 4; r++) o[r] = acc[r] * inv;
  if (MODE == 0) {
    const float4* q4 = (const float4*)(qrow + gr * 4);
    float4 qv = q4[0];
    o[0] += qv.x; o[1] += qv.y; o[2] += qv.z; o[3] += qv.w;
  }
  if (MODE == 2 && resid) {
    const float4* r4 = (const float4*)(resid + ((size_t)b * 1024 + qic) * 128 + h * 16 + gr * 4);
    float4 rv = r4[0];
    o[0] += rv.x; o[1] += rv.y; o[2] += rv.z; o[3] += rv.w;
  }
  if (qact) {
    int obh, otok;
    if (MODE == 0) {
      obh = (b / 5) * 8 + h;
      otok = (b % 5) * 200 + qoff + qi;
    } else {
      obh = bh;
      otok = qi;
    }
    *(uint2*)(op + (((size_t)obh * OTPB + otok) << 4) + gr * 4) =
        make_uint2(pk2(o[0], o[1]), pk2(o[2], o[3]));
  }
}

// ---------------------------------------------------------------------------
__global__ __launch_bounds__(256) void wtrans_kernel(
    const float* __restrict__ W, unsigned short* __restrict__ Wt, int K, int N) {
  int idx = blockIdx.x * 256 + threadIdx.x;
  if (idx >= K * N) return;
  int k = idx / N, n = idx - k * N;
  Wt[(size_t)n * K + k] = f2bf(W[idx]);
}

__global__ __launch_bounds__(256) void cvt_kernel(
    const float* __restrict__ in, unsigned short* __restrict__ out, int n8) {
  int i = blockIdx.x * 256 + threadIdx.x;
  if (i >= n8) return;
  float4 a = ((const float4*)in)[i * 2];
  float4 b = ((const float4*)in)[i * 2 + 1];
  uint4 o;
  o.x = pk2(a.x, a.y);
  o.y = pk2(a.z, a.w);
  o.z = pk2(b.x, b.y);
  o.w = pk2(b.z, b.w);
  ((uint4*)out)[i] = o;
}

__global__ __launch_bounds__(256) void iqp_kernel(
    const float* __restrict__ iq, const float* __restrict__ W,
    const float* __restrict__ b, float* __restrict__ out) {
  __shared__ float row[128];
  int r = blockIdx.x;
  if (threadIdx.x < 128) row[threadIdx.x] = iq[r * 128 + threadIdx.x];
  __syncthreads();
  int c = threadIdx.x;
  float acc = b[c];
#pragma unroll 8
  for (int k = 0; k < 128; ++k) acc += row[k] * W[k * 256 + c];
  out[r * 256 + c] = acc;
}

// ---------------------------------------------------------------------------
// fp32 row-blocked GEMM, gathered input rows, head-major K/V split store
// ---------------------------------------------------------------------------
template <int K, int N, int R>
__global__ __launch_bounds__(N) void gemm_kv_kernel(
    const float* __restrict__ in, const float* __restrict__ W,
    const float* __restrict__ bias, float* __restrict__ outK,
    float* __restrict__ outV, int rowoff) {
  __shared__ float rows[R][K];
  int r0 = blockIdx.x * R;
  for (int e = threadIdx.x; e < R * K; e += N) {
    int rr = e / K, k = e - rr * K;
    size_t r = r0 + rr;
    size_t irx = (r / 100) * 200 + rowoff + (r % 100);
    rows[rr][k] = in[irx * K + k];
  }
  __syncthreads();
  int c = threadIdx.x;
  float acc[R];
  float bb = bias[c];
#pragma unroll
  for (int rr = 0; rr < R; rr++) acc[rr] = bb;
  for (int k = 0; k < K; k += 4) {
    float w0 = W[(size_t)k * N + c];
    float w1 = W[(size_t)(k + 1) * N + c];
    float w2 = W[(size_t)(k + 2) * N + c];
    float w3 = W[(size_t)(k + 3) * N + c];
#pragma unroll
    for (int rr = 0; rr < R; rr++) {
      float4 r4 = *reinterpret_cast<const float4*>(&rows[rr][k]);
      acc[rr] = fmaf(r4.x, w0, acc[rr]);
      acc[rr] = fmaf(r4.y, w1, acc[rr]);
      acc[rr] = fmaf(r4.z, w2, acc[rr]);
      acc[rr] = fmaf(r4.w, w3, acc[rr]);
    }
  }
  int half = c >> 7, h = (c >> 4) & 7, d = c & 15;
  float* dst = half ? outV : outK;
#pragma unroll
  for (int rr = 0; rr < R; rr++) {
    int r = r0 + rr;
    int b = r / 100, tok = r - b * 100;
    dst[((((size_t)b * 8 + h) * 100 + tok) << 4) + d] = acc[rr];
  }
}

// aiq2 (40,100,128) copy out of SA (viewed as (40,200,128) rows 0..99)
__global__ __launch_bounds__(128) void copy_aiq2_kernel(
    const float* __restrict__ SA, float* __restrict__ out) {
  int r = blockIdx.x, c = threadIdx.x;
  size_t irx = (size_t)(r / 100) * 200 + (r % 100);
  out[(size_t)r * 128 + c] = SA[irx * 128 + c];
}

// ---------------------------------------------------------------------------
extern "C" void kernel_launch(void* const* d_in, const int* in_sizes, int n_in,
                              void* d_out, int out_size, void* d_ws, size_t ws_size,
                              hipStream_t stream) {
  const float* audio = (const float*)d_in[0];   // (40,1024,128)
  const float* vis   = (const float*)d_in[1];   // (40,1024,512)
  const float* iq    = (const float*)d_in[2];
  const float* w_iqp = (const float*)d_in[3];
  const float* b_iqp = (const float*)d_in[4];
  const float* w_afp = (const float*)d_in[5];
  const float* b_afp = (const float*)d_in[6];
  const float* w_vfp = (const float*)d_in[7];
  const float* b_vfp = (const float*)d_in[8];
  const float* g_an  = (const float*)d_in[9];
  const float* be_an = (const float*)d_in[10];
  const float* g_vn  = (const float*)d_in[11];
  const float* be_vn = (const float*)d_in[12];
  const float* w_aqp = (const float*)d_in[13];
  const float* b_aqp = (const float*)d_in[14];
  const float* w_vqp = (const float*)d_in[15];
  const float* b_vqp = (const float*)d_in[16];
  const float* w_aq  = (const float*)d_in[17];
  const float* b_aq  = (const float*)d_in[18];
  const float* w_vq  = (const float*)d_in[19];
  const float* b_vq  = (const float*)d_in[20];
  const float* w_in  = (const float*)d_in[21];
  const float* b_in  = (const float*)d_in[22];
  const float* w_o   = (const float*)d_in[23];
  const float* b_o   = (const float*)d_in[24];
  const float* w_ao  = (const float*)d_in[25];
  const float* b_ao  = (const float*)d_in[26];
  const float* w_vo  = (const float*)d_in[27];
  const float* b_vo  = (const float*)d_in[28];

  float* out = (float*)d_out;
  float* ws  = (float*)d_ws;

  // ---- d_out scratch (dead until final writes; stream-ordered) ----
  unsigned short* vis_bf = (unsigned short*)(out);  // [0,10485760) words
  float* akn = out + 10485760;   // K hm (40,8,1024,16); dead after stage-1
  float* avn = out + 15728640;   // V hm
  float* vkn = out + 20971520;
  float* vvn = out + 26214400;
  float* a_hm = out + 31457280;  // _a hm f32, written step 9
  float* v_hm = out + 36700160;  // _v hm f32, written step 9
  float* aiq2_out = out + 41943040;
  float* audio_out = out;
  float* vis_out   = out + 20971520;

  // ---- ws layout (f32-word offsets) ----
  unsigned short* WT       = (unsigned short*)(ws);            // [0, 262144)
  unsigned short* audio_bf = (unsigned short*)(ws + 262144);   // [.., 2883584)
  unsigned short* Q1hm     = (unsigned short*)(ws + 2883584);  // [8][8][1000][16] bf16
  unsigned short* saphm    = (unsigned short*)(ws + 3395584);  // [8][8][1000][16] bf16
  float* qkvhm             = ws + 3915776;                     // 3 x [8][8][1000][16] f32
  unsigned short* aatthm   = (unsigned short*)(ws + 3915776);  // overlays qkvhm
  unsigned short* vatthm   = (unsigned short*)(ws + 6987776);  // 2,621,440 w
  float* SA                = ws + 9609216;                     // (8000,128) f32
  float* Ka = ws + 10633216;  // [40][8][100][16] f32
  float* Va = ws + 11145216;
  float* Kv = ws + 11657216;
  float* Vv = ws + 12169216;
  float* aqvq = ws + 12681216;  // (100,256) f32

  unsigned short* afp_t = WT + 0;
  unsigned short* vfp_t = WT + 32768;
  unsigned short* aq_t  = WT + 163840;
  unsigned short* vq_t  = WT + 180224;
  unsigned short* in_t  = WT + 245760;
  unsigned short* o_t   = WT + 294912;
  unsigned short* ao_t  = WT + 311296;
  unsigned short* vo_t  = WT + 376832;

  // 0. weight transpose+convert, activation convert
  wtrans_kernel<<<128, 256, 0, stream>>>(w_afp, afp_t, 128, 256);
  wtrans_kernel<<<512, 256, 0, stream>>>(w_vfp, vfp_t, 512, 256);
  wtrans_kernel<<<64,  256, 0, stream>>>(w_aq,  aq_t,  128, 128);
  wtrans_kernel<<<256, 256, 0, stream>>>(w_vq,  vq_t,  512, 128);
  wtrans_kernel<<<192, 256, 0, stream>>>(w_in,  in_t,  128, 384);
  wtrans_kernel<<<64,  256, 0, stream>>>(w_o,   o_t,   128, 128);
  wtrans_kernel<<<256, 256, 0, stream>>>(w_ao,  ao_t,  128, 512);
  wtrans_kernel<<<256, 256, 0, stream>>>(w_vo,  vo_t,  128, 512);
  cvt_kernel<<<2560,  256, 0, stream>>>(audio, audio_bf, 655360);
  cvt_kernel<<<10240, 256, 0, stream>>>(vis,   vis_bf,   2621440);

  // 1. iq_emb projection (f32)
  iqp_kernel<<<100, 256, 0, stream>>>(iq, w_iqp, b_iqp, aqvq);

  // 2. proj + fused LN -> head-major K/V split (EPI1)
  mfma_gemm<128, 256, 1, false, false><<<dim3(320, 1), 512, 0, stream>>>(
      audio_bf, afp_t, b_afp, g_an, be_an, nullptr, akn, 40960, 256, 0, 1024, 5242880);
  mfma_gemm<512, 256, 1, false, false><<<dim3(320, 1), 512, 0, stream>>>(
      vis_bf, vfp_t, b_vfp, g_vn, be_vn, nullptr, vkn, 40960, 256, 0, 1024, 5242880);

  // 3. stage-1 cross-attn (MFMA flash, +q residual) -> Q1hm
  mattn<0><<<dim3(2, 8, 40), 256, 0, stream>>>(
      aqvq, 0, 16, 256, akn, avn, 1024, 100, Q1hm, 1000, 0, nullptr);
  mattn<0><<<dim3(2, 8, 40), 256, 0, stream>>>(
      aqvq + 128, 0, 16, 256, vkn, vvn, 1024, 100, Q1hm, 1000, 100, nullptr);

  // 4. qkv = queries @ w_in + b_in (A head-major, out 3-part head-major)
  mfma_gemm<128, 128, 2, false, true><<<dim3(63, 3), 256, 0, stream>>>(
      Q1hm, in_t, b_in, nullptr, nullptr, nullptr, qkvhm, 8000, 384, 1000, 1000, 1024000);

  // 5. self-attention (MFMA flash) -> saphm
  mattn<1><<<dim3(16, 8, 8), 256, 0, stream>>>(
      qkvhm, 128000, 16000, 16, qkvhm + 1024000, qkvhm + 2048000, 1000, 1000,
      saphm, 1000, 0, nullptr);

  // 6. SA = sa_pre @ w_o + b_o (A head-major -> token-major f32)
  mfma_gemm<128, 128, 0, false, true><<<dim3(63, 1), 256, 0, stream>>>(
      saphm, o_t, b_o, nullptr, nullptr, nullptr, SA, 8000, 128, 1000, 0, 0);

  // 7. aiq2 output
  copy_aiq2_kernel<<<4000, 128, 0, stream>>>(SA, aiq2_out);

  // 8. kf/vf projections -> head-major K/V
  gemm_kv_kernel<128, 256, 16><<<250, 256, 0, stream>>>(SA, w_aqp, b_aqp, Ka, Va, 0);
  gemm_kv_kernel<128, 256, 16><<<250, 256, 0, stream>>>(SA, w_vqp, b_vqp, Kv, Vv, 100);

  // 9. _a / _v projections -> head-major f32 (EPI2, 1 part)
  mfma_gemm<128, 128, 2, false, false><<<dim3(320, 1), 256, 0, stream>>>(
      audio_bf, aq_t, b_aq, nullptr, nullptr, nullptr, a_hm, 40960, 128, 0, 1024, 0);
  mfma_gemm<512, 128, 2, false, false><<<dim3(320, 1), 256, 0, stream>>>(
      vis_bf, vq_t, b_vq, nullptr, nullptr, nullptr, v_hm, 40960, 128, 0, 1024, 0);

  // 10. stage-3 cross-attn (MFMA flash); audio fuses +audio resid
  mattn<2><<<dim3(16, 8, 40), 256, 0, stream>>>(
      a_hm, 131072, 16384, 16, Kv, Vv, 100, 1024, aatthm, 1024, 0, audio);
  mattn<2><<<dim3(16, 8, 40), 256, 0, stream>>>(
      v_hm, 131072, 16384, 16, Ka, Va, 100, 1024, vatthm, 1024, 0, nullptr);

  // 11. output projections (A head-major); w_vo fuses +vis residual
  mfma_gemm<128, 128, 0, false, true><<<dim3(320, 4), 256, 0, stream>>>(
      aatthm, ao_t, b_ao, nullptr, nullptr, nullptr, audio_out, 40960, 512, 1024, 0, 0);
  mfma_gemm<128, 128, 0, true, true><<<dim3(320, 4), 256, 0, stream>>>(
      vatthm, vo_t, b_vo, nullptr, nullptr, vis, vis_out, 40960, 512, 1024, 0, 0);
}

// Round 8
// 395.648 us; speedup vs baseline: 4.1497x; 1.0618x over previous
//
#include <hip/hip_runtime.h>

#define EPSF 1e-5f
#define SCALEF 0.25f   // hd=16 -> 16^-0.5

typedef __attribute__((ext_vector_type(8))) __bf16 bf16x8;
typedef __attribute__((ext_vector_type(8))) unsigned short sh8;
typedef __attribute__((ext_vector_type(4))) float f32x4;

__device__ __forceinline__ unsigned short f2bf(float f) {
  unsigned u = __float_as_uint(f);
  return (unsigned short)((u + 0x7FFFu + ((u >> 16) & 1u)) >> 16);
}
__device__ __forceinline__ unsigned pk2(float lo, float hi) {
  return (unsigned)f2bf(lo) | ((unsigned)f2bf(hi) << 16);
}

// async global->LDS, 16B per lane; LDS dest = uniform base + lane*16
__device__ __forceinline__ void gll16(const void* g, void* l) {
  __builtin_amdgcn_global_load_lds((const __attribute__((address_space(1))) void*)g,
                                   (__attribute__((address_space(3))) void*)l,
                                   16, 0, 0);
}

// ---------------------------------------------------------------------------
// MFMA GEMM: C = A[M][K](bf16) x Wt[N][K](bf16)^T + bias
//  AHEAD: A stored head-major [B][8][ATPB][16] bf16 (per-lane gather source)
//  EPI 0: token-major f32 store (+POST residual)
//  EPI 1: fused LayerNorm (Ntot=256) then head-major split-2 store
//  EPI 2: head-major split-(Ntot/128) store, part p -> C + p*CPS
//  OBF: EPI1/EPI2 store bf16 (CPS then counted in bf16 elems)
// ---------------------------------------------------------------------------
template <int K, int BN, int EPI, bool POST, bool AHEAD, bool OBF>
__global__ __launch_bounds__(BN * 2) void mfma_gemm(
    const unsigned short* __restrict__ A, const unsigned short* __restrict__ Wt,
    const float* __restrict__ bias, const float* __restrict__ gg,
    const float* __restrict__ be, const float* __restrict__ post,
    float* __restrict__ C, int M, int Ntot, int ATPB, int CTPB, size_t CPS) {
  constexpr int NW = BN / 32;   // waves per block
  constexpr int NCW = BN / 64;  // wave columns
  __shared__ __align__(16) unsigned short As[128 * 32];
  __shared__ __align__(16) unsigned short Bs[BN * 32];
  __shared__ float2 part[128][4];
  const int tid = threadIdx.x;
  const int wid = tid >> 6, lane = tid & 63;
  const int wr = wid / NCW, wc = wid % NCW;
  const int m0t = blockIdx.x * 128, n0t = blockIdx.y * BN;
  const int ir = lane >> 2, sl = lane & 3;   // staging: row-in-16, slot
  const int sg = lane >> 4, li = lane & 15;  // frags: k-group, row/col
  f32x4 acc[4][4];
#pragma unroll
  for (int i = 0; i < 4; i++)
#pragma unroll
    for (int j = 0; j < 4; j++) acc[i][j] = (f32x4){0.f, 0.f, 0.f, 0.f};
  constexpr int nIss = 8 + BN / 16;  // 1KB issues: 8 for A, BN/16 for B

  for (int k0 = 0; k0 < K; k0 += 32) {
    __syncthreads();
    for (int is = wid; is < nIss; is += NW) {
      if (is < 8) {
        int r = is * 16 + ir;
        int sp = sl ^ ((r >> 1) & 3);
        const unsigned short* gsrc;
        if (AHEAD) {
          int rg = m0t + r;
          if (rg >= M) rg = M - 1;
          int b = rg / ATPB, tok = rg - b * ATPB;
          int e = k0 + sp * 8;
          gsrc = A + ((((size_t)b * 8 + (e >> 4)) * ATPB + tok) << 4) + (e & 15);
        } else {
          gsrc = A + (size_t)(m0t + r) * K + k0 + sp * 8;
        }
        gll16(gsrc, (void*)&As[is * 512]);
      } else {
        int r = (is - 8) * 16 + ir;
        int sp = sl ^ ((r >> 1) & 3);
        gll16(Wt + (size_t)(n0t + r) * K + k0 + sp * 8, (void*)&Bs[(is - 8) * 512]);
      }
    }
    __syncthreads();
    bf16x8 af[4], bfr[4];
#pragma unroll
    for (int mi = 0; mi < 4; mi++) {
      int m = wr * 64 + mi * 16 + li;
      sh8 t = *(const sh8*)&As[m * 32 + ((sg ^ ((m >> 1) & 3)) << 3)];
      af[mi] = __builtin_bit_cast(bf16x8, t);
    }
#pragma unroll
    for (int ni = 0; ni < 4; ni++) {
      int n = wc * 64 + ni * 16 + li;
      sh8 t = *(const sh8*)&Bs[n * 32 + ((sg ^ ((n >> 1) & 3)) << 3)];
      bfr[ni] = __builtin_bit_cast(bf16x8, t);
    }
#pragma unroll
    for (int mi = 0; mi < 4; mi++)
#pragma unroll
      for (int ni = 0; ni < 4; ni++)
        acc[mi][ni] = __builtin_amdgcn_mfma_f32_16x16x32_bf16(af[mi], bfr[ni],
                                                              acc[mi][ni], 0, 0, 0);
  }

  float bv[4];
#pragma unroll
  for (int ni = 0; ni < 4; ni++) bv[ni] = bias[n0t + wc * 64 + ni * 16 + li];

  if constexpr (EPI == 1) {
#pragma unroll
    for (int mi = 0; mi < 4; mi++)
#pragma unroll
      for (int ni = 0; ni < 4; ni++)
#pragma unroll
        for (int r = 0; r < 4; r++) acc[mi][ni][r] += bv[ni];
#pragma unroll
    for (int mi = 0; mi < 4; mi++)
#pragma unroll
      for (int r = 0; r < 4; r++) {
        float s = acc[mi][0][r] + acc[mi][1][r] + acc[mi][2][r] + acc[mi][3][r];
        float q2 = acc[mi][0][r] * acc[mi][0][r] + acc[mi][1][r] * acc[mi][1][r] +
                   acc[mi][2][r] * acc[mi][2][r] + acc[mi][3][r] * acc[mi][3][r];
#pragma unroll
        for (int off = 1; off < 16; off <<= 1) {
          s += __shfl_xor(s, off);
          q2 += __shfl_xor(q2, off);
        }
        if (li == 0) part[wr * 64 + mi * 16 + sg * 4 + r][wc] = make_float2(s, q2);
      }
    __syncthreads();
    float gv[4], bev[4];
#pragma unroll
    for (int ni = 0; ni < 4; ni++) {
      int col = wc * 64 + ni * 16 + li;
      gv[ni] = gg[col];
      bev[ni] = be[col];
    }
#pragma unroll
    for (int mi = 0; mi < 4; mi++)
#pragma unroll
      for (int r = 0; r < 4; r++) {
        int mrow = wr * 64 + mi * 16 + sg * 4 + r;
        float2 p0 = part[mrow][0], p1 = part[mrow][1], p2 = part[mrow][2], p3 = part[mrow][3];
        float S = p0.x + p1.x + p2.x + p3.x;
        float Qq = p0.y + p1.y + p2.y + p3.y;
        float mean = S * (1.f / 256.f);
        float var = Qq * (1.f / 256.f) - mean * mean;
        float rstd = rsqrtf(var + EPSF);
        int mg = m0t + mrow;
        int b = mg / CTPB, tok = mg - b * CTPB;
#pragma unroll
        for (int ni = 0; ni < 4; ni++) {
          int col = wc * 64 + ni * 16 + li;
          float val = (acc[mi][ni][r] - mean) * rstd * gv[ni] + bev[ni];
          int half = col >> 7, h = (col >> 4) & 7, d = col & 15;
          size_t idx = ((((size_t)b * 8 + h) * CTPB + tok) << 4) + d;
          if (OBF) {
            unsigned short* dst = (unsigned short*)C + (half ? CPS : 0);
            dst[idx] = f2bf(val);
          } else {
            float* dst = half ? (C + CPS) : C;
            dst[idx] = val;
          }
        }
      }
  } else if constexpr (EPI == 2) {
#pragma unroll
    for (int mi = 0; mi < 4; mi++)
#pragma unroll
      for (int r = 0; r < 4; r++) {
        int mg = m0t + wr * 64 + mi * 16 + sg * 4 + r;
        if (mg < M) {
          int b = mg / CTPB, tok = mg - b * CTPB;
#pragma unroll
          for (int ni = 0; ni < 4; ni++) {
            int col = n0t + wc * 64 + ni * 16 + li;
            float v = acc[mi][ni][r] + bv[ni];
            int pt = col >> 7, h = (col >> 4) & 7, d = col & 15;
            size_t idx = ((((size_t)b * 8 + h) * CTPB + tok) << 4) + d;
            if (OBF)
              ((unsigned short*)C + (size_t)pt * CPS)[idx] = f2bf(v);
            else
              (C + (size_t)pt * CPS)[idx] = v;
          }
        }
      }
  } else {
#pragma unroll
    for (int mi = 0; mi < 4; mi++)
#pragma unroll
      for (int r = 0; r < 4; r++) {
        int mrow = m0t + wr * 64 + mi * 16 + sg * 4 + r;
        if (mrow < M) {
#pragma unroll
          for (int ni = 0; ni < 4; ni++) {
            int col = n0t + wc * 64 + ni * 16 + li;
            float v = acc[mi][ni][r] + bv[ni];
            if (POST) v += post[(size_t)mrow * Ntot + col];
            C[(size_t)mrow * Ntot + col] = v;
          }
        }
      }
  }
}

// ---------------------------------------------------------------------------
// Stage-1 MFMA flash attention: both modalities, 8 waves (512 thr) = 128 q
// slots per (b,h) -> K/V staged ONCE. grid (1, 8, 80): z<40 audio, else vis.
// K/V bf16 head-major [bh][1024][16]; Q from aqvq f32 (qi*256 + mod*128 + h*16).
// Output bf16 head-major Q1hm: obh=(b/5)*8+h, otok=(b%5)*200+mod*100+qi; +q.
// ---------------------------------------------------------------------------
__global__ __launch_bounds__(512) void mattn1(
    const float* __restrict__ aqvq,
    const unsigned short* __restrict__ akn, const unsigned short* __restrict__ avn,
    const unsigned short* __restrict__ vkn, const unsigned short* __restrict__ vvn,
    unsigned short* __restrict__ op) {
  __shared__ __align__(16) unsigned short Klds[64][24];
  __shared__ __align__(16) unsigned short VTlds[16][72];
  __shared__ __align__(16) unsigned short Plds[8][16][72];
  const int tid = threadIdx.x, wid = tid >> 6, lane = tid & 63;
  const int li = lane & 15, gr = lane >> 4;
  const int z = blockIdx.z, h = blockIdx.y;
  const int mod = z >= 40 ? 1 : 0;
  const int b = z - mod * 40;
  const int bh = b * 8 + h;
  const int qi = wid * 16 + li;
  const bool qact = qi < 100;
  const int qic = qact ? qi : 99;
  const float* qrow = aqvq + mod * 128 + (size_t)qic * 256 + h * 16;
  const unsigned short* kp = mod ? vkn : akn;
  const unsigned short* vp = mod ? vvn : avn;

  // Q fragment: lane holds Q[q=li][d=gr*8+j], zero for d>=16
  sh8 z8 = (sh8)0;
  bf16x8 qf = __builtin_bit_cast(bf16x8, z8);
  if (gr < 2) {
    const float4* q4 = (const float4*)(qrow + gr * 8);
    float4 qa = q4[0], qb = q4[1];
    sh8 tt;
    tt[0] = f2bf(qa.x); tt[1] = f2bf(qa.y); tt[2] = f2bf(qa.z); tt[3] = f2bf(qa.w);
    tt[4] = f2bf(qb.x); tt[5] = f2bf(qb.y); tt[6] = f2bf(qb.z); tt[7] = f2bf(qb.w);
    qf = __builtin_bit_cast(bf16x8, tt);
  }

  float mrun = -3e38f, lrun = 0.f;
  f32x4 acc = (f32x4){0.f, 0.f, 0.f, 0.f};
  const f32x4 zero4 = (f32x4){0.f, 0.f, 0.f, 0.f};
  const unsigned* Ku = (const unsigned*)(kp + (size_t)bh * 1024 * 16);
  const unsigned* Vu = (const unsigned*)(vp + (size_t)bh * 1024 * 16);
  const int skey = tid >> 3, sdb = tid & 7;  // 8 threads/key, 4B each

  for (int kb = 0; kb < 1024; kb += 64) {
    __syncthreads();
    unsigned kw = Ku[(size_t)(kb + skey) * 8 + sdb];
    unsigned vw = Vu[(size_t)(kb + skey) * 8 + sdb];
    *(unsigned*)&Klds[skey][sdb * 2] = kw;
    VTlds[sdb * 2 + 0][skey] = (unsigned short)(vw & 0xffff);
    VTlds[sdb * 2 + 1][skey] = (unsigned short)(vw >> 16);
    __syncthreads();
    f32x4 st[4];
#pragma unroll
    for (int t = 0; t < 4; t++) {
      sh8 kk = *(const sh8*)&Klds[t * 16 + li][(gr & 1) * 8];
      st[t] = __builtin_amdgcn_mfma_f32_16x16x32_bf16(
          __builtin_bit_cast(bf16x8, kk), qf, zero4, 0, 0, 0);
    }
    float sv[4][4];
#pragma unroll
    for (int t = 0; t < 4; t++)
#pragma unroll
      for (int r = 0; r < 4; r++) sv[t][r] = st[t][r] * SCALEF;
    float bm = sv[0][0];
#pragma unroll
    for (int t = 0; t < 4; t++)
#pragma unroll
      for (int r = 0; r < 4; r++) bm = fmaxf(bm, sv[t][r]);
    bm = fmaxf(bm, __shfl_xor(bm, 16));
    bm = fmaxf(bm, __shfl_xor(bm, 32));
    float mnew = fmaxf(mrun, bm);
    float cf = __expf(mrun - mnew);
    mrun = mnew;
    lrun *= cf;
    acc[0] *= cf; acc[1] *= cf; acc[2] *= cf; acc[3] *= cf;
    float ls = 0.f;
    unsigned pw[4][2];
#pragma unroll
    for (int t = 0; t < 4; t++) {
      float p0 = __expf(sv[t][0] - mnew), p1 = __expf(sv[t][1] - mnew);
      float p2 = __expf(sv[t][2] - mnew), p3 = __expf(sv[t][3] - mnew);
      ls += (p0 + p1) + (p2 + p3);
      pw[t][0] = pk2(p0, p1);
      pw[t][1] = pk2(p2, p3);
    }
    ls += __shfl_xor(ls, 16);
    ls += __shfl_xor(ls, 32);
    lrun += ls;
#pragma unroll
    for (int t = 0; t < 4; t++)
      *(uint2*)&Plds[wid][li][t * 16 + gr * 4] = make_uint2(pw[t][0], pw[t][1]);
#pragma unroll
    for (int hh = 0; hh < 2; hh++) {
      sh8 vt = *(const sh8*)&VTlds[li][hh * 32 + gr * 8];
      sh8 pt = *(const sh8*)&Plds[wid][li][hh * 32 + gr * 8];
      acc = __builtin_amdgcn_mfma_f32_16x16x32_bf16(
          __builtin_bit_cast(bf16x8, vt), __builtin_bit_cast(bf16x8, pt), acc, 0, 0, 0);
    }
  }
  float inv = 1.f / lrun;
  float o[4];
#pragma unroll
  for (int r = 0; r < 4; r++) o[r] = acc[r] * inv;
  const float4* q4 = (const float4*)(qrow + gr * 4);
  float4 qv = q4[0];
  o[0] += qv.x; o[1] += qv.y; o[2] += qv.z; o[3] += qv.w;
  if (qact) {
    int obh = (b / 5) * 8 + h;
    int otok = (b % 5) * 200 + mod * 100 + qi;
    *(uint2*)(op + (((size_t)obh * 1000 + otok) << 4) + gr * 4) =
        make_uint2(pk2(o[0], o[1]), pk2(o[2], o[3]));
  }
}

// ---------------------------------------------------------------------------
// Generic MFMA flash attention, all operands bf16 head-major.
// MODE 1: plain (out tok = qi, obh = b*8+h)
// MODE 2: plain + optional token-major f32 residual
// ---------------------------------------------------------------------------
template <int MODE>
__global__ __launch_bounds__(256) void mattn(
    const unsigned short* __restrict__ qp, size_t qsb, size_t qsh, int qsr,
    const unsigned short* __restrict__ kp, const unsigned short* __restrict__ vp,
    int nk, int nq, unsigned short* __restrict__ op, int OTPB,
    const float* __restrict__ resid) {
  __shared__ __align__(16) unsigned short Klds[64][24];
  __shared__ __align__(16) unsigned short VTlds[16][72];
  __shared__ __align__(16) unsigned short Plds[4][16][72];
  const int tid = threadIdx.x, wid = tid >> 6, lane = tid & 63;
  const int li = lane & 15, gr = lane >> 4;
  const int b = blockIdx.z, h = blockIdx.y;
  const int bh = b * 8 + h;
  const int qi = blockIdx.x * 64 + wid * 16 + li;
  const bool qact = qi < nq;
  const int qic = qact ? qi : nq - 1;
  const unsigned short* qrow = qp + b * qsb + h * qsh + (size_t)qic * qsr;

  sh8 z8 = (sh8)0;
  bf16x8 qf = __builtin_bit_cast(bf16x8, z8);
  if (gr < 2) qf = __builtin_bit_cast(bf16x8, *(const sh8*)(qrow + gr * 8));

  float mrun = -3e38f, lrun = 0.f;
  f32x4 acc = (f32x4){0.f, 0.f, 0.f, 0.f};
  const f32x4 zero4 = (f32x4){0.f, 0.f, 0.f, 0.f};
  const uint2* Ku = (const uint2*)(kp + (size_t)bh * nk * 16);
  const uint2* Vu = (const uint2*)(vp + (size_t)bh * nk * 16);
  const int skey = tid >> 2, sdb = tid & 3;  // 4 threads/key, 8B each

  for (int kb = 0; kb < nk; kb += 64) {
    __syncthreads();
    int gk = kb + skey;
    bool ok = gk < nk;
    uint2 kw = ok ? Ku[(size_t)gk * 4 + sdb] : make_uint2(0u, 0u);
    uint2 vw = ok ? Vu[(size_t)gk * 4 + sdb] : make_uint2(0u, 0u);
    *(uint2*)&Klds[skey][sdb * 4] = kw;
    VTlds[sdb * 4 + 0][skey] = (unsigned short)(vw.x & 0xffff);
    VTlds[sdb * 4 + 1][skey] = (unsigned short)(vw.x >> 16);
    VTlds[sdb * 4 + 2][skey] = (unsigned short)(vw.y & 0xffff);
    VTlds[sdb * 4 + 3][skey] = (unsigned short)(vw.y >> 16);
    __syncthreads();
    f32x4 st[4];
#pragma unroll
    for (int t = 0; t < 4; t++) {
      sh8 kk = *(const sh8*)&Klds[t * 16 + li][(gr & 1) * 8];
      st[t] = __builtin_amdgcn_mfma_f32_16x16x32_bf16(
          __builtin_bit_cast(bf16x8, kk), qf, zero4, 0, 0, 0);
    }
    float sv[4][4];
#pragma unroll
    for (int t = 0; t < 4; t++)
#pragma unroll
      for (int r = 0; r < 4; r++) sv[t][r] = st[t][r] * SCALEF;
    if (kb + 64 > nk) {
#pragma unroll
      for (int t = 0; t < 4; t++) {
        int kbase = kb + t * 16 + gr * 4;
#pragma unroll
        for (int r = 0; r < 4; r++)
          if (kbase + r >= nk) sv[t][r] = -1e30f;
      }
    }
    float bm = sv[0][0];
#pragma unroll
    for (int t = 0; t < 4; t++)
#pragma unroll
      for (int r = 0; r < 4; r++) bm = fmaxf(bm, sv[t][r]);
    bm = fmaxf(bm, __shfl_xor(bm, 16));
    bm = fmaxf(bm, __shfl_xor(bm, 32));
    float mnew = fmaxf(mrun, bm);
    float cf = __expf(mrun - mnew);
    mrun = mnew;
    lrun *= cf;
    acc[0] *= cf; acc[1] *= cf; acc[2] *= cf; acc[3] *= cf;
    float ls = 0.f;
    unsigned pw[4][2];
#pragma unroll
    for (int t = 0; t < 4; t++) {
      float p0 = __expf(sv[t][0] - mnew), p1 = __expf(sv[t][1] - mnew);
      float p2 = __expf(sv[t][2] - mnew), p3 = __expf(sv[t][3] - mnew);
      ls += (p0 + p1) + (p2 + p3);
      pw[t][0] = pk2(p0, p1);
      pw[t][1] = pk2(p2, p3);
    }
    ls += __shfl_xor(ls, 16);
    ls += __shfl_xor(ls, 32);
    lrun += ls;
#pragma unroll
    for (int t = 0; t < 4; t++)
      *(uint2*)&Plds[wid][li][t * 16 + gr * 4] = make_uint2(pw[t][0], pw[t][1]);
#pragma unroll
    for (int hh = 0; hh < 2; hh++) {
      sh8 vt = *(const sh8*)&VTlds[li][hh * 32 + gr * 8];
      sh8 pt = *(const sh8*)&Plds[wid][li][hh * 32 + gr * 8];
      acc = __builtin_amdgcn_mfma_f32_16x16x32_bf16(
          __builtin_bit_cast(bf16x8, vt), __builtin_bit_cast(bf16x8, pt), acc, 0, 0, 0);
    }
  }
  float inv = 1.f / lrun;
  float o[4];
#pragma unroll
  for (int r = 0; r < 4; r++) o[r] = acc[r] * inv;
  if (MODE == 2 && resid) {
    const float4* r4 = (const float4*)(resid + ((size_t)b * 1024 + qic) * 128 + h * 16 + gr * 4);
    float4 rv = r4[0];
    o[0] += rv.x; o[1] += rv.y; o[2] += rv.z; o[3] += rv.w;
  }
  if (qact) {
    *(uint2*)(op + (((size_t)bh * OTPB + qi) << 4) + gr * 4) =
        make_uint2(pk2(o[0], o[1]), pk2(o[2], o[3]));
  }
}

// ---------------------------------------------------------------------------
__global__ __launch_bounds__(256) void wtrans_kernel(
    const float* __restrict__ W, unsigned short* __restrict__ Wt, int K, int N) {
  int idx = blockIdx.x * 256 + threadIdx.x;
  if (idx >= K * N) return;
  int k = idx / N, n = idx - k * N;
  Wt[(size_t)n * K + k] = f2bf(W[idx]);
}

__global__ __launch_bounds__(256) void cvt_kernel(
    const float* __restrict__ in, unsigned short* __restrict__ out, int n8) {
  int i = blockIdx.x * 256 + threadIdx.x;
  if (i >= n8) return;
  float4 a = ((const float4*)in)[i * 2];
  float4 b = ((const float4*)in)[i * 2 + 1];
  uint4 o;
  o.x = pk2(a.x, a.y);
  o.y = pk2(a.z, a.w);
  o.z = pk2(b.x, b.y);
  o.w = pk2(b.z, b.w);
  ((uint4*)out)[i] = o;
}

__global__ __launch_bounds__(256) void iqp_kernel(
    const float* __restrict__ iq, const float* __restrict__ W,
    const float* __restrict__ b, float* __restrict__ out) {
  __shared__ float row[128];
  int r = blockIdx.x;
  if (threadIdx.x < 128) row[threadIdx.x] = iq[r * 128 + threadIdx.x];
  __syncthreads();
  int c = threadIdx.x;
  float acc = b[c];
#pragma unroll 8
  for (int k = 0; k < 128; ++k) acc += row[k] * W[k * 256 + c];
  out[r * 256 + c] = acc;
}

// ---------------------------------------------------------------------------
// fp32 row-blocked GEMM, gathered input rows, head-major bf16 K/V split store
// ---------------------------------------------------------------------------
template <int K, int N, int R>
__global__ __launch_bounds__(N) void gemm_kv_kernel(
    const float* __restrict__ in, const float* __restrict__ W,
    const float* __restrict__ bias, unsigned short* __restrict__ outK,
    unsigned short* __restrict__ outV, int rowoff) {
  __shared__ float rows[R][K];
  int r0 = blockIdx.x * R;
  for (int e = threadIdx.x; e < R * K; e += N) {
    int rr = e / K, k = e - rr * K;
    size_t r = r0 + rr;
    size_t irx = (r / 100) * 200 + rowoff + (r % 100);
    rows[rr][k] = in[irx * K + k];
  }
  __syncthreads();
  int c = threadIdx.x;
  float acc[R];
  float bb = bias[c];
#pragma unroll
  for (int rr = 0; rr < R; rr++) acc[rr] = bb;
  for (int k = 0; k < K; k += 4) {
    float w0 = W[(size_t)k * N + c];
    float w1 = W[(size_t)(k + 1) * N + c];
    float w2 = W[(size_t)(k + 2) * N + c];
    float w3 = W[(size_t)(k + 3) * N + c];
#pragma unroll
    for (int rr = 0; rr < R; rr++) {
      float4 r4 = *reinterpret_cast<const float4*>(&rows[rr][k]);
      acc[rr] = fmaf(r4.x, w0, acc[rr]);
      acc[rr] = fmaf(r4.y, w1, acc[rr]);
      acc[rr] = fmaf(r4.z, w2, acc[rr]);
      acc[rr] = fmaf(r4.w, w3, acc[rr]);
    }
  }
  int half = c >> 7, h = (c >> 4) & 7, d = c & 15;
  unsigned short* dst = half ? outV : outK;
#pragma unroll
  for (int rr = 0; rr < R; rr++) {
    int r = r0 + rr;
    int b = r / 100, tok = r - b * 100;
    dst[((((size_t)b * 8 + h) * 100 + tok) << 4) + d] = f2bf(acc[rr]);
  }
}

// aiq2 (40,100,128) copy out of SA (viewed as (40,200,128) rows 0..99)
__global__ __launch_bounds__(128) void copy_aiq2_kernel(
    const float* __restrict__ SA, float* __restrict__ out) {
  int r = blockIdx.x, c = threadIdx.x;
  size_t irx = (size_t)(r / 100) * 200 + (r % 100);
  out[(size_t)r * 128 + c] = SA[irx * 128 + c];
}

// ---------------------------------------------------------------------------
extern "C" void kernel_launch(void* const* d_in, const int* in_sizes, int n_in,
                              void* d_out, int out_size, void* d_ws, size_t ws_size,
                              hipStream_t stream) {
  const float* audio = (const float*)d_in[0];   // (40,1024,128)
  const float* vis   = (const float*)d_in[1];   // (40,1024,512)
  const float* iq    = (const float*)d_in[2];
  const float* w_iqp = (const float*)d_in[3];
  const float* b_iqp = (const float*)d_in[4];
  const float* w_afp = (const float*)d_in[5];
  const float* b_afp = (const float*)d_in[6];
  const float* w_vfp = (const float*)d_in[7];
  const float* b_vfp = (const float*)d_in[8];
  const float* g_an  = (const float*)d_in[9];
  const float* be_an = (const float*)d_in[10];
  const float* g_vn  = (const float*)d_in[11];
  const float* be_vn = (const float*)d_in[12];
  const float* w_aqp = (const float*)d_in[13];
  const float* b_aqp = (const float*)d_in[14];
  const float* w_vqp = (const float*)d_in[15];
  const float* b_vqp = (const float*)d_in[16];
  const float* w_aq  = (const float*)d_in[17];
  const float* b_aq  = (const float*)d_in[18];
  const float* w_vq  = (const float*)d_in[19];
  const float* b_vq  = (const float*)d_in[20];
  const float* w_in  = (const float*)d_in[21];
  const float* b_in  = (const float*)d_in[22];
  const float* w_o   = (const float*)d_in[23];
  const float* b_o   = (const float*)d_in[24];
  const float* w_ao  = (const float*)d_in[25];
  const float* b_ao  = (const float*)d_in[26];
  const float* w_vo  = (const float*)d_in[27];
  const float* b_vo  = (const float*)d_in[28];

  float* out = (float*)d_out;
  float* ws  = (float*)d_ws;

  // ---- d_out scratch (dead until final writes; stream-ordered) ----
  unsigned short* vis_bf = (unsigned short*)(out);  // words [0,10485760)
  unsigned short* akn = (unsigned short*)(out + 10485760);  // [40][8][1024][16] bf16
  unsigned short* avn = akn + 5242880;
  unsigned short* vkn = akn + 10485760;
  unsigned short* vvn = akn + 15728640;   // region ends at word 20971520
  unsigned short* a_hm = (unsigned short*)(out + 20971520);  // bf16, written step 9
  unsigned short* v_hm = (unsigned short*)(out + 23592960);  // ends word 26214400
  float* aiq2_out = out + 41943040;
  float* audio_out = out;              // covers vis_bf+akn.. (dead by then)
  float* vis_out   = out + 20971520;   // covers a_hm/v_hm (dead by then)

  // ---- ws layout (f32-word offsets) ----
  unsigned short* WT       = (unsigned short*)(ws);            // [0, 262144)
  unsigned short* audio_bf = (unsigned short*)(ws + 262144);   // [.., 2883584)
  unsigned short* Q1hm     = (unsigned short*)(ws + 2883584);  // [8][8][1000][16] bf16
  unsigned short* saphm    = (unsigned short*)(ws + 3395584);  // [8][8][1000][16] bf16
  unsigned short* qkvhm    = (unsigned short*)(ws + 3915776);  // 3x[8][8][1000][16] bf16
  unsigned short* aatthm   = (unsigned short*)(ws + 3915776);  // overlays qkvhm
  unsigned short* vatthm   = (unsigned short*)(ws + 6987776);  // [40][8][1024][16] bf16
  float* SA                = ws + 9609216;                     // (8000,128) f32
  unsigned short* Ka = (unsigned short*)(ws + 10633216);  // [40][8][100][16] bf16
  unsigned short* Va = Ka + 512000;
  unsigned short* Kv = Ka + 1024000;
  unsigned short* Vv = Ka + 1536000;
  float* aqvq = ws + 12681216;  // (100,256) f32

  unsigned short* afp_t = WT + 0;
  unsigned short* vfp_t = WT + 32768;
  unsigned short* aq_t  = WT + 163840;
  unsigned short* vq_t  = WT + 180224;
  unsigned short* in_t  = WT + 245760;
  unsigned short* o_t   = WT + 294912;
  unsigned short* ao_t  = WT + 311296;
  unsigned short* vo_t  = WT + 376832;

  // 0. weight transpose+convert, activation convert
  wtrans_kernel<<<128, 256, 0, stream>>>(w_afp, afp_t, 128, 256);
  wtrans_kernel<<<512, 256, 0, stream>>>(w_vfp, vfp_t, 512, 256);
  wtrans_kernel<<<64,  256, 0, stream>>>(w_aq,  aq_t,  128, 128);
  wtrans_kernel<<<256, 256, 0, stream>>>(w_vq,  vq_t,  512, 128);
  wtrans_kernel<<<192, 256, 0, stream>>>(w_in,  in_t,  128, 384);
  wtrans_kernel<<<64,  256, 0, stream>>>(w_o,   o_t,   128, 128);
  wtrans_kernel<<<256, 256, 0, stream>>>(w_ao,  ao_t,  128, 512);
  wtrans_kernel<<<256, 256, 0, stream>>>(w_vo,  vo_t,  128, 512);
  cvt_kernel<<<2560,  256, 0, stream>>>(audio, audio_bf, 655360);
  cvt_kernel<<<10240, 256, 0, stream>>>(vis,   vis_bf,   2621440);

  // 1. iq_emb projection (f32)
  iqp_kernel<<<100, 256, 0, stream>>>(iq, w_iqp, b_iqp, aqvq);

  // 2. proj + fused LN -> head-major bf16 K/V split (EPI1, OBF)
  mfma_gemm<128, 256, 1, false, false, true><<<dim3(320, 1), 512, 0, stream>>>(
      audio_bf, afp_t, b_afp, g_an, be_an, nullptr, (float*)akn, 40960, 256, 0, 1024, 5242880);
  mfma_gemm<512, 256, 1, false, false, true><<<dim3(320, 1), 512, 0, stream>>>(
      vis_bf, vfp_t, b_vfp, g_vn, be_vn, nullptr, (float*)vkn, 40960, 256, 0, 1024, 5242880);

  // 3. stage-1 cross-attn (merged, 8-wave, K/V read once) -> Q1hm
  mattn1<<<dim3(1, 8, 80), 512, 0, stream>>>(aqvq, akn, avn, vkn, vvn, Q1hm);

  // 4. qkv = queries @ w_in + b_in (A head-major, out 3-part head-major bf16)
  mfma_gemm<128, 128, 2, false, true, true><<<dim3(63, 3), 256, 0, stream>>>(
      Q1hm, in_t, b_in, nullptr, nullptr, nullptr, (float*)qkvhm, 8000, 384, 1000, 1000, 1024000);

  // 5. self-attention (MFMA flash, bf16) -> saphm
  mattn<1><<<dim3(16, 8, 8), 256, 0, stream>>>(
      qkvhm, 128000, 16000, 16, qkvhm + 1024000, qkvhm + 2048000, 1000, 1000,
      saphm, 1000, nullptr);

  // 6. SA = sa_pre @ w_o + b_o (A head-major -> token-major f32)
  mfma_gemm<128, 128, 0, false, true, false><<<dim3(63, 1), 256, 0, stream>>>(
      saphm, o_t, b_o, nullptr, nullptr, nullptr, SA, 8000, 128, 1000, 0, 0);

  // 7. aiq2 output
  copy_aiq2_kernel<<<4000, 128, 0, stream>>>(SA, aiq2_out);

  // 8. kf/vf projections -> head-major bf16 K/V
  gemm_kv_kernel<128, 256, 16><<<250, 256, 0, stream>>>(SA, w_aqp, b_aqp, Ka, Va, 0);
  gemm_kv_kernel<128, 256, 16><<<250, 256, 0, stream>>>(SA, w_vqp, b_vqp, Kv, Vv, 100);

  // 9. _a / _v projections -> head-major bf16 (EPI2 OBF, 1 part)
  mfma_gemm<128, 128, 2, false, false, true><<<dim3(320, 1), 256, 0, stream>>>(
      audio_bf, aq_t, b_aq, nullptr, nullptr, nullptr, (float*)a_hm, 40960, 128, 0, 1024, 0);
  mfma_gemm<512, 128, 2, false, false, true><<<dim3(320, 1), 256, 0, stream>>>(
      vis_bf, vq_t, b_vq, nullptr, nullptr, nullptr, (float*)v_hm, 40960, 128, 0, 1024, 0);

  // 10. stage-3 cross-attn (bf16); audio fuses +audio resid
  mattn<2><<<dim3(16, 8, 40), 256, 0, stream>>>(
      a_hm, 131072, 16384, 16, Kv, Vv, 100, 1024, aatthm, 1024, audio);
  mattn<2><<<dim3(16, 8, 40), 256, 0, stream>>>(
      v_hm, 131072, 16384, 16, Ka, Va, 100, 1024, vatthm, 1024, nullptr);

  // 11. output projections (A head-major); w_vo fuses +vis residual
  mfma_gemm<128, 128, 0, false, true, false><<<dim3(320, 4), 256, 0, stream>>>(
      aatthm, ao_t, b_ao, nullptr, nullptr, nullptr, audio_out, 40960, 512, 1024, 0, 0);
  mfma_gemm<128, 128, 0, true, true, false><<<dim3(320, 4), 256, 0, stream>>>(
      vatthm, vo_t, b_vo, nullptr, nullptr, vis, vis_out, 40960, 512, 1024, 0, 0);
}

// Round 9
// 348.423 us; speedup vs baseline: 4.7122x; 1.1355x over previous
//
#include <hip/hip_runtime.h>

#define EPSF 1e-5f
#define SCALEF 0.25f   // hd=16 -> 16^-0.5

typedef __attribute__((ext_vector_type(8))) __bf16 bf16x8;
typedef __attribute__((ext_vector_type(8))) unsigned short sh8;
typedef __attribute__((ext_vector_type(4))) float f32x4;

__device__ __forceinline__ unsigned short f2bf(float f) {
  unsigned u = __float_as_uint(f);
  return (unsigned short)((u + 0x7FFFu + ((u >> 16) & 1u)) >> 16);
}
__device__ __forceinline__ unsigned pk2(float lo, float hi) {
  return (unsigned)f2bf(lo) | ((unsigned)f2bf(hi) << 16);
}
__device__ __forceinline__ float bf2f(unsigned short u) {
  return __uint_as_float((unsigned)u << 16);
}

// async global->LDS, 16B per lane; LDS dest = uniform base + lane*16
__device__ __forceinline__ void gll16(const void* g, void* l) {
  __builtin_amdgcn_global_load_lds((const __attribute__((address_space(1))) void*)g,
                                   (__attribute__((address_space(3))) void*)l,
                                   16, 0, 0);
}

// ---------------------------------------------------------------------------
// MFMA GEMM: C = A[M][K](bf16) x Wt[N][K](bf16)^T + bias
//  AHEAD: A stored head-major [B][8][ATPB][16] bf16
//  EPI 0: token-major f32 store (+POST residual; PBF: residual is bf16);
//         optional aiq2 dual-store (rows r with r%200<100 -> aiq2)
//  EPI 1: fused LayerNorm (Ntot=256) then head-major split-2 store
//  EPI 2: head-major split-(Ntot/128) store, part p -> C + p*CPS
//  OBF: EPI1/EPI2 store bf16 (CPS counted in bf16 elems)
// ---------------------------------------------------------------------------
template <int K, int BN, int EPI, bool POST, bool AHEAD, bool OBF, bool PBF>
__global__ __launch_bounds__(BN * 2) void mfma_gemm(
    const unsigned short* __restrict__ A, const unsigned short* __restrict__ Wt,
    const float* __restrict__ bias, const float* __restrict__ gg,
    const float* __restrict__ be, const float* __restrict__ post,
    float* __restrict__ C, int M, int Ntot, int ATPB, int CTPB, size_t CPS,
    float* __restrict__ aiq2) {
  constexpr int NW = BN / 32;   // waves per block
  constexpr int NCW = BN / 64;  // wave columns
  __shared__ __align__(16) unsigned short As[128 * 32];
  __shared__ __align__(16) unsigned short Bs[BN * 32];
  __shared__ float2 part[128][4];
  const int tid = threadIdx.x;
  const int wid = tid >> 6, lane = tid & 63;
  const int wr = wid / NCW, wc = wid % NCW;
  const int m0t = blockIdx.x * 128, n0t = blockIdx.y * BN;
  const int ir = lane >> 2, sl = lane & 3;   // staging: row-in-16, slot
  const int sg = lane >> 4, li = lane & 15;  // frags: k-group, row/col
  f32x4 acc[4][4];
#pragma unroll
  for (int i = 0; i < 4; i++)
#pragma unroll
    for (int j = 0; j < 4; j++) acc[i][j] = (f32x4){0.f, 0.f, 0.f, 0.f};
  constexpr int nIss = 8 + BN / 16;  // 1KB issues: 8 for A, BN/16 for B

  for (int k0 = 0; k0 < K; k0 += 32) {
    __syncthreads();
    for (int is = wid; is < nIss; is += NW) {
      if (is < 8) {
        int r = is * 16 + ir;
        int sp = sl ^ ((r >> 1) & 3);
        const unsigned short* gsrc;
        if (AHEAD) {
          int rg = m0t + r;
          if (rg >= M) rg = M - 1;
          int b = rg / ATPB, tok = rg - b * ATPB;
          int e = k0 + sp * 8;
          gsrc = A + ((((size_t)b * 8 + (e >> 4)) * ATPB + tok) << 4) + (e & 15);
        } else {
          gsrc = A + (size_t)(m0t + r) * K + k0 + sp * 8;
        }
        gll16(gsrc, (void*)&As[is * 512]);
      } else {
        int r = (is - 8) * 16 + ir;
        int sp = sl ^ ((r >> 1) & 3);
        gll16(Wt + (size_t)(n0t + r) * K + k0 + sp * 8, (void*)&Bs[(is - 8) * 512]);
      }
    }
    __syncthreads();
    bf16x8 af[4], bfr[4];
#pragma unroll
    for (int mi = 0; mi < 4; mi++) {
      int m = wr * 64 + mi * 16 + li;
      sh8 t = *(const sh8*)&As[m * 32 + ((sg ^ ((m >> 1) & 3)) << 3)];
      af[mi] = __builtin_bit_cast(bf16x8, t);
    }
#pragma unroll
    for (int ni = 0; ni < 4; ni++) {
      int n = wc * 64 + ni * 16 + li;
      sh8 t = *(const sh8*)&Bs[n * 32 + ((sg ^ ((n >> 1) & 3)) << 3)];
      bfr[ni] = __builtin_bit_cast(bf16x8, t);
    }
#pragma unroll
    for (int mi = 0; mi < 4; mi++)
#pragma unroll
      for (int ni = 0; ni < 4; ni++)
        acc[mi][ni] = __builtin_amdgcn_mfma_f32_16x16x32_bf16(af[mi], bfr[ni],
                                                              acc[mi][ni], 0, 0, 0);
  }

  float bv[4];
#pragma unroll
  for (int ni = 0; ni < 4; ni++) bv[ni] = bias[n0t + wc * 64 + ni * 16 + li];

  if constexpr (EPI == 1) {
#pragma unroll
    for (int mi = 0; mi < 4; mi++)
#pragma unroll
      for (int ni = 0; ni < 4; ni++)
#pragma unroll
        for (int r = 0; r < 4; r++) acc[mi][ni][r] += bv[ni];
#pragma unroll
    for (int mi = 0; mi < 4; mi++)
#pragma unroll
      for (int r = 0; r < 4; r++) {
        float s = acc[mi][0][r] + acc[mi][1][r] + acc[mi][2][r] + acc[mi][3][r];
        float q2 = acc[mi][0][r] * acc[mi][0][r] + acc[mi][1][r] * acc[mi][1][r] +
                   acc[mi][2][r] * acc[mi][2][r] + acc[mi][3][r] * acc[mi][3][r];
#pragma unroll
        for (int off = 1; off < 16; off <<= 1) {
          s += __shfl_xor(s, off);
          q2 += __shfl_xor(q2, off);
        }
        if (li == 0) part[wr * 64 + mi * 16 + sg * 4 + r][wc] = make_float2(s, q2);
      }
    __syncthreads();
    float gv[4], bev[4];
#pragma unroll
    for (int ni = 0; ni < 4; ni++) {
      int col = wc * 64 + ni * 16 + li;
      gv[ni] = gg[col];
      bev[ni] = be[col];
    }
#pragma unroll
    for (int mi = 0; mi < 4; mi++)
#pragma unroll
      for (int r = 0; r < 4; r++) {
        int mrow = wr * 64 + mi * 16 + sg * 4 + r;
        float2 p0 = part[mrow][0], p1 = part[mrow][1], p2 = part[mrow][2], p3 = part[mrow][3];
        float S = p0.x + p1.x + p2.x + p3.x;
        float Qq = p0.y + p1.y + p2.y + p3.y;
        float mean = S * (1.f / 256.f);
        float var = Qq * (1.f / 256.f) - mean * mean;
        float rstd = rsqrtf(var + EPSF);
        int mg = m0t + mrow;
        int b = mg / CTPB, tok = mg - b * CTPB;
#pragma unroll
        for (int ni = 0; ni < 4; ni++) {
          int col = wc * 64 + ni * 16 + li;
          float val = (acc[mi][ni][r] - mean) * rstd * gv[ni] + bev[ni];
          int half = col >> 7, h = (col >> 4) & 7, d = col & 15;
          size_t idx = ((((size_t)b * 8 + h) * CTPB + tok) << 4) + d;
          if (OBF) {
            unsigned short* dst = (unsigned short*)C + (half ? CPS : 0);
            dst[idx] = f2bf(val);
          } else {
            float* dst = half ? (C + CPS) : C;
            dst[idx] = val;
          }
        }
      }
  } else if constexpr (EPI == 2) {
#pragma unroll
    for (int mi = 0; mi < 4; mi++)
#pragma unroll
      for (int r = 0; r < 4; r++) {
        int mg = m0t + wr * 64 + mi * 16 + sg * 4 + r;
        if (mg < M) {
          int b = mg / CTPB, tok = mg - b * CTPB;
#pragma unroll
          for (int ni = 0; ni < 4; ni++) {
            int col = n0t + wc * 64 + ni * 16 + li;
            float v = acc[mi][ni][r] + bv[ni];
            int pt = col >> 7, h = (col >> 4) & 7, d = col & 15;
            size_t idx = ((((size_t)b * 8 + h) * CTPB + tok) << 4) + d;
            if (OBF)
              ((unsigned short*)C + (size_t)pt * CPS)[idx] = f2bf(v);
            else
              (C + (size_t)pt * CPS)[idx] = v;
          }
        }
      }
  } else {
#pragma unroll
    for (int mi = 0; mi < 4; mi++)
#pragma unroll
      for (int r = 0; r < 4; r++) {
        int mrow = m0t + wr * 64 + mi * 16 + sg * 4 + r;
        if (mrow < M) {
#pragma unroll
          for (int ni = 0; ni < 4; ni++) {
            int col = n0t + wc * 64 + ni * 16 + li;
            float v = acc[mi][ni][r] + bv[ni];
            if (POST) {
              if (PBF)
                v += bf2f(((const unsigned short*)post)[(size_t)mrow * Ntot + col]);
              else
                v += post[(size_t)mrow * Ntot + col];
            }
            C[(size_t)mrow * Ntot + col] = v;
            if (aiq2) {
              int fb = mrow / 200, wi2 = mrow % 200;
              if (wi2 < 100) aiq2[((size_t)fb * 100 + wi2) * Ntot + col] = v;
            }
          }
        }
      }
  }
}

// ---------------------------------------------------------------------------
// Stage-1 MFMA flash attention: both modalities, 8 waves, K/V staged once.
// (unchanged from R8 — verified)
// ---------------------------------------------------------------------------
__global__ __launch_bounds__(512) void mattn1(
    const float* __restrict__ aqvq,
    const unsigned short* __restrict__ akn, const unsigned short* __restrict__ avn,
    const unsigned short* __restrict__ vkn, const unsigned short* __restrict__ vvn,
    unsigned short* __restrict__ op) {
  __shared__ __align__(16) unsigned short Klds[64][24];
  __shared__ __align__(16) unsigned short VTlds[16][72];
  __shared__ __align__(16) unsigned short Plds[8][16][72];
  const int tid = threadIdx.x, wid = tid >> 6, lane = tid & 63;
  const int li = lane & 15, gr = lane >> 4;
  const int z = blockIdx.z, h = blockIdx.y;
  const int mod = z >= 40 ? 1 : 0;
  const int b = z - mod * 40;
  const int bh = b * 8 + h;
  const int qi = wid * 16 + li;
  const bool qact = qi < 100;
  const int qic = qact ? qi : 99;
  const float* qrow = aqvq + mod * 128 + (size_t)qic * 256 + h * 16;
  const unsigned short* kp = mod ? vkn : akn;
  const unsigned short* vp = mod ? vvn : avn;

  sh8 z8 = (sh8)0;
  bf16x8 qf = __builtin_bit_cast(bf16x8, z8);
  if (gr < 2) {
    const float4* q4 = (const float4*)(qrow + gr * 8);
    float4 qa = q4[0], qb = q4[1];
    sh8 tt;
    tt[0] = f2bf(qa.x); tt[1] = f2bf(qa.y); tt[2] = f2bf(qa.z); tt[3] = f2bf(qa.w);
    tt[4] = f2bf(qb.x); tt[5] = f2bf(qb.y); tt[6] = f2bf(qb.z); tt[7] = f2bf(qb.w);
    qf = __builtin_bit_cast(bf16x8, tt);
  }

  float mrun = -3e38f, lrun = 0.f;
  f32x4 acc = (f32x4){0.f, 0.f, 0.f, 0.f};
  const f32x4 zero4 = (f32x4){0.f, 0.f, 0.f, 0.f};
  const unsigned* Ku = (const unsigned*)(kp + (size_t)bh * 1024 * 16);
  const unsigned* Vu = (const unsigned*)(vp + (size_t)bh * 1024 * 16);
  const int skey = tid >> 3, sdb = tid & 7;

  for (int kb = 0; kb < 1024; kb += 64) {
    __syncthreads();
    unsigned kw = Ku[(size_t)(kb + skey) * 8 + sdb];
    unsigned vw = Vu[(size_t)(kb + skey) * 8 + sdb];
    *(unsigned*)&Klds[skey][sdb * 2] = kw;
    VTlds[sdb * 2 + 0][skey] = (unsigned short)(kw, vw & 0xffff);
    VTlds[sdb * 2 + 1][skey] = (unsigned short)(vw >> 16);
    __syncthreads();
    f32x4 st[4];
#pragma unroll
    for (int t = 0; t < 4; t++) {
      sh8 kk = *(const sh8*)&Klds[t * 16 + li][(gr & 1) * 8];
      st[t] = __builtin_amdgcn_mfma_f32_16x16x32_bf16(
          __builtin_bit_cast(bf16x8, kk), qf, zero4, 0, 0, 0);
    }
    float sv[4][4];
#pragma unroll
    for (int t = 0; t < 4; t++)
#pragma unroll
      for (int r = 0; r < 4; r++) sv[t][r] = st[t][r] * SCALEF;
    float bm = sv[0][0];
#pragma unroll
    for (int t = 0; t < 4; t++)
#pragma unroll
      for (int r = 0; r < 4; r++) bm = fmaxf(bm, sv[t][r]);
    bm = fmaxf(bm, __shfl_xor(bm, 16));
    bm = fmaxf(bm, __shfl_xor(bm, 32));
    float mnew = fmaxf(mrun, bm);
    float cf = __expf(mrun - mnew);
    mrun = mnew;
    lrun *= cf;
    acc[0] *= cf; acc[1] *= cf; acc[2] *= cf; acc[3] *= cf;
    float ls = 0.f;
    unsigned pw[4][2];
#pragma unroll
    for (int t = 0; t < 4; t++) {
      float p0 = __expf(sv[t][0] - mnew), p1 = __expf(sv[t][1] - mnew);
      float p2 = __expf(sv[t][2] - mnew), p3 = __expf(sv[t][3] - mnew);
      ls += (p0 + p1) + (p2 + p3);
      pw[t][0] = pk2(p0, p1);
      pw[t][1] = pk2(p2, p3);
    }
    ls += __shfl_xor(ls, 16);
    ls += __shfl_xor(ls, 32);
    lrun += ls;
#pragma unroll
    for (int t = 0; t < 4; t++)
      *(uint2*)&Plds[wid][li][t * 16 + gr * 4] = make_uint2(pw[t][0], pw[t][1]);
#pragma unroll
    for (int hh = 0; hh < 2; hh++) {
      sh8 vt = *(const sh8*)&VTlds[li][hh * 32 + gr * 8];
      sh8 pt = *(const sh8*)&Plds[wid][li][hh * 32 + gr * 8];
      acc = __builtin_amdgcn_mfma_f32_16x16x32_bf16(
          __builtin_bit_cast(bf16x8, vt), __builtin_bit_cast(bf16x8, pt), acc, 0, 0, 0);
    }
  }
  float inv = 1.f / lrun;
  float o[4];
#pragma unroll
  for (int r = 0; r < 4; r++) o[r] = acc[r] * inv;
  const float4* q4 = (const float4*)(qrow + gr * 4);
  float4 qv = q4[0];
  o[0] += qv.x; o[1] += qv.y; o[2] += qv.z; o[3] += qv.w;
  if (qact) {
    int obh = (b / 5) * 8 + h;
    int otok = (b % 5) * 200 + mod * 100 + qi;
    *(uint2*)(op + (((size_t)obh * 1000 + otok) << 4) + gr * 4) =
        make_uint2(pk2(o[0], o[1]), pk2(o[2], o[3]));
  }
}

// ---------------------------------------------------------------------------
// 8-wave (512-thread) MFMA flash attention, bf16 head-major operands.
// MODE 1: single stream (SA): q0/k0/v0/o0, b = blockIdx.z.
// MODE 2: merged modalities (stage-3): z<40 -> stream0 (+bf16 token-major
//         residual), z>=40 -> stream1.
// ---------------------------------------------------------------------------
template <int MODE>
__global__ __launch_bounds__(512) void mattn8(
    const unsigned short* __restrict__ q0s, const unsigned short* __restrict__ q1s,
    size_t qsb, size_t qsh, int qsr,
    const unsigned short* __restrict__ k0s, const unsigned short* __restrict__ v0s,
    const unsigned short* __restrict__ k1s, const unsigned short* __restrict__ v1s,
    int nk, int nq, unsigned short* __restrict__ o0s, unsigned short* __restrict__ o1s,
    int OTPB, const unsigned short* __restrict__ residbf) {
  __shared__ __align__(16) unsigned short Klds[64][24];
  __shared__ __align__(16) unsigned short VTlds[16][72];
  __shared__ __align__(16) unsigned short Plds[8][16][72];
  const int tid = threadIdx.x, wid = tid >> 6, lane = tid & 63;
  const int li = lane & 15, gr = lane >> 4;
  const int z = blockIdx.z, h = blockIdx.y;
  int mod = 0, b = z;
  const unsigned short *qp = q0s, *kp = k0s, *vp = v0s;
  unsigned short* op = o0s;
  if (MODE == 2) {
    mod = z >= 40 ? 1 : 0;
    b = z - mod * 40;
    if (mod) { qp = q1s; kp = k1s; vp = v1s; op = o1s; }
  }
  const int bh = b * 8 + h;
  const int qi = blockIdx.x * 128 + wid * 16 + li;
  const bool qact = qi < nq;
  const int qic = qact ? qi : nq - 1;
  const unsigned short* qrow = qp + b * qsb + h * qsh + (size_t)qic * qsr;

  sh8 z8 = (sh8)0;
  bf16x8 qf = __builtin_bit_cast(bf16x8, z8);
  if (gr < 2) qf = __builtin_bit_cast(bf16x8, *(const sh8*)(qrow + gr * 8));

  float mrun = -3e38f, lrun = 0.f;
  f32x4 acc = (f32x4){0.f, 0.f, 0.f, 0.f};
  const f32x4 zero4 = (f32x4){0.f, 0.f, 0.f, 0.f};
  const unsigned* Ku = (const unsigned*)(kp + (size_t)bh * nk * 16);
  const unsigned* Vu = (const unsigned*)(vp + (size_t)bh * nk * 16);
  const int skey = tid >> 3, sdb = tid & 7;

  for (int kb = 0; kb < nk; kb += 64) {
    __syncthreads();
    int gk = kb + skey;
    bool ok = gk < nk;
    unsigned kw = ok ? Ku[(size_t)gk * 8 + sdb] : 0u;
    unsigned vw = ok ? Vu[(size_t)gk * 8 + sdb] : 0u;
    *(unsigned*)&Klds[skey][sdb * 2] = kw;
    VTlds[sdb * 2 + 0][skey] = (unsigned short)(vw & 0xffff);
    VTlds[sdb * 2 + 1][skey] = (unsigned short)(vw >> 16);
    __syncthreads();
    f32x4 st[4];
#pragma unroll
    for (int t = 0; t < 4; t++) {
      sh8 kk = *(const sh8*)&Klds[t * 16 + li][(gr & 1) * 8];
      st[t] = __builtin_amdgcn_mfma_f32_16x16x32_bf16(
          __builtin_bit_cast(bf16x8, kk), qf, zero4, 0, 0, 0);
    }
    float sv[4][4];
#pragma unroll
    for (int t = 0; t < 4; t++)
#pragma unroll
      for (int r = 0; r < 4; r++) sv[t][r] = st[t][r] * SCALEF;
    if (kb + 64 > nk) {
#pragma unroll
      for (int t = 0; t < 4; t++) {
        int kbase = kb + t * 16 + gr * 4;
#pragma unroll
        for (int r = 0; r < 4; r++)
          if (kbase + r >= nk) sv[t][r] = -1e30f;
      }
    }
    float bm = sv[0][0];
#pragma unroll
    for (int t = 0; t < 4; t++)
#pragma unroll
      for (int r = 0; r < 4; r++) bm = fmaxf(bm, sv[t][r]);
    bm = fmaxf(bm, __shfl_xor(bm, 16));
    bm = fmaxf(bm, __shfl_xor(bm, 32));
    float mnew = fmaxf(mrun, bm);
    float cf = __expf(mrun - mnew);
    mrun = mnew;
    lrun *= cf;
    acc[0] *= cf; acc[1] *= cf; acc[2] *= cf; acc[3] *= cf;
    float ls = 0.f;
    unsigned pw[4][2];
#pragma unroll
    for (int t = 0; t < 4; t++) {
      float p0 = __expf(sv[t][0] - mnew), p1 = __expf(sv[t][1] - mnew);
      float p2 = __expf(sv[t][2] - mnew), p3 = __expf(sv[t][3] - mnew);
      ls += (p0 + p1) + (p2 + p3);
      pw[t][0] = pk2(p0, p1);
      pw[t][1] = pk2(p2, p3);
    }
    ls += __shfl_xor(ls, 16);
    ls += __shfl_xor(ls, 32);
    lrun += ls;
#pragma unroll
    for (int t = 0; t < 4; t++)
      *(uint2*)&Plds[wid][li][t * 16 + gr * 4] = make_uint2(pw[t][0], pw[t][1]);
#pragma unroll
    for (int hh = 0; hh < 2; hh++) {
      sh8 vt = *(const sh8*)&VTlds[li][hh * 32 + gr * 8];
      sh8 pt = *(const sh8*)&Plds[wid][li][hh * 32 + gr * 8];
      acc = __builtin_amdgcn_mfma_f32_16x16x32_bf16(
          __builtin_bit_cast(bf16x8, vt), __builtin_bit_cast(bf16x8, pt), acc, 0, 0, 0);
    }
  }
  float inv = 1.f / lrun;
  float o[4];
#pragma unroll
  for (int r = 0; r < 4; r++) o[r] = acc[r] * inv;
  if (MODE == 2 && mod == 0 && residbf) {
    uint2 rv = *(const uint2*)(residbf + ((size_t)b * 1024 + qic) * 128 + h * 16 + gr * 4);
    o[0] += bf2f((unsigned short)(rv.x & 0xffff));
    o[1] += bf2f((unsigned short)(rv.x >> 16));
    o[2] += bf2f((unsigned short)(rv.y & 0xffff));
    o[3] += bf2f((unsigned short)(rv.y >> 16));
  }
  if (qact) {
    *(uint2*)(op + (((size_t)bh * OTPB + qi) << 4) + gr * 4) =
        make_uint2(pk2(o[0], o[1]), pk2(o[2], o[3]));
  }
}

// ---------------------------------------------------------------------------
// Consolidated prep: cvt audio, cvt vis, 8 weight transposes, iqp projection.
// Block ranges: [0,2560) audio cvt, [2560,12800) vis cvt,
//               [12800,14528) wtrans, [14528,14628) iqp.
// ---------------------------------------------------------------------------
__global__ __launch_bounds__(256) void prep_kernel(
    const float* __restrict__ audio, const float* __restrict__ vis,
    const float* __restrict__ iq, const float* __restrict__ w_iqp,
    const float* __restrict__ b_iqp,
    const float* __restrict__ w_afp, const float* __restrict__ w_vfp,
    const float* __restrict__ w_aq, const float* __restrict__ w_vq,
    const float* __restrict__ w_in, const float* __restrict__ w_o,
    const float* __restrict__ w_ao, const float* __restrict__ w_vo,
    unsigned short* __restrict__ WT, unsigned short* __restrict__ audio_bf,
    unsigned short* __restrict__ vis_bf, float* __restrict__ aqvq) {
  __shared__ float row[128];
  const int g = blockIdx.x, tid = threadIdx.x;
  if (g < 12800) {
    const float* in = (g < 2560) ? audio : vis;
    unsigned short* outp = (g < 2560) ? audio_bf : vis_bf;
    int i = (g < 2560 ? g : g - 2560) * 256 + tid;
    float4 a = ((const float4*)in)[i * 2];
    float4 b = ((const float4*)in)[i * 2 + 1];
    uint4 o;
    o.x = pk2(a.x, a.y);
    o.y = pk2(a.z, a.w);
    o.z = pk2(b.x, b.y);
    o.w = pk2(b.z, b.w);
    ((uint4*)outp)[i] = o;
  } else if (g < 14528) {
    int lg = g - 12800;
    int K, N;
    const float* W;
    unsigned dst;
    if (lg < 128)       { K = 128; N = 256; W = w_afp; dst = 0; }
    else if (lg < 640)  { K = 512; N = 256; W = w_vfp; dst = 32768;  lg -= 128; }
    else if (lg < 704)  { K = 128; N = 128; W = w_aq;  dst = 163840; lg -= 640; }
    else if (lg < 960)  { K = 512; N = 128; W = w_vq;  dst = 180224; lg -= 704; }
    else if (lg < 1152) { K = 128; N = 384; W = w_in;  dst = 245760; lg -= 960; }
    else if (lg < 1216) { K = 128; N = 128; W = w_o;   dst = 294912; lg -= 1152; }
    else if (lg < 1472) { K = 128; N = 512; W = w_ao;  dst = 311296; lg -= 1216; }
    else                { K = 128; N = 512; W = w_vo;  dst = 376832; lg -= 1472; }
    int idx = lg * 256 + tid;
    if (idx < K * N) {
      int k = idx / N, n = idx - k * N;
      WT[dst + (size_t)n * K + k] = f2bf(W[idx]);
    }
  } else {
    int r = g - 14528;
    if (tid < 128) row[tid] = iq[r * 128 + tid];
    __syncthreads();
    float acc = b_iqp[tid];
#pragma unroll 8
    for (int k = 0; k < 128; ++k) acc += row[k] * w_iqp[k * 256 + tid];
    aqvq[r * 256 + tid] = acc;
  }
}

// ---------------------------------------------------------------------------
// fp32 row-blocked GEMM, gathered rows, head-major bf16 K/V split store.
// grid.y selects (W,bias,outK,outV,rowoff) pair: 0 -> aqp/Ka/Va/0,
// 1 -> vqp/Kv/Vv/100.
// ---------------------------------------------------------------------------
template <int K, int N, int R>
__global__ __launch_bounds__(N) void gemm_kv_kernel(
    const float* __restrict__ in,
    const float* __restrict__ Wa, const float* __restrict__ ba,
    const float* __restrict__ Wv, const float* __restrict__ bvv,
    unsigned short* __restrict__ Ka, unsigned short* __restrict__ Va,
    unsigned short* __restrict__ Kv, unsigned short* __restrict__ Vv) {
  __shared__ float rows[R][K];
  const int sel = blockIdx.y;
  const float* W = sel ? Wv : Wa;
  const float* bias = sel ? bvv : ba;
  unsigned short* outK = sel ? Kv : Ka;
  unsigned short* outV = sel ? Vv : Va;
  const int rowoff = sel ? 100 : 0;
  int r0 = blockIdx.x * R;
  for (int e = threadIdx.x; e < R * K; e += N) {
    int rr = e / K, k = e - rr * K;
    size_t r = r0 + rr;
    size_t irx = (r / 100) * 200 + rowoff + (r % 100);
    rows[rr][k] = in[irx * K + k];
  }
  __syncthreads();
  int c = threadIdx.x;
  float acc[R];
  float bb = bias[c];
#pragma unroll
  for (int rr = 0; rr < R; rr++) acc[rr] = bb;
  for (int k = 0; k < K; k += 4) {
    float w0 = W[(size_t)k * N + c];
    float w1 = W[(size_t)(k + 1) * N + c];
    float w2 = W[(size_t)(k + 2) * N + c];
    float w3 = W[(size_t)(k + 3) * N + c];
#pragma unroll
    for (int rr = 0; rr < R; rr++) {
      float4 r4 = *reinterpret_cast<const float4*>(&rows[rr][k]);
      acc[rr] = fmaf(r4.x, w0, acc[rr]);
      acc[rr] = fmaf(r4.y, w1, acc[rr]);
      acc[rr] = fmaf(r4.z, w2, acc[rr]);
      acc[rr] = fmaf(r4.w, w3, acc[rr]);
    }
  }
  int half = c >> 7, h = (c >> 4) & 7, d = c & 15;
  unsigned short* dst = half ? outV : outK;
#pragma unroll
  for (int rr = 0; rr < R; rr++) {
    int r = r0 + rr;
    int b = r / 100, tok = r - b * 100;
    dst[((((size_t)b * 8 + h) * 100 + tok) << 4) + d] = f2bf(acc[rr]);
  }
}

// ---------------------------------------------------------------------------
extern "C" void kernel_launch(void* const* d_in, const int* in_sizes, int n_in,
                              void* d_out, int out_size, void* d_ws, size_t ws_size,
                              hipStream_t stream) {
  const float* audio = (const float*)d_in[0];   // (40,1024,128)
  const float* vis   = (const float*)d_in[1];   // (40,1024,512)
  const float* iq    = (const float*)d_in[2];
  const float* w_iqp = (const float*)d_in[3];
  const float* b_iqp = (const float*)d_in[4];
  const float* w_afp = (const float*)d_in[5];
  const float* b_afp = (const float*)d_in[6];
  const float* w_vfp = (const float*)d_in[7];
  const float* b_vfp = (const float*)d_in[8];
  const float* g_an  = (const float*)d_in[9];
  const float* be_an = (const float*)d_in[10];
  const float* g_vn  = (const float*)d_in[11];
  const float* be_vn = (const float*)d_in[12];
  const float* w_aqp = (const float*)d_in[13];
  const float* b_aqp = (const float*)d_in[14];
  const float* w_vqp = (const float*)d_in[15];
  const float* b_vqp = (const float*)d_in[16];
  const float* w_aq  = (const float*)d_in[17];
  const float* b_aq  = (const float*)d_in[18];
  const float* w_vq  = (const float*)d_in[19];
  const float* b_vq  = (const float*)d_in[20];
  const float* w_in  = (const float*)d_in[21];
  const float* b_in  = (const float*)d_in[22];
  const float* w_o   = (const float*)d_in[23];
  const float* b_o   = (const float*)d_in[24];
  const float* w_ao  = (const float*)d_in[25];
  const float* b_ao  = (const float*)d_in[26];
  const float* w_vo  = (const float*)d_in[27];
  const float* b_vo  = (const float*)d_in[28];

  float* out = (float*)d_out;
  float* ws  = (float*)d_ws;

  // ---- d_out scratch (dead until final writes; stream-ordered) ----
  unsigned short* vis_bf = (unsigned short*)(out);  // words [0,10485760)
  unsigned short* akn = (unsigned short*)(out + 10485760);  // [40][8][1024][16] bf16
  unsigned short* avn = akn + 5242880;
  unsigned short* vkn = akn + 10485760;
  unsigned short* vvn = akn + 15728640;   // region ends at word 20971520
  unsigned short* a_hm = (unsigned short*)(out + 20971520);  // bf16, written step 9
  unsigned short* v_hm = (unsigned short*)(out + 23592960);  // ends word 26214400
  float* aiq2_out = out + 41943040;
  float* audio_out = out;              // written LAST (covers vis_bf+akn..)
  float* vis_out   = out + 20971520;   // written before audio_out (covers a_hm/v_hm)

  // ---- ws layout (f32-word offsets) ----
  unsigned short* WT       = (unsigned short*)(ws);            // [0, 262144)
  unsigned short* audio_bf = (unsigned short*)(ws + 262144);   // [.., 2883584)
  unsigned short* Q1hm     = (unsigned short*)(ws + 2883584);  // [8][8][1000][16] bf16
  unsigned short* saphm    = (unsigned short*)(ws + 3395584);  // [8][8][1000][16] bf16
  unsigned short* qkvhm    = (unsigned short*)(ws + 3915776);  // 3x[8][8][1000][16] bf16
  unsigned short* aatthm   = (unsigned short*)(ws + 3915776);  // overlays qkvhm
  unsigned short* vatthm   = (unsigned short*)(ws + 6987776);  // [40][8][1024][16] bf16
  float* SA                = ws + 9609216;                     // (8000,128) f32
  unsigned short* Ka = (unsigned short*)(ws + 10633216);  // [40][8][100][16] bf16
  unsigned short* Va = Ka + 512000;
  unsigned short* Kv = Ka + 1024000;
  unsigned short* Vv = Ka + 1536000;
  float* aqvq = ws + 12681216;  // (100,256) f32

  unsigned short* ao_t = WT + 311296;
  unsigned short* vo_t = WT + 376832;
  unsigned short* afp_t = WT + 0;
  unsigned short* vfp_t = WT + 32768;
  unsigned short* aq_t  = WT + 163840;
  unsigned short* vq_t  = WT + 180224;
  unsigned short* in_t  = WT + 245760;
  unsigned short* o_t   = WT + 294912;

  // 1. consolidated prep (cvts + 8 wtrans + iqp)
  prep_kernel<<<14628, 256, 0, stream>>>(
      audio, vis, iq, w_iqp, b_iqp, w_afp, w_vfp, w_aq, w_vq, w_in, w_o, w_ao,
      w_vo, WT, audio_bf, vis_bf, aqvq);

  // 2. proj + fused LN -> head-major bf16 K/V split (EPI1, OBF)
  mfma_gemm<128, 256, 1, false, false, true, false><<<dim3(320, 1), 512, 0, stream>>>(
      audio_bf, afp_t, b_afp, g_an, be_an, nullptr, (float*)akn, 40960, 256, 0, 1024,
      5242880, nullptr);
  mfma_gemm<512, 256, 1, false, false, true, false><<<dim3(320, 1), 512, 0, stream>>>(
      vis_bf, vfp_t, b_vfp, g_vn, be_vn, nullptr, (float*)vkn, 40960, 256, 0, 1024,
      5242880, nullptr);

  // 3. stage-1 cross-attn (merged, 8-wave, K/V read once) -> Q1hm
  mattn1<<<dim3(1, 8, 80), 512, 0, stream>>>(aqvq, akn, avn, vkn, vvn, Q1hm);

  // 4. qkv = queries @ w_in + b_in (A head-major, out 3-part head-major bf16)
  mfma_gemm<128, 128, 2, false, true, true, false><<<dim3(63, 3), 256, 0, stream>>>(
      Q1hm, in_t, b_in, nullptr, nullptr, nullptr, (float*)qkvhm, 8000, 384, 1000, 1000,
      1024000, nullptr);

  // 5. self-attention (8-wave MFMA flash) -> saphm
  mattn8<1><<<dim3(8, 8, 8), 512, 0, stream>>>(
      qkvhm, nullptr, 128000, 16000, 16, qkvhm + 1024000, qkvhm + 2048000,
      nullptr, nullptr, 1000, 1000, saphm, nullptr, 1000, nullptr);

  // 6. SA = sa_pre @ w_o + b_o; fused aiq2 dual-store
  mfma_gemm<128, 128, 0, false, true, false, false><<<dim3(63, 1), 256, 0, stream>>>(
      saphm, o_t, b_o, nullptr, nullptr, nullptr, SA, 8000, 128, 1000, 0, 0, aiq2_out);

  // 7. kf/vf projections -> head-major bf16 K/V (merged)
  gemm_kv_kernel<128, 256, 16><<<dim3(250, 2), 256, 0, stream>>>(
      SA, w_aqp, b_aqp, w_vqp, b_vqp, Ka, Va, Kv, Vv);

  // 8. _a / _v projections -> head-major bf16 (EPI2 OBF, 1 part)
  mfma_gemm<128, 128, 2, false, false, true, false><<<dim3(320, 1), 256, 0, stream>>>(
      audio_bf, aq_t, b_aq, nullptr, nullptr, nullptr, (float*)a_hm, 40960, 128, 0, 1024,
      0, nullptr);
  mfma_gemm<512, 128, 2, false, false, true, false><<<dim3(320, 1), 256, 0, stream>>>(
      vis_bf, vq_t, b_vq, nullptr, nullptr, nullptr, (float*)v_hm, 40960, 128, 0, 1024,
      0, nullptr);

  // 9. stage-3 cross-attn merged (8-wave); audio side fuses +audio_bf resid
  mattn8<2><<<dim3(8, 8, 80), 512, 0, stream>>>(
      a_hm, v_hm, 131072, 16384, 16, Kv, Vv, Ka, Va, 100, 1024,
      aatthm, vatthm, 1024, audio_bf);

  // 10. vis_out first (reads vis_bf which audio_out will overwrite)
  mfma_gemm<128, 128, 0, true, true, false, true><<<dim3(320, 4), 256, 0, stream>>>(
      vatthm, vo_t, b_vo, nullptr, nullptr, (const float*)vis_bf, vis_out, 40960, 512,
      1024, 0, 0, nullptr);

  // 11. audio_out last
  mfma_gemm<128, 128, 0, false, true, false, false><<<dim3(320, 4), 256, 0, stream>>>(
      aatthm, ao_t, b_ao, nullptr, nullptr, nullptr, audio_out, 40960, 512, 1024, 0, 0,
      nullptr);
}

// Round 10
// 339.470 us; speedup vs baseline: 4.8365x; 1.0264x over previous
//
#include <hip/hip_runtime.h>

#define EPSF 1e-5f
#define SCALEF 0.25f   // hd=16 -> 16^-0.5

typedef __attribute__((ext_vector_type(8))) __bf16 bf16x8;
typedef __attribute__((ext_vector_type(8))) unsigned short sh8;
typedef __attribute__((ext_vector_type(4))) float f32x4;

__device__ __forceinline__ unsigned short f2bf(float f) {
  unsigned u = __float_as_uint(f);
  return (unsigned short)((u + 0x7FFFu + ((u >> 16) & 1u)) >> 16);
}
__device__ __forceinline__ unsigned pk2(float lo, float hi) {
  return (unsigned)f2bf(lo) | ((unsigned)f2bf(hi) << 16);
}
__device__ __forceinline__ float bf2f(unsigned short u) {
  return __uint_as_float((unsigned)u << 16);
}

// async global->LDS, 16B per lane; LDS dest = uniform base + lane*16
__device__ __forceinline__ void gll16(const void* g, void* l) {
  __builtin_amdgcn_global_load_lds((const __attribute__((address_space(1))) void*)g,
                                   (__attribute__((address_space(3))) void*)l,
                                   16, 0, 0);
}

// ---------------------------------------------------------------------------
// MFMA GEMM: C = A[M][K](bf16) x Wt[N][K](bf16)^T + bias
//  AHEAD: A stored head-major [B][8][ATPB][16] bf16
//  AF32:  A is f32 (Af32); staged via reg-convert; bf16 copy side-written to
//         Aside. Requires BN==256 (512 threads) and grid.y==1.
//  EPI 0: token-major f32 store (+POST residual; PBF: residual bf16);
//         optional aiq2 dual-store
//  EPI 1: fused LayerNorm (Ntot=256) then head-major split-2 store
//  EPI 2: head-major split-(Ntot/128) store, part p -> C + p*CPS
//  OBF: EPI1/EPI2 store bf16 (CPS counted in bf16 elems)
// ---------------------------------------------------------------------------
template <int K, int BN, int EPI, bool POST, bool AHEAD, bool OBF, bool PBF, bool AF32>
__global__ __launch_bounds__(BN * 2) void mfma_gemm(
    const unsigned short* __restrict__ A, const unsigned short* __restrict__ Wt,
    const float* __restrict__ bias, const float* __restrict__ gg,
    const float* __restrict__ be, const float* __restrict__ post,
    float* __restrict__ C, int M, int Ntot, int ATPB, int CTPB, size_t CPS,
    float* __restrict__ aiq2, const float* __restrict__ Af32,
    unsigned short* __restrict__ Aside) {
  constexpr int NW = BN / 32;   // waves per block
  constexpr int NCW = BN / 64;  // wave columns
  __shared__ __align__(16) unsigned short As[128 * 32];
  __shared__ __align__(16) unsigned short Bs[BN * 32];
  __shared__ float2 part[128][4];
  const int tid = threadIdx.x;
  const int wid = tid >> 6, lane = tid & 63;
  const int wr = wid / NCW, wc = wid % NCW;
  const int m0t = blockIdx.x * 128, n0t = blockIdx.y * BN;
  const int ir = lane >> 2, sl = lane & 3;   // staging: row-in-16, slot
  const int sg = lane >> 4, li = lane & 15;  // frags: k-group, row/col
  f32x4 acc[4][4];
#pragma unroll
  for (int i = 0; i < 4; i++)
#pragma unroll
    for (int j = 0; j < 4; j++) acc[i][j] = (f32x4){0.f, 0.f, 0.f, 0.f};
  constexpr int nIss = 8 + BN / 16;  // 1KB issues: 8 for A, BN/16 for B

  for (int k0 = 0; k0 < K; k0 += 32) {
    __syncthreads();
    if constexpr (AF32) {
      // A: reg-stage f32 -> bf16 (512 threads = 128 rows x 4 slots)
      int r = tid >> 2, slp = tid & 3;
      int sp = slp ^ ((r >> 1) & 3);
      const float4* src = (const float4*)(Af32 + (size_t)(m0t + r) * K + k0 + sp * 8);
      float4 aa = src[0], bb = src[1];
      uint4 w;
      w.x = pk2(aa.x, aa.y); w.y = pk2(aa.z, aa.w);
      w.z = pk2(bb.x, bb.y); w.w = pk2(bb.z, bb.w);
      *(uint4*)&As[r * 32 + slp * 8] = w;
      *(uint4*)(Aside + (size_t)(m0t + r) * K + k0 + sp * 8) = w;
      for (int is = 8 + wid; is < nIss; is += NW) {
        int r2 = (is - 8) * 16 + ir;
        int sp2 = sl ^ ((r2 >> 1) & 3);
        gll16(Wt + (size_t)(n0t + r2) * K + k0 + sp2 * 8, (void*)&Bs[(is - 8) * 512]);
      }
    } else {
      for (int is = wid; is < nIss; is += NW) {
        if (is < 8) {
          int r = is * 16 + ir;
          int sp = sl ^ ((r >> 1) & 3);
          const unsigned short* gsrc;
          if (AHEAD) {
            int rg = m0t + r;
            if (rg >= M) rg = M - 1;
            int b = rg / ATPB, tok = rg - b * ATPB;
            int e = k0 + sp * 8;
            gsrc = A + ((((size_t)b * 8 + (e >> 4)) * ATPB + tok) << 4) + (e & 15);
          } else {
            gsrc = A + (size_t)(m0t + r) * K + k0 + sp * 8;
          }
          gll16(gsrc, (void*)&As[is * 512]);
        } else {
          int r = (is - 8) * 16 + ir;
          int sp = sl ^ ((r >> 1) & 3);
          gll16(Wt + (size_t)(n0t + r) * K + k0 + sp * 8, (void*)&Bs[(is - 8) * 512]);
        }
      }
    }
    __syncthreads();
    bf16x8 af[4], bfr[4];
#pragma unroll
    for (int mi = 0; mi < 4; mi++) {
      int m = wr * 64 + mi * 16 + li;
      sh8 t = *(const sh8*)&As[m * 32 + ((sg ^ ((m >> 1) & 3)) << 3)];
      af[mi] = __builtin_bit_cast(bf16x8, t);
    }
#pragma unroll
    for (int ni = 0; ni < 4; ni++) {
      int n = wc * 64 + ni * 16 + li;
      sh8 t = *(const sh8*)&Bs[n * 32 + ((sg ^ ((n >> 1) & 3)) << 3)];
      bfr[ni] = __builtin_bit_cast(bf16x8, t);
    }
#pragma unroll
    for (int mi = 0; mi < 4; mi++)
#pragma unroll
      for (int ni = 0; ni < 4; ni++)
        acc[mi][ni] = __builtin_amdgcn_mfma_f32_16x16x32_bf16(af[mi], bfr[ni],
                                                              acc[mi][ni], 0, 0, 0);
  }

  float bv[4];
#pragma unroll
  for (int ni = 0; ni < 4; ni++) bv[ni] = bias[n0t + wc * 64 + ni * 16 + li];

  if constexpr (EPI == 1) {
#pragma unroll
    for (int mi = 0; mi < 4; mi++)
#pragma unroll
      for (int ni = 0; ni < 4; ni++)
#pragma unroll
        for (int r = 0; r < 4; r++) acc[mi][ni][r] += bv[ni];
#pragma unroll
    for (int mi = 0; mi < 4; mi++)
#pragma unroll
      for (int r = 0; r < 4; r++) {
        float s = acc[mi][0][r] + acc[mi][1][r] + acc[mi][2][r] + acc[mi][3][r];
        float q2 = acc[mi][0][r] * acc[mi][0][r] + acc[mi][1][r] * acc[mi][1][r] +
                   acc[mi][2][r] * acc[mi][2][r] + acc[mi][3][r] * acc[mi][3][r];
#pragma unroll
        for (int off = 1; off < 16; off <<= 1) {
          s += __shfl_xor(s, off);
          q2 += __shfl_xor(q2, off);
        }
        if (li == 0) part[wr * 64 + mi * 16 + sg * 4 + r][wc] = make_float2(s, q2);
      }
    __syncthreads();
    float gv[4], bev[4];
#pragma unroll
    for (int ni = 0; ni < 4; ni++) {
      int col = wc * 64 + ni * 16 + li;
      gv[ni] = gg[col];
      bev[ni] = be[col];
    }
#pragma unroll
    for (int mi = 0; mi < 4; mi++)
#pragma unroll
      for (int r = 0; r < 4; r++) {
        int mrow = wr * 64 + mi * 16 + sg * 4 + r;
        float2 p0 = part[mrow][0], p1 = part[mrow][1], p2 = part[mrow][2], p3 = part[mrow][3];
        float S = p0.x + p1.x + p2.x + p3.x;
        float Qq = p0.y + p1.y + p2.y + p3.y;
        float mean = S * (1.f / 256.f);
        float var = Qq * (1.f / 256.f) - mean * mean;
        float rstd = rsqrtf(var + EPSF);
        int mg = m0t + mrow;
        int b = mg / CTPB, tok = mg - b * CTPB;
#pragma unroll
        for (int ni = 0; ni < 4; ni++) {
          int col = wc * 64 + ni * 16 + li;
          float val = (acc[mi][ni][r] - mean) * rstd * gv[ni] + bev[ni];
          int half = col >> 7, h = (col >> 4) & 7, d = col & 15;
          size_t idx = ((((size_t)b * 8 + h) * CTPB + tok) << 4) + d;
          if (OBF) {
            unsigned short* dst = (unsigned short*)C + (half ? CPS : 0);
            dst[idx] = f2bf(val);
          } else {
            float* dst = half ? (C + CPS) : C;
            dst[idx] = val;
          }
        }
      }
  } else if constexpr (EPI == 2) {
#pragma unroll
    for (int mi = 0; mi < 4; mi++)
#pragma unroll
      for (int r = 0; r < 4; r++) {
        int mg = m0t + wr * 64 + mi * 16 + sg * 4 + r;
        if (mg < M) {
          int b = mg / CTPB, tok = mg - b * CTPB;
#pragma unroll
          for (int ni = 0; ni < 4; ni++) {
            int col = n0t + wc * 64 + ni * 16 + li;
            float v = acc[mi][ni][r] + bv[ni];
            int pt = col >> 7, h = (col >> 4) & 7, d = col & 15;
            size_t idx = ((((size_t)b * 8 + h) * CTPB + tok) << 4) + d;
            if (OBF)
              ((unsigned short*)C + (size_t)pt * CPS)[idx] = f2bf(v);
            else
              (C + (size_t)pt * CPS)[idx] = v;
          }
        }
      }
  } else {
#pragma unroll
    for (int mi = 0; mi < 4; mi++)
#pragma unroll
      for (int r = 0; r < 4; r++) {
        int mrow = m0t + wr * 64 + mi * 16 + sg * 4 + r;
        if (mrow < M) {
#pragma unroll
          for (int ni = 0; ni < 4; ni++) {
            int col = n0t + wc * 64 + ni * 16 + li;
            float v = acc[mi][ni][r] + bv[ni];
            if (POST) {
              if (PBF)
                v += bf2f(((const unsigned short*)post)[(size_t)mrow * Ntot + col]);
              else
                v += post[(size_t)mrow * Ntot + col];
            }
            C[(size_t)mrow * Ntot + col] = v;
            if (aiq2) {
              int fb = mrow / 200, wi2 = mrow % 200;
              if (wi2 < 100) aiq2[((size_t)fb * 100 + wi2) * Ntot + col] = v;
            }
          }
        }
      }
  }
}

// ---------------------------------------------------------------------------
// Stage-1 MFMA flash attention: both modalities, 8 waves, K/V staged once;
// K/V global loads prefetched one block ahead (latency hidden under compute).
// ---------------------------------------------------------------------------
__global__ __launch_bounds__(512) void mattn1(
    const float* __restrict__ aqvq,
    const unsigned short* __restrict__ akn, const unsigned short* __restrict__ avn,
    const unsigned short* __restrict__ vkn, const unsigned short* __restrict__ vvn,
    unsigned short* __restrict__ op) {
  __shared__ __align__(16) unsigned short Klds[64][24];
  __shared__ __align__(16) unsigned short VTlds[16][72];
  __shared__ __align__(16) unsigned short Plds[8][16][72];
  const int tid = threadIdx.x, wid = tid >> 6, lane = tid & 63;
  const int li = lane & 15, gr = lane >> 4;
  const int z = blockIdx.z, h = blockIdx.y;
  const int mod = z >= 40 ? 1 : 0;
  const int b = z - mod * 40;
  const int bh = b * 8 + h;
  const int qi = wid * 16 + li;
  const bool qact = qi < 100;
  const int qic = qact ? qi : 99;
  const float* qrow = aqvq + mod * 128 + (size_t)qic * 256 + h * 16;
  const unsigned short* kp = mod ? vkn : akn;
  const unsigned short* vp = mod ? vvn : avn;

  sh8 z8 = (sh8)0;
  bf16x8 qf = __builtin_bit_cast(bf16x8, z8);
  if (gr < 2) {
    const float4* q4 = (const float4*)(qrow + gr * 8);
    float4 qa = q4[0], qb = q4[1];
    sh8 tt;
    tt[0] = f2bf(qa.x); tt[1] = f2bf(qa.y); tt[2] = f2bf(qa.z); tt[3] = f2bf(qa.w);
    tt[4] = f2bf(qb.x); tt[5] = f2bf(qb.y); tt[6] = f2bf(qb.z); tt[7] = f2bf(qb.w);
    qf = __builtin_bit_cast(bf16x8, tt);
  }

  float mrun = -3e38f, lrun = 0.f;
  f32x4 acc = (f32x4){0.f, 0.f, 0.f, 0.f};
  const f32x4 zero4 = (f32x4){0.f, 0.f, 0.f, 0.f};
  const unsigned* Ku = (const unsigned*)(kp + (size_t)bh * 1024 * 16);
  const unsigned* Vu = (const unsigned*)(vp + (size_t)bh * 1024 * 16);
  const int skey = tid >> 3, sdb = tid & 7;

  unsigned kw = Ku[(size_t)skey * 8 + sdb];
  unsigned vw = Vu[(size_t)skey * 8 + sdb];
  for (int kb = 0; kb < 1024; kb += 64) {
    __syncthreads();
    *(unsigned*)&Klds[skey][sdb * 2] = kw;
    VTlds[sdb * 2 + 0][skey] = (unsigned short)(vw & 0xffff);
    VTlds[sdb * 2 + 1][skey] = (unsigned short)(vw >> 16);
    if (kb + 64 < 1024) {
      kw = Ku[(size_t)(kb + 64 + skey) * 8 + sdb];
      vw = Vu[(size_t)(kb + 64 + skey) * 8 + sdb];
    }
    __syncthreads();
    f32x4 st[4];
#pragma unroll
    for (int t = 0; t < 4; t++) {
      sh8 kk = *(const sh8*)&Klds[t * 16 + li][(gr & 1) * 8];
      st[t] = __builtin_amdgcn_mfma_f32_16x16x32_bf16(
          __builtin_bit_cast(bf16x8, kk), qf, zero4, 0, 0, 0);
    }
    float sv[4][4];
#pragma unroll
    for (int t = 0; t < 4; t++)
#pragma unroll
      for (int r = 0; r < 4; r++) sv[t][r] = st[t][r] * SCALEF;
    float bm = sv[0][0];
#pragma unroll
    for (int t = 0; t < 4; t++)
#pragma unroll
      for (int r = 0; r < 4; r++) bm = fmaxf(bm, sv[t][r]);
    bm = fmaxf(bm, __shfl_xor(bm, 16));
    bm = fmaxf(bm, __shfl_xor(bm, 32));
    float mnew = fmaxf(mrun, bm);
    float cf = __expf(mrun - mnew);
    mrun = mnew;
    lrun *= cf;
    acc[0] *= cf; acc[1] *= cf; acc[2] *= cf; acc[3] *= cf;
    float ls = 0.f;
    unsigned pw[4][2];
#pragma unroll
    for (int t = 0; t < 4; t++) {
      float p0 = __expf(sv[t][0] - mnew), p1 = __expf(sv[t][1] - mnew);
      float p2 = __expf(sv[t][2] - mnew), p3 = __expf(sv[t][3] - mnew);
      ls += (p0 + p1) + (p2 + p3);
      pw[t][0] = pk2(p0, p1);
      pw[t][1] = pk2(p2, p3);
    }
    ls += __shfl_xor(ls, 16);
    ls += __shfl_xor(ls, 32);
    lrun += ls;
#pragma unroll
    for (int t = 0; t < 4; t++)
      *(uint2*)&Plds[wid][li][t * 16 + gr * 4] = make_uint2(pw[t][0], pw[t][1]);
#pragma unroll
    for (int hh = 0; hh < 2; hh++) {
      sh8 vt = *(const sh8*)&VTlds[li][hh * 32 + gr * 8];
      sh8 pt = *(const sh8*)&Plds[wid][li][hh * 32 + gr * 8];
      acc = __builtin_amdgcn_mfma_f32_16x16x32_bf16(
          __builtin_bit_cast(bf16x8, vt), __builtin_bit_cast(bf16x8, pt), acc, 0, 0, 0);
    }
  }
  float inv = 1.f / lrun;
  float o[4];
#pragma unroll
  for (int r = 0; r < 4; r++) o[r] = acc[r] * inv;
  const float4* q4 = (const float4*)(qrow + gr * 4);
  float4 qv = q4[0];
  o[0] += qv.x; o[1] += qv.y; o[2] += qv.z; o[3] += qv.w;
  if (qact) {
    int obh = (b / 5) * 8 + h;
    int otok = (b % 5) * 200 + mod * 100 + qi;
    *(uint2*)(op + (((size_t)obh * 1000 + otok) << 4) + gr * 4) =
        make_uint2(pk2(o[0], o[1]), pk2(o[2], o[3]));
  }
}

// ---------------------------------------------------------------------------
// 8-wave (512-thread) MFMA flash attention, bf16 head-major operands,
// K/V global loads prefetched one block ahead.
// MODE 1: single stream (SA). MODE 2: merged modalities (stage-3), audio
// side (+bf16 token-major residual).
// ---------------------------------------------------------------------------
template <int MODE>
__global__ __launch_bounds__(512) void mattn8(
    const unsigned short* __restrict__ q0s, const unsigned short* __restrict__ q1s,
    size_t qsb, size_t qsh, int qsr,
    const unsigned short* __restrict__ k0s, const unsigned short* __restrict__ v0s,
    const unsigned short* __restrict__ k1s, const unsigned short* __restrict__ v1s,
    int nk, int nq, unsigned short* __restrict__ o0s, unsigned short* __restrict__ o1s,
    int OTPB, const unsigned short* __restrict__ residbf) {
  __shared__ __align__(16) unsigned short Klds[64][24];
  __shared__ __align__(16) unsigned short VTlds[16][72];
  __shared__ __align__(16) unsigned short Plds[8][16][72];
  const int tid = threadIdx.x, wid = tid >> 6, lane = tid & 63;
  const int li = lane & 15, gr = lane >> 4;
  const int z = blockIdx.z, h = blockIdx.y;
  int mod = 0, b = z;
  const unsigned short *qp = q0s, *kp = k0s, *vp = v0s;
  unsigned short* op = o0s;
  if (MODE == 2) {
    mod = z >= 40 ? 1 : 0;
    b = z - mod * 40;
    if (mod) { qp = q1s; kp = k1s; vp = v1s; op = o1s; }
  }
  const int bh = b * 8 + h;
  const int qi = blockIdx.x * 128 + wid * 16 + li;
  const bool qact = qi < nq;
  const int qic = qact ? qi : nq - 1;
  const unsigned short* qrow = qp + b * qsb + h * qsh + (size_t)qic * qsr;

  sh8 z8 = (sh8)0;
  bf16x8 qf = __builtin_bit_cast(bf16x8, z8);
  if (gr < 2) qf = __builtin_bit_cast(bf16x8, *(const sh8*)(qrow + gr * 8));

  float mrun = -3e38f, lrun = 0.f;
  f32x4 acc = (f32x4){0.f, 0.f, 0.f, 0.f};
  const f32x4 zero4 = (f32x4){0.f, 0.f, 0.f, 0.f};
  const unsigned* Ku = (const unsigned*)(kp + (size_t)bh * nk * 16);
  const unsigned* Vu = (const unsigned*)(vp + (size_t)bh * nk * 16);
  const int skey = tid >> 3, sdb = tid & 7;

  unsigned kw = (skey < nk) ? Ku[(size_t)skey * 8 + sdb] : 0u;
  unsigned vw = (skey < nk) ? Vu[(size_t)skey * 8 + sdb] : 0u;
  for (int kb = 0; kb < nk; kb += 64) {
    __syncthreads();
    *(unsigned*)&Klds[skey][sdb * 2] = kw;
    VTlds[sdb * 2 + 0][skey] = (unsigned short)(vw & 0xffff);
    VTlds[sdb * 2 + 1][skey] = (unsigned short)(vw >> 16);
    if (kb + 64 < nk) {
      int gk = kb + 64 + skey;
      kw = (gk < nk) ? Ku[(size_t)gk * 8 + sdb] : 0u;
      vw = (gk < nk) ? Vu[(size_t)gk * 8 + sdb] : 0u;
    }
    __syncthreads();
    f32x4 st[4];
#pragma unroll
    for (int t = 0; t < 4; t++) {
      sh8 kk = *(const sh8*)&Klds[t * 16 + li][(gr & 1) * 8];
      st[t] = __builtin_amdgcn_mfma_f32_16x16x32_bf16(
          __builtin_bit_cast(bf16x8, kk), qf, zero4, 0, 0, 0);
    }
    float sv[4][4];
#pragma unroll
    for (int t = 0; t < 4; t++)
#pragma unroll
      for (int r = 0; r < 4; r++) sv[t][r] = st[t][r] * SCALEF;
    if (kb + 64 > nk) {
#pragma unroll
      for (int t = 0; t < 4; t++) {
        int kbase = kb + t * 16 + gr * 4;
#pragma unroll
        for (int r = 0; r < 4; r++)
          if (kbase + r >= nk) sv[t][r] = -1e30f;
      }
    }
    float bm = sv[0][0];
#pragma unroll
    for (int t = 0; t < 4; t++)
#pragma unroll
      for (int r = 0; r < 4; r++) bm = fmaxf(bm, sv[t][r]);
    bm = fmaxf(bm, __shfl_xor(bm, 16));
    bm = fmaxf(bm, __shfl_xor(bm, 32));
    float mnew = fmaxf(mrun, bm);
    float cf = __expf(mrun - mnew);
    mrun = mnew;
    lrun *= cf;
    acc[0] *= cf; acc[1] *= cf; acc[2] *= cf; acc[3] *= cf;
    float ls = 0.f;
    unsigned pw[4][2];
#pragma unroll
    for (int t = 0; t < 4; t++) {
      float p0 = __expf(sv[t][0] - mnew), p1 = __expf(sv[t][1] - mnew);
      float p2 = __expf(sv[t][2] - mnew), p3 = __expf(sv[t][3] - mnew);
      ls += (p0 + p1) + (p2 + p3);
      pw[t][0] = pk2(p0, p1);
      pw[t][1] = pk2(p2, p3);
    }
    ls += __shfl_xor(ls, 16);
    ls += __shfl_xor(ls, 32);
    lrun += ls;
#pragma unroll
    for (int t = 0; t < 4; t++)
      *(uint2*)&Plds[wid][li][t * 16 + gr * 4] = make_uint2(pw[t][0], pw[t][1]);
#pragma unroll
    for (int hh = 0; hh < 2; hh++) {
      sh8 vt = *(const sh8*)&VTlds[li][hh * 32 + gr * 8];
      sh8 pt = *(const sh8*)&Plds[wid][li][hh * 32 + gr * 8];
      acc = __builtin_amdgcn_mfma_f32_16x16x32_bf16(
          __builtin_bit_cast(bf16x8, vt), __builtin_bit_cast(bf16x8, pt), acc, 0, 0, 0);
    }
  }
  float inv = 1.f / lrun;
  float o[4];
#pragma unroll
  for (int r = 0; r < 4; r++) o[r] = acc[r] * inv;
  if (MODE == 2 && mod == 0 && residbf) {
    uint2 rv = *(const uint2*)(residbf + ((size_t)b * 1024 + qic) * 128 + h * 16 + gr * 4);
    o[0] += bf2f((unsigned short)(rv.x & 0xffff));
    o[1] += bf2f((unsigned short)(rv.x >> 16));
    o[2] += bf2f((unsigned short)(rv.y & 0xffff));
    o[3] += bf2f((unsigned short)(rv.y >> 16));
  }
  if (qact) {
    *(uint2*)(op + (((size_t)bh * OTPB + qi) << 4) + gr * 4) =
        make_uint2(pk2(o[0], o[1]), pk2(o[2], o[3]));
  }
}

// ---------------------------------------------------------------------------
// Consolidated prep: 8 weight transposes + iqp projection.
// Block ranges: [0,1728) wtrans, [1728,1828) iqp.
// ---------------------------------------------------------------------------
__global__ __launch_bounds__(256) void prep_kernel(
    const float* __restrict__ iq, const float* __restrict__ w_iqp,
    const float* __restrict__ b_iqp,
    const float* __restrict__ w_afp, const float* __restrict__ w_vfp,
    const float* __restrict__ w_aq, const float* __restrict__ w_vq,
    const float* __restrict__ w_in, const float* __restrict__ w_o,
    const float* __restrict__ w_ao, const float* __restrict__ w_vo,
    unsigned short* __restrict__ WT, float* __restrict__ aqvq) {
  __shared__ float row[128];
  const int g = blockIdx.x, tid = threadIdx.x;
  if (g < 1728) {
    int lg = g;
    int K, N;
    const float* W;
    unsigned dst;
    if (lg < 128)       { K = 128; N = 256; W = w_afp; dst = 0; }
    else if (lg < 640)  { K = 512; N = 256; W = w_vfp; dst = 32768;  lg -= 128; }
    else if (lg < 704)  { K = 128; N = 128; W = w_aq;  dst = 163840; lg -= 640; }
    else if (lg < 960)  { K = 512; N = 128; W = w_vq;  dst = 180224; lg -= 704; }
    else if (lg < 1152) { K = 128; N = 384; W = w_in;  dst = 245760; lg -= 960; }
    else if (lg < 1216) { K = 128; N = 128; W = w_o;   dst = 294912; lg -= 1152; }
    else if (lg < 1472) { K = 128; N = 512; W = w_ao;  dst = 311296; lg -= 1216; }
    else                { K = 128; N = 512; W = w_vo;  dst = 376832; lg -= 1472; }
    int idx = lg * 256 + tid;
    if (idx < K * N) {
      int k = idx / N, n = idx - k * N;
      WT[dst + (size_t)n * K + k] = f2bf(W[idx]);
    }
  } else {
    int r = g - 1728;
    if (tid < 128) row[tid] = iq[r * 128 + tid];
    __syncthreads();
    float acc = b_iqp[tid];
#pragma unroll 8
    for (int k = 0; k < 128; ++k) acc += row[k] * w_iqp[k * 256 + tid];
    aqvq[r * 256 + tid] = acc;
  }
}

// ---------------------------------------------------------------------------
// fp32 row-blocked GEMM, gathered rows, head-major bf16 K/V split store.
// grid.y selects: 0 -> aqp/Ka/Va/rowoff 0, 1 -> vqp/Kv/Vv/rowoff 100.
// ---------------------------------------------------------------------------
template <int K, int N, int R>
__global__ __launch_bounds__(N) void gemm_kv_kernel(
    const float* __restrict__ in,
    const float* __restrict__ Wa, const float* __restrict__ ba,
    const float* __restrict__ Wv, const float* __restrict__ bvv,
    unsigned short* __restrict__ Ka, unsigned short* __restrict__ Va,
    unsigned short* __restrict__ Kv, unsigned short* __restrict__ Vv) {
  __shared__ float rows[R][K];
  const int sel = blockIdx.y;
  const float* W = sel ? Wv : Wa;
  const float* bias = sel ? bvv : ba;
  unsigned short* outK = sel ? Kv : Ka;
  unsigned short* outV = sel ? Vv : Va;
  const int rowoff = sel ? 100 : 0;
  int r0 = blockIdx.x * R;
  for (int e = threadIdx.x; e < R * K; e += N) {
    int rr = e / K, k = e - rr * K;
    size_t r = r0 + rr;
    size_t irx = (r / 100) * 200 + rowoff + (r % 100);
    rows[rr][k] = in[irx * K + k];
  }
  __syncthreads();
  int c = threadIdx.x;
  float acc[R];
  float bb = bias[c];
#pragma unroll
  for (int rr = 0; rr < R; rr++) acc[rr] = bb;
  for (int k = 0; k < K; k += 4) {
    float w0 = W[(size_t)k * N + c];
    float w1 = W[(size_t)(k + 1) * N + c];
    float w2 = W[(size_t)(k + 2) * N + c];
    float w3 = W[(size_t)(k + 3) * N + c];
#pragma unroll
    for (int rr = 0; rr < R; rr++) {
      float4 r4 = *reinterpret_cast<const float4*>(&rows[rr][k]);
      acc[rr] = fmaf(r4.x, w0, acc[rr]);
      acc[rr] = fmaf(r4.y, w1, acc[rr]);
      acc[rr] = fmaf(r4.z, w2, acc[rr]);
      acc[rr] = fmaf(r4.w, w3, acc[rr]);
    }
  }
  int half = c >> 7, h = (c >> 4) & 7, d = c & 15;
  unsigned short* dst = half ? outV : outK;
#pragma unroll
  for (int rr = 0; rr < R; rr++) {
    int r = r0 + rr;
    int b = r / 100, tok = r - b * 100;
    dst[((((size_t)b * 8 + h) * 100 + tok) << 4) + d] = f2bf(acc[rr]);
  }
}

// ---------------------------------------------------------------------------
extern "C" void kernel_launch(void* const* d_in, const int* in_sizes, int n_in,
                              void* d_out, int out_size, void* d_ws, size_t ws_size,
                              hipStream_t stream) {
  const float* audio = (const float*)d_in[0];   // (40,1024,128)
  const float* vis   = (const float*)d_in[1];   // (40,1024,512)
  const float* iq    = (const float*)d_in[2];
  const float* w_iqp = (const float*)d_in[3];
  const float* b_iqp = (const float*)d_in[4];
  const float* w_afp = (const float*)d_in[5];
  const float* b_afp = (const float*)d_in[6];
  const float* w_vfp = (const float*)d_in[7];
  const float* b_vfp = (const float*)d_in[8];
  const float* g_an  = (const float*)d_in[9];
  const float* be_an = (const float*)d_in[10];
  const float* g_vn  = (const float*)d_in[11];
  const float* be_vn = (const float*)d_in[12];
  const float* w_aqp = (const float*)d_in[13];
  const float* b_aqp = (const float*)d_in[14];
  const float* w_vqp = (const float*)d_in[15];
  const float* b_vqp = (const float*)d_in[16];
  const float* w_aq  = (const float*)d_in[17];
  const float* b_aq  = (const float*)d_in[18];
  const float* w_vq  = (const float*)d_in[19];
  const float* b_vq  = (const float*)d_in[20];
  const float* w_in  = (const float*)d_in[21];
  const float* b_in  = (const float*)d_in[22];
  const float* w_o   = (const float*)d_in[23];
  const float* b_o   = (const float*)d_in[24];
  const float* w_ao  = (const float*)d_in[25];
  const float* b_ao  = (const float*)d_in[26];
  const float* w_vo  = (const float*)d_in[27];
  const float* b_vo  = (const float*)d_in[28];

  float* out = (float*)d_out;
  float* ws  = (float*)d_ws;

  // ---- d_out scratch (dead until final writes; stream-ordered) ----
  unsigned short* vis_bf = (unsigned short*)(out);  // words [0,10485760)
  unsigned short* akn = (unsigned short*)(out + 10485760);  // [40][8][1024][16] bf16
  unsigned short* avn = akn + 5242880;
  unsigned short* vkn = akn + 10485760;
  unsigned short* vvn = akn + 15728640;   // region ends at word 20971520
  unsigned short* a_hm = (unsigned short*)(out + 20971520);  // bf16, written step 8
  unsigned short* v_hm = (unsigned short*)(out + 23592960);  // ends word 26214400
  float* aiq2_out = out + 41943040;
  float* audio_out = out;              // written LAST (covers vis_bf+akn..)
  float* vis_out   = out + 20971520;   // written before audio_out (covers a_hm/v_hm)

  // ---- ws layout (f32-word offsets) ----
  unsigned short* WT       = (unsigned short*)(ws);            // [0, 262144)
  unsigned short* audio_bf = (unsigned short*)(ws + 262144);   // [.., 2883584)
  unsigned short* Q1hm     = (unsigned short*)(ws + 2883584);  // [8][8][1000][16] bf16
  unsigned short* saphm    = (unsigned short*)(ws + 3395584);  // [8][8][1000][16] bf16
  unsigned short* qkvhm    = (unsigned short*)(ws + 3915776);  // 3x[8][8][1000][16] bf16
  unsigned short* aatthm   = (unsigned short*)(ws + 3915776);  // overlays qkvhm
  unsigned short* vatthm   = (unsigned short*)(ws + 6987776);  // [40][8][1024][16] bf16
  float* SA                = ws + 9609216;                     // (8000,128) f32
  unsigned short* Ka = (unsigned short*)(ws + 10633216);  // [40][8][100][16] bf16
  unsigned short* Va = Ka + 512000;
  unsigned short* Kv = Ka + 1024000;
  unsigned short* Vv = Ka + 1536000;
  float* aqvq = ws + 12681216;  // (100,256) f32

  unsigned short* afp_t = WT + 0;
  unsigned short* vfp_t = WT + 32768;
  unsigned short* aq_t  = WT + 163840;
  unsigned short* vq_t  = WT + 180224;
  unsigned short* in_t  = WT + 245760;
  unsigned short* o_t   = WT + 294912;
  unsigned short* ao_t  = WT + 311296;
  unsigned short* vo_t  = WT + 376832;

  // 1. consolidated prep (8 wtrans + iqp); cvts now fused into step 2
  prep_kernel<<<1828, 256, 0, stream>>>(
      iq, w_iqp, b_iqp, w_afp, w_vfp, w_aq, w_vq, w_in, w_o, w_ao, w_vo, WT, aqvq);

  // 2. proj + fused LN -> head-major bf16 K/V split (EPI1, OBF); A read as
  //    f32 with bf16 side-write to audio_bf / vis_bf (AF32)
  mfma_gemm<128, 256, 1, false, false, true, false, true><<<dim3(320, 1), 512, 0, stream>>>(
      nullptr, afp_t, b_afp, g_an, be_an, nullptr, (float*)akn, 40960, 256, 0, 1024,
      5242880, nullptr, audio, audio_bf);
  mfma_gemm<512, 256, 1, false, false, true, false, true><<<dim3(320, 1), 512, 0, stream>>>(
      nullptr, vfp_t, b_vfp, g_vn, be_vn, nullptr, (float*)vkn, 40960, 256, 0, 1024,
      5242880, nullptr, vis, vis_bf);

  // 3. stage-1 cross-attn (merged, 8-wave, K/V read once, prefetch) -> Q1hm
  mattn1<<<dim3(1, 8, 80), 512, 0, stream>>>(aqvq, akn, avn, vkn, vvn, Q1hm);

  // 4. qkv = queries @ w_in + b_in (A head-major, out 3-part head-major bf16)
  mfma_gemm<128, 128, 2, false, true, true, false, false><<<dim3(63, 3), 256, 0, stream>>>(
      Q1hm, in_t, b_in, nullptr, nullptr, nullptr, (float*)qkvhm, 8000, 384, 1000, 1000,
      1024000, nullptr, nullptr, nullptr);

  // 5. self-attention (8-wave MFMA flash, prefetch) -> saphm
  mattn8<1><<<dim3(8, 8, 8), 512, 0, stream>>>(
      qkvhm, nullptr, 128000, 16000, 16, qkvhm + 1024000, qkvhm + 2048000,
      nullptr, nullptr, 1000, 1000, saphm, nullptr, 1000, nullptr);

  // 6. SA = sa_pre @ w_o + b_o; fused aiq2 dual-store
  mfma_gemm<128, 128, 0, false, true, false, false, false><<<dim3(63, 1), 256, 0, stream>>>(
      saphm, o_t, b_o, nullptr, nullptr, nullptr, SA, 8000, 128, 1000, 0, 0, aiq2_out,
      nullptr, nullptr);

  // 7. kf/vf projections -> head-major bf16 K/V (merged)
  gemm_kv_kernel<128, 256, 16><<<dim3(250, 2), 256, 0, stream>>>(
      SA, w_aqp, b_aqp, w_vqp, b_vqp, Ka, Va, Kv, Vv);

  // 8. _a / _v projections -> head-major bf16 (EPI2 OBF, 1 part)
  mfma_gemm<128, 128, 2, false, false, true, false, false><<<dim3(320, 1), 256, 0, stream>>>(
      audio_bf, aq_t, b_aq, nullptr, nullptr, nullptr, (float*)a_hm, 40960, 128, 0, 1024,
      0, nullptr, nullptr, nullptr);
  mfma_gemm<512, 128, 2, false, false, true, false, false><<<dim3(320, 1), 256, 0, stream>>>(
      vis_bf, vq_t, b_vq, nullptr, nullptr, nullptr, (float*)v_hm, 40960, 128, 0, 1024,
      0, nullptr, nullptr, nullptr);

  // 9. stage-3 cross-attn merged (8-wave, prefetch); audio +audio_bf resid
  mattn8<2><<<dim3(8, 8, 80), 512, 0, stream>>>(
      a_hm, v_hm, 131072, 16384, 16, Kv, Vv, Ka, Va, 100, 1024,
      aatthm, vatthm, 1024, audio_bf);

  // 10. vis_out first (reads vis_bf which audio_out will overwrite)
  mfma_gemm<128, 128, 0, true, true, false, true, false><<<dim3(320, 4), 256, 0, stream>>>(
      vatthm, vo_t, b_vo, nullptr, nullptr, (const float*)vis_bf, vis_out, 40960, 512,
      1024, 0, 0, nullptr, nullptr, nullptr);

  // 11. audio_out last
  mfma_gemm<128, 128, 0, false, true, false, false, false><<<dim3(320, 4), 256, 0, stream>>>(
      aatthm, ao_t, b_ao, nullptr, nullptr, nullptr, audio_out, 40960, 512, 1024, 0, 0,
      nullptr, nullptr, nullptr);
}

// Round 11
// 291.891 us; speedup vs baseline: 5.6248x; 1.1630x over previous
//
#include <hip/hip_runtime.h>

#define EPSF 1e-5f
#define SCALEF 0.25f   // hd=16 -> 16^-0.5

typedef __attribute__((ext_vector_type(8))) __bf16 bf16x8;
typedef __attribute__((ext_vector_type(8))) unsigned short sh8;
typedef __attribute__((ext_vector_type(4))) float f32x4;

__device__ __forceinline__ unsigned short f2bf(float f) {
  return __builtin_bit_cast(unsigned short, (__bf16)f);
}
__device__ __forceinline__ unsigned pk2(float lo, float hi) {
  return (unsigned)f2bf(lo) | ((unsigned)f2bf(hi) << 16);
}
__device__ __forceinline__ float bf2f(unsigned short u) {
  return __uint_as_float((unsigned)u << 16);
}

// async global->LDS, 16B per lane; LDS dest = uniform base + lane*16
__device__ __forceinline__ void gll16(const void* g, void* l) {
  __builtin_amdgcn_global_load_lds((const __attribute__((address_space(1))) void*)g,
                                   (__attribute__((address_space(3))) void*)l,
                                   16, 0, 0);
}

// ---------------------------------------------------------------------------
// MFMA GEMM: C = A[M][K](bf16) x Wt[N][K](bf16)^T + bias
//  AHEAD: A stored head-major [B][8][ATPB][16] bf16
//  EPI 0: token-major f32 store (+POST residual; PBF: residual bf16);
//         optional aiq2 dual-store
//  EPI 2: head-major split-(Ntot/128) store, part p -> C + p*CPS
//  OBF: EPI2 stores bf16 (CPS counted in bf16 elems)
//  QSC: EPI2 scales part 0 by SCALEF before store (pre-scaled Q for attn)
// ---------------------------------------------------------------------------
template <int K, int BN, int EPI, bool POST, bool AHEAD, bool OBF, bool PBF, bool QSC>
__global__ __launch_bounds__(BN * 2) void mfma_gemm(
    const unsigned short* __restrict__ A, const unsigned short* __restrict__ Wt,
    const float* __restrict__ bias, const float* __restrict__ post,
    float* __restrict__ C, int M, int Ntot, int ATPB, int CTPB, size_t CPS,
    float* __restrict__ aiq2) {
  constexpr int NW = BN / 32;   // waves per block
  constexpr int NCW = BN / 64;  // wave columns
  __shared__ __align__(16) unsigned short As[128 * 32];
  __shared__ __align__(16) unsigned short Bs[BN * 32];
  const int tid = threadIdx.x;
  const int wid = tid >> 6, lane = tid & 63;
  const int wr = wid / NCW, wc = wid % NCW;
  const int m0t = blockIdx.x * 128, n0t = blockIdx.y * BN;
  const int ir = lane >> 2, sl = lane & 3;   // staging: row-in-16, slot
  const int sg = lane >> 4, li = lane & 15;  // frags: k-group, row/col
  f32x4 acc[4][4];
#pragma unroll
  for (int i = 0; i < 4; i++)
#pragma unroll
    for (int j = 0; j < 4; j++) acc[i][j] = (f32x4){0.f, 0.f, 0.f, 0.f};
  constexpr int nIss = 8 + BN / 16;

  for (int k0 = 0; k0 < K; k0 += 32) {
    __syncthreads();
    for (int is = wid; is < nIss; is += NW) {
      if (is < 8) {
        int r = is * 16 + ir;
        int sp = sl ^ ((r >> 1) & 3);
        const unsigned short* gsrc;
        if (AHEAD) {
          int rg = m0t + r;
          if (rg >= M) rg = M - 1;
          int b = rg / ATPB, tok = rg - b * ATPB;
          int e = k0 + sp * 8;
          gsrc = A + ((((size_t)b * 8 + (e >> 4)) * ATPB + tok) << 4) + (e & 15);
        } else {
          gsrc = A + (size_t)(m0t + r) * K + k0 + sp * 8;
        }
        gll16(gsrc, (void*)&As[is * 512]);
      } else {
        int r = (is - 8) * 16 + ir;
        int sp = sl ^ ((r >> 1) & 3);
        gll16(Wt + (size_t)(n0t + r) * K + k0 + sp * 8, (void*)&Bs[(is - 8) * 512]);
      }
    }
    __syncthreads();
    bf16x8 af[4], bfr[4];
#pragma unroll
    for (int mi = 0; mi < 4; mi++) {
      int m = wr * 64 + mi * 16 + li;
      sh8 t = *(const sh8*)&As[m * 32 + ((sg ^ ((m >> 1) & 3)) << 3)];
      af[mi] = __builtin_bit_cast(bf16x8, t);
    }
#pragma unroll
    for (int ni = 0; ni < 4; ni++) {
      int n = wc * 64 + ni * 16 + li;
      sh8 t = *(const sh8*)&Bs[n * 32 + ((sg ^ ((n >> 1) & 3)) << 3)];
      bfr[ni] = __builtin_bit_cast(bf16x8, t);
    }
#pragma unroll
    for (int mi = 0; mi < 4; mi++)
#pragma unroll
      for (int ni = 0; ni < 4; ni++)
        acc[mi][ni] = __builtin_amdgcn_mfma_f32_16x16x32_bf16(af[mi], bfr[ni],
                                                              acc[mi][ni], 0, 0, 0);
  }

  float bv[4];
#pragma unroll
  for (int ni = 0; ni < 4; ni++) bv[ni] = bias[n0t + wc * 64 + ni * 16 + li];

  if constexpr (EPI == 2) {
#pragma unroll
    for (int mi = 0; mi < 4; mi++)
#pragma unroll
      for (int r = 0; r < 4; r++) {
        int mg = m0t + wr * 64 + mi * 16 + sg * 4 + r;
        if (mg < M) {
          int b = mg / CTPB, tok = mg - b * CTPB;
#pragma unroll
          for (int ni = 0; ni < 4; ni++) {
            int col = n0t + wc * 64 + ni * 16 + li;
            float v = acc[mi][ni][r] + bv[ni];
            int pt = col >> 7, h = (col >> 4) & 7, d = col & 15;
            if (QSC && pt == 0) v *= SCALEF;
            size_t idx = ((((size_t)b * 8 + h) * CTPB + tok) << 4) + d;
            if (OBF)
              ((unsigned short*)C + (size_t)pt * CPS)[idx] = f2bf(v);
            else
              (C + (size_t)pt * CPS)[idx] = v;
          }
        }
      }
  } else {
#pragma unroll
    for (int mi = 0; mi < 4; mi++)
#pragma unroll
      for (int r = 0; r < 4; r++) {
        int mrow = m0t + wr * 64 + mi * 16 + sg * 4 + r;
        if (mrow < M) {
#pragma unroll
          for (int ni = 0; ni < 4; ni++) {
            int col = n0t + wc * 64 + ni * 16 + li;
            float v = acc[mi][ni][r] + bv[ni];
            if (POST) {
              if (PBF)
                v += bf2f(((const unsigned short*)post)[(size_t)mrow * Ntot + col]);
              else
                v += post[(size_t)mrow * Ntot + col];
            }
            C[(size_t)mrow * Ntot + col] = v;
            if (aiq2) {
              int fb = mrow / 200, wi2 = mrow % 200;
              if (wi2 < 100) aiq2[((size_t)fb * 100 + wi2) * Ntot + col] = v;
            }
          }
        }
      }
  }
}

// ---------------------------------------------------------------------------
// Merged proj+LN (audio z=0, vis z=1): A f32 reg-staged w/ bf16 side-write;
// fused LayerNorm; head-major bf16 K/V split store. 512 threads, (320,1,2).
// ---------------------------------------------------------------------------
__global__ __launch_bounds__(512) void ln_gemm(
    const float* __restrict__ audio, const float* __restrict__ vis,
    const unsigned short* __restrict__ afp_t, const unsigned short* __restrict__ vfp_t,
    const float* __restrict__ b_afp, const float* __restrict__ b_vfp,
    const float* __restrict__ g_an, const float* __restrict__ g_vn,
    const float* __restrict__ be_an, const float* __restrict__ be_vn,
    unsigned short* __restrict__ akn, unsigned short* __restrict__ vkn,
    unsigned short* __restrict__ audio_bf, unsigned short* __restrict__ vis_bf) {
  constexpr int BN = 256, NW = 8, NCW = 4;
  constexpr size_t CPS = 5242880;
  __shared__ __align__(16) unsigned short As[128 * 32];
  __shared__ __align__(16) unsigned short Bs[BN * 32];
  __shared__ float2 part[128][4];
  const int z = blockIdx.z;
  const float* Af32 = z ? vis : audio;
  const unsigned short* Wt = z ? vfp_t : afp_t;
  const float* bias = z ? b_vfp : b_afp;
  const float* gg = z ? g_vn : g_an;
  const float* be = z ? be_vn : be_an;
  unsigned short* C = z ? vkn : akn;
  unsigned short* Aside = z ? vis_bf : audio_bf;
  const int K = z ? 512 : 128;
  const int tid = threadIdx.x;
  const int wid = tid >> 6, lane = tid & 63;
  const int wr = wid / NCW, wc = wid % NCW;
  const int m0t = blockIdx.x * 128;
  const int ir = lane >> 2, sl = lane & 3;
  const int sg = lane >> 4, li = lane & 15;
  f32x4 acc[4][4];
#pragma unroll
  for (int i = 0; i < 4; i++)
#pragma unroll
    for (int j = 0; j < 4; j++) acc[i][j] = (f32x4){0.f, 0.f, 0.f, 0.f};

  for (int k0 = 0; k0 < K; k0 += 32) {
    __syncthreads();
    {
      int r = tid >> 2, slp = tid & 3;
      int sp = slp ^ ((r >> 1) & 3);
      const float4* src = (const float4*)(Af32 + (size_t)(m0t + r) * K + k0 + sp * 8);
      float4 aa = src[0], bb = src[1];
      uint4 w;
      w.x = pk2(aa.x, aa.y); w.y = pk2(aa.z, aa.w);
      w.z = pk2(bb.x, bb.y); w.w = pk2(bb.z, bb.w);
      *(uint4*)&As[r * 32 + slp * 8] = w;
      *(uint4*)(Aside + (size_t)(m0t + r) * K + k0 + sp * 8) = w;
    }
    for (int is = 8 + wid; is < 8 + BN / 16; is += NW) {
      int r2 = (is - 8) * 16 + ir;
      int sp2 = sl ^ ((r2 >> 1) & 3);
      gll16(Wt + (size_t)r2 * K + k0 + sp2 * 8, (void*)&Bs[(is - 8) * 512]);
    }
    __syncthreads();
    bf16x8 af[4], bfr[4];
#pragma unroll
    for (int mi = 0; mi < 4; mi++) {
      int m = wr * 64 + mi * 16 + li;
      sh8 t = *(const sh8*)&As[m * 32 + ((sg ^ ((m >> 1) & 3)) << 3)];
      af[mi] = __builtin_bit_cast(bf16x8, t);
    }
#pragma unroll
    for (int ni = 0; ni < 4; ni++) {
      int n = wc * 64 + ni * 16 + li;
      sh8 t = *(const sh8*)&Bs[n * 32 + ((sg ^ ((n >> 1) & 3)) << 3)];
      bfr[ni] = __builtin_bit_cast(bf16x8, t);
    }
#pragma unroll
    for (int mi = 0; mi < 4; mi++)
#pragma unroll
      for (int ni = 0; ni < 4; ni++)
        acc[mi][ni] = __builtin_amdgcn_mfma_f32_16x16x32_bf16(af[mi], bfr[ni],
                                                              acc[mi][ni], 0, 0, 0);
  }

  float bv[4];
#pragma unroll
  for (int ni = 0; ni < 4; ni++) bv[ni] = bias[wc * 64 + ni * 16 + li];
#pragma unroll
  for (int mi = 0; mi < 4; mi++)
#pragma unroll
    for (int ni = 0; ni < 4; ni++)
#pragma unroll
      for (int r = 0; r < 4; r++) acc[mi][ni][r] += bv[ni];
#pragma unroll
  for (int mi = 0; mi < 4; mi++)
#pragma unroll
    for (int r = 0; r < 4; r++) {
      float s = acc[mi][0][r] + acc[mi][1][r] + acc[mi][2][r] + acc[mi][3][r];
      float q2 = acc[mi][0][r] * acc[mi][0][r] + acc[mi][1][r] * acc[mi][1][r] +
                 acc[mi][2][r] * acc[mi][2][r] + acc[mi][3][r] * acc[mi][3][r];
#pragma unroll
      for (int off = 1; off < 16; off <<= 1) {
        s += __shfl_xor(s, off);
        q2 += __shfl_xor(q2, off);
      }
      if (li == 0) part[wr * 64 + mi * 16 + sg * 4 + r][wc] = make_float2(s, q2);
    }
  __syncthreads();
  float gv[4], bev[4];
#pragma unroll
  for (int ni = 0; ni < 4; ni++) {
    int col = wc * 64 + ni * 16 + li;
    gv[ni] = gg[col];
    bev[ni] = be[col];
  }
#pragma unroll
  for (int mi = 0; mi < 4; mi++)
#pragma unroll
    for (int r = 0; r < 4; r++) {
      int mrow = wr * 64 + mi * 16 + sg * 4 + r;
      float2 p0 = part[mrow][0], p1 = part[mrow][1], p2 = part[mrow][2], p3 = part[mrow][3];
      float S = p0.x + p1.x + p2.x + p3.x;
      float Qq = p0.y + p1.y + p2.y + p3.y;
      float mean = S * (1.f / 256.f);
      float var = Qq * (1.f / 256.f) - mean * mean;
      float rstd = rsqrtf(var + EPSF);
      int mg = m0t + mrow;
      int b = mg >> 10, tok = mg & 1023;
#pragma unroll
      for (int ni = 0; ni < 4; ni++) {
        int col = wc * 64 + ni * 16 + li;
        float val = (acc[mi][ni][r] - mean) * rstd * gv[ni] + bev[ni];
        int half = col >> 7, h = (col >> 4) & 7, d = col & 15;
        size_t idx = ((((size_t)b * 8 + h) * 1024 + tok) << 4) + d;
        (C + (half ? CPS : 0))[idx] = f2bf(val);
      }
    }
}

// ---------------------------------------------------------------------------
// Merged _a/_v projection (z=0 audio K=128, z=1 vis K=512): head-major bf16
// store PRE-SCALED by SCALEF (consumed as Q by stage-3). 256 thr, (320,1,2).
// ---------------------------------------------------------------------------
__global__ __launch_bounds__(256) void projq_kernel(
    const unsigned short* __restrict__ audio_bf, const unsigned short* __restrict__ vis_bf,
    const unsigned short* __restrict__ aq_t, const unsigned short* __restrict__ vq_t,
    const float* __restrict__ b_aq, const float* __restrict__ b_vq,
    unsigned short* __restrict__ a_hm, unsigned short* __restrict__ v_hm) {
  constexpr int BN = 128, NW = 4, NCW = 2;
  __shared__ __align__(16) unsigned short As[128 * 32];
  __shared__ __align__(16) unsigned short Bs[BN * 32];
  const int z = blockIdx.z;
  const unsigned short* A = z ? vis_bf : audio_bf;
  const unsigned short* Wt = z ? vq_t : aq_t;
  const float* bias = z ? b_vq : b_aq;
  unsigned short* C = z ? v_hm : a_hm;
  const int K = z ? 512 : 128;
  const int tid = threadIdx.x;
  const int wid = tid >> 6, lane = tid & 63;
  const int wr = wid / NCW, wc = wid % NCW;
  const int m0t = blockIdx.x * 128;
  const int ir = lane >> 2, sl = lane & 3;
  const int sg = lane >> 4, li = lane & 15;
  f32x4 acc[4][4];
#pragma unroll
  for (int i = 0; i < 4; i++)
#pragma unroll
    for (int j = 0; j < 4; j++) acc[i][j] = (f32x4){0.f, 0.f, 0.f, 0.f};

  for (int k0 = 0; k0 < K; k0 += 32) {
    __syncthreads();
    for (int is = wid; is < 8 + BN / 16; is += NW) {
      if (is < 8) {
        int r = is * 16 + ir;
        int sp = sl ^ ((r >> 1) & 3);
        gll16(A + (size_t)(m0t + r) * K + k0 + sp * 8, (void*)&As[is * 512]);
      } else {
        int r = (is - 8) * 16 + ir;
        int sp = sl ^ ((r >> 1) & 3);
        gll16(Wt + (size_t)r * K + k0 + sp * 8, (void*)&Bs[(is - 8) * 512]);
      }
    }
    __syncthreads();
    bf16x8 af[4], bfr[4];
#pragma unroll
    for (int mi = 0; mi < 4; mi++) {
      int m = wr * 64 + mi * 16 + li;
      sh8 t = *(const sh8*)&As[m * 32 + ((sg ^ ((m >> 1) & 3)) << 3)];
      af[mi] = __builtin_bit_cast(bf16x8, t);
    }
#pragma unroll
    for (int ni = 0; ni < 4; ni++) {
      int n = wc * 64 + ni * 16 + li;
      sh8 t = *(const sh8*)&Bs[n * 32 + ((sg ^ ((n >> 1) & 3)) << 3)];
      bfr[ni] = __builtin_bit_cast(bf16x8, t);
    }
#pragma unroll
    for (int mi = 0; mi < 4; mi++)
#pragma unroll
      for (int ni = 0; ni < 4; ni++)
        acc[mi][ni] = __builtin_amdgcn_mfma_f32_16x16x32_bf16(af[mi], bfr[ni],
                                                              acc[mi][ni], 0, 0, 0);
  }

  float bv[4];
#pragma unroll
  for (int ni = 0; ni < 4; ni++) bv[ni] = bias[wc * 64 + ni * 16 + li];
#pragma unroll
  for (int mi = 0; mi < 4; mi++)
#pragma unroll
    for (int r = 0; r < 4; r++) {
      int mg = m0t + wr * 64 + mi * 16 + sg * 4 + r;
      int b = mg >> 10, tok = mg & 1023;
#pragma unroll
      for (int ni = 0; ni < 4; ni++) {
        int col = wc * 64 + ni * 16 + li;
        float v = (acc[mi][ni][r] + bv[ni]) * SCALEF;
        int h = (col >> 4) & 7, d = col & 15;
        C[((((size_t)b * 8 + h) * 1024 + tok) << 4) + d] = f2bf(v);
      }
    }
}

// ---------------------------------------------------------------------------
// Stage-1 MFMA flash attention: both modalities, 8 waves, K/V staged once;
// prefetch one block ahead; Q pre-scaled at load; defer-max rescale.
// ---------------------------------------------------------------------------
__global__ __launch_bounds__(512) void mattn1(
    const float* __restrict__ aqvq,
    const unsigned short* __restrict__ akn, const unsigned short* __restrict__ avn,
    const unsigned short* __restrict__ vkn, const unsigned short* __restrict__ vvn,
    unsigned short* __restrict__ op) {
  __shared__ __align__(16) unsigned short Klds[64][24];
  __shared__ __align__(16) unsigned short VTlds[16][72];
  __shared__ __align__(16) unsigned short Plds[8][16][72];
  const int tid = threadIdx.x, wid = tid >> 6, lane = tid & 63;
  const int li = lane & 15, gr = lane >> 4;
  const int z = blockIdx.z, h = blockIdx.y;
  const int mod = z >= 40 ? 1 : 0;
  const int b = z - mod * 40;
  const int bh = b * 8 + h;
  const int qi = wid * 16 + li;
  const bool qact = qi < 100;
  const int qic = qact ? qi : 99;
  const float* qrow = aqvq + mod * 128 + (size_t)qic * 256 + h * 16;
  const unsigned short* kp = mod ? vkn : akn;
  const unsigned short* vp = mod ? vvn : avn;

  sh8 z8 = (sh8)0;
  bf16x8 qf = __builtin_bit_cast(bf16x8, z8);
  if (gr < 2) {
    const float4* q4 = (const float4*)(qrow + gr * 8);
    float4 qa = q4[0], qb = q4[1];
    sh8 tt;
    tt[0] = f2bf(qa.x * SCALEF); tt[1] = f2bf(qa.y * SCALEF);
    tt[2] = f2bf(qa.z * SCALEF); tt[3] = f2bf(qa.w * SCALEF);
    tt[4] = f2bf(qb.x * SCALEF); tt[5] = f2bf(qb.y * SCALEF);
    tt[6] = f2bf(qb.z * SCALEF); tt[7] = f2bf(qb.w * SCALEF);
    qf = __builtin_bit_cast(bf16x8, tt);
  }

  float mrun = -3e38f, lrun = 0.f;
  f32x4 acc = (f32x4){0.f, 0.f, 0.f, 0.f};
  const f32x4 zero4 = (f32x4){0.f, 0.f, 0.f, 0.f};
  const unsigned* Ku = (const unsigned*)(kp + (size_t)bh * 1024 * 16);
  const unsigned* Vu = (const unsigned*)(vp + (size_t)bh * 1024 * 16);
  const int skey = tid >> 3, sdb = tid & 7;

  unsigned kw = Ku[(size_t)skey * 8 + sdb];
  unsigned vw = Vu[(size_t)skey * 8 + sdb];
  for (int kb = 0; kb < 1024; kb += 64) {
    __syncthreads();
    *(unsigned*)&Klds[skey][sdb * 2] = kw;
    VTlds[sdb * 2 + 0][skey] = (unsigned short)(vw & 0xffff);
    VTlds[sdb * 2 + 1][skey] = (unsigned short)(vw >> 16);
    if (kb + 64 < 1024) {
      kw = Ku[(size_t)(kb + 64 + skey) * 8 + sdb];
      vw = Vu[(size_t)(kb + 64 + skey) * 8 + sdb];
    }
    __syncthreads();
    f32x4 st[4];
#pragma unroll
    for (int t = 0; t < 4; t++) {
      sh8 kk = *(const sh8*)&Klds[t * 16 + li][(gr & 1) * 8];
      st[t] = __builtin_amdgcn_mfma_f32_16x16x32_bf16(
          __builtin_bit_cast(bf16x8, kk), qf, zero4, 0, 0, 0);
    }
    float bm = st[0][0];
#pragma unroll
    for (int t = 0; t < 4; t++)
#pragma unroll
      for (int r = 0; r < 4; r++) bm = fmaxf(bm, st[t][r]);
    bm = fmaxf(bm, __shfl_xor(bm, 16));
    bm = fmaxf(bm, __shfl_xor(bm, 32));
    if (bm > mrun + 8.f) {  // defer-max rescale (T13)
      float cf = __expf(mrun - bm);
      lrun *= cf;
      acc[0] *= cf; acc[1] *= cf; acc[2] *= cf; acc[3] *= cf;
      mrun = bm;
    }
    float ls = 0.f;
    unsigned pw[4][2];
#pragma unroll
    for (int t = 0; t < 4; t++) {
      float p0 = __expf(st[t][0] - mrun), p1 = __expf(st[t][1] - mrun);
      float p2 = __expf(st[t][2] - mrun), p3 = __expf(st[t][3] - mrun);
      ls += (p0 + p1) + (p2 + p3);
      pw[t][0] = pk2(p0, p1);
      pw[t][1] = pk2(p2, p3);
    }
    ls += __shfl_xor(ls, 16);
    ls += __shfl_xor(ls, 32);
    lrun += ls;
#pragma unroll
    for (int t = 0; t < 4; t++)
      *(uint2*)&Plds[wid][li][t * 16 + gr * 4] = make_uint2(pw[t][0], pw[t][1]);
#pragma unroll
    for (int hh = 0; hh < 2; hh++) {
      sh8 vt = *(const sh8*)&VTlds[li][hh * 32 + gr * 8];
      sh8 pt = *(const sh8*)&Plds[wid][li][hh * 32 + gr * 8];
      acc = __builtin_amdgcn_mfma_f32_16x16x32_bf16(
          __builtin_bit_cast(bf16x8, vt), __builtin_bit_cast(bf16x8, pt), acc, 0, 0, 0);
    }
  }
  float inv = 1.f / lrun;
  float o[4];
#pragma unroll
  for (int r = 0; r < 4; r++) o[r] = acc[r] * inv;
  const float4* q4 = (const float4*)(qrow + gr * 4);
  float4 qv = q4[0];
  o[0] += qv.x; o[1] += qv.y; o[2] += qv.z; o[3] += qv.w;
  if (qact) {
    int obh = (b / 5) * 8 + h;
    int otok = (b % 5) * 200 + mod * 100 + qi;
    *(uint2*)(op + (((size_t)obh * 1000 + otok) << 4) + gr * 4) =
        make_uint2(pk2(o[0], o[1]), pk2(o[2], o[3]));
  }
}

// ---------------------------------------------------------------------------
// 8-wave MFMA flash attention, bf16 head-major operands, Q PRE-SCALED by
// producer, prefetch one block ahead, defer-max rescale.
// MODE 1: single stream (SA). MODE 2: merged modalities (stage-3), audio
// side (+bf16 token-major residual).
// ---------------------------------------------------------------------------
template <int MODE>
__global__ __launch_bounds__(512) void mattn8(
    const unsigned short* __restrict__ q0s, const unsigned short* __restrict__ q1s,
    size_t qsb, size_t qsh, int qsr,
    const unsigned short* __restrict__ k0s, const unsigned short* __restrict__ v0s,
    const unsigned short* __restrict__ k1s, const unsigned short* __restrict__ v1s,
    int nk, int nq, unsigned short* __restrict__ o0s, unsigned short* __restrict__ o1s,
    int OTPB, const unsigned short* __restrict__ residbf) {
  __shared__ __align__(16) unsigned short Klds[64][24];
  __shared__ __align__(16) unsigned short VTlds[16][72];
  __shared__ __align__(16) unsigned short Plds[8][16][72];
  const int tid = threadIdx.x, wid = tid >> 6, lane = tid & 63;
  const int li = lane & 15, gr = lane >> 4;
  const int z = blockIdx.z, h = blockIdx.y;
  int mod = 0, b = z;
  const unsigned short *qp = q0s, *kp = k0s, *vp = v0s;
  unsigned short* op = o0s;
  if (MODE == 2) {
    mod = z >= 40 ? 1 : 0;
    b = z - mod * 40;
    if (mod) { qp = q1s; kp = k1s; vp = v1s; op = o1s; }
  }
  const int bh = b * 8 + h;
  const int qi = blockIdx.x * 128 + wid * 16 + li;
  const bool qact = qi < nq;
  const int qic = qact ? qi : nq - 1;
  const unsigned short* qrow = qp + b * qsb + h * qsh + (size_t)qic * qsr;

  sh8 z8 = (sh8)0;
  bf16x8 qf = __builtin_bit_cast(bf16x8, z8);
  if (gr < 2) qf = __builtin_bit_cast(bf16x8, *(const sh8*)(qrow + gr * 8));

  float mrun = -3e38f, lrun = 0.f;
  f32x4 acc = (f32x4){0.f, 0.f, 0.f, 0.f};
  const f32x4 zero4 = (f32x4){0.f, 0.f, 0.f, 0.f};
  const unsigned* Ku = (const unsigned*)(kp + (size_t)bh * nk * 16);
  const unsigned* Vu = (const unsigned*)(vp + (size_t)bh * nk * 16);
  const int skey = tid >> 3, sdb = tid & 7;

  unsigned kw = (skey < nk) ? Ku[(size_t)skey * 8 + sdb] : 0u;
  unsigned vw = (skey < nk) ? Vu[(size_t)skey * 8 + sdb] : 0u;
  for (int kb = 0; kb < nk; kb += 64) {
    __syncthreads();
    *(unsigned*)&Klds[skey][sdb * 2] = kw;
    VTlds[sdb * 2 + 0][skey] = (unsigned short)(vw & 0xffff);
    VTlds[sdb * 2 + 1][skey] = (unsigned short)(vw >> 16);
    if (kb + 64 < nk) {
      int gk = kb + 64 + skey;
      kw = (gk < nk) ? Ku[(size_t)gk * 8 + sdb] : 0u;
      vw = (gk < nk) ? Vu[(size_t)gk * 8 + sdb] : 0u;
    }
    __syncthreads();
    f32x4 st[4];
#pragma unroll
    for (int t = 0; t < 4; t++) {
      sh8 kk = *(const sh8*)&Klds[t * 16 + li][(gr & 1) * 8];
      st[t] = __builtin_amdgcn_mfma_f32_16x16x32_bf16(
          __builtin_bit_cast(bf16x8, kk), qf, zero4, 0, 0, 0);
    }
    if (kb + 64 > nk) {
#pragma unroll
      for (int t = 0; t < 4; t++) {
        int kbase = kb + t * 16 + gr * 4;
#pragma unroll
        for (int r = 0; r < 4; r++)
          if (kbase + r >= nk) st[t][r] = -1e30f;
      }
    }
    float bm = st[0][0];
#pragma unroll
    for (int t = 0; t < 4; t++)
#pragma unroll
      for (int r = 0; r < 4; r++) bm = fmaxf(bm, st[t][r]);
    bm = fmaxf(bm, __shfl_xor(bm, 16));
    bm = fmaxf(bm, __shfl_xor(bm, 32));
    if (bm > mrun + 8.f) {  // defer-max rescale (T13)
      float cf = __expf(mrun - bm);
      lrun *= cf;
      acc[0] *= cf; acc[1] *= cf; acc[2] *= cf; acc[3] *= cf;
      mrun = bm;
    }
    float ls = 0.f;
    unsigned pw[4][2];
#pragma unroll
    for (int t = 0; t < 4; t++) {
      float p0 = __expf(st[t][0] - mrun), p1 = __expf(st[t][1] - mrun);
      float p2 = __expf(st[t][2] - mrun), p3 = __expf(st[t][3] - mrun);
      ls += (p0 + p1) + (p2 + p3);
      pw[t][0] = pk2(p0, p1);
      pw[t][1] = pk2(p2, p3);
    }
    ls += __shfl_xor(ls, 16);
    ls += __shfl_xor(ls, 32);
    lrun += ls;
#pragma unroll
    for (int t = 0; t < 4; t++)
      *(uint2*)&Plds[wid][li][t * 16 + gr * 4] = make_uint2(pw[t][0], pw[t][1]);
#pragma unroll
    for (int hh = 0; hh < 2; hh++) {
      sh8 vt = *(const sh8*)&VTlds[li][hh * 32 + gr * 8];
      sh8 pt = *(const sh8*)&Plds[wid][li][hh * 32 + gr * 8];
      acc = __builtin_amdgcn_mfma_f32_16x16x32_bf16(
          __builtin_bit_cast(bf16x8, vt), __builtin_bit_cast(bf16x8, pt), acc, 0, 0, 0);
    }
  }
  float inv = 1.f / lrun;
  float o[4];
#pragma unroll
  for (int r = 0; r < 4; r++) o[r] = acc[r] * inv;
  if (MODE == 2 && mod == 0 && residbf) {
    uint2 rv = *(const uint2*)(residbf + ((size_t)b * 1024 + qic) * 128 + h * 16 + gr * 4);
    o[0] += bf2f((unsigned short)(rv.x & 0xffff));
    o[1] += bf2f((unsigned short)(rv.x >> 16));
    o[2] += bf2f((unsigned short)(rv.y & 0xffff));
    o[3] += bf2f((unsigned short)(rv.y >> 16));
  }
  if (qact) {
    *(uint2*)(op + (((size_t)bh * OTPB + qi) << 4) + gr * 4) =
        make_uint2(pk2(o[0], o[1]), pk2(o[2], o[3]));
  }
}

// ---------------------------------------------------------------------------
// Consolidated prep: 8 weight transposes + iqp projection.
// ---------------------------------------------------------------------------
__global__ __launch_bounds__(256) void prep_kernel(
    const float* __restrict__ iq, const float* __restrict__ w_iqp,
    const float* __restrict__ b_iqp,
    const float* __restrict__ w_afp, const float* __restrict__ w_vfp,
    const float* __restrict__ w_aq, const float* __restrict__ w_vq,
    const float* __restrict__ w_in, const float* __restrict__ w_o,
    const float* __restrict__ w_ao, const float* __restrict__ w_vo,
    unsigned short* __restrict__ WT, float* __restrict__ aqvq) {
  __shared__ float row[128];
  const int g = blockIdx.x, tid = threadIdx.x;
  if (g < 1728) {
    int lg = g;
    int K, N;
    const float* W;
    unsigned dst;
    if (lg < 128)       { K = 128; N = 256; W = w_afp; dst = 0; }
    else if (lg < 640)  { K = 512; N = 256; W = w_vfp; dst = 32768;  lg -= 128; }
    else if (lg < 704)  { K = 128; N = 128; W = w_aq;  dst = 163840; lg -= 640; }
    else if (lg < 960)  { K = 512; N = 128; W = w_vq;  dst = 180224; lg -= 704; }
    else if (lg < 1152) { K = 128; N = 384; W = w_in;  dst = 245760; lg -= 960; }
    else if (lg < 1216) { K = 128; N = 128; W = w_o;   dst = 294912; lg -= 1152; }
    else if (lg < 1472) { K = 128; N = 512; W = w_ao;  dst = 311296; lg -= 1216; }
    else                { K = 128; N = 512; W = w_vo;  dst = 376832; lg -= 1472; }
    int idx = lg * 256 + tid;
    if (idx < K * N) {
      int k = idx / N, n = idx - k * N;
      WT[dst + (size_t)n * K + k] = f2bf(W[idx]);
    }
  } else {
    int r = g - 1728;
    if (tid < 128) row[tid] = iq[r * 128 + tid];
    __syncthreads();
    float acc = b_iqp[tid];
#pragma unroll 8
    for (int k = 0; k < 128; ++k) acc += row[k] * w_iqp[k * 256 + tid];
    aqvq[r * 256 + tid] = acc;
  }
}

// ---------------------------------------------------------------------------
// fp32 row-blocked GEMM, gathered rows, head-major bf16 K/V split store.
// ---------------------------------------------------------------------------
template <int K, int N, int R>
__global__ __launch_bounds__(N) void gemm_kv_kernel(
    const float* __restrict__ in,
    const float* __restrict__ Wa, const float* __restrict__ ba,
    const float* __restrict__ Wv, const float* __restrict__ bvv,
    unsigned short* __restrict__ Ka, unsigned short* __restrict__ Va,
    unsigned short* __restrict__ Kv, unsigned short* __restrict__ Vv) {
  __shared__ float rows[R][K];
  const int sel = blockIdx.y;
  const float* W = sel ? Wv : Wa;
  const float* bias = sel ? bvv : ba;
  unsigned short* outK = sel ? Kv : Ka;
  unsigned short* outV = sel ? Vv : Va;
  const int rowoff = sel ? 100 : 0;
  int r0 = blockIdx.x * R;
  for (int e = threadIdx.x; e < R * K; e += N) {
    int rr = e / K, k = e - rr * K;
    size_t r = r0 + rr;
    size_t irx = (r / 100) * 200 + rowoff + (r % 100);
    rows[rr][k] = in[irx * K + k];
  }
  __syncthreads();
  int c = threadIdx.x;
  float acc[R];
  float bb = bias[c];
#pragma unroll
  for (int rr = 0; rr < R; rr++) acc[rr] = bb;
  for (int k = 0; k < K; k += 4) {
    float w0 = W[(size_t)k * N + c];
    float w1 = W[(size_t)(k + 1) * N + c];
    float w2 = W[(size_t)(k + 2) * N + c];
    float w3 = W[(size_t)(k + 3) * N + c];
#pragma unroll
    for (int rr = 0; rr < R; rr++) {
      float4 r4 = *reinterpret_cast<const float4*>(&rows[rr][k]);
      acc[rr] = fmaf(r4.x, w0, acc[rr]);
      acc[rr] = fmaf(r4.y, w1, acc[rr]);
      acc[rr] = fmaf(r4.z, w2, acc[rr]);
      acc[rr] = fmaf(r4.w, w3, acc[rr]);
    }
  }
  int half = c >> 7, h = (c >> 4) & 7, d = c & 15;
  unsigned short* dst = half ? outV : outK;
#pragma unroll
  for (int rr = 0; rr < R; rr++) {
    int r = r0 + rr;
    int b = r / 100, tok = r - b * 100;
    dst[((((size_t)b * 8 + h) * 100 + tok) << 4) + d] = f2bf(acc[rr]);
  }
}

// ---------------------------------------------------------------------------
extern "C" void kernel_launch(void* const* d_in, const int* in_sizes, int n_in,
                              void* d_out, int out_size, void* d_ws, size_t ws_size,
                              hipStream_t stream) {
  const float* audio = (const float*)d_in[0];   // (40,1024,128)
  const float* vis   = (const float*)d_in[1];   // (40,1024,512)
  const float* iq    = (const float*)d_in[2];
  const float* w_iqp = (const float*)d_in[3];
  const float* b_iqp = (const float*)d_in[4];
  const float* w_afp = (const float*)d_in[5];
  const float* b_afp = (const float*)d_in[6];
  const float* w_vfp = (const float*)d_in[7];
  const float* b_vfp = (const float*)d_in[8];
  const float* g_an  = (const float*)d_in[9];
  const float* be_an = (const float*)d_in[10];
  const float* g_vn  = (const float*)d_in[11];
  const float* be_vn = (const float*)d_in[12];
  const float* w_aqp = (const float*)d_in[13];
  const float* b_aqp = (const float*)d_in[14];
  const float* w_vqp = (const float*)d_in[15];
  const float* b_vqp = (const float*)d_in[16];
  const float* w_aq  = (const float*)d_in[17];
  const float* b_aq  = (const float*)d_in[18];
  const float* w_vq  = (const float*)d_in[19];
  const float* b_vq  = (const float*)d_in[20];
  const float* w_in  = (const float*)d_in[21];
  const float* b_in  = (const float*)d_in[22];
  const float* w_o   = (const float*)d_in[23];
  const float* b_o   = (const float*)d_in[24];
  const float* w_ao  = (const float*)d_in[25];
  const float* b_ao  = (const float*)d_in[26];
  const float* w_vo  = (const float*)d_in[27];
  const float* b_vo  = (const float*)d_in[28];

  float* out = (float*)d_out;
  float* ws  = (float*)d_ws;

  // ---- d_out scratch (dead until final writes; stream-ordered) ----
  unsigned short* vis_bf = (unsigned short*)(out);  // words [0,10485760)
  unsigned short* akn = (unsigned short*)(out + 10485760);  // [40][8][1024][16] bf16
  unsigned short* avn = akn + 5242880;
  unsigned short* vkn = akn + 10485760;
  unsigned short* vvn = akn + 15728640;   // region ends at word 20971520
  unsigned short* a_hm = (unsigned short*)(out + 20971520);  // bf16, written step 8
  unsigned short* v_hm = (unsigned short*)(out + 23592960);  // ends word 26214400
  float* aiq2_out = out + 41943040;
  float* audio_out = out;              // written LAST
  float* vis_out   = out + 20971520;   // written before audio_out

  // ---- ws layout (f32-word offsets) ----
  unsigned short* WT       = (unsigned short*)(ws);            // [0, 262144)
  unsigned short* audio_bf = (unsigned short*)(ws + 262144);   // [.., 2883584)
  unsigned short* Q1hm     = (unsigned short*)(ws + 2883584);  // [8][8][1000][16] bf16
  unsigned short* saphm    = (unsigned short*)(ws + 3395584);  // [8][8][1000][16] bf16
  unsigned short* qkvhm    = (unsigned short*)(ws + 3915776);  // 3x[8][8][1000][16] bf16
  unsigned short* aatthm   = (unsigned short*)(ws + 3915776);  // overlays qkvhm
  unsigned short* vatthm   = (unsigned short*)(ws + 6987776);  // [40][8][1024][16] bf16
  float* SA                = ws + 9609216;                     // (8000,128) f32
  unsigned short* Ka = (unsigned short*)(ws + 10633216);  // [40][8][100][16] bf16
  unsigned short* Va = Ka + 512000;
  unsigned short* Kv = Ka + 1024000;
  unsigned short* Vv = Ka + 1536000;
  float* aqvq = ws + 12681216;  // (100,256) f32

  unsigned short* afp_t = WT + 0;
  unsigned short* vfp_t = WT + 32768;
  unsigned short* aq_t  = WT + 163840;
  unsigned short* vq_t  = WT + 180224;
  unsigned short* in_t  = WT + 245760;
  unsigned short* o_t   = WT + 294912;
  unsigned short* ao_t  = WT + 311296;
  unsigned short* vo_t  = WT + 376832;

  // 1. consolidated prep (8 wtrans + iqp)
  prep_kernel<<<1828, 256, 0, stream>>>(
      iq, w_iqp, b_iqp, w_afp, w_vfp, w_aq, w_vq, w_in, w_o, w_ao, w_vo, WT, aqvq);

  // 2. merged proj+LN (audio z=0, vis z=1) -> head-major bf16 K/V + side bf16
  ln_gemm<<<dim3(320, 1, 2), 512, 0, stream>>>(
      audio, vis, afp_t, vfp_t, b_afp, b_vfp, g_an, g_vn, be_an, be_vn,
      akn, vkn, audio_bf, vis_bf);

  // 3. stage-1 cross-attn (merged, 8-wave, K/V read once, prefetch) -> Q1hm
  mattn1<<<dim3(1, 8, 80), 512, 0, stream>>>(aqvq, akn, avn, vkn, vvn, Q1hm);

  // 4. qkv = queries @ w_in + b_in (head-major bf16; q part pre-scaled QSC)
  mfma_gemm<128, 128, 2, false, true, true, false, true><<<dim3(63, 3), 256, 0, stream>>>(
      Q1hm, in_t, b_in, nullptr, (float*)qkvhm, 8000, 384, 1000, 1000, 1024000, nullptr);

  // 5. self-attention (8-wave MFMA flash, prefetch, pre-scaled q) -> saphm
  mattn8<1><<<dim3(8, 8, 8), 512, 0, stream>>>(
      qkvhm, nullptr, 128000, 16000, 16, qkvhm + 1024000, qkvhm + 2048000,
      nullptr, nullptr, 1000, 1000, saphm, nullptr, 1000, nullptr);

  // 6. SA = sa_pre @ w_o + b_o; fused aiq2 dual-store
  mfma_gemm<128, 128, 0, false, true, false, false, false><<<dim3(63, 1), 256, 0, stream>>>(
      saphm, o_t, b_o, nullptr, SA, 8000, 128, 1000, 0, 0, aiq2_out);

  // 7. kf/vf projections -> head-major bf16 K/V (merged)
  gemm_kv_kernel<128, 256, 16><<<dim3(250, 2), 256, 0, stream>>>(
      SA, w_aqp, b_aqp, w_vqp, b_vqp, Ka, Va, Kv, Vv);

  // 8. merged _a/_v projections -> head-major bf16, PRE-SCALED (stage-3 Q)
  projq_kernel<<<dim3(320, 1, 2), 256, 0, stream>>>(
      audio_bf, vis_bf, aq_t, vq_t, b_aq, b_vq, a_hm, v_hm);

  // 9. stage-3 cross-attn merged (8-wave, prefetch); audio +audio_bf resid
  mattn8<2><<<dim3(8, 8, 80), 512, 0, stream>>>(
      a_hm, v_hm, 131072, 16384, 16, Kv, Vv, Ka, Va, 100, 1024,
      aatthm, vatthm, 1024, audio_bf);

  // 10. vis_out first (reads vis_bf which audio_out will overwrite)
  mfma_gemm<128, 128, 0, true, true, false, true, false><<<dim3(320, 4), 256, 0, stream>>>(
      vatthm, vo_t, b_vo, (const float*)vis_bf, vis_out, 40960, 512, 1024, 0, 0, nullptr);

  // 11. audio_out last
  mfma_gemm<128, 128, 0, false, true, false, false, false><<<dim3(320, 4), 256, 0, stream>>>(
      aatthm, ao_t, b_ao, nullptr, audio_out, 40960, 512, 1024, 0, 0, nullptr);
}

// Round 12
// 286.736 us; speedup vs baseline: 5.7259x; 1.0180x over previous
//
#include <hip/hip_runtime.h>

#define EPSF 1e-5f
#define SCALEF 0.25f   // hd=16 -> 16^-0.5

typedef __attribute__((ext_vector_type(8))) __bf16 bf16x8;
typedef __attribute__((ext_vector_type(8))) unsigned short sh8;
typedef __attribute__((ext_vector_type(4))) float f32x4;

__device__ __forceinline__ unsigned short f2bf(float f) {
  return __builtin_bit_cast(unsigned short, (__bf16)f);
}
__device__ __forceinline__ unsigned pk2(float lo, float hi) {
  return (unsigned)f2bf(lo) | ((unsigned)f2bf(hi) << 16);
}
__device__ __forceinline__ float bf2f(unsigned short u) {
  return __uint_as_float((unsigned)u << 16);
}

// async global->LDS, 16B per lane; LDS dest = uniform base + lane*16
__device__ __forceinline__ void gll16(const void* g, void* l) {
  __builtin_amdgcn_global_load_lds((const __attribute__((address_space(1))) void*)g,
                                   (__attribute__((address_space(3))) void*)l,
                                   16, 0, 0);
}

// ---------------------------------------------------------------------------
// MFMA GEMM: C = A[M][K](bf16) x Wt[N][K](bf16)^T + bias
//  AHEAD: A stored head-major [B][8][ATPB][16] bf16
//  EPI 0: token-major store (f32, or bf16 if CBF); optional aiq2 f32 dual-store
//  EPI 2: head-major split-(Ntot/128) store, part p -> C + p*CPS
//  OBF: EPI2 stores bf16 (CPS counted in bf16 elems)
//  QSC: EPI2 scales part 0 by SCALEF before store (pre-scaled Q for attn)
// ---------------------------------------------------------------------------
template <int K, int BN, int EPI, bool AHEAD, bool OBF, bool QSC, bool CBF>
__global__ __launch_bounds__(BN * 2) void mfma_gemm(
    const unsigned short* __restrict__ A, const unsigned short* __restrict__ Wt,
    const float* __restrict__ bias,
    float* __restrict__ C, int M, int Ntot, int ATPB, int CTPB, size_t CPS,
    float* __restrict__ aiq2) {
  constexpr int NW = BN / 32;   // waves per block
  constexpr int NCW = BN / 64;  // wave columns
  __shared__ __align__(16) unsigned short As[128 * 32];
  __shared__ __align__(16) unsigned short Bs[BN * 32];
  const int tid = threadIdx.x;
  const int wid = tid >> 6, lane = tid & 63;
  const int wr = wid / NCW, wc = wid % NCW;
  const int m0t = blockIdx.x * 128, n0t = blockIdx.y * BN;
  const int ir = lane >> 2, sl = lane & 3;   // staging: row-in-16, slot
  const int sg = lane >> 4, li = lane & 15;  // frags: k-group, row/col
  f32x4 acc[4][4];
#pragma unroll
  for (int i = 0; i < 4; i++)
#pragma unroll
    for (int j = 0; j < 4; j++) acc[i][j] = (f32x4){0.f, 0.f, 0.f, 0.f};
  constexpr int nIss = 8 + BN / 16;

  for (int k0 = 0; k0 < K; k0 += 32) {
    __syncthreads();
    for (int is = wid; is < nIss; is += NW) {
      if (is < 8) {
        int r = is * 16 + ir;
        int sp = sl ^ ((r >> 1) & 3);
        const unsigned short* gsrc;
        if (AHEAD) {
          int rg = m0t + r;
          if (rg >= M) rg = M - 1;
          int b = rg / ATPB, tok = rg - b * ATPB;
          int e = k0 + sp * 8;
          gsrc = A + ((((size_t)b * 8 + (e >> 4)) * ATPB + tok) << 4) + (e & 15);
        } else {
          gsrc = A + (size_t)(m0t + r) * K + k0 + sp * 8;
        }
        gll16(gsrc, (void*)&As[is * 512]);
      } else {
        int r = (is - 8) * 16 + ir;
        int sp = sl ^ ((r >> 1) & 3);
        gll16(Wt + (size_t)(n0t + r) * K + k0 + sp * 8, (void*)&Bs[(is - 8) * 512]);
      }
    }
    __syncthreads();
    bf16x8 af[4], bfr[4];
#pragma unroll
    for (int mi = 0; mi < 4; mi++) {
      int m = wr * 64 + mi * 16 + li;
      sh8 t = *(const sh8*)&As[m * 32 + ((sg ^ ((m >> 1) & 3)) << 3)];
      af[mi] = __builtin_bit_cast(bf16x8, t);
    }
#pragma unroll
    for (int ni = 0; ni < 4; ni++) {
      int n = wc * 64 + ni * 16 + li;
      sh8 t = *(const sh8*)&Bs[n * 32 + ((sg ^ ((n >> 1) & 3)) << 3)];
      bfr[ni] = __builtin_bit_cast(bf16x8, t);
    }
#pragma unroll
    for (int mi = 0; mi < 4; mi++)
#pragma unroll
      for (int ni = 0; ni < 4; ni++)
        acc[mi][ni] = __builtin_amdgcn_mfma_f32_16x16x32_bf16(af[mi], bfr[ni],
                                                              acc[mi][ni], 0, 0, 0);
  }

  float bv[4];
#pragma unroll
  for (int ni = 0; ni < 4; ni++) bv[ni] = bias[n0t + wc * 64 + ni * 16 + li];

  if constexpr (EPI == 2) {
#pragma unroll
    for (int mi = 0; mi < 4; mi++)
#pragma unroll
      for (int r = 0; r < 4; r++) {
        int mg = m0t + wr * 64 + mi * 16 + sg * 4 + r;
        if (mg < M) {
          int b = mg / CTPB, tok = mg - b * CTPB;
#pragma unroll
          for (int ni = 0; ni < 4; ni++) {
            int col = n0t + wc * 64 + ni * 16 + li;
            float v = acc[mi][ni][r] + bv[ni];
            int pt = col >> 7, h = (col >> 4) & 7, d = col & 15;
            if (QSC && pt == 0) v *= SCALEF;
            size_t idx = ((((size_t)b * 8 + h) * CTPB + tok) << 4) + d;
            if (OBF)
              ((unsigned short*)C + (size_t)pt * CPS)[idx] = f2bf(v);
            else
              (C + (size_t)pt * CPS)[idx] = v;
          }
        }
      }
  } else {
#pragma unroll
    for (int mi = 0; mi < 4; mi++)
#pragma unroll
      for (int r = 0; r < 4; r++) {
        int mrow = m0t + wr * 64 + mi * 16 + sg * 4 + r;
        if (mrow < M) {
#pragma unroll
          for (int ni = 0; ni < 4; ni++) {
            int col = n0t + wc * 64 + ni * 16 + li;
            float v = acc[mi][ni][r] + bv[ni];
            if (CBF)
              ((unsigned short*)C)[(size_t)mrow * Ntot + col] = f2bf(v);
            else
              C[(size_t)mrow * Ntot + col] = v;
            if (aiq2) {
              int fb = mrow / 200, wi2 = mrow % 200;
              if (wi2 < 100) aiq2[((size_t)fb * 100 + wi2) * Ntot + col] = v;
            }
          }
        }
      }
  }
}

// ---------------------------------------------------------------------------
// Merged proj+LN (audio z=0, vis z=1): A f32 reg-staged w/ bf16 side-write;
// fused LayerNorm; head-major bf16 K/V split store. 512 threads, (320,1,2).
// ---------------------------------------------------------------------------
__global__ __launch_bounds__(512) void ln_gemm(
    const float* __restrict__ audio, const float* __restrict__ vis,
    const unsigned short* __restrict__ afp_t, const unsigned short* __restrict__ vfp_t,
    const float* __restrict__ b_afp, const float* __restrict__ b_vfp,
    const float* __restrict__ g_an, const float* __restrict__ g_vn,
    const float* __restrict__ be_an, const float* __restrict__ be_vn,
    unsigned short* __restrict__ akn, unsigned short* __restrict__ vkn,
    unsigned short* __restrict__ audio_bf, unsigned short* __restrict__ vis_bf) {
  constexpr int BN = 256, NW = 8, NCW = 4;
  constexpr size_t CPS = 5242880;
  __shared__ __align__(16) unsigned short As[128 * 32];
  __shared__ __align__(16) unsigned short Bs[BN * 32];
  __shared__ float2 part[128][4];
  const int z = blockIdx.z;
  const float* Af32 = z ? vis : audio;
  const unsigned short* Wt = z ? vfp_t : afp_t;
  const float* bias = z ? b_vfp : b_afp;
  const float* gg = z ? g_vn : g_an;
  const float* be = z ? be_vn : be_an;
  unsigned short* C = z ? vkn : akn;
  unsigned short* Aside = z ? vis_bf : audio_bf;
  const int K = z ? 512 : 128;
  const int tid = threadIdx.x;
  const int wid = tid >> 6, lane = tid & 63;
  const int wr = wid / NCW, wc = wid % NCW;
  const int m0t = blockIdx.x * 128;
  const int ir = lane >> 2, sl = lane & 3;
  const int sg = lane >> 4, li = lane & 15;
  f32x4 acc[4][4];
#pragma unroll
  for (int i = 0; i < 4; i++)
#pragma unroll
    for (int j = 0; j < 4; j++) acc[i][j] = (f32x4){0.f, 0.f, 0.f, 0.f};

  for (int k0 = 0; k0 < K; k0 += 32) {
    __syncthreads();
    {
      int r = tid >> 2, slp = tid & 3;
      int sp = slp ^ ((r >> 1) & 3);
      const float4* src = (const float4*)(Af32 + (size_t)(m0t + r) * K + k0 + sp * 8);
      float4 aa = src[0], bb = src[1];
      uint4 w;
      w.x = pk2(aa.x, aa.y); w.y = pk2(aa.z, aa.w);
      w.z = pk2(bb.x, bb.y); w.w = pk2(bb.z, bb.w);
      *(uint4*)&As[r * 32 + slp * 8] = w;
      *(uint4*)(Aside + (size_t)(m0t + r) * K + k0 + sp * 8) = w;
    }
    for (int is = 8 + wid; is < 8 + BN / 16; is += NW) {
      int r2 = (is - 8) * 16 + ir;
      int sp2 = sl ^ ((r2 >> 1) & 3);
      gll16(Wt + (size_t)r2 * K + k0 + sp2 * 8, (void*)&Bs[(is - 8) * 512]);
    }
    __syncthreads();
    bf16x8 af[4], bfr[4];
#pragma unroll
    for (int mi = 0; mi < 4; mi++) {
      int m = wr * 64 + mi * 16 + li;
      sh8 t = *(const sh8*)&As[m * 32 + ((sg ^ ((m >> 1) & 3)) << 3)];
      af[mi] = __builtin_bit_cast(bf16x8, t);
    }
#pragma unroll
    for (int ni = 0; ni < 4; ni++) {
      int n = wc * 64 + ni * 16 + li;
      sh8 t = *(const sh8*)&Bs[n * 32 + ((sg ^ ((n >> 1) & 3)) << 3)];
      bfr[ni] = __builtin_bit_cast(bf16x8, t);
    }
#pragma unroll
    for (int mi = 0; mi < 4; mi++)
#pragma unroll
      for (int ni = 0; ni < 4; ni++)
        acc[mi][ni] = __builtin_amdgcn_mfma_f32_16x16x32_bf16(af[mi], bfr[ni],
                                                              acc[mi][ni], 0, 0, 0);
  }

  float bv[4];
#pragma unroll
  for (int ni = 0; ni < 4; ni++) bv[ni] = bias[wc * 64 + ni * 16 + li];
#pragma unroll
  for (int mi = 0; mi < 4; mi++)
#pragma unroll
    for (int ni = 0; ni < 4; ni++)
#pragma unroll
      for (int r = 0; r < 4; r++) acc[mi][ni][r] += bv[ni];
#pragma unroll
  for (int mi = 0; mi < 4; mi++)
#pragma unroll
    for (int r = 0; r < 4; r++) {
      float s = acc[mi][0][r] + acc[mi][1][r] + acc[mi][2][r] + acc[mi][3][r];
      float q2 = acc[mi][0][r] * acc[mi][0][r] + acc[mi][1][r] * acc[mi][1][r] +
                 acc[mi][2][r] * acc[mi][2][r] + acc[mi][3][r] * acc[mi][3][r];
#pragma unroll
      for (int off = 1; off < 16; off <<= 1) {
        s += __shfl_xor(s, off);
        q2 += __shfl_xor(q2, off);
      }
      if (li == 0) part[wr * 64 + mi * 16 + sg * 4 + r][wc] = make_float2(s, q2);
    }
  __syncthreads();
  float gv[4], bev[4];
#pragma unroll
  for (int ni = 0; ni < 4; ni++) {
    int col = wc * 64 + ni * 16 + li;
    gv[ni] = gg[col];
    bev[ni] = be[col];
  }
#pragma unroll
  for (int mi = 0; mi < 4; mi++)
#pragma unroll
    for (int r = 0; r < 4; r++) {
      int mrow = wr * 64 + mi * 16 + sg * 4 + r;
      float2 p0 = part[mrow][0], p1 = part[mrow][1], p2 = part[mrow][2], p3 = part[mrow][3];
      float S = p0.x + p1.x + p2.x + p3.x;
      float Qq = p0.y + p1.y + p2.y + p3.y;
      float mean = S * (1.f / 256.f);
      float var = Qq * (1.f / 256.f) - mean * mean;
      float rstd = rsqrtf(var + EPSF);
      int mg = m0t + mrow;
      int b = mg >> 10, tok = mg & 1023;
#pragma unroll
      for (int ni = 0; ni < 4; ni++) {
        int col = wc * 64 + ni * 16 + li;
        float val = (acc[mi][ni][r] - mean) * rstd * gv[ni] + bev[ni];
        int half = col >> 7, h = (col >> 4) & 7, d = col & 15;
        size_t idx = ((((size_t)b * 8 + h) * 1024 + tok) << 4) + d;
        (C + (half ? CPS : 0))[idx] = f2bf(val);
      }
    }
}

// ---------------------------------------------------------------------------
// kf/vf projection as MFMA (z=0: aiq2 rows -> Ka/Va, z=1: viq2 rows -> Kv/Vv):
// A = SAb bf16 (8000x128) with gathered rows irx=(r/100)*200+off+r%100.
// M=4000 (32 tiles of 128), BN=256, 512 thr, grid (32,1,2).
// Head-major bf16 K/V split store, CTPB=100.
// ---------------------------------------------------------------------------
__global__ __launch_bounds__(512) void kvproj_gemm(
    const unsigned short* __restrict__ SAb,
    const unsigned short* __restrict__ aqp_t, const unsigned short* __restrict__ vqp_t,
    const float* __restrict__ b_aqp, const float* __restrict__ b_vqp,
    unsigned short* __restrict__ Ka, unsigned short* __restrict__ Va,
    unsigned short* __restrict__ Kv, unsigned short* __restrict__ Vv) {
  constexpr int BN = 256, NW = 8, NCW = 4, K = 128;
  __shared__ __align__(16) unsigned short As[128 * 32];
  __shared__ __align__(16) unsigned short Bs[BN * 32];
  const int z = blockIdx.z;
  const unsigned short* Wt = z ? vqp_t : aqp_t;
  const float* bias = z ? b_vqp : b_aqp;
  unsigned short* outK = z ? Kv : Ka;
  unsigned short* outV = z ? Vv : Va;
  const int rowoff = z ? 100 : 0;
  const int tid = threadIdx.x;
  const int wid = tid >> 6, lane = tid & 63;
  const int wr = wid / NCW, wc = wid % NCW;
  const int m0t = blockIdx.x * 128;
  const int ir = lane >> 2, sl = lane & 3;
  const int sg = lane >> 4, li = lane & 15;
  f32x4 acc[4][4];
#pragma unroll
  for (int i = 0; i < 4; i++)
#pragma unroll
    for (int j = 0; j < 4; j++) acc[i][j] = (f32x4){0.f, 0.f, 0.f, 0.f};
  constexpr int nIss = 8 + BN / 16;

  for (int k0 = 0; k0 < K; k0 += 32) {
    __syncthreads();
    for (int is = wid; is < nIss; is += NW) {
      if (is < 8) {
        int r = is * 16 + ir;
        int rg = m0t + r;
        if (rg >= 4000) rg = 3999;
        size_t irx = (size_t)(rg / 100) * 200 + rowoff + (rg % 100);
        int sp = sl ^ ((r >> 1) & 3);
        gll16(SAb + irx * 128 + k0 + sp * 8, (void*)&As[is * 512]);
      } else {
        int r = (is - 8) * 16 + ir;
        int sp = sl ^ ((r >> 1) & 3);
        gll16(Wt + (size_t)r * K + k0 + sp * 8, (void*)&Bs[(is - 8) * 512]);
      }
    }
    __syncthreads();
    bf16x8 af[4], bfr[4];
#pragma unroll
    for (int mi = 0; mi < 4; mi++) {
      int m = wr * 64 + mi * 16 + li;
      sh8 t = *(const sh8*)&As[m * 32 + ((sg ^ ((m >> 1) & 3)) << 3)];
      af[mi] = __builtin_bit_cast(bf16x8, t);
    }
#pragma unroll
    for (int ni = 0; ni < 4; ni++) {
      int n = wc * 64 + ni * 16 + li;
      sh8 t = *(const sh8*)&Bs[n * 32 + ((sg ^ ((n >> 1) & 3)) << 3)];
      bfr[ni] = __builtin_bit_cast(bf16x8, t);
    }
#pragma unroll
    for (int mi = 0; mi < 4; mi++)
#pragma unroll
      for (int ni = 0; ni < 4; ni++)
        acc[mi][ni] = __builtin_amdgcn_mfma_f32_16x16x32_bf16(af[mi], bfr[ni],
                                                              acc[mi][ni], 0, 0, 0);
  }

  float bv[4];
#pragma unroll
  for (int ni = 0; ni < 4; ni++) bv[ni] = bias[wc * 64 + ni * 16 + li];
#pragma unroll
  for (int mi = 0; mi < 4; mi++)
#pragma unroll
    for (int r = 0; r < 4; r++) {
      int mg = m0t + wr * 64 + mi * 16 + sg * 4 + r;
      if (mg < 4000) {
        int b = mg / 100, tok = mg - b * 100;
#pragma unroll
        for (int ni = 0; ni < 4; ni++) {
          int col = wc * 64 + ni * 16 + li;
          float v = acc[mi][ni][r] + bv[ni];
          int half = col >> 7, h = (col >> 4) & 7, d = col & 15;
          unsigned short* dst = half ? outV : outK;
          dst[((((size_t)b * 8 + h) * 100 + tok) << 4) + d] = f2bf(v);
        }
      }
    }
}

// ---------------------------------------------------------------------------
// Merged _a/_v projection (z=0 audio K=128, z=1 vis K=512): head-major bf16
// store PRE-SCALED by SCALEF (consumed as Q by stage-3). 256 thr, (320,1,2).
// ---------------------------------------------------------------------------
__global__ __launch_bounds__(256) void projq_kernel(
    const unsigned short* __restrict__ audio_bf, const unsigned short* __restrict__ vis_bf,
    const unsigned short* __restrict__ aq_t, const unsigned short* __restrict__ vq_t,
    const float* __restrict__ b_aq, const float* __restrict__ b_vq,
    unsigned short* __restrict__ a_hm, unsigned short* __restrict__ v_hm) {
  constexpr int BN = 128, NW = 4, NCW = 2;
  __shared__ __align__(16) unsigned short As[128 * 32];
  __shared__ __align__(16) unsigned short Bs[BN * 32];
  const int z = blockIdx.z;
  const unsigned short* A = z ? vis_bf : audio_bf;
  const unsigned short* Wt = z ? vq_t : aq_t;
  const float* bias = z ? b_vq : b_aq;
  unsigned short* C = z ? v_hm : a_hm;
  const int K = z ? 512 : 128;
  const int tid = threadIdx.x;
  const int wid = tid >> 6, lane = tid & 63;
  const int wr = wid / NCW, wc = wid % NCW;
  const int m0t = blockIdx.x * 128;
  const int ir = lane >> 2, sl = lane & 3;
  const int sg = lane >> 4, li = lane & 15;
  f32x4 acc[4][4];
#pragma unroll
  for (int i = 0; i < 4; i++)
#pragma unroll
    for (int j = 0; j < 4; j++) acc[i][j] = (f32x4){0.f, 0.f, 0.f, 0.f};

  for (int k0 = 0; k0 < K; k0 += 32) {
    __syncthreads();
    for (int is = wid; is < 8 + BN / 16; is += NW) {
      if (is < 8) {
        int r = is * 16 + ir;
        int sp = sl ^ ((r >> 1) & 3);
        gll16(A + (size_t)(m0t + r) * K + k0 + sp * 8, (void*)&As[is * 512]);
      } else {
        int r = (is - 8) * 16 + ir;
        int sp = sl ^ ((r >> 1) & 3);
        gll16(Wt + (size_t)r * K + k0 + sp * 8, (void*)&Bs[(is - 8) * 512]);
      }
    }
    __syncthreads();
    bf16x8 af[4], bfr[4];
#pragma unroll
    for (int mi = 0; mi < 4; mi++) {
      int m = wr * 64 + mi * 16 + li;
      sh8 t = *(const sh8*)&As[m * 32 + ((sg ^ ((m >> 1) & 3)) << 3)];
      af[mi] = __builtin_bit_cast(bf16x8, t);
    }
#pragma unroll
    for (int ni = 0; ni < 4; ni++) {
      int n = wc * 64 + ni * 16 + li;
      sh8 t = *(const sh8*)&Bs[n * 32 + ((sg ^ ((n >> 1) & 3)) << 3)];
      bfr[ni] = __builtin_bit_cast(bf16x8, t);
    }
#pragma unroll
    for (int mi = 0; mi < 4; mi++)
#pragma unroll
      for (int ni = 0; ni < 4; ni++)
        acc[mi][ni] = __builtin_amdgcn_mfma_f32_16x16x32_bf16(af[mi], bfr[ni],
                                                              acc[mi][ni], 0, 0, 0);
  }

  float bv[4];
#pragma unroll
  for (int ni = 0; ni < 4; ni++) bv[ni] = bias[wc * 64 + ni * 16 + li];
#pragma unroll
  for (int mi = 0; mi < 4; mi++)
#pragma unroll
    for (int r = 0; r < 4; r++) {
      int mg = m0t + wr * 64 + mi * 16 + sg * 4 + r;
      int b = mg >> 10, tok = mg & 1023;
#pragma unroll
      for (int ni = 0; ni < 4; ni++) {
        int col = wc * 64 + ni * 16 + li;
        float v = (acc[mi][ni][r] + bv[ni]) * SCALEF;
        int h = (col >> 4) & 7, d = col & 15;
        C[((((size_t)b * 8 + h) * 1024 + tok) << 4) + d] = f2bf(v);
      }
    }
}

// ---------------------------------------------------------------------------
// Merged output projection, grid (320,4,2), 256 thr:
//  z=0: vis_out = vatthm @ vo_t + b_vo + vis(f32 residual)
//  z=1: audio_out = aatthm @ ao_t + b_ao
// A head-major [40][8][1024][16] bf16; K=128, BN=128.
// ---------------------------------------------------------------------------
__global__ __launch_bounds__(256) void out_gemm(
    const unsigned short* __restrict__ vatthm, const unsigned short* __restrict__ aatthm,
    const unsigned short* __restrict__ vo_t, const unsigned short* __restrict__ ao_t,
    const float* __restrict__ b_vo, const float* __restrict__ b_ao,
    const float* __restrict__ vis, float* __restrict__ vis_out,
    float* __restrict__ audio_out) {
  constexpr int BN = 128, NW = 4, NCW = 2, K = 128;
  __shared__ __align__(16) unsigned short As[128 * 32];
  __shared__ __align__(16) unsigned short Bs[BN * 32];
  const int z = blockIdx.z;
  const unsigned short* A = z ? aatthm : vatthm;
  const unsigned short* Wt = z ? ao_t : vo_t;
  const float* bias = z ? b_ao : b_vo;
  float* C = z ? audio_out : vis_out;
  const int tid = threadIdx.x;
  const int wid = tid >> 6, lane = tid & 63;
  const int wr = wid / NCW, wc = wid % NCW;
  const int m0t = blockIdx.x * 128, n0t = blockIdx.y * BN;
  const int ir = lane >> 2, sl = lane & 3;
  const int sg = lane >> 4, li = lane & 15;
  f32x4 acc[4][4];
#pragma unroll
  for (int i = 0; i < 4; i++)
#pragma unroll
    for (int j = 0; j < 4; j++) acc[i][j] = (f32x4){0.f, 0.f, 0.f, 0.f};

  for (int k0 = 0; k0 < K; k0 += 32) {
    __syncthreads();
    for (int is = wid; is < 8 + BN / 16; is += NW) {
      if (is < 8) {
        int r = is * 16 + ir;
        int rg = m0t + r;
        int b = rg >> 10, tok = rg & 1023;
        int e = k0 + ((sl ^ ((r >> 1) & 3)) << 3);
        gll16(A + ((((size_t)b * 8 + (e >> 4)) * 1024 + tok) << 4) + (e & 15),
              (void*)&As[is * 512]);
      } else {
        int r = (is - 8) * 16 + ir;
        int sp = sl ^ ((r >> 1) & 3);
        gll16(Wt + (size_t)(n0t + r) * K + k0 + sp * 8, (void*)&Bs[(is - 8) * 512]);
      }
    }
    __syncthreads();
    bf16x8 af[4], bfr[4];
#pragma unroll
    for (int mi = 0; mi < 4; mi++) {
      int m = wr * 64 + mi * 16 + li;
      sh8 t = *(const sh8*)&As[m * 32 + ((sg ^ ((m >> 1) & 3)) << 3)];
      af[mi] = __builtin_bit_cast(bf16x8, t);
    }
#pragma unroll
    for (int ni = 0; ni < 4; ni++) {
      int n = wc * 64 + ni * 16 + li;
      sh8 t = *(const sh8*)&Bs[n * 32 + ((sg ^ ((n >> 1) & 3)) << 3)];
      bfr[ni] = __builtin_bit_cast(bf16x8, t);
    }
#pragma unroll
    for (int mi = 0; mi < 4; mi++)
#pragma unroll
      for (int ni = 0; ni < 4; ni++)
        acc[mi][ni] = __builtin_amdgcn_mfma_f32_16x16x32_bf16(af[mi], bfr[ni],
                                                              acc[mi][ni], 0, 0, 0);
  }

  float bv[4];
#pragma unroll
  for (int ni = 0; ni < 4; ni++) bv[ni] = bias[n0t + wc * 64 + ni * 16 + li];
#pragma unroll
  for (int mi = 0; mi < 4; mi++)
#pragma unroll
    for (int r = 0; r < 4; r++) {
      int mrow = m0t + wr * 64 + mi * 16 + sg * 4 + r;
#pragma unroll
      for (int ni = 0; ni < 4; ni++) {
        int col = n0t + wc * 64 + ni * 16 + li;
        float v = acc[mi][ni][r] + bv[ni];
        if (z == 0) v += vis[(size_t)mrow * 512 + col];
        C[(size_t)mrow * 512 + col] = v;
      }
    }
}

// ---------------------------------------------------------------------------
// Stage-1 MFMA flash attention: both modalities, 8 waves, K/V staged once;
// prefetch one block ahead; Q pre-scaled at load; defer-max rescale.
// ---------------------------------------------------------------------------
__global__ __launch_bounds__(512) void mattn1(
    const float* __restrict__ aqvq,
    const unsigned short* __restrict__ akn, const unsigned short* __restrict__ avn,
    const unsigned short* __restrict__ vkn, const unsigned short* __restrict__ vvn,
    unsigned short* __restrict__ op) {
  __shared__ __align__(16) unsigned short Klds[64][24];
  __shared__ __align__(16) unsigned short VTlds[16][72];
  __shared__ __align__(16) unsigned short Plds[8][16][72];
  const int tid = threadIdx.x, wid = tid >> 6, lane = tid & 63;
  const int li = lane & 15, gr = lane >> 4;
  const int z = blockIdx.z, h = blockIdx.y;
  const int mod = z >= 40 ? 1 : 0;
  const int b = z - mod * 40;
  const int bh = b * 8 + h;
  const int qi = wid * 16 + li;
  const bool qact = qi < 100;
  const int qic = qact ? qi : 99;
  const float* qrow = aqvq + mod * 128 + (size_t)qic * 256 + h * 16;
  const unsigned short* kp = mod ? vkn : akn;
  const unsigned short* vp = mod ? vvn : avn;

  sh8 z8 = (sh8)0;
  bf16x8 qf = __builtin_bit_cast(bf16x8, z8);
  if (gr < 2) {
    const float4* q4 = (const float4*)(qrow + gr * 8);
    float4 qa = q4[0], qb = q4[1];
    sh8 tt;
    tt[0] = f2bf(qa.x * SCALEF); tt[1] = f2bf(qa.y * SCALEF);
    tt[2] = f2bf(qa.z * SCALEF); tt[3] = f2bf(qa.w * SCALEF);
    tt[4] = f2bf(qb.x * SCALEF); tt[5] = f2bf(qb.y * SCALEF);
    tt[6] = f2bf(qb.z * SCALEF); tt[7] = f2bf(qb.w * SCALEF);
    qf = __builtin_bit_cast(bf16x8, tt);
  }

  float mrun = -3e38f, lrun = 0.f;
  f32x4 acc = (f32x4){0.f, 0.f, 0.f, 0.f};
  const f32x4 zero4 = (f32x4){0.f, 0.f, 0.f, 0.f};
  const unsigned* Ku = (const unsigned*)(kp + (size_t)bh * 1024 * 16);
  const unsigned* Vu = (const unsigned*)(vp + (size_t)bh * 1024 * 16);
  const int skey = tid >> 3, sdb = tid & 7;

  unsigned kw = Ku[(size_t)skey * 8 + sdb];
  unsigned vw = Vu[(size_t)skey * 8 + sdb];
  for (int kb = 0; kb < 1024; kb += 64) {
    __syncthreads();
    *(unsigned*)&Klds[skey][sdb * 2] = kw;
    VTlds[sdb * 2 + 0][skey] = (unsigned short)(vw & 0xffff);
    VTlds[sdb * 2 + 1][skey] = (unsigned short)(vw >> 16);
    if (kb + 64 < 1024) {
      kw = Ku[(size_t)(kb + 64 + skey) * 8 + sdb];
      vw = Vu[(size_t)(kb + 64 + skey) * 8 + sdb];
    }
    __syncthreads();
    f32x4 st[4];
#pragma unroll
    for (int t = 0; t < 4; t++) {
      sh8 kk = *(const sh8*)&Klds[t * 16 + li][(gr & 1) * 8];
      st[t] = __builtin_amdgcn_mfma_f32_16x16x32_bf16(
          __builtin_bit_cast(bf16x8, kk), qf, zero4, 0, 0, 0);
    }
    float bm = st[0][0];
#pragma unroll
    for (int t = 0; t < 4; t++)
#pragma unroll
      for (int r = 0; r < 4; r++) bm = fmaxf(bm, st[t][r]);
    bm = fmaxf(bm, __shfl_xor(bm, 16));
    bm = fmaxf(bm, __shfl_xor(bm, 32));
    if (bm > mrun + 8.f) {
      float cf = __expf(mrun - bm);
      lrun *= cf;
      acc[0] *= cf; acc[1] *= cf; acc[2] *= cf; acc[3] *= cf;
      mrun = bm;
    }
    float ls = 0.f;
    unsigned pw[4][2];
#pragma unroll
    for (int t = 0; t < 4; t++) {
      float p0 = __expf(st[t][0] - mrun), p1 = __expf(st[t][1] - mrun);
      float p2 = __expf(st[t][2] - mrun), p3 = __expf(st[t][3] - mrun);
      ls += (p0 + p1) + (p2 + p3);
      pw[t][0] = pk2(p0, p1);
      pw[t][1] = pk2(p2, p3);
    }
    ls += __shfl_xor(ls, 16);
    ls += __shfl_xor(ls, 32);
    lrun += ls;
#pragma unroll
    for (int t = 0; t < 4; t++)
      *(uint2*)&Plds[wid][li][t * 16 + gr * 4] = make_uint2(pw[t][0], pw[t][1]);
#pragma unroll
    for (int hh = 0; hh < 2; hh++) {
      sh8 vt = *(const sh8*)&VTlds[li][hh * 32 + gr * 8];
      sh8 pt = *(const sh8*)&Plds[wid][li][hh * 32 + gr * 8];
      acc = __builtin_amdgcn_mfma_f32_16x16x32_bf16(
          __builtin_bit_cast(bf16x8, vt), __builtin_bit_cast(bf16x8, pt), acc, 0, 0, 0);
    }
  }
  float inv = 1.f / lrun;
  float o[4];
#pragma unroll
  for (int r = 0; r < 4; r++) o[r] = acc[r] * inv;
  const float4* q4 = (const float4*)(qrow + gr * 4);
  float4 qv = q4[0];
  o[0] += qv.x; o[1] += qv.y; o[2] += qv.z; o[3] += qv.w;
  if (qact) {
    int obh = (b / 5) * 8 + h;
    int otok = (b % 5) * 200 + mod * 100 + qi;
    *(uint2*)(op + (((size_t)obh * 1000 + otok) << 4) + gr * 4) =
        make_uint2(pk2(o[0], o[1]), pk2(o[2], o[3]));
  }
}

// ---------------------------------------------------------------------------
// 8-wave MFMA flash attention, bf16 head-major operands, Q PRE-SCALED,
// prefetch one block ahead, defer-max rescale.
// MODE 1: single stream (SA). MODE 2: merged modalities (stage-3), audio
// side (+bf16 token-major residual).
// ---------------------------------------------------------------------------
template <int MODE>
__global__ __launch_bounds__(512) void mattn8(
    const unsigned short* __restrict__ q0s, const unsigned short* __restrict__ q1s,
    size_t qsb, size_t qsh, int qsr,
    const unsigned short* __restrict__ k0s, const unsigned short* __restrict__ v0s,
    const unsigned short* __restrict__ k1s, const unsigned short* __restrict__ v1s,
    int nk, int nq, unsigned short* __restrict__ o0s, unsigned short* __restrict__ o1s,
    int OTPB, const unsigned short* __restrict__ residbf) {
  __shared__ __align__(16) unsigned short Klds[64][24];
  __shared__ __align__(16) unsigned short VTlds[16][72];
  __shared__ __align__(16) unsigned short Plds[8][16][72];
  const int tid = threadIdx.x, wid = tid >> 6, lane = tid & 63;
  const int li = lane & 15, gr = lane >> 4;
  const int z = blockIdx.z, h = blockIdx.y;
  int mod = 0, b = z;
  const unsigned short *qp = q0s, *kp = k0s, *vp = v0s;
  unsigned short* op = o0s;
  if (MODE == 2) {
    mod = z >= 40 ? 1 : 0;
    b = z - mod * 40;
    if (mod) { qp = q1s; kp = k1s; vp = v1s; op = o1s; }
  }
  const int bh = b * 8 + h;
  const int qi = blockIdx.x * 128 + wid * 16 + li;
  const bool qact = qi < nq;
  const int qic = qact ? qi : nq - 1;
  const unsigned short* qrow = qp + b * qsb + h * qsh + (size_t)qic * qsr;

  sh8 z8 = (sh8)0;
  bf16x8 qf = __builtin_bit_cast(bf16x8, z8);
  if (gr < 2) qf = __builtin_bit_cast(bf16x8, *(const sh8*)(qrow + gr * 8));

  float mrun = -3e38f, lrun = 0.f;
  f32x4 acc = (f32x4){0.f, 0.f, 0.f, 0.f};
  const f32x4 zero4 = (f32x4){0.f, 0.f, 0.f, 0.f};
  const unsigned* Ku = (const unsigned*)(kp + (size_t)bh * nk * 16);
  const unsigned* Vu = (const unsigned*)(vp + (size_t)bh * nk * 16);
  const int skey = tid >> 3, sdb = tid & 7;

  unsigned kw = (skey < nk) ? Ku[(size_t)skey * 8 + sdb] : 0u;
  unsigned vw = (skey < nk) ? Vu[(size_t)skey * 8 + sdb] : 0u;
  for (int kb = 0; kb < nk; kb += 64) {
    __syncthreads();
    *(unsigned*)&Klds[skey][sdb * 2] = kw;
    VTlds[sdb * 2 + 0][skey] = (unsigned short)(vw & 0xffff);
    VTlds[sdb * 2 + 1][skey] = (unsigned short)(vw >> 16);
    if (kb + 64 < nk) {
      int gk = kb + 64 + skey;
      kw = (gk < nk) ? Ku[(size_t)gk * 8 + sdb] : 0u;
      vw = (gk < nk) ? Vu[(size_t)gk * 8 + sdb] : 0u;
    }
    __syncthreads();
    f32x4 st[4];
#pragma unroll
    for (int t = 0; t < 4; t++) {
      sh8 kk = *(const sh8*)&Klds[t * 16 + li][(gr & 1) * 8];
      st[t] = __builtin_amdgcn_mfma_f32_16x16x32_bf16(
          __builtin_bit_cast(bf16x8, kk), qf, zero4, 0, 0, 0);
    }
    if (kb + 64 > nk) {
#pragma unroll
      for (int t = 0; t < 4; t++) {
        int kbase = kb + t * 16 + gr * 4;
#pragma unroll
        for (int r = 0; r < 4; r++)
          if (kbase + r >= nk) st[t][r] = -1e30f;
      }
    }
    float bm = st[0][0];
#pragma unroll
    for (int t = 0; t < 4; t++)
#pragma unroll
      for (int r = 0; r < 4; r++) bm = fmaxf(bm, st[t][r]);
    bm = fmaxf(bm, __shfl_xor(bm, 16));
    bm = fmaxf(bm, __shfl_xor(bm, 32));
    if (bm > mrun + 8.f) {
      float cf = __expf(mrun - bm);
      lrun *= cf;
      acc[0] *= cf; acc[1] *= cf; acc[2] *= cf; acc[3] *= cf;
      mrun = bm;
    }
    float ls = 0.f;
    unsigned pw[4][2];
#pragma unroll
    for (int t = 0; t < 4; t++) {
      float p0 = __expf(st[t][0] - mrun), p1 = __expf(st[t][1] - mrun);
      float p2 = __expf(st[t][2] - mrun), p3 = __expf(st[t][3] - mrun);
      ls += (p0 + p1) + (p2 + p3);
      pw[t][0] = pk2(p0, p1);
      pw[t][1] = pk2(p2, p3);
    }
    ls += __shfl_xor(ls, 16);
    ls += __shfl_xor(ls, 32);
    lrun += ls;
#pragma unroll
    for (int t = 0; t < 4; t++)
      *(uint2*)&Plds[wid][li][t * 16 + gr * 4] = make_uint2(pw[t][0], pw[t][1]);
#pragma unroll
    for (int hh = 0; hh < 2; hh++) {
      sh8 vt = *(const sh8*)&VTlds[li][hh * 32 + gr * 8];
      sh8 pt = *(const sh8*)&Plds[wid][li][hh * 32 + gr * 8];
      acc = __builtin_amdgcn_mfma_f32_16x16x32_bf16(
          __builtin_bit_cast(bf16x8, vt), __builtin_bit_cast(bf16x8, pt), acc, 0, 0, 0);
    }
  }
  float inv = 1.f / lrun;
  float o[4];
#pragma unroll
  for (int r = 0; r < 4; r++) o[r] = acc[r] * inv;
  if (MODE == 2 && mod == 0 && residbf) {
    uint2 rv = *(const uint2*)(residbf + ((size_t)b * 1024 + qic) * 128 + h * 16 + gr * 4);
    o[0] += bf2f((unsigned short)(rv.x & 0xffff));
    o[1] += bf2f((unsigned short)(rv.x >> 16));
    o[2] += bf2f((unsigned short)(rv.y & 0xffff));
    o[3] += bf2f((unsigned short)(rv.y >> 16));
  }
  if (qact) {
    *(uint2*)(op + (((size_t)bh * OTPB + qi) << 4) + gr * 4) =
        make_uint2(pk2(o[0], o[1]), pk2(o[2], o[3]));
  }
}

// ---------------------------------------------------------------------------
// Consolidated prep: 10 weight transposes + iqp projection.
// [0,1728) original 8; [1728,1856) w_aqp; [1856,1984) w_vqp; [1984,2084) iqp.
// ---------------------------------------------------------------------------
__global__ __launch_bounds__(256) void prep_kernel(
    const float* __restrict__ iq, const float* __restrict__ w_iqp,
    const float* __restrict__ b_iqp,
    const float* __restrict__ w_afp, const float* __restrict__ w_vfp,
    const float* __restrict__ w_aq, const float* __restrict__ w_vq,
    const float* __restrict__ w_in, const float* __restrict__ w_o,
    const float* __restrict__ w_ao, const float* __restrict__ w_vo,
    const float* __restrict__ w_aqp, const float* __restrict__ w_vqp,
    unsigned short* __restrict__ WT, float* __restrict__ aqvq) {
  __shared__ float row[128];
  const int g = blockIdx.x, tid = threadIdx.x;
  if (g < 1984) {
    int lg = g;
    int K, N;
    const float* W;
    unsigned dst;
    if (lg < 128)       { K = 128; N = 256; W = w_afp; dst = 0; }
    else if (lg < 640)  { K = 512; N = 256; W = w_vfp; dst = 32768;  lg -= 128; }
    else if (lg < 704)  { K = 128; N = 128; W = w_aq;  dst = 163840; lg -= 640; }
    else if (lg < 960)  { K = 512; N = 128; W = w_vq;  dst = 180224; lg -= 704; }
    else if (lg < 1152) { K = 128; N = 384; W = w_in;  dst = 245760; lg -= 960; }
    else if (lg < 1216) { K = 128; N = 128; W = w_o;   dst = 294912; lg -= 1152; }
    else if (lg < 1472) { K = 128; N = 512; W = w_ao;  dst = 311296; lg -= 1216; }
    else if (lg < 1728) { K = 128; N = 512; W = w_vo;  dst = 376832; lg -= 1472; }
    else if (lg < 1856) { K = 128; N = 256; W = w_aqp; dst = 442368; lg -= 1728; }
    else                { K = 128; N = 256; W = w_vqp; dst = 475136; lg -= 1856; }
    int idx = lg * 256 + tid;
    if (idx < K * N) {
      int k = idx / N, n = idx - k * N;
      WT[dst + (size_t)n * K + k] = f2bf(W[idx]);
    }
  } else {
    int r = g - 1984;
    if (tid < 128) row[tid] = iq[r * 128 + tid];
    __syncthreads();
    float acc = b_iqp[tid];
#pragma unroll 8
    for (int k = 0; k < 128; ++k) acc += row[k] * w_iqp[k * 256 + tid];
    aqvq[r * 256 + tid] = acc;
  }
}

// ---------------------------------------------------------------------------
extern "C" void kernel_launch(void* const* d_in, const int* in_sizes, int n_in,
                              void* d_out, int out_size, void* d_ws, size_t ws_size,
                              hipStream_t stream) {
  const float* audio = (const float*)d_in[0];   // (40,1024,128)
  const float* vis   = (const float*)d_in[1];   // (40,1024,512)
  const float* iq    = (const float*)d_in[2];
  const float* w_iqp = (const float*)d_in[3];
  const float* b_iqp = (const float*)d_in[4];
  const float* w_afp = (const float*)d_in[5];
  const float* b_afp = (const float*)d_in[6];
  const float* w_vfp = (const float*)d_in[7];
  const float* b_vfp = (const float*)d_in[8];
  const float* g_an  = (const float*)d_in[9];
  const float* be_an = (const float*)d_in[10];
  const float* g_vn  = (const float*)d_in[11];
  const float* be_vn = (const float*)d_in[12];
  const float* w_aqp = (const float*)d_in[13];
  const float* b_aqp = (const float*)d_in[14];
  const float* w_vqp = (const float*)d_in[15];
  const float* b_vqp = (const float*)d_in[16];
  const float* w_aq  = (const float*)d_in[17];
  const float* b_aq  = (const float*)d_in[18];
  const float* w_vq  = (const float*)d_in[19];
  const float* b_vq  = (const float*)d_in[20];
  const float* w_in  = (const float*)d_in[21];
  const float* b_in  = (const float*)d_in[22];
  const float* w_o   = (const float*)d_in[23];
  const float* b_o   = (const float*)d_in[24];
  const float* w_ao  = (const float*)d_in[25];
  const float* b_ao  = (const float*)d_in[26];
  const float* w_vo  = (const float*)d_in[27];
  const float* b_vo  = (const float*)d_in[28];

  float* out = (float*)d_out;
  float* ws  = (float*)d_ws;

  // ---- d_out scratch (dead until final writes; stream-ordered) ----
  unsigned short* vis_bf = (unsigned short*)(out);  // words [0,10485760)
  unsigned short* akn = (unsigned short*)(out + 10485760);  // [40][8][1024][16] bf16
  unsigned short* avn = akn + 5242880;
  unsigned short* vkn = akn + 10485760;
  unsigned short* vvn = akn + 15728640;
  unsigned short* a_hm = (unsigned short*)(out + 20971520);
  unsigned short* v_hm = (unsigned short*)(out + 23592960);
  float* aiq2_out = out + 41943040;
  float* audio_out = out;
  float* vis_out   = out + 20971520;

  // ---- ws layout (f32-word offsets) ----
  unsigned short* WT       = (unsigned short*)(ws);            // [0, 262144) words
  unsigned short* audio_bf = (unsigned short*)(ws + 262144);
  unsigned short* Q1hm     = (unsigned short*)(ws + 2883584);
  unsigned short* saphm    = (unsigned short*)(ws + 3395584);
  unsigned short* qkvhm    = (unsigned short*)(ws + 3915776);
  unsigned short* aatthm   = (unsigned short*)(ws + 3915776);  // overlays qkvhm
  unsigned short* vatthm   = (unsigned short*)(ws + 6987776);
  unsigned short* SAb      = (unsigned short*)(ws + 9609216);  // (8000,128) bf16
  unsigned short* Ka = (unsigned short*)(ws + 10633216);
  unsigned short* Va = Ka + 512000;
  unsigned short* Kv = Ka + 1024000;
  unsigned short* Vv = Ka + 1536000;
  float* aqvq = ws + 12681216;

  unsigned short* afp_t = WT + 0;
  unsigned short* vfp_t = WT + 32768;
  unsigned short* aq_t  = WT + 163840;
  unsigned short* vq_t  = WT + 180224;
  unsigned short* in_t  = WT + 245760;
  unsigned short* o_t   = WT + 294912;
  unsigned short* ao_t  = WT + 311296;
  unsigned short* vo_t  = WT + 376832;
  unsigned short* aqp_t = WT + 442368;
  unsigned short* vqp_t = WT + 475136;

  // 1. consolidated prep (10 wtrans + iqp)
  prep_kernel<<<2084, 256, 0, stream>>>(
      iq, w_iqp, b_iqp, w_afp, w_vfp, w_aq, w_vq, w_in, w_o, w_ao, w_vo,
      w_aqp, w_vqp, WT, aqvq);

  // 2. merged proj+LN -> head-major bf16 K/V + side bf16 copies
  ln_gemm<<<dim3(320, 1, 2), 512, 0, stream>>>(
      audio, vis, afp_t, vfp_t, b_afp, b_vfp, g_an, g_vn, be_an, be_vn,
      akn, vkn, audio_bf, vis_bf);

  // 3. stage-1 cross-attn -> Q1hm
  mattn1<<<dim3(1, 8, 80), 512, 0, stream>>>(aqvq, akn, avn, vkn, vvn, Q1hm);

  // 4. qkv = queries @ w_in + b_in (head-major bf16; q part pre-scaled QSC)
  mfma_gemm<128, 128, 2, true, true, true, false><<<dim3(63, 3), 256, 0, stream>>>(
      Q1hm, in_t, b_in, (float*)qkvhm, 8000, 384, 1000, 1000, 1024000, nullptr);

  // 5. self-attention -> saphm
  mattn8<1><<<dim3(8, 8, 8), 512, 0, stream>>>(
      qkvhm, nullptr, 128000, 16000, 16, qkvhm + 1024000, qkvhm + 2048000,
      nullptr, nullptr, 1000, 1000, saphm, nullptr, 1000, nullptr);

  // 6. SA = sa_pre @ w_o + b_o -> bf16 SAb (CBF) + f32 aiq2 dual-store
  mfma_gemm<128, 128, 0, true, false, false, true><<<dim3(63, 1), 256, 0, stream>>>(
      saphm, o_t, b_o, (float*)SAb, 8000, 128, 1000, 0, 0, aiq2_out);

  // 7. kf/vf projections (MFMA, gathered bf16 A) -> head-major bf16 K/V
  kvproj_gemm<<<dim3(32, 1, 2), 512, 0, stream>>>(
      SAb, aqp_t, vqp_t, b_aqp, b_vqp, Ka, Va, Kv, Vv);

  // 8. merged _a/_v projections -> head-major bf16, PRE-SCALED (stage-3 Q)
  projq_kernel<<<dim3(320, 1, 2), 256, 0, stream>>>(
      audio_bf, vis_bf, aq_t, vq_t, b_aq, b_vq, a_hm, v_hm);

  // 9. stage-3 cross-attn merged; audio +audio_bf resid
  mattn8<2><<<dim3(8, 8, 80), 512, 0, stream>>>(
      a_hm, v_hm, 131072, 16384, 16, Kv, Vv, Ka, Va, 100, 1024,
      aatthm, vatthm, 1024, audio_bf);

  // 10. merged output projections (vis residual from ORIGINAL f32 vis ->
  //     no scratch hazard; both z-slices independent)
  out_gemm<<<dim3(320, 4, 2), 256, 0, stream>>>(
      vatthm, aatthm, vo_t, ao_t, b_vo, b_ao, vis, vis_out, audio_out);
}

// Round 13
// 285.987 us; speedup vs baseline: 5.7409x; 1.0026x over previous
//
#include <hip/hip_runtime.h>

#define EPSF 1e-5f
#define SCALEF 0.25f   // hd=16 -> 16^-0.5

typedef __attribute__((ext_vector_type(8))) __bf16 bf16x8;
typedef __attribute__((ext_vector_type(8))) unsigned short sh8;
typedef __attribute__((ext_vector_type(4))) float f32x4;

__device__ __forceinline__ unsigned short f2bf(float f) {
  return __builtin_bit_cast(unsigned short, (__bf16)f);
}
__device__ __forceinline__ unsigned pk2(float lo, float hi) {
  return (unsigned)f2bf(lo) | ((unsigned)f2bf(hi) << 16);
}
__device__ __forceinline__ float bf2f(unsigned short u) {
  return __uint_as_float((unsigned)u << 16);
}

// async global->LDS, 16B per lane; LDS dest = uniform base + lane*16
__device__ __forceinline__ void gll16(const void* g, void* l) {
  __builtin_amdgcn_global_load_lds((const __attribute__((address_space(1))) void*)g,
                                   (__attribute__((address_space(3))) void*)l,
                                   16, 0, 0);
}

// ---------------------------------------------------------------------------
// MFMA GEMM: C = A[M][K](bf16) x Wt[N][K](bf16)^T + bias
//  AHEAD: A stored head-major [B][8][ATPB][16] bf16
//  EPI 0: token-major store (f32, or bf16 if CBF); optional aiq2 f32 dual-store
//  EPI 2: head-major split-(Ntot/128) store, part p -> C + p*CPS
//  OBF: EPI2 stores bf16 (CPS counted in bf16 elems)
//  QSC: EPI2 scales part 0 by SCALEF before store (pre-scaled Q for attn)
// ---------------------------------------------------------------------------
template <int K, int BN, int EPI, bool AHEAD, bool OBF, bool QSC, bool CBF>
__global__ __launch_bounds__(BN * 2) void mfma_gemm(
    const unsigned short* __restrict__ A, const unsigned short* __restrict__ Wt,
    const float* __restrict__ bias,
    float* __restrict__ C, int M, int Ntot, int ATPB, int CTPB, size_t CPS,
    float* __restrict__ aiq2) {
  constexpr int NW = BN / 32;   // waves per block
  constexpr int NCW = BN / 64;  // wave columns
  __shared__ __align__(16) unsigned short As[128 * 32];
  __shared__ __align__(16) unsigned short Bs[BN * 32];
  const int tid = threadIdx.x;
  const int wid = tid >> 6, lane = tid & 63;
  const int wr = wid / NCW, wc = wid % NCW;
  const int m0t = blockIdx.x * 128, n0t = blockIdx.y * BN;
  const int ir = lane >> 2, sl = lane & 3;   // staging: row-in-16, slot
  const int sg = lane >> 4, li = lane & 15;  // frags: k-group, row/col
  f32x4 acc[4][4];
#pragma unroll
  for (int i = 0; i < 4; i++)
#pragma unroll
    for (int j = 0; j < 4; j++) acc[i][j] = (f32x4){0.f, 0.f, 0.f, 0.f};
  constexpr int nIss = 8 + BN / 16;

  for (int k0 = 0; k0 < K; k0 += 32) {
    __syncthreads();
    for (int is = wid; is < nIss; is += NW) {
      if (is < 8) {
        int r = is * 16 + ir;
        int sp = sl ^ ((r >> 1) & 3);
        const unsigned short* gsrc;
        if (AHEAD) {
          int rg = m0t + r;
          if (rg >= M) rg = M - 1;
          int b = rg / ATPB, tok = rg - b * ATPB;
          int e = k0 + sp * 8;
          gsrc = A + ((((size_t)b * 8 + (e >> 4)) * ATPB + tok) << 4) + (e & 15);
        } else {
          gsrc = A + (size_t)(m0t + r) * K + k0 + sp * 8;
        }
        gll16(gsrc, (void*)&As[is * 512]);
      } else {
        int r = (is - 8) * 16 + ir;
        int sp = sl ^ ((r >> 1) & 3);
        gll16(Wt + (size_t)(n0t + r) * K + k0 + sp * 8, (void*)&Bs[(is - 8) * 512]);
      }
    }
    __syncthreads();
    bf16x8 af[4], bfr[4];
#pragma unroll
    for (int mi = 0; mi < 4; mi++) {
      int m = wr * 64 + mi * 16 + li;
      sh8 t = *(const sh8*)&As[m * 32 + ((sg ^ ((m >> 1) & 3)) << 3)];
      af[mi] = __builtin_bit_cast(bf16x8, t);
    }
#pragma unroll
    for (int ni = 0; ni < 4; ni++) {
      int n = wc * 64 + ni * 16 + li;
      sh8 t = *(const sh8*)&Bs[n * 32 + ((sg ^ ((n >> 1) & 3)) << 3)];
      bfr[ni] = __builtin_bit_cast(bf16x8, t);
    }
#pragma unroll
    for (int mi = 0; mi < 4; mi++)
#pragma unroll
      for (int ni = 0; ni < 4; ni++)
        acc[mi][ni] = __builtin_amdgcn_mfma_f32_16x16x32_bf16(af[mi], bfr[ni],
                                                              acc[mi][ni], 0, 0, 0);
  }

  float bv[4];
#pragma unroll
  for (int ni = 0; ni < 4; ni++) bv[ni] = bias[n0t + wc * 64 + ni * 16 + li];

  if constexpr (EPI == 2) {
#pragma unroll
    for (int mi = 0; mi < 4; mi++)
#pragma unroll
      for (int r = 0; r < 4; r++) {
        int mg = m0t + wr * 64 + mi * 16 + sg * 4 + r;
        if (mg < M) {
          int b = mg / CTPB, tok = mg - b * CTPB;
#pragma unroll
          for (int ni = 0; ni < 4; ni++) {
            int col = n0t + wc * 64 + ni * 16 + li;
            float v = acc[mi][ni][r] + bv[ni];
            int pt = col >> 7, h = (col >> 4) & 7, d = col & 15;
            if (QSC && pt == 0) v *= SCALEF;
            size_t idx = ((((size_t)b * 8 + h) * CTPB + tok) << 4) + d;
            if (OBF)
              ((unsigned short*)C + (size_t)pt * CPS)[idx] = f2bf(v);
            else
              (C + (size_t)pt * CPS)[idx] = v;
          }
        }
      }
  } else {
#pragma unroll
    for (int mi = 0; mi < 4; mi++)
#pragma unroll
      for (int r = 0; r < 4; r++) {
        int mrow = m0t + wr * 64 + mi * 16 + sg * 4 + r;
        if (mrow < M) {
#pragma unroll
          for (int ni = 0; ni < 4; ni++) {
            int col = n0t + wc * 64 + ni * 16 + li;
            float v = acc[mi][ni][r] + bv[ni];
            if (CBF)
              ((unsigned short*)C)[(size_t)mrow * Ntot + col] = f2bf(v);
            else
              C[(size_t)mrow * Ntot + col] = v;
            if (aiq2) {
              int fb = mrow / 200, wi2 = mrow % 200;
              if (wi2 < 100) aiq2[((size_t)fb * 100 + wi2) * Ntot + col] = v;
            }
          }
        }
      }
  }
}

// ---------------------------------------------------------------------------
// Merged proj+LN (audio z=0, vis z=1): A f32 reg-staged w/ bf16 side-write;
// fused LayerNorm; head-major bf16 K/V split store. 512 threads, (320,1,2).
// ---------------------------------------------------------------------------
__global__ __launch_bounds__(512) void ln_gemm(
    const float* __restrict__ audio, const float* __restrict__ vis,
    const unsigned short* __restrict__ afp_t, const unsigned short* __restrict__ vfp_t,
    const float* __restrict__ b_afp, const float* __restrict__ b_vfp,
    const float* __restrict__ g_an, const float* __restrict__ g_vn,
    const float* __restrict__ be_an, const float* __restrict__ be_vn,
    unsigned short* __restrict__ akn, unsigned short* __restrict__ vkn,
    unsigned short* __restrict__ audio_bf, unsigned short* __restrict__ vis_bf) {
  constexpr int BN = 256, NW = 8, NCW = 4;
  constexpr size_t CPS = 5242880;
  __shared__ __align__(16) unsigned short As[128 * 32];
  __shared__ __align__(16) unsigned short Bs[BN * 32];
  __shared__ float2 part[128][4];
  const int z = blockIdx.z;
  const float* Af32 = z ? vis : audio;
  const unsigned short* Wt = z ? vfp_t : afp_t;
  const float* bias = z ? b_vfp : b_afp;
  const float* gg = z ? g_vn : g_an;
  const float* be = z ? be_vn : be_an;
  unsigned short* C = z ? vkn : akn;
  unsigned short* Aside = z ? vis_bf : audio_bf;
  const int K = z ? 512 : 128;
  const int tid = threadIdx.x;
  const int wid = tid >> 6, lane = tid & 63;
  const int wr = wid / NCW, wc = wid % NCW;
  const int m0t = blockIdx.x * 128;
  const int ir = lane >> 2, sl = lane & 3;
  const int sg = lane >> 4, li = lane & 15;
  f32x4 acc[4][4];
#pragma unroll
  for (int i = 0; i < 4; i++)
#pragma unroll
    for (int j = 0; j < 4; j++) acc[i][j] = (f32x4){0.f, 0.f, 0.f, 0.f};

  for (int k0 = 0; k0 < K; k0 += 32) {
    __syncthreads();
    {
      int r = tid >> 2, slp = tid & 3;
      int sp = slp ^ ((r >> 1) & 3);
      const float4* src = (const float4*)(Af32 + (size_t)(m0t + r) * K + k0 + sp * 8);
      float4 aa = src[0], bb = src[1];
      uint4 w;
      w.x = pk2(aa.x, aa.y); w.y = pk2(aa.z, aa.w);
      w.z = pk2(bb.x, bb.y); w.w = pk2(bb.z, bb.w);
      *(uint4*)&As[r * 32 + slp * 8] = w;
      *(uint4*)(Aside + (size_t)(m0t + r) * K + k0 + sp * 8) = w;
    }
    for (int is = 8 + wid; is < 8 + BN / 16; is += NW) {
      int r2 = (is - 8) * 16 + ir;
      int sp2 = sl ^ ((r2 >> 1) & 3);
      gll16(Wt + (size_t)r2 * K + k0 + sp2 * 8, (void*)&Bs[(is - 8) * 512]);
    }
    __syncthreads();
    bf16x8 af[4], bfr[4];
#pragma unroll
    for (int mi = 0; mi < 4; mi++) {
      int m = wr * 64 + mi * 16 + li;
      sh8 t = *(const sh8*)&As[m * 32 + ((sg ^ ((m >> 1) & 3)) << 3)];
      af[mi] = __builtin_bit_cast(bf16x8, t);
    }
#pragma unroll
    for (int ni = 0; ni < 4; ni++) {
      int n = wc * 64 + ni * 16 + li;
      sh8 t = *(const sh8*)&Bs[n * 32 + ((sg ^ ((n >> 1) & 3)) << 3)];
      bfr[ni] = __builtin_bit_cast(bf16x8, t);
    }
#pragma unroll
    for (int mi = 0; mi < 4; mi++)
#pragma unroll
      for (int ni = 0; ni < 4; ni++)
        acc[mi][ni] = __builtin_amdgcn_mfma_f32_16x16x32_bf16(af[mi], bfr[ni],
                                                              acc[mi][ni], 0, 0, 0);
  }

  float bv[4];
#pragma unroll
  for (int ni = 0; ni < 4; ni++) bv[ni] = bias[wc * 64 + ni * 16 + li];
#pragma unroll
  for (int mi = 0; mi < 4; mi++)
#pragma unroll
    for (int ni = 0; ni < 4; ni++)
#pragma unroll
      for (int r = 0; r < 4; r++) acc[mi][ni][r] += bv[ni];
#pragma unroll
  for (int mi = 0; mi < 4; mi++)
#pragma unroll
    for (int r = 0; r < 4; r++) {
      float s = acc[mi][0][r] + acc[mi][1][r] + acc[mi][2][r] + acc[mi][3][r];
      float q2 = acc[mi][0][r] * acc[mi][0][r] + acc[mi][1][r] * acc[mi][1][r] +
                 acc[mi][2][r] * acc[mi][2][r] + acc[mi][3][r] * acc[mi][3][r];
#pragma unroll
      for (int off = 1; off < 16; off <<= 1) {
        s += __shfl_xor(s, off);
        q2 += __shfl_xor(q2, off);
      }
      if (li == 0) part[wr * 64 + mi * 16 + sg * 4 + r][wc] = make_float2(s, q2);
    }
  __syncthreads();
  float gv[4], bev[4];
#pragma unroll
  for (int ni = 0; ni < 4; ni++) {
    int col = wc * 64 + ni * 16 + li;
    gv[ni] = gg[col];
    bev[ni] = be[col];
  }
#pragma unroll
  for (int mi = 0; mi < 4; mi++)
#pragma unroll
    for (int r = 0; r < 4; r++) {
      int mrow = wr * 64 + mi * 16 + sg * 4 + r;
      float2 p0 = part[mrow][0], p1 = part[mrow][1], p2 = part[mrow][2], p3 = part[mrow][3];
      float S = p0.x + p1.x + p2.x + p3.x;
      float Qq = p0.y + p1.y + p2.y + p3.y;
      float mean = S * (1.f / 256.f);
      float var = Qq * (1.f / 256.f) - mean * mean;
      float rstd = rsqrtf(var + EPSF);
      int mg = m0t + mrow;
      int b = mg >> 10, tok = mg & 1023;
#pragma unroll
      for (int ni = 0; ni < 4; ni++) {
        int col = wc * 64 + ni * 16 + li;
        float val = (acc[mi][ni][r] - mean) * rstd * gv[ni] + bev[ni];
        int half = col >> 7, h = (col >> 4) & 7, d = col & 15;
        size_t idx = ((((size_t)b * 8 + h) * 1024 + tok) << 4) + d;
        (C + (half ? CPS : 0))[idx] = f2bf(val);
      }
    }
}

// ---------------------------------------------------------------------------
// kf/vf projection as MFMA (z=0: aiq2 rows -> Ka/Va, z=1: viq2 rows -> Kv/Vv)
// ---------------------------------------------------------------------------
__global__ __launch_bounds__(512) void kvproj_gemm(
    const unsigned short* __restrict__ SAb,
    const unsigned short* __restrict__ aqp_t, const unsigned short* __restrict__ vqp_t,
    const float* __restrict__ b_aqp, const float* __restrict__ b_vqp,
    unsigned short* __restrict__ Ka, unsigned short* __restrict__ Va,
    unsigned short* __restrict__ Kv, unsigned short* __restrict__ Vv) {
  constexpr int BN = 256, NW = 8, NCW = 4, K = 128;
  __shared__ __align__(16) unsigned short As[128 * 32];
  __shared__ __align__(16) unsigned short Bs[BN * 32];
  const int z = blockIdx.z;
  const unsigned short* Wt = z ? vqp_t : aqp_t;
  const float* bias = z ? b_vqp : b_aqp;
  unsigned short* outK = z ? Kv : Ka;
  unsigned short* outV = z ? Vv : Va;
  const int rowoff = z ? 100 : 0;
  const int tid = threadIdx.x;
  const int wid = tid >> 6, lane = tid & 63;
  const int wr = wid / NCW, wc = wid % NCW;
  const int m0t = blockIdx.x * 128;
  const int ir = lane >> 2, sl = lane & 3;
  const int sg = lane >> 4, li = lane & 15;
  f32x4 acc[4][4];
#pragma unroll
  for (int i = 0; i < 4; i++)
#pragma unroll
    for (int j = 0; j < 4; j++) acc[i][j] = (f32x4){0.f, 0.f, 0.f, 0.f};
  constexpr int nIss = 8 + BN / 16;

  for (int k0 = 0; k0 < K; k0 += 32) {
    __syncthreads();
    for (int is = wid; is < nIss; is += NW) {
      if (is < 8) {
        int r = is * 16 + ir;
        int rg = m0t + r;
        if (rg >= 4000) rg = 3999;
        size_t irx = (size_t)(rg / 100) * 200 + rowoff + (rg % 100);
        int sp = sl ^ ((r >> 1) & 3);
        gll16(SAb + irx * 128 + k0 + sp * 8, (void*)&As[is * 512]);
      } else {
        int r = (is - 8) * 16 + ir;
        int sp = sl ^ ((r >> 1) & 3);
        gll16(Wt + (size_t)r * K + k0 + sp * 8, (void*)&Bs[(is - 8) * 512]);
      }
    }
    __syncthreads();
    bf16x8 af[4], bfr[4];
#pragma unroll
    for (int mi = 0; mi < 4; mi++) {
      int m = wr * 64 + mi * 16 + li;
      sh8 t = *(const sh8*)&As[m * 32 + ((sg ^ ((m >> 1) & 3)) << 3)];
      af[mi] = __builtin_bit_cast(bf16x8, t);
    }
#pragma unroll
    for (int ni = 0; ni < 4; ni++) {
      int n = wc * 64 + ni * 16 + li;
      sh8 t = *(const sh8*)&Bs[n * 32 + ((sg ^ ((n >> 1) & 3)) << 3)];
      bfr[ni] = __builtin_bit_cast(bf16x8, t);
    }
#pragma unroll
    for (int mi = 0; mi < 4; mi++)
#pragma unroll
      for (int ni = 0; ni < 4; ni++)
        acc[mi][ni] = __builtin_amdgcn_mfma_f32_16x16x32_bf16(af[mi], bfr[ni],
                                                              acc[mi][ni], 0, 0, 0);
  }

  float bv[4];
#pragma unroll
  for (int ni = 0; ni < 4; ni++) bv[ni] = bias[wc * 64 + ni * 16 + li];
#pragma unroll
  for (int mi = 0; mi < 4; mi++)
#pragma unroll
    for (int r = 0; r < 4; r++) {
      int mg = m0t + wr * 64 + mi * 16 + sg * 4 + r;
      if (mg < 4000) {
        int b = mg / 100, tok = mg - b * 100;
#pragma unroll
        for (int ni = 0; ni < 4; ni++) {
          int col = wc * 64 + ni * 16 + li;
          float v = acc[mi][ni][r] + bv[ni];
          int half = col >> 7, h = (col >> 4) & 7, d = col & 15;
          unsigned short* dst = half ? outV : outK;
          dst[((((size_t)b * 8 + h) * 100 + tok) << 4) + d] = f2bf(v);
        }
      }
    }
}

// ---------------------------------------------------------------------------
// Merged _a/_v projection (z=0 audio K=128, z=1 vis K=512): head-major bf16
// store PRE-SCALED by SCALEF (consumed as Q by stage-3). 256 thr, (320,1,2).
// ---------------------------------------------------------------------------
__global__ __launch_bounds__(256) void projq_kernel(
    const unsigned short* __restrict__ audio_bf, const unsigned short* __restrict__ vis_bf,
    const unsigned short* __restrict__ aq_t, const unsigned short* __restrict__ vq_t,
    const float* __restrict__ b_aq, const float* __restrict__ b_vq,
    unsigned short* __restrict__ a_hm, unsigned short* __restrict__ v_hm) {
  constexpr int BN = 128, NW = 4, NCW = 2;
  __shared__ __align__(16) unsigned short As[128 * 32];
  __shared__ __align__(16) unsigned short Bs[BN * 32];
  const int z = blockIdx.z;
  const unsigned short* A = z ? vis_bf : audio_bf;
  const unsigned short* Wt = z ? vq_t : aq_t;
  const float* bias = z ? b_vq : b_aq;
  unsigned short* C = z ? v_hm : a_hm;
  const int K = z ? 512 : 128;
  const int tid = threadIdx.x;
  const int wid = tid >> 6, lane = tid & 63;
  const int wr = wid / NCW, wc = wid % NCW;
  const int m0t = blockIdx.x * 128;
  const int ir = lane >> 2, sl = lane & 3;
  const int sg = lane >> 4, li = lane & 15;
  f32x4 acc[4][4];
#pragma unroll
  for (int i = 0; i < 4; i++)
#pragma unroll
    for (int j = 0; j < 4; j++) acc[i][j] = (f32x4){0.f, 0.f, 0.f, 0.f};

  for (int k0 = 0; k0 < K; k0 += 32) {
    __syncthreads();
    for (int is = wid; is < 8 + BN / 16; is += NW) {
      if (is < 8) {
        int r = is * 16 + ir;
        int sp = sl ^ ((r >> 1) & 3);
        gll16(A + (size_t)(m0t + r) * K + k0 + sp * 8, (void*)&As[is * 512]);
      } else {
        int r = (is - 8) * 16 + ir;
        int sp = sl ^ ((r >> 1) & 3);
        gll16(Wt + (size_t)r * K + k0 + sp * 8, (void*)&Bs[(is - 8) * 512]);
      }
    }
    __syncthreads();
    bf16x8 af[4], bfr[4];
#pragma unroll
    for (int mi = 0; mi < 4; mi++) {
      int m = wr * 64 + mi * 16 + li;
      sh8 t = *(const sh8*)&As[m * 32 + ((sg ^ ((m >> 1) & 3)) << 3)];
      af[mi] = __builtin_bit_cast(bf16x8, t);
    }
#pragma unroll
    for (int ni = 0; ni < 4; ni++) {
      int n = wc * 64 + ni * 16 + li;
      sh8 t = *(const sh8*)&Bs[n * 32 + ((sg ^ ((n >> 1) & 3)) << 3)];
      bfr[ni] = __builtin_bit_cast(bf16x8, t);
    }
#pragma unroll
    for (int mi = 0; mi < 4; mi++)
#pragma unroll
      for (int ni = 0; ni < 4; ni++)
        acc[mi][ni] = __builtin_amdgcn_mfma_f32_16x16x32_bf16(af[mi], bfr[ni],
                                                              acc[mi][ni], 0, 0, 0);
  }

  float bv[4];
#pragma unroll
  for (int ni = 0; ni < 4; ni++) bv[ni] = bias[wc * 64 + ni * 16 + li];
#pragma unroll
  for (int mi = 0; mi < 4; mi++)
#pragma unroll
    for (int r = 0; r < 4; r++) {
      int mg = m0t + wr * 64 + mi * 16 + sg * 4 + r;
      int b = mg >> 10, tok = mg & 1023;
#pragma unroll
      for (int ni = 0; ni < 4; ni++) {
        int col = wc * 64 + ni * 16 + li;
        float v = (acc[mi][ni][r] + bv[ni]) * SCALEF;
        int h = (col >> 4) & 7, d = col & 15;
        C[((((size_t)b * 8 + h) * 1024 + tok) << 4) + d] = f2bf(v);
      }
    }
}

// ---------------------------------------------------------------------------
// Merged output projection, 128x256 tile (512 thr), grid (320,2,2):
//  z=0: vis_out = vatthm @ vo_t + b_vo + vis(f32 residual)
//  z=1: audio_out = aatthm @ ao_t + b_ao
// A head-major [40][8][1024][16] bf16; K=128, BN=256 -> A re-read 2x (was 4x).
// ---------------------------------------------------------------------------
__global__ __launch_bounds__(512) void out_gemm(
    const unsigned short* __restrict__ vatthm, const unsigned short* __restrict__ aatthm,
    const unsigned short* __restrict__ vo_t, const unsigned short* __restrict__ ao_t,
    const float* __restrict__ b_vo, const float* __restrict__ b_ao,
    const float* __restrict__ vis, float* __restrict__ vis_out,
    float* __restrict__ audio_out) {
  constexpr int BN = 256, NW = 8, NCW = 4, K = 128;
  __shared__ __align__(16) unsigned short As[128 * 32];
  __shared__ __align__(16) unsigned short Bs[BN * 32];
  const int z = blockIdx.z;
  const unsigned short* A = z ? aatthm : vatthm;
  const unsigned short* Wt = z ? ao_t : vo_t;
  const float* bias = z ? b_ao : b_vo;
  float* C = z ? audio_out : vis_out;
  const int tid = threadIdx.x;
  const int wid = tid >> 6, lane = tid & 63;
  const int wr = wid / NCW, wc = wid % NCW;
  const int m0t = blockIdx.x * 128, n0t = blockIdx.y * BN;
  const int ir = lane >> 2, sl = lane & 3;
  const int sg = lane >> 4, li = lane & 15;
  f32x4 acc[4][4];
#pragma unroll
  for (int i = 0; i < 4; i++)
#pragma unroll
    for (int j = 0; j < 4; j++) acc[i][j] = (f32x4){0.f, 0.f, 0.f, 0.f};
  constexpr int nIss = 8 + BN / 16;

  for (int k0 = 0; k0 < K; k0 += 32) {
    __syncthreads();
    for (int is = wid; is < nIss; is += NW) {
      if (is < 8) {
        int r = is * 16 + ir;
        int rg = m0t + r;
        int b = rg >> 10, tok = rg & 1023;
        int e = k0 + ((sl ^ ((r >> 1) & 3)) << 3);
        gll16(A + ((((size_t)b * 8 + (e >> 4)) * 1024 + tok) << 4) + (e & 15),
              (void*)&As[is * 512]);
      } else {
        int r = (is - 8) * 16 + ir;
        int sp = sl ^ ((r >> 1) & 3);
        gll16(Wt + (size_t)(n0t + r) * K + k0 + sp * 8, (void*)&Bs[(is - 8) * 512]);
      }
    }
    __syncthreads();
    bf16x8 af[4], bfr[4];
#pragma unroll
    for (int mi = 0; mi < 4; mi++) {
      int m = wr * 64 + mi * 16 + li;
      sh8 t = *(const sh8*)&As[m * 32 + ((sg ^ ((m >> 1) & 3)) << 3)];
      af[mi] = __builtin_bit_cast(bf16x8, t);
    }
#pragma unroll
    for (int ni = 0; ni < 4; ni++) {
      int n = wc * 64 + ni * 16 + li;
      sh8 t = *(const sh8*)&Bs[n * 32 + ((sg ^ ((n >> 1) & 3)) << 3)];
      bfr[ni] = __builtin_bit_cast(bf16x8, t);
    }
#pragma unroll
    for (int mi = 0; mi < 4; mi++)
#pragma unroll
      for (int ni = 0; ni < 4; ni++)
        acc[mi][ni] = __builtin_amdgcn_mfma_f32_16x16x32_bf16(af[mi], bfr[ni],
                                                              acc[mi][ni], 0, 0, 0);
  }

  float bv[4];
#pragma unroll
  for (int ni = 0; ni < 4; ni++) bv[ni] = bias[n0t + wc * 64 + ni * 16 + li];
#pragma unroll
  for (int mi = 0; mi < 4; mi++)
#pragma unroll
    for (int r = 0; r < 4; r++) {
      int mrow = m0t + wr * 64 + mi * 16 + sg * 4 + r;
#pragma unroll
      for (int ni = 0; ni < 4; ni++) {
        int col = n0t + wc * 64 + ni * 16 + li;
        float v = acc[mi][ni][r] + bv[ni];
        if (z == 0) v += vis[(size_t)mrow * 512 + col];
        C[(size_t)mrow * 512 + col] = v;
      }
    }
}

// ---------------------------------------------------------------------------
// Stage-1 MFMA flash attention: both modalities, 8 waves, K/V staged once;
// prefetch one block ahead; Q pre-scaled at load; defer-max rescale.
// ---------------------------------------------------------------------------
__global__ __launch_bounds__(512) void mattn1(
    const float* __restrict__ aqvq,
    const unsigned short* __restrict__ akn, const unsigned short* __restrict__ avn,
    const unsigned short* __restrict__ vkn, const unsigned short* __restrict__ vvn,
    unsigned short* __restrict__ op) {
  __shared__ __align__(16) unsigned short Klds[64][24];
  __shared__ __align__(16) unsigned short VTlds[16][72];
  __shared__ __align__(16) unsigned short Plds[8][16][72];
  const int tid = threadIdx.x, wid = tid >> 6, lane = tid & 63;
  const int li = lane & 15, gr = lane >> 4;
  const int z = blockIdx.z, h = blockIdx.y;
  const int mod = z >= 40 ? 1 : 0;
  const int b = z - mod * 40;
  const int bh = b * 8 + h;
  const int qi = wid * 16 + li;
  const bool qact = qi < 100;
  const int qic = qact ? qi : 99;
  const float* qrow = aqvq + mod * 128 + (size_t)qic * 256 + h * 16;
  const unsigned short* kp = mod ? vkn : akn;
  const unsigned short* vp = mod ? vvn : avn;

  sh8 z8 = (sh8)0;
  bf16x8 qf = __builtin_bit_cast(bf16x8, z8);
  if (gr < 2) {
    const float4* q4 = (const float4*)(qrow + gr * 8);
    float4 qa = q4[0], qb = q4[1];
    sh8 tt;
    tt[0] = f2bf(qa.x * SCALEF); tt[1] = f2bf(qa.y * SCALEF);
    tt[2] = f2bf(qa.z * SCALEF); tt[3] = f2bf(qa.w * SCALEF);
    tt[4] = f2bf(qb.x * SCALEF); tt[5] = f2bf(qb.y * SCALEF);
    tt[6] = f2bf(qb.z * SCALEF); tt[7] = f2bf(qb.w * SCALEF);
    qf = __builtin_bit_cast(bf16x8, tt);
  }

  float mrun = -3e38f, lrun = 0.f;
  f32x4 acc = (f32x4){0.f, 0.f, 0.f, 0.f};
  const f32x4 zero4 = (f32x4){0.f, 0.f, 0.f, 0.f};
  const unsigned* Ku = (const unsigned*)(kp + (size_t)bh * 1024 * 16);
  const unsigned* Vu = (const unsigned*)(vp + (size_t)bh * 1024 * 16);
  const int skey = tid >> 3, sdb = tid & 7;

  unsigned kw = Ku[(size_t)skey * 8 + sdb];
  unsigned vw = Vu[(size_t)skey * 8 + sdb];
  for (int kb = 0; kb < 1024; kb += 64) {
    __syncthreads();
    *(unsigned*)&Klds[skey][sdb * 2] = kw;
    VTlds[sdb * 2 + 0][skey] = (unsigned short)(vw & 0xffff);
    VTlds[sdb * 2 + 1][skey] = (unsigned short)(vw >> 16);
    if (kb + 64 < 1024) {
      kw = Ku[(size_t)(kb + 64 + skey) * 8 + sdb];
      vw = Vu[(size_t)(kb + 64 + skey) * 8 + sdb];
    }
    __syncthreads();
    f32x4 st[4];
#pragma unroll
    for (int t = 0; t < 4; t++) {
      sh8 kk = *(const sh8*)&Klds[t * 16 + li][(gr & 1) * 8];
      st[t] = __builtin_amdgcn_mfma_f32_16x16x32_bf16(
          __builtin_bit_cast(bf16x8, kk), qf, zero4, 0, 0, 0);
    }
    float bm = st[0][0];
#pragma unroll
    for (int t = 0; t < 4; t++)
#pragma unroll
      for (int r = 0; r < 4; r++) bm = fmaxf(bm, st[t][r]);
    bm = fmaxf(bm, __shfl_xor(bm, 16));
    bm = fmaxf(bm, __shfl_xor(bm, 32));
    if (bm > mrun + 8.f) {
      float cf = __expf(mrun - bm);
      lrun *= cf;
      acc[0] *= cf; acc[1] *= cf; acc[2] *= cf; acc[3] *= cf;
      mrun = bm;
    }
    float ls = 0.f;
    unsigned pw[4][2];
#pragma unroll
    for (int t = 0; t < 4; t++) {
      float p0 = __expf(st[t][0] - mrun), p1 = __expf(st[t][1] - mrun);
      float p2 = __expf(st[t][2] - mrun), p3 = __expf(st[t][3] - mrun);
      ls += (p0 + p1) + (p2 + p3);
      pw[t][0] = pk2(p0, p1);
      pw[t][1] = pk2(p2, p3);
    }
    ls += __shfl_xor(ls, 16);
    ls += __shfl_xor(ls, 32);
    lrun += ls;
#pragma unroll
    for (int t = 0; t < 4; t++)
      *(uint2*)&Plds[wid][li][t * 16 + gr * 4] = make_uint2(pw[t][0], pw[t][1]);
#pragma unroll
    for (int hh = 0; hh < 2; hh++) {
      sh8 vt = *(const sh8*)&VTlds[li][hh * 32 + gr * 8];
      sh8 pt = *(const sh8*)&Plds[wid][li][hh * 32 + gr * 8];
      acc = __builtin_amdgcn_mfma_f32_16x16x32_bf16(
          __builtin_bit_cast(bf16x8, vt), __builtin_bit_cast(bf16x8, pt), acc, 0, 0, 0);
    }
  }
  float inv = 1.f / lrun;
  float o[4];
#pragma unroll
  for (int r = 0; r < 4; r++) o[r] = acc[r] * inv;
  const float4* q4 = (const float4*)(qrow + gr * 4);
  float4 qv = q4[0];
  o[0] += qv.x; o[1] += qv.y; o[2] += qv.z; o[3] += qv.w;
  if (qact) {
    int obh = (b / 5) * 8 + h;
    int otok = (b % 5) * 200 + mod * 100 + qi;
    *(uint2*)(op + (((size_t)obh * 1000 + otok) << 4) + gr * 4) =
        make_uint2(pk2(o[0], o[1]), pk2(o[2], o[3]));
  }
}

// ---------------------------------------------------------------------------
// 8-wave MFMA flash attention, bf16 head-major operands, Q PRE-SCALED,
// prefetch one block ahead, defer-max rescale.
// MODE 1: single stream (SA). MODE 2: merged modalities (stage-3), audio
// side (+bf16 token-major residual).
// ---------------------------------------------------------------------------
template <int MODE>
__global__ __launch_bounds__(512) void mattn8(
    const unsigned short* __restrict__ q0s, const unsigned short* __restrict__ q1s,
    size_t qsb, size_t qsh, int qsr,
    const unsigned short* __restrict__ k0s, const unsigned short* __restrict__ v0s,
    const unsigned short* __restrict__ k1s, const unsigned short* __restrict__ v1s,
    int nk, int nq, unsigned short* __restrict__ o0s, unsigned short* __restrict__ o1s,
    int OTPB, const unsigned short* __restrict__ residbf) {
  __shared__ __align__(16) unsigned short Klds[64][24];
  __shared__ __align__(16) unsigned short VTlds[16][72];
  __shared__ __align__(16) unsigned short Plds[8][16][72];
  const int tid = threadIdx.x, wid = tid >> 6, lane = tid & 63;
  const int li = lane & 15, gr = lane >> 4;
  const int z = blockIdx.z, h = blockIdx.y;
  int mod = 0, b = z;
  const unsigned short *qp = q0s, *kp = k0s, *vp = v0s;
  unsigned short* op = o0s;
  if (MODE == 2) {
    mod = z >= 40 ? 1 : 0;
    b = z - mod * 40;
    if (mod) { qp = q1s; kp = k1s; vp = v1s; op = o1s; }
  }
  const int bh = b * 8 + h;
  const int qi = blockIdx.x * 128 + wid * 16 + li;
  const bool qact = qi < nq;
  const int qic = qact ? qi : nq - 1;
  const unsigned short* qrow = qp + b * qsb + h * qsh + (size_t)qic * qsr;

  sh8 z8 = (sh8)0;
  bf16x8 qf = __builtin_bit_cast(bf16x8, z8);
  if (gr < 2) qf = __builtin_bit_cast(bf16x8, *(const sh8*)(qrow + gr * 8));

  float mrun = -3e38f, lrun = 0.f;
  f32x4 acc = (f32x4){0.f, 0.f, 0.f, 0.f};
  const f32x4 zero4 = (f32x4){0.f, 0.f, 0.f, 0.f};
  const unsigned* Ku = (const unsigned*)(kp + (size_t)bh * nk * 16);
  const unsigned* Vu = (const unsigned*)(vp + (size_t)bh * nk * 16);
  const int skey = tid >> 3, sdb = tid & 7;

  unsigned kw = (skey < nk) ? Ku[(size_t)skey * 8 + sdb] : 0u;
  unsigned vw = (skey < nk) ? Vu[(size_t)skey * 8 + sdb] : 0u;
  for (int kb = 0; kb < nk; kb += 64) {
    __syncthreads();
    *(unsigned*)&Klds[skey][sdb * 2] = kw;
    VTlds[sdb * 2 + 0][skey] = (unsigned short)(vw & 0xffff);
    VTlds[sdb * 2 + 1][skey] = (unsigned short)(vw >> 16);
    if (kb + 64 < nk) {
      int gk = kb + 64 + skey;
      kw = (gk < nk) ? Ku[(size_t)gk * 8 + sdb] : 0u;
      vw = (gk < nk) ? Vu[(size_t)gk * 8 + sdb] : 0u;
    }
    __syncthreads();
    f32x4 st[4];
#pragma unroll
    for (int t = 0; t < 4; t++) {
      sh8 kk = *(const sh8*)&Klds[t * 16 + li][(gr & 1) * 8];
      st[t] = __builtin_amdgcn_mfma_f32_16x16x32_bf16(
          __builtin_bit_cast(bf16x8, kk), qf, zero4, 0, 0, 0);
    }
    if (kb + 64 > nk) {
#pragma unroll
      for (int t = 0; t < 4; t++) {
        int kbase = kb + t * 16 + gr * 4;
#pragma unroll
        for (int r = 0; r < 4; r++)
          if (kbase + r >= nk) st[t][r] = -1e30f;
      }
    }
    float bm = st[0][0];
#pragma unroll
    for (int t = 0; t < 4; t++)
#pragma unroll
      for (int r = 0; r < 4; r++) bm = fmaxf(bm, st[t][r]);
    bm = fmaxf(bm, __shfl_xor(bm, 16));
    bm = fmaxf(bm, __shfl_xor(bm, 32));
    if (bm > mrun + 8.f) {
      float cf = __expf(mrun - bm);
      lrun *= cf;
      acc[0] *= cf; acc[1] *= cf; acc[2] *= cf; acc[3] *= cf;
      mrun = bm;
    }
    float ls = 0.f;
    unsigned pw[4][2];
#pragma unroll
    for (int t = 0; t < 4; t++) {
      float p0 = __expf(st[t][0] - mrun), p1 = __expf(st[t][1] - mrun);
      float p2 = __expf(st[t][2] - mrun), p3 = __expf(st[t][3] - mrun);
      ls += (p0 + p1) + (p2 + p3);
      pw[t][0] = pk2(p0, p1);
      pw[t][1] = pk2(p2, p3);
    }
    ls += __shfl_xor(ls, 16);
    ls += __shfl_xor(ls, 32);
    lrun += ls;
#pragma unroll
    for (int t = 0; t < 4; t++)
      *(uint2*)&Plds[wid][li][t * 16 + gr * 4] = make_uint2(pw[t][0], pw[t][1]);
#pragma unroll
    for (int hh = 0; hh < 2; hh++) {
      sh8 vt = *(const sh8*)&VTlds[li][hh * 32 + gr * 8];
      sh8 pt = *(const sh8*)&Plds[wid][li][hh * 32 + gr * 8];
      acc = __builtin_amdgcn_mfma_f32_16x16x32_bf16(
          __builtin_bit_cast(bf16x8, vt), __builtin_bit_cast(bf16x8, pt), acc, 0, 0, 0);
    }
  }
  float inv = 1.f / lrun;
  float o[4];
#pragma unroll
  for (int r = 0; r < 4; r++) o[r] = acc[r] * inv;
  if (MODE == 2 && mod == 0 && residbf) {
    uint2 rv = *(const uint2*)(residbf + ((size_t)b * 1024 + qic) * 128 + h * 16 + gr * 4);
    o[0] += bf2f((unsigned short)(rv.x & 0xffff));
    o[1] += bf2f((unsigned short)(rv.x >> 16));
    o[2] += bf2f((unsigned short)(rv.y & 0xffff));
    o[3] += bf2f((unsigned short)(rv.y >> 16));
  }
  if (qact) {
    *(uint2*)(op + (((size_t)bh * OTPB + qi) << 4) + gr * 4) =
        make_uint2(pk2(o[0], o[1]), pk2(o[2], o[3]));
  }
}

// ---------------------------------------------------------------------------
// Consolidated prep: 10 weight transposes + iqp projection.
// ---------------------------------------------------------------------------
__global__ __launch_bounds__(256) void prep_kernel(
    const float* __restrict__ iq, const float* __restrict__ w_iqp,
    const float* __restrict__ b_iqp,
    const float* __restrict__ w_afp, const float* __restrict__ w_vfp,
    const float* __restrict__ w_aq, const float* __restrict__ w_vq,
    const float* __restrict__ w_in, const float* __restrict__ w_o,
    const float* __restrict__ w_ao, const float* __restrict__ w_vo,
    const float* __restrict__ w_aqp, const float* __restrict__ w_vqp,
    unsigned short* __restrict__ WT, float* __restrict__ aqvq) {
  __shared__ float row[128];
  const int g = blockIdx.x, tid = threadIdx.x;
  if (g < 1984) {
    int lg = g;
    int K, N;
    const float* W;
    unsigned dst;
    if (lg < 128)       { K = 128; N = 256; W = w_afp; dst = 0; }
    else if (lg < 640)  { K = 512; N = 256; W = w_vfp; dst = 32768;  lg -= 128; }
    else if (lg < 704)  { K = 128; N = 128; W = w_aq;  dst = 163840; lg -= 640; }
    else if (lg < 960)  { K = 512; N = 128; W = w_vq;  dst = 180224; lg -= 704; }
    else if (lg < 1152) { K = 128; N = 384; W = w_in;  dst = 245760; lg -= 960; }
    else if (lg < 1216) { K = 128; N = 128; W = w_o;   dst = 294912; lg -= 1152; }
    else if (lg < 1472) { K = 128; N = 512; W = w_ao;  dst = 311296; lg -= 1216; }
    else if (lg < 1728) { K = 128; N = 512; W = w_vo;  dst = 376832; lg -= 1472; }
    else if (lg < 1856) { K = 128; N = 256; W = w_aqp; dst = 442368; lg -= 1728; }
    else                { K = 128; N = 256; W = w_vqp; dst = 475136; lg -= 1856; }
    int idx = lg * 256 + tid;
    if (idx < K * N) {
      int k = idx / N, n = idx - k * N;
      WT[dst + (size_t)n * K + k] = f2bf(W[idx]);
    }
  } else {
    int r = g - 1984;
    if (tid < 128) row[tid] = iq[r * 128 + tid];
    __syncthreads();
    float acc = b_iqp[tid];
#pragma unroll 8
    for (int k = 0; k < 128; ++k) acc += row[k] * w_iqp[k * 256 + tid];
    aqvq[r * 256 + tid] = acc;
  }
}

// ---------------------------------------------------------------------------
extern "C" void kernel_launch(void* const* d_in, const int* in_sizes, int n_in,
                              void* d_out, int out_size, void* d_ws, size_t ws_size,
                              hipStream_t stream) {
  const float* audio = (const float*)d_in[0];   // (40,1024,128)
  const float* vis   = (const float*)d_in[1];   // (40,1024,512)
  const float* iq    = (const float*)d_in[2];
  const float* w_iqp = (const float*)d_in[3];
  const float* b_iqp = (const float*)d_in[4];
  const float* w_afp = (const float*)d_in[5];
  const float* b_afp = (const float*)d_in[6];
  const float* w_vfp = (const float*)d_in[7];
  const float* b_vfp = (const float*)d_in[8];
  const float* g_an  = (const float*)d_in[9];
  const float* be_an = (const float*)d_in[10];
  const float* g_vn  = (const float*)d_in[11];
  const float* be_vn = (const float*)d_in[12];
  const float* w_aqp = (const float*)d_in[13];
  const float* b_aqp = (const float*)d_in[14];
  const float* w_vqp = (const float*)d_in[15];
  const float* b_vqp = (const float*)d_in[16];
  const float* w_aq  = (const float*)d_in[17];
  const float* b_aq  = (const float*)d_in[18];
  const float* w_vq  = (const float*)d_in[19];
  const float* b_vq  = (const float*)d_in[20];
  const float* w_in  = (const float*)d_in[21];
  const float* b_in  = (const float*)d_in[22];
  const float* w_o   = (const float*)d_in[23];
  const float* b_o   = (const float*)d_in[24];
  const float* w_ao  = (const float*)d_in[25];
  const float* b_ao  = (const float*)d_in[26];
  const float* w_vo  = (const float*)d_in[27];
  const float* b_vo  = (const float*)d_in[28];

  float* out = (float*)d_out;
  float* ws  = (float*)d_ws;

  // ---- d_out scratch (dead until final writes; stream-ordered) ----
  unsigned short* vis_bf = (unsigned short*)(out);  // words [0,10485760)
  unsigned short* akn = (unsigned short*)(out + 10485760);  // [40][8][1024][16] bf16
  unsigned short* avn = akn + 5242880;
  unsigned short* vkn = akn + 10485760;
  unsigned short* vvn = akn + 15728640;
  unsigned short* a_hm = (unsigned short*)(out + 20971520);
  unsigned short* v_hm = (unsigned short*)(out + 23592960);
  float* aiq2_out = out + 41943040;
  float* audio_out = out;
  float* vis_out   = out + 20971520;

  // ---- ws layout (f32-word offsets) ----
  unsigned short* WT       = (unsigned short*)(ws);
  unsigned short* audio_bf = (unsigned short*)(ws + 262144);
  unsigned short* Q1hm     = (unsigned short*)(ws + 2883584);
  unsigned short* saphm    = (unsigned short*)(ws + 3395584);
  unsigned short* qkvhm    = (unsigned short*)(ws + 3915776);
  unsigned short* aatthm   = (unsigned short*)(ws + 3915776);  // overlays qkvhm
  unsigned short* vatthm   = (unsigned short*)(ws + 6987776);
  unsigned short* SAb      = (unsigned short*)(ws + 9609216);  // (8000,128) bf16
  unsigned short* Ka = (unsigned short*)(ws + 10633216);
  unsigned short* Va = Ka + 512000;
  unsigned short* Kv = Ka + 1024000;
  unsigned short* Vv = Ka + 1536000;
  float* aqvq = ws + 12681216;

  unsigned short* afp_t = WT + 0;
  unsigned short* vfp_t = WT + 32768;
  unsigned short* aq_t  = WT + 163840;
  unsigned short* vq_t  = WT + 180224;
  unsigned short* in_t  = WT + 245760;
  unsigned short* o_t   = WT + 294912;
  unsigned short* ao_t  = WT + 311296;
  unsigned short* vo_t  = WT + 376832;
  unsigned short* aqp_t = WT + 442368;
  unsigned short* vqp_t = WT + 475136;

  // 1. consolidated prep (10 wtrans + iqp)
  prep_kernel<<<2084, 256, 0, stream>>>(
      iq, w_iqp, b_iqp, w_afp, w_vfp, w_aq, w_vq, w_in, w_o, w_ao, w_vo,
      w_aqp, w_vqp, WT, aqvq);

  // 2. merged proj+LN -> head-major bf16 K/V + side bf16 copies
  ln_gemm<<<dim3(320, 1, 2), 512, 0, stream>>>(
      audio, vis, afp_t, vfp_t, b_afp, b_vfp, g_an, g_vn, be_an, be_vn,
      akn, vkn, audio_bf, vis_bf);

  // 3. stage-1 cross-attn -> Q1hm
  mattn1<<<dim3(1, 8, 80), 512, 0, stream>>>(aqvq, akn, avn, vkn, vvn, Q1hm);

  // 4. qkv = queries @ w_in + b_in (head-major bf16; q part pre-scaled QSC)
  mfma_gemm<128, 128, 2, true, true, true, false><<<dim3(63, 3), 256, 0, stream>>>(
      Q1hm, in_t, b_in, (float*)qkvhm, 8000, 384, 1000, 1000, 1024000, nullptr);

  // 5. self-attention -> saphm
  mattn8<1><<<dim3(8, 8, 8), 512, 0, stream>>>(
      qkvhm, nullptr, 128000, 16000, 16, qkvhm + 1024000, qkvhm + 2048000,
      nullptr, nullptr, 1000, 1000, saphm, nullptr, 1000, nullptr);

  // 6. SA = sa_pre @ w_o + b_o -> bf16 SAb (CBF) + f32 aiq2 dual-store
  mfma_gemm<128, 128, 0, true, false, false, true><<<dim3(63, 1), 256, 0, stream>>>(
      saphm, o_t, b_o, (float*)SAb, 8000, 128, 1000, 0, 0, aiq2_out);

  // 7. kf/vf projections (MFMA, gathered bf16 A) -> head-major bf16 K/V
  kvproj_gemm<<<dim3(32, 1, 2), 512, 0, stream>>>(
      SAb, aqp_t, vqp_t, b_aqp, b_vqp, Ka, Va, Kv, Vv);

  // 8. merged _a/_v projections -> head-major bf16, PRE-SCALED (stage-3 Q)
  projq_kernel<<<dim3(320, 1, 2), 256, 0, stream>>>(
      audio_bf, vis_bf, aq_t, vq_t, b_aq, b_vq, a_hm, v_hm);

  // 9. stage-3 cross-attn merged; audio +audio_bf resid
  mattn8<2><<<dim3(8, 8, 80), 512, 0, stream>>>(
      a_hm, v_hm, 131072, 16384, 16, Kv, Vv, Ka, Va, 100, 1024,
      aatthm, vatthm, 1024, audio_bf);

  // 10. merged output projections, 128x256 tile (A re-read halved)
  out_gemm<<<dim3(320, 2, 2), 512, 0, stream>>>(
      vatthm, aatthm, vo_t, ao_t, b_vo, b_ao, vis, vis_out, audio_out);
}